// Round 3
// baseline (3846.836 us; speedup 1.0000x reference)
//
#include <hip/hip_runtime.h>
#include <hip/hip_bf16.h>
#include <float.h>

#define N_PTS 2048
#define B_SZ  4
#define KNN   20
#define LRELU_S 0.2f

typedef __hip_bfloat16 bf16;

__device__ __forceinline__ float b2f(const bf16 v) { return __bfloat162float(v); }
__device__ __forceinline__ float ldf(const float* p) { return *p; }
__device__ __forceinline__ float ldf(const bf16* p)  { return __bfloat162float(*p); }

// ---------------------------------------------------------------------------
// Dtype sniffer: decide whether tensors are bf16 (flag=1) or fp32 (flag=0).
// Looks at 64 EVEN halfwords of points. If the buffer is bf16, those are real
// bf16 values ~N(0,1) -> exponent in [100,140] nearly always. If fp32, those
// halfwords are raw mantissa bits -> exponent ~uniform -> rarely in range.
// Reads only 256 bytes (safe under both interpretations).
__global__ void k_sniff(const unsigned short* __restrict__ pts_hw, int* __restrict__ flag) {
    if (threadIdx.x != 0 || blockIdx.x != 0) return;
    int sane = 0;
    for (int j = 0; j < 64; ++j) {
        unsigned short v = pts_hw[2 * j];
        int e = (v >> 7) & 0xFF;
        if (e >= 100 && e <= 140) ++sane;
    }
    *flag = (sane >= 32) ? 1 : 0;
}

// ---------------------------------------------------------------------------
// Repack the 23 weight tensors into one contiguous fp32 array in ws.
struct WPack {
    const void* src[23];
    int off[24];      // prefix offsets (elements)
};

__global__ void k_repack(WPack wp, const int* __restrict__ flag, float* __restrict__ dst, int total) {
    const int isb = *flag;
    for (int i = blockIdx.x * blockDim.x + threadIdx.x; i < total; i += gridDim.x * blockDim.x) {
        int lo = 0, hi = 23;
        while (lo + 1 < hi) { int mid = (lo + hi) >> 1; if (i >= wp.off[mid]) lo = mid; else hi = mid; }
        int j = i - wp.off[lo];
        dst[i] = isb ? b2f(((const bf16*)wp.src[lo])[j]) : ((const float*)wp.src[lo])[j];
    }
}

// ---------------------------------------------------------------------------
// points (B,N,3) -> x0 (B,3,N) fp32, dtype-dynamic.
__global__ void k_transpose(const void* __restrict__ pts, const int* __restrict__ flag,
                            float* __restrict__ x0) {
    const int isb = *flag;
    int i = blockIdx.x * blockDim.x + threadIdx.x;   // over B*N
    if (i >= B_SZ * N_PTS) return;
    int b = i / N_PTS, n = i % N_PTS;
    for (int c = 0; c < 3; ++c) {
        size_t s = ((size_t)b * N_PTS + n) * 3 + c;
        float v = isb ? b2f(((const bf16*)pts)[s]) : ((const float*)pts)[s];
        x0[((size_t)b * 3 + c) * N_PTS + n] = v;
    }
}

// ---------------------------------------------------------------------------
// kNN: block handles QT=4 query points of one batch; x is a (C,N) slice base
// (already channel-offset); batch_stride jumps batches. Writes idx (B,N,K).
template<typename T, int C>
__global__ void k_knn(const T* __restrict__ x, int batch_stride, int* __restrict__ idx) {
    const int QT = 4;
    __shared__ float qf[QT][C];
    __shared__ float dist[QT][N_PTS];        // 32 KB
    __shared__ float rv[256];
    __shared__ int   ri[256];

    int tile = blockIdx.x;                   // 0 .. B*N/QT-1
    int b  = tile / (N_PTS / QT);
    int q0 = (tile % (N_PTS / QT)) * QT;
    const T* xb = x + (size_t)b * batch_stride;

    for (int t = threadIdx.x; t < QT * C; t += 256) {
        int q = t / C, c = t % C;
        qf[q][c] = ldf(&xb[(size_t)c * N_PTS + (q0 + q)]);
    }
    __syncthreads();

    for (int m = threadIdx.x; m < N_PTS; m += 256) {
        float d0 = 0.f, d1 = 0.f, d2 = 0.f, d3 = 0.f;
        for (int c = 0; c < C; ++c) {
            float xv = ldf(&xb[(size_t)c * N_PTS + m]);
            float t0 = xv - qf[0][c]; d0 += t0 * t0;
            float t1 = xv - qf[1][c]; d1 += t1 * t1;
            float t2 = xv - qf[2][c]; d2 += t2 * t2;
            float t3 = xv - qf[3][c]; d3 += t3 * t3;
        }
        dist[0][m] = d0; dist[1][m] = d1; dist[2][m] = d2; dist[3][m] = d3;
    }
    __syncthreads();

    // 20 rounds of argmin (tie -> lowest index), matching top_k on -dist
    for (int q = 0; q < QT; ++q) {
        for (int k = 0; k < KNN; ++k) {
            float bv = FLT_MAX; int bi = 0x7fffffff;
            for (int m = threadIdx.x; m < N_PTS; m += 256) {
                float d = dist[q][m];
                if (d < bv) { bv = d; bi = m; }   // m ascending per thread: lowest index wins ties
            }
            rv[threadIdx.x] = bv; ri[threadIdx.x] = bi;
            __syncthreads();
            for (int s = 128; s > 0; s >>= 1) {
                if (threadIdx.x < s) {
                    float ov = rv[threadIdx.x + s]; int oi = ri[threadIdx.x + s];
                    if (ov < rv[threadIdx.x] || (ov == rv[threadIdx.x] && oi < ri[threadIdx.x])) {
                        rv[threadIdx.x] = ov; ri[threadIdx.x] = oi;
                    }
                }
                __syncthreads();
            }
            if (threadIdx.x == 0) {
                int r0 = ri[0];
                if ((unsigned)r0 >= (unsigned)N_PTS) r0 = 0;   // NaN / degenerate guard
                idx[((size_t)b * N_PTS + (q0 + q)) * KNN + k] = r0;
                dist[q][r0] = FLT_MAX;
            }
            __syncthreads();
        }
    }
}

// ---------------------------------------------------------------------------
// EdgeConv: out[b,o,n] = max_k lrelu(bn( W @ [x_n ; x_k - x_n] ))
//         = max_k lrelu( (base_o + sum_c W2[o,c]*x_k[c]) * scale_o + bias_o )
// where base_o = sum_c (W1[o,c]-W2[o,c]) * x_n[c].  Weights fp32. Output bf16.
template<typename T, int C, int COUT>
__global__ void k_edgeconv(const T* __restrict__ x, int batch_stride,
                           const int* __restrict__ idx,
                           const float* __restrict__ W,     // (COUT, 2C) fp32
                           const float* __restrict__ gam,
                           const float* __restrict__ bet,
                           bf16* __restrict__ out, int out_batch_stride) {
    int i = blockIdx.x;                      // b*N + n
    int b = i / N_PTS, n = i % N_PTS;
    const T* xb = x + (size_t)b * batch_stride;

    __shared__ float xn[C];
    __shared__ float nb[KNN][C];
    for (int t = threadIdx.x; t < C; t += 256) xn[t] = ldf(&xb[(size_t)t * N_PTS + n]);
    for (int t = threadIdx.x; t < KNN * C; t += 256) {
        int k = t / C, c = t % C;
        int m = idx[((size_t)b * N_PTS + n) * KNN + k] & (N_PTS - 1);
        nb[k][c] = ldf(&xb[(size_t)c * N_PTS + m]);
    }
    __syncthreads();

    const float inv = rsqrtf(1.0f + 1e-5f);
    for (int o = threadIdx.x; o < COUT; o += 256) {
        const float* wr = W + (size_t)o * 2 * C;
        float base = 0.f;
        float acc[KNN];
#pragma unroll
        for (int k = 0; k < KNN; ++k) acc[k] = 0.f;
        for (int c = 0; c < C; ++c) {
            float w1 = wr[c];
            float w2 = wr[C + c];
            base += (w1 - w2) * xn[c];
#pragma unroll
            for (int k = 0; k < KNN; ++k) acc[k] += w2 * nb[k][c];
        }
        float scale = gam[o] * inv, bias = bet[o];
        float mx = -FLT_MAX;
#pragma unroll
        for (int k = 0; k < KNN; ++k) {
            float h = (base + acc[k]) * scale + bias;
            h = h > 0.f ? h : LRELU_S * h;
            mx = fmaxf(mx, h);
        }
        out[(size_t)b * out_batch_stride + (size_t)o * N_PTS + n] = __float2bfloat16(mx);
    }
}

// ---------------------------------------------------------------------------
// conv5 (1024x512) + BN + LReLU fused with max & sum pooling over N.
__global__ void k_conv5pool(const bf16* __restrict__ feat,               // (B,512,N)
                            const float* __restrict__ w5,                // (1024,512) fp32
                            const float* __restrict__ g5,
                            const float* __restrict__ b5,
                            float* __restrict__ fmax, float* __restrict__ fsum) {
    const int OT = 16;
    __shared__ float wl[OT][512];            // 32 KB, reused as reduction scratch
    int b  = blockIdx.x / (1024 / OT);
    int o0 = (blockIdx.x % (1024 / OT)) * OT;
    const bf16* fb = feat + (size_t)b * 512 * N_PTS;

    for (int t = threadIdx.x; t < OT * 512; t += 256) {
        int o = t / 512, c = t % 512;
        wl[o][c] = w5[(size_t)(o0 + o) * 512 + c];
    }
    __syncthreads();

    const float inv = rsqrtf(1.0f + 1e-5f);
    float scale[OT], bias[OT], mxv[OT], smv[OT];
#pragma unroll
    for (int o = 0; o < OT; ++o) {
        scale[o] = g5[o0 + o] * inv;
        bias[o]  = b5[o0 + o];
        mxv[o] = -FLT_MAX; smv[o] = 0.f;
    }

    for (int n = threadIdx.x; n < N_PTS; n += 256) {
        float acc[OT];
#pragma unroll
        for (int o = 0; o < OT; ++o) acc[o] = 0.f;
        for (int c = 0; c < 512; ++c) {
            float f = b2f(fb[(size_t)c * N_PTS + n]);
#pragma unroll
            for (int o = 0; o < OT; ++o) acc[o] += wl[o][c] * f;
        }
#pragma unroll
        for (int o = 0; o < OT; ++o) {
            float h = acc[o] * scale[o] + bias[o];
            h = h > 0.f ? h : LRELU_S * h;
            mxv[o] = fmaxf(mxv[o], h);
            smv[o] += h;
        }
    }
    __syncthreads();                          // done with wl as weights

    float* red = &wl[0][0];                   // [0..255] max, [256..511] sum
    for (int o = 0; o < OT; ++o) {
        red[threadIdx.x]       = mxv[o];
        red[256 + threadIdx.x] = smv[o];
        __syncthreads();
        for (int s = 128; s > 0; s >>= 1) {
            if (threadIdx.x < s) {
                red[threadIdx.x] = fmaxf(red[threadIdx.x], red[threadIdx.x + s]);
                red[256 + threadIdx.x] += red[256 + threadIdx.x + s];
            }
            __syncthreads();
        }
        if (threadIdx.x == 0) {
            fmax[(size_t)b * 1024 + o0 + o] = red[0];
            fsum[(size_t)b * 1024 + o0 + o] = red[256];
        }
        __syncthreads();
    }
}

// ---------------------------------------------------------------------------
// Head: f = [max(1024), mean(1024)] -> fc1+bn+lrelu -> fc2+bn -> out (B,256)
// Output dtype selected by flag (bf16 or fp32).
__global__ void k_head(const float* __restrict__ fmax, const float* __restrict__ fsum,
                       const float* __restrict__ fw1, const float* __restrict__ fb1,
                       const float* __restrict__ g6,  const float* __restrict__ b6,
                       const float* __restrict__ fw2, const float* __restrict__ fb2,
                       const float* __restrict__ g7,  const float* __restrict__ b7,
                       const int* __restrict__ flag, void* __restrict__ out) {
    __shared__ float f[2048];
    __shared__ float t[512];
    int b = blockIdx.x;
    for (int i = threadIdx.x; i < 1024; i += 256) {
        f[i]        = fmax[(size_t)b * 1024 + i];
        f[1024 + i] = fsum[(size_t)b * 1024 + i] * (1.0f / N_PTS);
    }
    __syncthreads();
    const float inv = rsqrtf(1.0f + 1e-5f);
    for (int o = threadIdx.x; o < 512; o += 256) {
        const float* wr = fw1 + (size_t)o * 2048;
        float acc = fb1[o];
        for (int j = 0; j < 2048; ++j) acc += wr[j] * f[j];
        float h = acc * g6[o] * inv + b6[o];
        t[o] = h > 0.f ? h : LRELU_S * h;
    }
    __syncthreads();
    {
        int o = threadIdx.x;                  // 256 threads, 256 outputs
        const float* wr = fw2 + (size_t)o * 512;
        float acc = fb2[o];
        for (int j = 0; j < 512; ++j) acc += wr[j] * t[j];
        float h = acc * g7[o] * inv + b7[o];
        if (*flag) ((bf16*)out)[(size_t)b * 256 + o] = __float2bfloat16(h);
        else       ((float*)out)[(size_t)b * 256 + o] = h;
    }
}

// ---------------------------------------------------------------------------
extern "C" void kernel_launch(void* const* d_in, const int* in_sizes, int n_in,
                              void* d_out, int out_size, void* d_ws, size_t ws_size,
                              hipStream_t stream) {
    // weight tensor element counts, d_in[1..23]
    static const int wsz[23] = {
        384, 64, 64,            // w1,g1,b1
        8192, 64, 64,           // w2,g2,b2
        16384, 128, 128,        // w3,g3,b3
        65536, 256, 256,        // w4,g4,b4
        524288, 1024, 1024,     // w5,g5,b5
        1048576, 512,           // fw1,fb1
        512, 512,               // g6,b6
        131072, 256,            // fw2,fb2
        256, 256                // g7,b7
    };
    WPack wp;
    int total = 0;
    for (int i = 0; i < 23; ++i) { wp.src[i] = d_in[i + 1]; wp.off[i] = total; total += wsz[i]; }
    wp.off[23] = total;   // 1,799,808 elements

    // workspace layout
    const size_t flag_bytes = 16;
    const size_t x0_bytes   = (size_t)B_SZ * 3 * N_PTS * 4;          //   98,304
    const size_t feat_bytes = (size_t)B_SZ * 512 * N_PTS * 2;        // 8,388,608
    const size_t idx_bytes  = (size_t)B_SZ * N_PTS * KNN * 4;        //   655,360
    const size_t pool_bytes = (size_t)B_SZ * 1024 * 4 * 2;           //    32,768
    const size_t wf_bytes   = (size_t)total * 4;                     // 7,199,232
    const size_t need = flag_bytes + x0_bytes + feat_bytes + idx_bytes + pool_bytes + wf_bytes;
    if (ws_size < need) return;   // graceful fail (harness zeroed d_out -> stub absmax)

    char* w = (char*)d_ws;
    int*   flag = (int*)w;              w += flag_bytes;
    float* x0   = (float*)w;            w += x0_bytes;
    bf16*  feat = (bf16*)w;             w += feat_bytes;
    int*   idx  = (int*)w;              w += idx_bytes;
    float* fmx  = (float*)w;            w += (size_t)B_SZ * 1024 * 4;
    float* fsm  = (float*)w;            w += (size_t)B_SZ * 1024 * 4;
    float* wf   = (float*)w;

    const int FBS = 512 * N_PTS;   // feat batch stride (elements)

    k_sniff<<<1, 64, 0, stream>>>((const unsigned short*)d_in[0], flag);
    k_repack<<<256, 256, 0, stream>>>(wp, flag, wf, total);
    k_transpose<<<(B_SZ * N_PTS + 255) / 256, 256, 0, stream>>>(d_in[0], flag, x0);

    const float* w1 = wf + wp.off[0],  *g1 = wf + wp.off[1],  *b1 = wf + wp.off[2];
    const float* w2 = wf + wp.off[3],  *g2 = wf + wp.off[4],  *b2 = wf + wp.off[5];
    const float* w3 = wf + wp.off[6],  *g3 = wf + wp.off[7],  *b3 = wf + wp.off[8];
    const float* w4 = wf + wp.off[9],  *g4 = wf + wp.off[10], *b4 = wf + wp.off[11];
    const float* w5 = wf + wp.off[12], *g5 = wf + wp.off[13], *b5 = wf + wp.off[14];
    const float* fw1 = wf + wp.off[15], *fb1 = wf + wp.off[16];
    const float* g6 = wf + wp.off[17], *b6 = wf + wp.off[18];
    const float* fw2 = wf + wp.off[19], *fb2 = wf + wp.off[20];
    const float* g7 = wf + wp.off[21], *b7 = wf + wp.off[22];

    // EdgeConv 1: x0 (C=3, fp32) -> feat channels [0,64)
    k_knn<float, 3><<<B_SZ * N_PTS / 4, 256, 0, stream>>>(x0, 3 * N_PTS, idx);
    k_edgeconv<float, 3, 64><<<B_SZ * N_PTS, 256, 0, stream>>>(x0, 3 * N_PTS, idx, w1, g1, b1,
                                                               feat + 0 * N_PTS, FBS);
    // EdgeConv 2: feat[0,64) -> feat [64,128)
    k_knn<bf16, 64><<<B_SZ * N_PTS / 4, 256, 0, stream>>>(feat + 0 * N_PTS, FBS, idx);
    k_edgeconv<bf16, 64, 64><<<B_SZ * N_PTS, 256, 0, stream>>>(feat + 0 * N_PTS, FBS, idx, w2, g2, b2,
                                                               feat + 64 * N_PTS, FBS);
    // EdgeConv 3: feat[64,128) -> feat [128,256)
    k_knn<bf16, 64><<<B_SZ * N_PTS / 4, 256, 0, stream>>>(feat + 64 * N_PTS, FBS, idx);
    k_edgeconv<bf16, 64, 128><<<B_SZ * N_PTS, 256, 0, stream>>>(feat + 64 * N_PTS, FBS, idx, w3, g3, b3,
                                                                feat + 128 * N_PTS, FBS);
    // EdgeConv 4: feat[128,256) -> feat [256,512)
    k_knn<bf16, 128><<<B_SZ * N_PTS / 4, 256, 0, stream>>>(feat + 128 * N_PTS, FBS, idx);
    k_edgeconv<bf16, 128, 256><<<B_SZ * N_PTS, 256, 0, stream>>>(feat + 128 * N_PTS, FBS, idx, w4, g4, b4,
                                                                 feat + 256 * N_PTS, FBS);
    // conv5 + BN + LReLU + max/sum pool
    k_conv5pool<<<B_SZ * (1024 / 16), 256, 0, stream>>>(feat, w5, g5, b5, fmx, fsm);
    // FC head
    k_head<<<B_SZ, 256, 0, stream>>>(fmx, fsm, fw1, fb1, g6, b6, fw2, fb2, g7, b7,
                                     flag, d_out);
}

// Round 4
// 2014.566 us; speedup vs baseline: 1.9095x; 1.9095x over previous
//
#include <hip/hip_runtime.h>
#include <hip/hip_bf16.h>
#include <float.h>

#define N_PTS 2048
#define B_SZ  4
#define KNN   20
#define LRELU_S 0.2f

typedef __hip_bfloat16 bf16;

__device__ __forceinline__ float b2f(const bf16 v) { return __bfloat162float(v); }
__device__ __forceinline__ float ldf(const float* p) { return *p; }
__device__ __forceinline__ float ldf(const bf16* p)  { return __bfloat162float(*p); }

// ---------------------------------------------------------------------------
// Dtype sniffer (robustness): bf16 (flag=1) vs fp32 (flag=0). Reads 256 B.
__global__ void k_sniff(const unsigned short* __restrict__ pts_hw, int* __restrict__ flag) {
    if (threadIdx.x != 0 || blockIdx.x != 0) return;
    int sane = 0;
    for (int j = 0; j < 64; ++j) {
        unsigned short v = pts_hw[2 * j];
        int e = (v >> 7) & 0xFF;
        if (e >= 100 && e <= 140) ++sane;
    }
    *flag = (sane >= 32) ? 1 : 0;
}

// ---------------------------------------------------------------------------
// Repack 23 weight tensors to fp32; EdgeConv W tensors stored TRANSPOSED:
// src (COUT, 2C) row-major -> dst (2C, COUT):  Wt[cc*COUT + o] = W[o*2C + cc].
struct WPack {
    const void* src[23];
    int off[24];      // prefix offsets (elements)
    int rows[23];     // COUT (0 = no transpose)
    int cols[23];     // 2C  (0 = no transpose)
};

__global__ void k_repack(WPack wp, const int* __restrict__ flag, float* __restrict__ dst, int total) {
    const int isb = *flag;
    for (int i = blockIdx.x * blockDim.x + threadIdx.x; i < total; i += gridDim.x * blockDim.x) {
        int lo = 0, hi = 23;
        while (lo + 1 < hi) { int mid = (lo + hi) >> 1; if (i >= wp.off[mid]) lo = mid; else hi = mid; }
        int j = i - wp.off[lo];
        float v = isb ? b2f(((const bf16*)wp.src[lo])[j]) : ((const float*)wp.src[lo])[j];
        int dj = j;
        int cols = wp.cols[lo];
        if (cols) dj = (j % cols) * wp.rows[lo] + (j / cols);
        dst[wp.off[lo] + dj] = v;
    }
}

// ---------------------------------------------------------------------------
// points (B,N,3) -> x0 (B,3,N) fp32, dtype-dynamic.
__global__ void k_transpose(const void* __restrict__ pts, const int* __restrict__ flag,
                            float* __restrict__ x0) {
    const int isb = *flag;
    int i = blockIdx.x * blockDim.x + threadIdx.x;
    if (i >= B_SZ * N_PTS) return;
    int b = i / N_PTS, n = i % N_PTS;
    for (int c = 0; c < 3; ++c) {
        size_t s = ((size_t)b * N_PTS + n) * 3 + c;
        float v = isb ? b2f(((const bf16*)pts)[s]) : ((const float*)pts)[s];
        x0[((size_t)b * 3 + c) * N_PTS + n] = v;
    }
}

// ---------------------------------------------------------------------------
// 32-candidate row loads (lane chunk), fp32 out.
__device__ __forceinline__ void load32(const float* row, int mbase, float* r) {
    const float4* p = (const float4*)(row + mbase);
#pragma unroll
    for (int i = 0; i < 8; ++i) {
        float4 f = p[i];
        r[4 * i + 0] = f.x; r[4 * i + 1] = f.y; r[4 * i + 2] = f.z; r[4 * i + 3] = f.w;
    }
}
__device__ __forceinline__ void load32(const bf16* row, int mbase, float* r) {
    const uint4* p = (const uint4*)(row + mbase);
#pragma unroll
    for (int i = 0; i < 4; ++i) {
        uint4 u = p[i];
        r[8 * i + 0] = __uint_as_float(u.x << 16);
        r[8 * i + 1] = __uint_as_float(u.x & 0xFFFF0000u);
        r[8 * i + 2] = __uint_as_float(u.y << 16);
        r[8 * i + 3] = __uint_as_float(u.y & 0xFFFF0000u);
        r[8 * i + 4] = __uint_as_float(u.z << 16);
        r[8 * i + 5] = __uint_as_float(u.z & 0xFFFF0000u);
        r[8 * i + 6] = __uint_as_float(u.w << 16);
        r[8 * i + 7] = __uint_as_float(u.w & 0xFFFF0000u);
    }
}

// ---------------------------------------------------------------------------
// kNN: one WAVE per query (4 queries/block). All 2048 distances live in
// v[32] registers per lane; 20 argmin rounds via register scan + 64-lane
// shfl_xor butterfly (tie -> lowest index). No __syncthreads in rounds.
template<typename T, int C>
__global__ __launch_bounds__(256) void k_knn(const T* __restrict__ x, int bstride,
                                             int* __restrict__ idx) {
    __shared__ float qf[4][C];
    int ib = blockIdx.x;
    int b  = ib / (N_PTS / 4);
    int q0 = (ib % (N_PTS / 4)) * 4;
    const T* xb = x + (size_t)b * bstride;

    for (int t = threadIdx.x; t < 4 * C; t += 256) {
        int pt = t / C, c = t % C;
        qf[pt][c] = ldf(&xb[(size_t)c * N_PTS + (q0 + pt)]);
    }
    __syncthreads();

    int w = threadIdx.x >> 6, lane = threadIdx.x & 63;
    int q = q0 + w;
    int mbase = lane * 32;

    float v[32];
#pragma unroll
    for (int j = 0; j < 32; ++j) v[j] = 0.f;

    for (int c = 0; c < C; ++c) {
        float qc = qf[w][c];
        float r[32];
        load32(xb + (size_t)c * N_PTS, mbase, r);
#pragma unroll
        for (int j = 0; j < 32; ++j) { float t = r[j] - qc; v[j] = fmaf(t, t, v[j]); }
    }

    for (int k = 0; k < KNN; ++k) {
        float bv = FLT_MAX; int bi = 0x7FFFFFFF;
#pragma unroll
        for (int j = 0; j < 32; ++j)
            if (v[j] < bv) { bv = v[j]; bi = mbase + j; }
#pragma unroll
        for (int off = 32; off >= 1; off >>= 1) {
            float ov = __shfl_xor(bv, off);
            int   oi = __shfl_xor(bi, off);
            if (ov < bv || (ov == bv && oi < bi)) { bv = ov; bi = oi; }
        }
        if (lane == 0) idx[((size_t)b * N_PTS + q) * KNN + k] = bi;
        int wl = bi >> 5, wj = bi & 31;
        if (lane == wl) {
#pragma unroll
            for (int j = 0; j < 32; ++j) if (j == wj) v[j] = FLT_MAX;
        }
    }
}

// ---------------------------------------------------------------------------
// EdgeConv: wave-per-point, PT=4 points/block, OT=COUT/64 outputs/lane.
// Wt is (2C, COUT): rows [0,C) = W1 (center), rows [C,2C) = W2 (neighbor).
// out[o] = max_k lrelu( (base_o + sum_c W2[o,c]*x_k[c]) * scale + bias ),
// base_o = sum_c (W1-W2)[o,c]*x_n[c].  c-ascending fp32 fma (== round 3).
template<typename T, int C, int COUT>
__global__ __launch_bounds__(256) void k_edgeconv(const T* __restrict__ x, int bstride,
                           const int* __restrict__ idx,
                           const float* __restrict__ Wt,
                           const float* __restrict__ gam,
                           const float* __restrict__ bet,
                           bf16* __restrict__ out, int ostride) {
    const int PT = 4;
    const int OT = COUT / 64;
    const int CP = (C + 3) & ~3;
    __shared__ float sh[PT][KNN + 1][CP];     // row 0 = center, 1..20 = neighbors

    int ib = blockIdx.x;
    int b  = ib / (N_PTS / PT);
    int n0 = (ib % (N_PTS / PT)) * PT;
    const T* xb = x + (size_t)b * bstride;

    const int TOT = PT * (KNN + 1) * C;
    for (int t = threadIdx.x; t < TOT; t += 256) {
        int pt = t / ((KNN + 1) * C);
        int r  = t % ((KNN + 1) * C);
        int row = r / C, c = r % C;
        int n = n0 + pt;
        int m = (row == 0) ? n
                           : (idx[((size_t)b * N_PTS + n) * KNN + (row - 1)] & (N_PTS - 1));
        sh[pt][row][c] = ldf(&xb[(size_t)c * N_PTS + m]);
    }
    __syncthreads();

    int w = threadIdx.x >> 6, lane = threadIdx.x & 63;
    int n = n0 + w;

    float base[OT];
    float acc[OT][KNN];
#pragma unroll
    for (int j = 0; j < OT; ++j) {
        base[j] = 0.f;
#pragma unroll
        for (int k = 0; k < KNN; ++k) acc[j][k] = 0.f;
    }

    for (int c = 0; c < C; ++c) {
        float xq = sh[w][0][c];
        float w1v[OT], w2v[OT];
#pragma unroll
        for (int j = 0; j < OT; ++j) {
            w1v[j] = Wt[(size_t)c * COUT + lane + 64 * j];
            w2v[j] = Wt[(size_t)(C + c) * COUT + lane + 64 * j];
        }
#pragma unroll
        for (int j = 0; j < OT; ++j) base[j] = fmaf(w1v[j] - w2v[j], xq, base[j]);
#pragma unroll
        for (int k = 0; k < KNN; ++k) {
            float nv = sh[w][1 + k][c];
#pragma unroll
            for (int j = 0; j < OT; ++j) acc[j][k] = fmaf(w2v[j], nv, acc[j][k]);
        }
    }

    const float inv = rsqrtf(1.0f + 1e-5f);
#pragma unroll
    for (int j = 0; j < OT; ++j) {
        int o = lane + 64 * j;
        float scale = gam[o] * inv, bias = bet[o];
        float mx = -FLT_MAX;
#pragma unroll
        for (int k = 0; k < KNN; ++k) {
            float h = (base[j] + acc[j][k]) * scale + bias;
            h = h > 0.f ? h : LRELU_S * h;
            mx = fmaxf(mx, h);
        }
        out[(size_t)b * ostride + (size_t)o * N_PTS + n] = __float2bfloat16(mx);
    }
}

// ---------------------------------------------------------------------------
// conv5 (1024x512) + BN + LReLU + max/sum partial pooling over an N-chunk.
// Grid: B * 64 o-tiles * NCH chunks. Partials (B,1024,NCH) reduced in k_head.
#define NCH 4
__global__ __launch_bounds__(256) void k_conv5pool(const bf16* __restrict__ feat,
                            const float* __restrict__ w5,
                            const float* __restrict__ g5,
                            const float* __restrict__ b5,
                            float* __restrict__ fmxp, float* __restrict__ fsmp) {
    const int OT = 16;
    const int CHN = N_PTS / NCH;             // 512
    __shared__ float wl[OT][512];            // 32 KB, reused as reduction scratch
    int ib = blockIdx.x;
    int ch = ib % NCH;
    int ot = (ib / NCH) % (1024 / OT);
    int b  = ib / (NCH * (1024 / OT));
    int o0 = ot * OT;
    const bf16* fb = feat + (size_t)b * 512 * N_PTS;

    for (int t = threadIdx.x; t < OT * 512; t += 256) {
        int o = t / 512, c = t % 512;
        wl[o][c] = w5[(size_t)(o0 + o) * 512 + c];
    }
    __syncthreads();

    const float inv = rsqrtf(1.0f + 1e-5f);
    float scale[OT], bias[OT], mxv[OT], smv[OT];
#pragma unroll
    for (int o = 0; o < OT; ++o) {
        scale[o] = g5[o0 + o] * inv;
        bias[o]  = b5[o0 + o];
        mxv[o] = -FLT_MAX; smv[o] = 0.f;
    }

    for (int n = ch * CHN + threadIdx.x; n < (ch + 1) * CHN; n += 256) {
        float acc[OT];
#pragma unroll
        for (int o = 0; o < OT; ++o) acc[o] = 0.f;
        for (int c = 0; c < 512; ++c) {
            float f = b2f(fb[(size_t)c * N_PTS + n]);
#pragma unroll
            for (int o = 0; o < OT; ++o) acc[o] += wl[o][c] * f;
        }
#pragma unroll
        for (int o = 0; o < OT; ++o) {
            float h = acc[o] * scale[o] + bias[o];
            h = h > 0.f ? h : LRELU_S * h;
            mxv[o] = fmaxf(mxv[o], h);
            smv[o] += h;
        }
    }
    __syncthreads();

    float* red = &wl[0][0];
    for (int o = 0; o < OT; ++o) {
        red[threadIdx.x]       = mxv[o];
        red[256 + threadIdx.x] = smv[o];
        __syncthreads();
        for (int s = 128; s > 0; s >>= 1) {
            if (threadIdx.x < s) {
                red[threadIdx.x] = fmaxf(red[threadIdx.x], red[threadIdx.x + s]);
                red[256 + threadIdx.x] += red[256 + threadIdx.x + s];
            }
            __syncthreads();
        }
        if (threadIdx.x == 0) {
            fmxp[((size_t)b * 1024 + o0 + o) * NCH + ch] = red[0];
            fsmp[((size_t)b * 1024 + o0 + o) * NCH + ch] = red[256];
        }
        __syncthreads();
    }
}

// ---------------------------------------------------------------------------
// Head: reduce NCH partials -> f = [max(1024), mean(1024)] -> fc1 -> fc2.
__global__ void k_head(const float* __restrict__ fmxp, const float* __restrict__ fsmp,
                       const float* __restrict__ fw1, const float* __restrict__ fb1,
                       const float* __restrict__ g6,  const float* __restrict__ b6,
                       const float* __restrict__ fw2, const float* __restrict__ fb2,
                       const float* __restrict__ g7,  const float* __restrict__ b7,
                       const int* __restrict__ flag, void* __restrict__ out) {
    __shared__ float f[2048];
    __shared__ float t[512];
    int b = blockIdx.x;
    for (int i = threadIdx.x; i < 1024; i += 256) {
        float mx = -FLT_MAX, sm = 0.f;
        for (int ch = 0; ch < NCH; ++ch) {
            mx = fmaxf(mx, fmxp[((size_t)b * 1024 + i) * NCH + ch]);
            sm += fsmp[((size_t)b * 1024 + i) * NCH + ch];
        }
        f[i]        = mx;
        f[1024 + i] = sm * (1.0f / N_PTS);
    }
    __syncthreads();
    const float inv = rsqrtf(1.0f + 1e-5f);
    for (int o = threadIdx.x; o < 512; o += 256) {
        const float* wr = fw1 + (size_t)o * 2048;
        float acc = fb1[o];
        for (int j = 0; j < 2048; ++j) acc += wr[j] * f[j];
        float h = acc * g6[o] * inv + b6[o];
        t[o] = h > 0.f ? h : LRELU_S * h;
    }
    __syncthreads();
    {
        int o = threadIdx.x;
        const float* wr = fw2 + (size_t)o * 512;
        float acc = fb2[o];
        for (int j = 0; j < 512; ++j) acc += wr[j] * t[j];
        float h = acc * g7[o] * inv + b7[o];
        if (*flag) ((bf16*)out)[(size_t)b * 256 + o] = __float2bfloat16(h);
        else       ((float*)out)[(size_t)b * 256 + o] = h;
    }
}

// ---------------------------------------------------------------------------
extern "C" void kernel_launch(void* const* d_in, const int* in_sizes, int n_in,
                              void* d_out, int out_size, void* d_ws, size_t ws_size,
                              hipStream_t stream) {
    static const int wsz[23] = {
        384, 64, 64,   8192, 64, 64,   16384, 128, 128,   65536, 256, 256,
        524288, 1024, 1024,   1048576, 512,   512, 512,   131072, 256,   256, 256
    };
    // transpose dims for w1..w4 (index 0,3,6,9): rows=COUT, cols=2C
    static const int trows[23] = {64,0,0, 64,0,0, 128,0,0, 256,0,0, 0,0,0, 0,0, 0,0, 0,0, 0,0};
    static const int tcols[23] = { 6,0,0,128,0,0, 128,0,0, 256,0,0, 0,0,0, 0,0, 0,0, 0,0, 0,0};

    WPack wp;
    int total = 0;
    for (int i = 0; i < 23; ++i) {
        wp.src[i] = d_in[i + 1]; wp.off[i] = total; total += wsz[i];
        wp.rows[i] = trows[i]; wp.cols[i] = tcols[i];
    }
    wp.off[23] = total;

    const size_t flag_bytes = 16;
    const size_t x0_bytes   = (size_t)B_SZ * 3 * N_PTS * 4;
    const size_t feat_bytes = (size_t)B_SZ * 512 * N_PTS * 2;
    const size_t idx_bytes  = (size_t)B_SZ * N_PTS * KNN * 4;     // also holds pool partials later
    const size_t pool_bytes = (size_t)B_SZ * 1024 * 4 * 2;
    const size_t wf_bytes   = (size_t)total * 4;
    const size_t need = flag_bytes + x0_bytes + feat_bytes + idx_bytes + pool_bytes + wf_bytes;
    if (ws_size < need) return;   // graceful fail

    char* w = (char*)d_ws;
    int*   flag = (int*)w;              w += flag_bytes;
    float* x0   = (float*)w;            w += x0_bytes;
    bf16*  feat = (bf16*)w;             w += feat_bytes;
    int*   idx  = (int*)w;              w += idx_bytes;
    w += pool_bytes;                    // (legacy slot, unused)
    float* wf   = (float*)w;

    // pool partials overlay the idx region (idx dead after EdgeConv4):
    float* fmxp = (float*)idx;                         // B*1024*NCH
    float* fsmp = fmxp + (size_t)B_SZ * 1024 * NCH;    // B*1024*NCH  (128 KB <= 640 KB)

    const int FBS = 512 * N_PTS;

    k_sniff<<<1, 64, 0, stream>>>((const unsigned short*)d_in[0], flag);
    k_repack<<<256, 256, 0, stream>>>(wp, flag, wf, total);
    k_transpose<<<(B_SZ * N_PTS + 255) / 256, 256, 0, stream>>>(d_in[0], flag, x0);

    const float* w1t = wf + wp.off[0],  *g1 = wf + wp.off[1],  *b1 = wf + wp.off[2];
    const float* w2t = wf + wp.off[3],  *g2 = wf + wp.off[4],  *b2 = wf + wp.off[5];
    const float* w3t = wf + wp.off[6],  *g3 = wf + wp.off[7],  *b3 = wf + wp.off[8];
    const float* w4t = wf + wp.off[9],  *g4 = wf + wp.off[10], *b4 = wf + wp.off[11];
    const float* w5  = wf + wp.off[12], *g5 = wf + wp.off[13], *b5 = wf + wp.off[14];
    const float* fw1 = wf + wp.off[15], *fb1 = wf + wp.off[16];
    const float* g6  = wf + wp.off[17], *b6 = wf + wp.off[18];
    const float* fw2 = wf + wp.off[19], *fb2 = wf + wp.off[20];
    const float* g7  = wf + wp.off[21], *b7 = wf + wp.off[22];

    const int GK = B_SZ * N_PTS / 4;   // 2048 blocks (kNN and EdgeConv)

    k_knn<float, 3><<<GK, 256, 0, stream>>>(x0, 3 * N_PTS, idx);
    k_edgeconv<float, 3, 64><<<GK, 256, 0, stream>>>(x0, 3 * N_PTS, idx, w1t, g1, b1,
                                                     feat + 0 * N_PTS, FBS);
    k_knn<bf16, 64><<<GK, 256, 0, stream>>>(feat + 0 * N_PTS, FBS, idx);
    k_edgeconv<bf16, 64, 64><<<GK, 256, 0, stream>>>(feat + 0 * N_PTS, FBS, idx, w2t, g2, b2,
                                                     feat + 64 * N_PTS, FBS);
    k_knn<bf16, 64><<<GK, 256, 0, stream>>>(feat + 64 * N_PTS, FBS, idx);
    k_edgeconv<bf16, 64, 128><<<GK, 256, 0, stream>>>(feat + 64 * N_PTS, FBS, idx, w3t, g3, b3,
                                                      feat + 128 * N_PTS, FBS);
    k_knn<bf16, 128><<<GK, 256, 0, stream>>>(feat + 128 * N_PTS, FBS, idx);
    k_edgeconv<bf16, 128, 256><<<GK, 256, 0, stream>>>(feat + 128 * N_PTS, FBS, idx, w4t, g4, b4,
                                                       feat + 256 * N_PTS, FBS);

    k_conv5pool<<<B_SZ * (1024 / 16) * NCH, 256, 0, stream>>>(feat, w5, g5, b5, fmxp, fsmp);
    k_head<<<B_SZ, 256, 0, stream>>>(fmxp, fsmp, fw1, fb1, g6, b6, fw2, fb2, g7, b7,
                                     flag, d_out);
}

// Round 5
// 1514.651 us; speedup vs baseline: 2.5398x; 1.3301x over previous
//
#include <hip/hip_runtime.h>
#include <hip/hip_bf16.h>
#include <float.h>

#define N_PTS 2048
#define B_SZ  4
#define KNN   20
#define LRELU_S 0.2f

typedef __hip_bfloat16 bf16;

__device__ __forceinline__ float b2f(const bf16 v) { return __bfloat162float(v); }
__device__ __forceinline__ float ldf(const float* p) { return *p; }
__device__ __forceinline__ float ldf(const bf16* p)  { return __bfloat162float(*p); }

// ---------------------------------------------------------------------------
// Dtype sniffer (robustness): bf16 (flag=1) vs fp32 (flag=0). Reads 256 B.
__global__ void k_sniff(const unsigned short* __restrict__ pts_hw, int* __restrict__ flag) {
    if (threadIdx.x != 0 || blockIdx.x != 0) return;
    int sane = 0;
    for (int j = 0; j < 64; ++j) {
        unsigned short v = pts_hw[2 * j];
        int e = (v >> 7) & 0xFF;
        if (e >= 100 && e <= 140) ++sane;
    }
    *flag = (sane >= 32) ? 1 : 0;
}

// ---------------------------------------------------------------------------
// Repack 23 weight tensors to fp32; EdgeConv W tensors stored TRANSPOSED:
// src (COUT, 2C) row-major -> dst (2C, COUT):  Wt[cc*COUT + o] = W[o*2C + cc].
struct WPack {
    const void* src[23];
    int off[24];      // prefix offsets (elements)
    int rows[23];     // COUT (0 = no transpose)
    int cols[23];     // 2C  (0 = no transpose)
};

__global__ void k_repack(WPack wp, const int* __restrict__ flag, float* __restrict__ dst, int total) {
    const int isb = *flag;
    for (int i = blockIdx.x * blockDim.x + threadIdx.x; i < total; i += gridDim.x * blockDim.x) {
        int lo = 0, hi = 23;
        while (lo + 1 < hi) { int mid = (lo + hi) >> 1; if (i >= wp.off[mid]) lo = mid; else hi = mid; }
        int j = i - wp.off[lo];
        float v = isb ? b2f(((const bf16*)wp.src[lo])[j]) : ((const float*)wp.src[lo])[j];
        int dj = j;
        int cols = wp.cols[lo];
        if (cols) dj = (j % cols) * wp.rows[lo] + (j / cols);
        dst[wp.off[lo] + dj] = v;
    }
}

// ---------------------------------------------------------------------------
// points (B,N,3) -> x0 (B,3,N) fp32, dtype-dynamic.
__global__ void k_transpose(const void* __restrict__ pts, const int* __restrict__ flag,
                            float* __restrict__ x0) {
    const int isb = *flag;
    int i = blockIdx.x * blockDim.x + threadIdx.x;
    if (i >= B_SZ * N_PTS) return;
    int b = i / N_PTS, n = i % N_PTS;
    for (int c = 0; c < 3; ++c) {
        size_t s = ((size_t)b * N_PTS + n) * 3 + c;
        float v = isb ? b2f(((const bf16*)pts)[s]) : ((const float*)pts)[s];
        x0[((size_t)b * 3 + c) * N_PTS + n] = v;
    }
}

// ---------------------------------------------------------------------------
// 32-candidate row loads (lane chunk), fp32 out.
__device__ __forceinline__ void load32(const float* row, int mbase, float* r) {
    const float4* p = (const float4*)(row + mbase);
#pragma unroll
    for (int i = 0; i < 8; ++i) {
        float4 f = p[i];
        r[4 * i + 0] = f.x; r[4 * i + 1] = f.y; r[4 * i + 2] = f.z; r[4 * i + 3] = f.w;
    }
}
__device__ __forceinline__ void load32(const bf16* row, int mbase, float* r) {
    const uint4* p = (const uint4*)(row + mbase);
#pragma unroll
    for (int i = 0; i < 4; ++i) {
        uint4 u = p[i];
        r[8 * i + 0] = __uint_as_float(u.x << 16);
        r[8 * i + 1] = __uint_as_float(u.x & 0xFFFF0000u);
        r[8 * i + 2] = __uint_as_float(u.y << 16);
        r[8 * i + 3] = __uint_as_float(u.y & 0xFFFF0000u);
        r[8 * i + 4] = __uint_as_float(u.z << 16);
        r[8 * i + 5] = __uint_as_float(u.z & 0xFFFF0000u);
        r[8 * i + 6] = __uint_as_float(u.w << 16);
        r[8 * i + 7] = __uint_as_float(u.w & 0xFFFF0000u);
    }
}

// ---------------------------------------------------------------------------
// kNN: one WAVE per query (4 queries/block). All 2048 distances live in
// v[32] registers per lane; 20 argmin rounds via register scan + 64-lane
// shfl_xor butterfly (tie -> lowest index). No __syncthreads in rounds.
template<typename T, int C>
__global__ __launch_bounds__(256) void k_knn(const T* __restrict__ x, int bstride,
                                             int* __restrict__ idx) {
    __shared__ float qf[4][C];
    int ib = blockIdx.x;
    int b  = ib / (N_PTS / 4);
    int q0 = (ib % (N_PTS / 4)) * 4;
    const T* xb = x + (size_t)b * bstride;

    for (int t = threadIdx.x; t < 4 * C; t += 256) {
        int pt = t / C, c = t % C;
        qf[pt][c] = ldf(&xb[(size_t)c * N_PTS + (q0 + pt)]);
    }
    __syncthreads();

    int w = threadIdx.x >> 6, lane = threadIdx.x & 63;
    int q = q0 + w;
    int mbase = lane * 32;

    float v[32];
#pragma unroll
    for (int j = 0; j < 32; ++j) v[j] = 0.f;

    for (int c = 0; c < C; ++c) {
        float qc = qf[w][c];
        float r[32];
        load32(xb + (size_t)c * N_PTS, mbase, r);
#pragma unroll
        for (int j = 0; j < 32; ++j) { float t = r[j] - qc; v[j] = fmaf(t, t, v[j]); }
    }

    for (int k = 0; k < KNN; ++k) {
        float bv = FLT_MAX; int bi = 0x7FFFFFFF;
#pragma unroll
        for (int j = 0; j < 32; ++j)
            if (v[j] < bv) { bv = v[j]; bi = mbase + j; }
#pragma unroll
        for (int off = 32; off >= 1; off >>= 1) {
            float ov = __shfl_xor(bv, off);
            int   oi = __shfl_xor(bi, off);
            if (ov < bv || (ov == bv && oi < bi)) { bv = ov; bi = oi; }
        }
        if (lane == 0) idx[((size_t)b * N_PTS + q) * KNN + k] = bi;
        int wl = bi >> 5, wj = bi & 31;
        if (lane == wl) {
#pragma unroll
            for (int j = 0; j < 32; ++j) if (j == wj) v[j] = FLT_MAX;
        }
    }
}

// ---------------------------------------------------------------------------
// EdgeConv: wave-per-point, PT=4 points/block, OT=COUT/64 outputs/lane.
// Wt is (2C, COUT): rows [0,C) = W1 (center), rows [C,2C) = W2 (neighbor).
template<typename T, int C, int COUT>
__global__ __launch_bounds__(256) void k_edgeconv(const T* __restrict__ x, int bstride,
                           const int* __restrict__ idx,
                           const float* __restrict__ Wt,
                           const float* __restrict__ gam,
                           const float* __restrict__ bet,
                           bf16* __restrict__ out, int ostride) {
    const int PT = 4;
    const int OT = COUT / 64;
    const int CP = (C + 3) & ~3;
    __shared__ float sh[PT][KNN + 1][CP];     // row 0 = center, 1..20 = neighbors

    int ib = blockIdx.x;
    int b  = ib / (N_PTS / PT);
    int n0 = (ib % (N_PTS / PT)) * PT;
    const T* xb = x + (size_t)b * bstride;

    const int TOT = PT * (KNN + 1) * C;
    for (int t = threadIdx.x; t < TOT; t += 256) {
        int pt = t / ((KNN + 1) * C);
        int r  = t % ((KNN + 1) * C);
        int row = r / C, c = r % C;
        int n = n0 + pt;
        int m = (row == 0) ? n
                           : (idx[((size_t)b * N_PTS + n) * KNN + (row - 1)] & (N_PTS - 1));
        sh[pt][row][c] = ldf(&xb[(size_t)c * N_PTS + m]);
    }
    __syncthreads();

    int w = threadIdx.x >> 6, lane = threadIdx.x & 63;
    int n = n0 + w;

    float base[OT];
    float acc[OT][KNN];
#pragma unroll
    for (int j = 0; j < OT; ++j) {
        base[j] = 0.f;
#pragma unroll
        for (int k = 0; k < KNN; ++k) acc[j][k] = 0.f;
    }

    for (int c = 0; c < C; ++c) {
        float xq = sh[w][0][c];
        float w1v[OT], w2v[OT];
#pragma unroll
        for (int j = 0; j < OT; ++j) {
            w1v[j] = Wt[(size_t)c * COUT + lane + 64 * j];
            w2v[j] = Wt[(size_t)(C + c) * COUT + lane + 64 * j];
        }
#pragma unroll
        for (int j = 0; j < OT; ++j) base[j] = fmaf(w1v[j] - w2v[j], xq, base[j]);
#pragma unroll
        for (int k = 0; k < KNN; ++k) {
            float nv = sh[w][1 + k][c];
#pragma unroll
            for (int j = 0; j < OT; ++j) acc[j][k] = fmaf(w2v[j], nv, acc[j][k]);
        }
    }

    const float inv = rsqrtf(1.0f + 1e-5f);
#pragma unroll
    for (int j = 0; j < OT; ++j) {
        int o = lane + 64 * j;
        float scale = gam[o] * inv, bias = bet[o];
        float mx = -FLT_MAX;
#pragma unroll
        for (int k = 0; k < KNN; ++k) {
            float h = (base[j] + acc[j][k]) * scale + bias;
            h = h > 0.f ? h : LRELU_S * h;
            mx = fmaxf(mx, h);
        }
        out[(size_t)b * ostride + (size_t)o * N_PTS + n] = __float2bfloat16(mx);
    }
}

// ---------------------------------------------------------------------------
// conv5 (1024x512) + BN + LReLU + max/sum partial pooling over an N-chunk.
// OT=8 outputs/block, NT=4 n-points/thread (1024-n chunk per block), weights
// in LDS read as float4 (ds_read_b128): per c-group of 4 -> 8 LDS b128 +
// 4x8B coalesced feat loads + 128 FMAs (VALU-bound).
#define NCH 2
__global__ __launch_bounds__(256) void k_conv5pool(const bf16* __restrict__ feat,
                            const float* __restrict__ w5,
                            const float* __restrict__ g5,
                            const float* __restrict__ b5,
                            float* __restrict__ fmxp, float* __restrict__ fsmp) {
    const int OT = 8;
    const int NT = 4;
    const int CHN = N_PTS / NCH;             // 1024 = 256 threads * NT
    __shared__ float wl[OT][512];            // 16 KB
    __shared__ float rmx[4][OT];
    __shared__ float rsm[4][OT];

    int ib = blockIdx.x;
    int ch = ib % NCH;
    int ot = (ib / NCH) % (1024 / OT);
    int b  = ib / (NCH * (1024 / OT));
    int o0 = ot * OT;
    const bf16* fb = feat + (size_t)b * 512 * N_PTS;

    for (int t = threadIdx.x; t < OT * 512; t += 256) {
        int o = t >> 9, c = t & 511;
        wl[o][c] = w5[(size_t)(o0 + o) * 512 + c];
    }
    __syncthreads();

    const int n0 = ch * CHN + threadIdx.x * NT;

    float acc[OT][NT];
#pragma unroll
    for (int o = 0; o < OT; ++o)
#pragma unroll
        for (int t = 0; t < NT; ++t) acc[o][t] = 0.f;

    for (int c = 0; c < 512; c += 4) {
        float fv[4][NT];
#pragma unroll
        for (int j = 0; j < 4; ++j) {
            uint2 u = *(const uint2*)(fb + (size_t)(c + j) * N_PTS + n0);
            fv[j][0] = __uint_as_float(u.x << 16);
            fv[j][1] = __uint_as_float(u.x & 0xFFFF0000u);
            fv[j][2] = __uint_as_float(u.y << 16);
            fv[j][3] = __uint_as_float(u.y & 0xFFFF0000u);
        }
#pragma unroll
        for (int o = 0; o < OT; ++o) {
            float4 wv = *(const float4*)&wl[o][c];
#pragma unroll
            for (int t = 0; t < NT; ++t) {
                acc[o][t] = fmaf(wv.x, fv[0][t], acc[o][t]);
                acc[o][t] = fmaf(wv.y, fv[1][t], acc[o][t]);
                acc[o][t] = fmaf(wv.z, fv[2][t], acc[o][t]);
                acc[o][t] = fmaf(wv.w, fv[3][t], acc[o][t]);
            }
        }
    }

    const float inv = rsqrtf(1.0f + 1e-5f);
    int w = threadIdx.x >> 6, lane = threadIdx.x & 63;
#pragma unroll
    for (int o = 0; o < OT; ++o) {
        float scale = g5[o0 + o] * inv, bias = b5[o0 + o];
        float mx = -FLT_MAX, sm = 0.f;
#pragma unroll
        for (int t = 0; t < NT; ++t) {
            float h = acc[o][t] * scale + bias;
            h = h > 0.f ? h : LRELU_S * h;
            mx = fmaxf(mx, h);
            sm += h;
        }
#pragma unroll
        for (int off = 32; off >= 1; off >>= 1) {
            mx = fmaxf(mx, __shfl_xor(mx, off));
            sm += __shfl_xor(sm, off);
        }
        if (lane == 0) { rmx[w][o] = mx; rsm[w][o] = sm; }
    }
    __syncthreads();
    if (threadIdx.x < OT) {
        int o = threadIdx.x;
        float mx = -FLT_MAX, sm = 0.f;
#pragma unroll
        for (int ww = 0; ww < 4; ++ww) { mx = fmaxf(mx, rmx[ww][o]); sm += rsm[ww][o]; }
        fmxp[((size_t)b * 1024 + o0 + o) * NCH + ch] = mx;
        fsmp[((size_t)b * 1024 + o0 + o) * NCH + ch] = sm;
    }
}

// ---------------------------------------------------------------------------
// Head: reduce NCH partials -> f = [max(1024), mean(1024)] -> fc1 -> fc2.
__global__ void k_head(const float* __restrict__ fmxp, const float* __restrict__ fsmp,
                       const float* __restrict__ fw1, const float* __restrict__ fb1,
                       const float* __restrict__ g6,  const float* __restrict__ b6,
                       const float* __restrict__ fw2, const float* __restrict__ fb2,
                       const float* __restrict__ g7,  const float* __restrict__ b7,
                       const int* __restrict__ flag, void* __restrict__ out) {
    __shared__ float f[2048];
    __shared__ float t[512];
    int b = blockIdx.x;
    for (int i = threadIdx.x; i < 1024; i += 256) {
        float mx = -FLT_MAX, sm = 0.f;
        for (int ch = 0; ch < NCH; ++ch) {
            mx = fmaxf(mx, fmxp[((size_t)b * 1024 + i) * NCH + ch]);
            sm += fsmp[((size_t)b * 1024 + i) * NCH + ch];
        }
        f[i]        = mx;
        f[1024 + i] = sm * (1.0f / N_PTS);
    }
    __syncthreads();
    const float inv = rsqrtf(1.0f + 1e-5f);
    for (int o = threadIdx.x; o < 512; o += 256) {
        const float* wr = fw1 + (size_t)o * 2048;
        float acc = fb1[o];
        for (int j = 0; j < 2048; ++j) acc += wr[j] * f[j];
        float h = acc * g6[o] * inv + b6[o];
        t[o] = h > 0.f ? h : LRELU_S * h;
    }
    __syncthreads();
    {
        int o = threadIdx.x;
        const float* wr = fw2 + (size_t)o * 512;
        float acc = fb2[o];
        for (int j = 0; j < 512; ++j) acc += wr[j] * t[j];
        float h = acc * g7[o] * inv + b7[o];
        if (*flag) ((bf16*)out)[(size_t)b * 256 + o] = __float2bfloat16(h);
        else       ((float*)out)[(size_t)b * 256 + o] = h;
    }
}

// ---------------------------------------------------------------------------
extern "C" void kernel_launch(void* const* d_in, const int* in_sizes, int n_in,
                              void* d_out, int out_size, void* d_ws, size_t ws_size,
                              hipStream_t stream) {
    static const int wsz[23] = {
        384, 64, 64,   8192, 64, 64,   16384, 128, 128,   65536, 256, 256,
        524288, 1024, 1024,   1048576, 512,   512, 512,   131072, 256,   256, 256
    };
    static const int trows[23] = {64,0,0, 64,0,0, 128,0,0, 256,0,0, 0,0,0, 0,0, 0,0, 0,0, 0,0};
    static const int tcols[23] = { 6,0,0,128,0,0, 128,0,0, 256,0,0, 0,0,0, 0,0, 0,0, 0,0, 0,0};

    WPack wp;
    int total = 0;
    for (int i = 0; i < 23; ++i) {
        wp.src[i] = d_in[i + 1]; wp.off[i] = total; total += wsz[i];
        wp.rows[i] = trows[i]; wp.cols[i] = tcols[i];
    }
    wp.off[23] = total;

    const size_t flag_bytes = 16;
    const size_t x0_bytes   = (size_t)B_SZ * 3 * N_PTS * 4;
    const size_t feat_bytes = (size_t)B_SZ * 512 * N_PTS * 2;
    const size_t idx_bytes  = (size_t)B_SZ * N_PTS * KNN * 4;     // also holds pool partials later
    const size_t pool_bytes = (size_t)B_SZ * 1024 * 4 * 2;
    const size_t wf_bytes   = (size_t)total * 4;
    const size_t need = flag_bytes + x0_bytes + feat_bytes + idx_bytes + pool_bytes + wf_bytes;
    if (ws_size < need) return;   // graceful fail

    char* w = (char*)d_ws;
    int*   flag = (int*)w;              w += flag_bytes;
    float* x0   = (float*)w;            w += x0_bytes;
    bf16*  feat = (bf16*)w;             w += feat_bytes;
    int*   idx  = (int*)w;              w += idx_bytes;
    w += pool_bytes;                    // (legacy slot, unused)
    float* wf   = (float*)w;

    // pool partials overlay the idx region (idx dead after EdgeConv4):
    float* fmxp = (float*)idx;                         // B*1024*NCH
    float* fsmp = fmxp + (size_t)B_SZ * 1024 * NCH;    // B*1024*NCH

    const int FBS = 512 * N_PTS;

    k_sniff<<<1, 64, 0, stream>>>((const unsigned short*)d_in[0], flag);
    k_repack<<<256, 256, 0, stream>>>(wp, flag, wf, total);
    k_transpose<<<(B_SZ * N_PTS + 255) / 256, 256, 0, stream>>>(d_in[0], flag, x0);

    const float* w1t = wf + wp.off[0],  *g1 = wf + wp.off[1],  *b1 = wf + wp.off[2];
    const float* w2t = wf + wp.off[3],  *g2 = wf + wp.off[4],  *b2 = wf + wp.off[5];
    const float* w3t = wf + wp.off[6],  *g3 = wf + wp.off[7],  *b3 = wf + wp.off[8];
    const float* w4t = wf + wp.off[9],  *g4 = wf + wp.off[10], *b4 = wf + wp.off[11];
    const float* w5  = wf + wp.off[12], *g5 = wf + wp.off[13], *b5 = wf + wp.off[14];
    const float* fw1 = wf + wp.off[15], *fb1 = wf + wp.off[16];
    const float* g6  = wf + wp.off[17], *b6 = wf + wp.off[18];
    const float* fw2 = wf + wp.off[19], *fb2 = wf + wp.off[20];
    const float* g7  = wf + wp.off[21], *b7 = wf + wp.off[22];

    const int GK = B_SZ * N_PTS / 4;   // 2048 blocks (kNN and EdgeConv)

    k_knn<float, 3><<<GK, 256, 0, stream>>>(x0, 3 * N_PTS, idx);
    k_edgeconv<float, 3, 64><<<GK, 256, 0, stream>>>(x0, 3 * N_PTS, idx, w1t, g1, b1,
                                                     feat + 0 * N_PTS, FBS);
    k_knn<bf16, 64><<<GK, 256, 0, stream>>>(feat + 0 * N_PTS, FBS, idx);
    k_edgeconv<bf16, 64, 64><<<GK, 256, 0, stream>>>(feat + 0 * N_PTS, FBS, idx, w2t, g2, b2,
                                                     feat + 64 * N_PTS, FBS);
    k_knn<bf16, 64><<<GK, 256, 0, stream>>>(feat + 64 * N_PTS, FBS, idx);
    k_edgeconv<bf16, 64, 128><<<GK, 256, 0, stream>>>(feat + 64 * N_PTS, FBS, idx, w3t, g3, b3,
                                                      feat + 128 * N_PTS, FBS);
    k_knn<bf16, 128><<<GK, 256, 0, stream>>>(feat + 128 * N_PTS, FBS, idx);
    k_edgeconv<bf16, 128, 256><<<GK, 256, 0, stream>>>(feat + 128 * N_PTS, FBS, idx, w4t, g4, b4,
                                                       feat + 256 * N_PTS, FBS);

    k_conv5pool<<<B_SZ * (1024 / 8) * NCH, 256, 0, stream>>>(feat, w5, g5, b5, fmxp, fsmp);
    k_head<<<B_SZ, 256, 0, stream>>>(fmxp, fsmp, fw1, fb1, g6, b6, fw2, fb2, g7, b7,
                                     flag, d_out);
}

// Round 6
// 1171.872 us; speedup vs baseline: 3.2826x; 1.2925x over previous
//
#include <hip/hip_runtime.h>
#include <hip/hip_bf16.h>
#include <float.h>

#define N_PTS 2048
#define B_SZ  4
#define KNN   20
#define LRELU_S 0.2f

typedef __hip_bfloat16 bf16;
typedef __attribute__((ext_vector_type(8))) short short8v;   // 8 bf16 (4 VGPRs)
typedef __attribute__((ext_vector_type(4))) float floatx4;

__device__ __forceinline__ float b2f(const bf16 v) { return __bfloat162float(v); }
__device__ __forceinline__ float ldf(const float* p) { return *p; }
__device__ __forceinline__ float ldf(const bf16* p)  { return __bfloat162float(*p); }

// ---------------------------------------------------------------------------
// Dtype sniffer (robustness): bf16 (flag=1) vs fp32 (flag=0). Reads 256 B.
__global__ void k_sniff(const unsigned short* __restrict__ pts_hw, int* __restrict__ flag) {
    if (threadIdx.x != 0 || blockIdx.x != 0) return;
    int sane = 0;
    for (int j = 0; j < 64; ++j) {
        unsigned short v = pts_hw[2 * j];
        int e = (v >> 7) & 0xFF;
        if (e >= 100 && e <= 140) ++sane;
    }
    *flag = (sane >= 32) ? 1 : 0;
}

// ---------------------------------------------------------------------------
// Repack 23 weight tensors to fp32; EdgeConv W tensors stored TRANSPOSED.
struct WPack {
    const void* src[23];
    int off[24];
    int rows[23];
    int cols[23];
};

__global__ void k_repack(WPack wp, const int* __restrict__ flag, float* __restrict__ dst, int total) {
    const int isb = *flag;
    for (int i = blockIdx.x * blockDim.x + threadIdx.x; i < total; i += gridDim.x * blockDim.x) {
        int lo = 0, hi = 23;
        while (lo + 1 < hi) { int mid = (lo + hi) >> 1; if (i >= wp.off[mid]) lo = mid; else hi = mid; }
        int j = i - wp.off[lo];
        float v = isb ? b2f(((const bf16*)wp.src[lo])[j]) : ((const float*)wp.src[lo])[j];
        int dj = j;
        int cols = wp.cols[lo];
        if (cols) dj = (j % cols) * wp.rows[lo] + (j / cols);
        dst[wp.off[lo] + dj] = v;
    }
}

// ---------------------------------------------------------------------------
// points (B,N,3) -> x0 (B,3,N) fp32, dtype-dynamic.
__global__ void k_transpose(const void* __restrict__ pts, const int* __restrict__ flag,
                            float* __restrict__ x0) {
    const int isb = *flag;
    int i = blockIdx.x * blockDim.x + threadIdx.x;
    if (i >= B_SZ * N_PTS) return;
    int b = i / N_PTS, n = i % N_PTS;
    for (int c = 0; c < 3; ++c) {
        size_t s = ((size_t)b * N_PTS + n) * 3 + c;
        float v = isb ? b2f(((const bf16*)pts)[s]) : ((const float*)pts)[s];
        x0[((size_t)b * 3 + c) * N_PTS + n] = v;
    }
}

// ---------------------------------------------------------------------------
// 32-candidate row loads (lane chunk), fp32 out. (Used by fallback kNN.)
__device__ __forceinline__ void load32(const float* row, int mbase, float* r) {
    const float4* p = (const float4*)(row + mbase);
#pragma unroll
    for (int i = 0; i < 8; ++i) {
        float4 f = p[i];
        r[4 * i + 0] = f.x; r[4 * i + 1] = f.y; r[4 * i + 2] = f.z; r[4 * i + 3] = f.w;
    }
}
__device__ __forceinline__ void load32(const bf16* row, int mbase, float* r) {
    const uint4* p = (const uint4*)(row + mbase);
#pragma unroll
    for (int i = 0; i < 4; ++i) {
        uint4 u = p[i];
        r[8 * i + 0] = __uint_as_float(u.x << 16);
        r[8 * i + 1] = __uint_as_float(u.x & 0xFFFF0000u);
        r[8 * i + 2] = __uint_as_float(u.y << 16);
        r[8 * i + 3] = __uint_as_float(u.y & 0xFFFF0000u);
        r[8 * i + 4] = __uint_as_float(u.z << 16);
        r[8 * i + 5] = __uint_as_float(u.z & 0xFFFF0000u);
        r[8 * i + 6] = __uint_as_float(u.w << 16);
        r[8 * i + 7] = __uint_as_float(u.w & 0xFFFF0000u);
    }
}

// ---------------------------------------------------------------------------
// kNN (direct): wave-per-query; used for layer 1 (C=3) and as ws fallback.
template<typename T, int C>
__global__ __launch_bounds__(256) void k_knn(const T* __restrict__ x, int bstride,
                                             int* __restrict__ idx) {
    __shared__ float qf[4][C];
    int ib = blockIdx.x;
    int b  = ib / (N_PTS / 4);
    int q0 = (ib % (N_PTS / 4)) * 4;
    const T* xb = x + (size_t)b * bstride;

    for (int t = threadIdx.x; t < 4 * C; t += 256) {
        int pt = t / C, c = t % C;
        qf[pt][c] = ldf(&xb[(size_t)c * N_PTS + (q0 + pt)]);
    }
    __syncthreads();

    int w = threadIdx.x >> 6, lane = threadIdx.x & 63;
    int q = q0 + w;
    int mbase = lane * 32;

    float v[32];
#pragma unroll
    for (int j = 0; j < 32; ++j) v[j] = 0.f;

    for (int c = 0; c < C; ++c) {
        float qc = qf[w][c];
        float r[32];
        load32(xb + (size_t)c * N_PTS, mbase, r);
#pragma unroll
        for (int j = 0; j < 32; ++j) { float t = r[j] - qc; v[j] = fmaf(t, t, v[j]); }
    }

    for (int k = 0; k < KNN; ++k) {
        float bv = FLT_MAX; int bi = 0x7FFFFFFF;
#pragma unroll
        for (int j = 0; j < 32; ++j)
            if (v[j] < bv) { bv = v[j]; bi = mbase + j; }
#pragma unroll
        for (int off = 32; off >= 1; off >>= 1) {
            float ov = __shfl_xor(bv, off);
            int   oi = __shfl_xor(bi, off);
            if (ov < bv || (ov == bv && oi < bi)) { bv = ov; bi = oi; }
        }
        if (lane == 0) idx[((size_t)b * N_PTS + q) * KNN + k] = bi;
        int wl = bi >> 5, wj = bi & 31;
        if (lane == wl) {
#pragma unroll
            for (int j = 0; j < 32; ++j) if (j == wj) v[j] = FLT_MAX;
        }
    }
}

// ---------------------------------------------------------------------------
// Candidate squared norms over a channel slice: xx[b*N+m] = sum_c featT[b,m,c0+c]^2
template<int C>
__global__ void k_xx(const bf16* __restrict__ featT, int c0, float* __restrict__ xx) {
    int i = blockIdx.x * blockDim.x + threadIdx.x;
    if (i >= B_SZ * N_PTS) return;
    const bf16* row = featT + (size_t)i * 256 + c0;
    float s = 0.f;
    for (int c = 0; c < C; c += 8) {
        uint4 u = *(const uint4*)(row + c);
        float v0 = __uint_as_float(u.x << 16), v1 = __uint_as_float(u.x & 0xFFFF0000u);
        float v2 = __uint_as_float(u.y << 16), v3 = __uint_as_float(u.y & 0xFFFF0000u);
        float v4 = __uint_as_float(u.z << 16), v5 = __uint_as_float(u.z & 0xFFFF0000u);
        float v6 = __uint_as_float(u.w << 16), v7 = __uint_as_float(u.w & 0xFFFF0000u);
        s = fmaf(v0, v0, s); s = fmaf(v1, v1, s); s = fmaf(v2, v2, s); s = fmaf(v3, v3, s);
        s = fmaf(v4, v4, s); s = fmaf(v5, v5, s); s = fmaf(v6, v6, s); s = fmaf(v7, v7, s);
    }
    xx[i] = s;
}

// ---------------------------------------------------------------------------
// Gram matrix via MFMA: G[b][n][m] = sum_c X[c][n]*X[c][m], X = featT slice.
// Block: 128x128 output tile; 4 waves, each 64x64 = 4x4 MFMA 16x16x32_bf16.
// featT[n][c] rows are c-contiguous -> both A and B frags are ds_read_b128
// from row-major LDS tiles (rows padded to 72 elems: 144 B, 16B-aligned).
template<int C>
__global__ __launch_bounds__(256) void k_gram(const bf16* __restrict__ featT, int c0,
                                              float* __restrict__ G) {
    const int KC = 64;
    __shared__ __align__(16) short At[128 * 72];
    __shared__ __align__(16) short Bt[128 * 72];

    int ib = blockIdx.x;
    int b  = ib >> 8;
    int t  = ib & 255;
    int n0 = (t >> 4) << 7;
    int m0 = (t & 15) << 7;

    int tid = threadIdx.x;
    int w = tid >> 6, lane = tid & 63;
    int rw = (w & 1) * 64, cw = (w >> 1) * 64;
    int lrow = lane & 15, quad = lane >> 4;

    floatx4 acc[4][4];
#pragma unroll
    for (int ri = 0; ri < 4; ++ri)
#pragma unroll
        for (int ci = 0; ci < 4; ++ci) acc[ri][ci] = (floatx4){0.f, 0.f, 0.f, 0.f};

    for (int ck = 0; ck < C; ck += KC) {
        __syncthreads();
        for (int s = tid; s < 1024; s += 256) {
            int row = s >> 3, g = s & 7;
            *(uint4*)&At[row * 72 + g * 8] =
                *(const uint4*)(featT + ((size_t)(b * N_PTS + n0 + row) * 256) + c0 + ck + g * 8);
            *(uint4*)&Bt[row * 72 + g * 8] =
                *(const uint4*)(featT + ((size_t)(b * N_PTS + m0 + row) * 256) + c0 + ck + g * 8);
        }
        __syncthreads();
#pragma unroll
        for (int kk = 0; kk < KC; kk += 32) {
            short8v a[4], bb[4];
#pragma unroll
            for (int ri = 0; ri < 4; ++ri)
                a[ri] = *(const short8v*)&At[(rw + ri * 16 + lrow) * 72 + kk + quad * 8];
#pragma unroll
            for (int ci = 0; ci < 4; ++ci)
                bb[ci] = *(const short8v*)&Bt[(cw + ci * 16 + lrow) * 72 + kk + quad * 8];
#pragma unroll
            for (int ri = 0; ri < 4; ++ri)
#pragma unroll
                for (int ci = 0; ci < 4; ++ci)
                    acc[ri][ci] = __builtin_amdgcn_mfma_f32_16x16x32_bf16(a[ri], bb[ci], acc[ri][ci], 0, 0, 0);
        }
    }

#pragma unroll
    for (int ri = 0; ri < 4; ++ri)
#pragma unroll
        for (int ci = 0; ci < 4; ++ci) {
            int n = n0 + rw + ri * 16 + quad * 4;
            int m = m0 + cw + ci * 16 + lrow;
            float* gp = G + ((size_t)b * N_PTS + n) * N_PTS + m;
#pragma unroll
            for (int reg = 0; reg < 4; ++reg)
                gp[(size_t)reg * N_PTS] = acc[ri][ci][reg];
        }
}

// ---------------------------------------------------------------------------
// Top-K selection on precomputed scores: score = xx[m] - 2*G[q][m];
// wave-per-query, candidates interleaved: v[4r+t] <-> m = r*256 + lane*4 + t.
__global__ __launch_bounds__(256) void k_select(const float* __restrict__ G,
                                                const float* __restrict__ xx,
                                                int* __restrict__ idx) {
    int ib = blockIdx.x;
    int b = ib >> 9;
    int q0 = (ib & 511) * 4;
    int w = threadIdx.x >> 6, lane = threadIdx.x & 63;
    int q = q0 + w;
    const float* grow = G + ((size_t)b * N_PTS + q) * N_PTS;
    const float* xrow = xx + (size_t)b * N_PTS;

    float v[32];
#pragma unroll
    for (int r = 0; r < 8; ++r) {
        float4 g4 = *(const float4*)(grow + r * 256 + (lane << 2));
        float4 x4 = *(const float4*)(xrow + r * 256 + (lane << 2));
        v[4 * r + 0] = fmaf(-2.f, g4.x, x4.x);
        v[4 * r + 1] = fmaf(-2.f, g4.y, x4.y);
        v[4 * r + 2] = fmaf(-2.f, g4.z, x4.z);
        v[4 * r + 3] = fmaf(-2.f, g4.w, x4.w);
    }

    for (int k = 0; k < KNN; ++k) {
        float bv = FLT_MAX; int bi = 0x7FFFFFFF;
#pragma unroll
        for (int j = 0; j < 32; ++j) {
            if (v[j] < bv) { bv = v[j]; bi = ((j >> 2) << 8) + (lane << 2) + (j & 3); }
        }
#pragma unroll
        for (int off = 32; off >= 1; off >>= 1) {
            float ov = __shfl_xor(bv, off);
            int   oi = __shfl_xor(bi, off);
            if (ov < bv || (ov == bv && oi < bi)) { bv = ov; bi = oi; }
        }
        if (lane == 0) idx[((size_t)b * N_PTS + q) * KNN + k] = bi;
        int wl = (bi >> 2) & 63;
        int jj = ((bi >> 8) << 2) | (bi & 3);
        if (lane == wl) {
#pragma unroll
            for (int j = 0; j < 32; ++j) if (j == jj) v[j] = FLT_MAX;
        }
    }
}

// ---------------------------------------------------------------------------
// EdgeConv: wave-per-point, PT=4 points/block, OT=COUT/64 outputs/lane.
// Optionally also writes featT[b][n][c0f + o] (transposed copy for kNN-gram).
template<typename T, int C, int COUT, bool WF>
__global__ __launch_bounds__(256) void k_edgeconv(const T* __restrict__ x, int bstride,
                           const int* __restrict__ idx,
                           const float* __restrict__ Wt,
                           const float* __restrict__ gam,
                           const float* __restrict__ bet,
                           bf16* __restrict__ out, int ostride,
                           bf16* __restrict__ featT, int c0f) {
    const int PT = 4;
    const int OT = COUT / 64;
    const int CP = (C + 3) & ~3;
    __shared__ float sh[PT][KNN + 1][CP];

    int ib = blockIdx.x;
    int b  = ib / (N_PTS / PT);
    int n0 = (ib % (N_PTS / PT)) * PT;
    const T* xb = x + (size_t)b * bstride;

    const int TOT = PT * (KNN + 1) * C;
    for (int t = threadIdx.x; t < TOT; t += 256) {
        int pt = t / ((KNN + 1) * C);
        int r  = t % ((KNN + 1) * C);
        int row = r / C, c = r % C;
        int n = n0 + pt;
        int m = (row == 0) ? n
                           : (idx[((size_t)b * N_PTS + n) * KNN + (row - 1)] & (N_PTS - 1));
        sh[pt][row][c] = ldf(&xb[(size_t)c * N_PTS + m]);
    }
    __syncthreads();

    int w = threadIdx.x >> 6, lane = threadIdx.x & 63;
    int n = n0 + w;

    float base[OT];
    float acc[OT][KNN];
#pragma unroll
    for (int j = 0; j < OT; ++j) {
        base[j] = 0.f;
#pragma unroll
        for (int k = 0; k < KNN; ++k) acc[j][k] = 0.f;
    }

    for (int c = 0; c < C; ++c) {
        float xq = sh[w][0][c];
        float w1v[OT], w2v[OT];
#pragma unroll
        for (int j = 0; j < OT; ++j) {
            w1v[j] = Wt[(size_t)c * COUT + lane + 64 * j];
            w2v[j] = Wt[(size_t)(C + c) * COUT + lane + 64 * j];
        }
#pragma unroll
        for (int j = 0; j < OT; ++j) base[j] = fmaf(w1v[j] - w2v[j], xq, base[j]);
#pragma unroll
        for (int k = 0; k < KNN; ++k) {
            float nv = sh[w][1 + k][c];
#pragma unroll
            for (int j = 0; j < OT; ++j) acc[j][k] = fmaf(w2v[j], nv, acc[j][k]);
        }
    }

    const float inv = rsqrtf(1.0f + 1e-5f);
#pragma unroll
    for (int j = 0; j < OT; ++j) {
        int o = lane + 64 * j;
        float scale = gam[o] * inv, bias = bet[o];
        float mx = -FLT_MAX;
#pragma unroll
        for (int k = 0; k < KNN; ++k) {
            float h = (base[j] + acc[j][k]) * scale + bias;
            h = h > 0.f ? h : LRELU_S * h;
            mx = fmaxf(mx, h);
        }
        bf16 bv = __float2bfloat16(mx);
        out[(size_t)b * ostride + (size_t)o * N_PTS + n] = bv;
        if (WF) featT[((size_t)b * N_PTS + n) * 256 + c0f + o] = bv;
    }
}

// ---------------------------------------------------------------------------
// conv5 (1024x512) + BN + LReLU + max/sum partial pooling over an N-chunk.
#define NCH 2
__global__ __launch_bounds__(256) void k_conv5pool(const bf16* __restrict__ feat,
                            const float* __restrict__ w5,
                            const float* __restrict__ g5,
                            const float* __restrict__ b5,
                            float* __restrict__ fmxp, float* __restrict__ fsmp) {
    const int OT = 8;
    const int NT = 4;
    const int CHN = N_PTS / NCH;
    __shared__ float wl[OT][512];
    __shared__ float rmx[4][OT];
    __shared__ float rsm[4][OT];

    int ib = blockIdx.x;
    int ch = ib % NCH;
    int ot = (ib / NCH) % (1024 / OT);
    int b  = ib / (NCH * (1024 / OT));
    int o0 = ot * OT;
    const bf16* fb = feat + (size_t)b * 512 * N_PTS;

    for (int t = threadIdx.x; t < OT * 512; t += 256) {
        int o = t >> 9, c = t & 511;
        wl[o][c] = w5[(size_t)(o0 + o) * 512 + c];
    }
    __syncthreads();

    const int n0 = ch * CHN + threadIdx.x * NT;

    float acc[OT][NT];
#pragma unroll
    for (int o = 0; o < OT; ++o)
#pragma unroll
        for (int t = 0; t < NT; ++t) acc[o][t] = 0.f;

    for (int c = 0; c < 512; c += 4) {
        float fv[4][NT];
#pragma unroll
        for (int j = 0; j < 4; ++j) {
            uint2 u = *(const uint2*)(fb + (size_t)(c + j) * N_PTS + n0);
            fv[j][0] = __uint_as_float(u.x << 16);
            fv[j][1] = __uint_as_float(u.x & 0xFFFF0000u);
            fv[j][2] = __uint_as_float(u.y << 16);
            fv[j][3] = __uint_as_float(u.y & 0xFFFF0000u);
        }
#pragma unroll
        for (int o = 0; o < OT; ++o) {
            float4 wv = *(const float4*)&wl[o][c];
#pragma unroll
            for (int t = 0; t < NT; ++t) {
                acc[o][t] = fmaf(wv.x, fv[0][t], acc[o][t]);
                acc[o][t] = fmaf(wv.y, fv[1][t], acc[o][t]);
                acc[o][t] = fmaf(wv.z, fv[2][t], acc[o][t]);
                acc[o][t] = fmaf(wv.w, fv[3][t], acc[o][t]);
            }
        }
    }

    const float inv = rsqrtf(1.0f + 1e-5f);
    int w = threadIdx.x >> 6, lane = threadIdx.x & 63;
#pragma unroll
    for (int o = 0; o < OT; ++o) {
        float scale = g5[o0 + o] * inv, bias = b5[o0 + o];
        float mx = -FLT_MAX, sm = 0.f;
#pragma unroll
        for (int t = 0; t < NT; ++t) {
            float h = acc[o][t] * scale + bias;
            h = h > 0.f ? h : LRELU_S * h;
            mx = fmaxf(mx, h);
            sm += h;
        }
#pragma unroll
        for (int off = 32; off >= 1; off >>= 1) {
            mx = fmaxf(mx, __shfl_xor(mx, off));
            sm += __shfl_xor(sm, off);
        }
        if (lane == 0) { rmx[w][o] = mx; rsm[w][o] = sm; }
    }
    __syncthreads();
    if (threadIdx.x < OT) {
        int o = threadIdx.x;
        float mx = -FLT_MAX, sm = 0.f;
#pragma unroll
        for (int ww = 0; ww < 4; ++ww) { mx = fmaxf(mx, rmx[ww][o]); sm += rsm[ww][o]; }
        fmxp[((size_t)b * 1024 + o0 + o) * NCH + ch] = mx;
        fsmp[((size_t)b * 1024 + o0 + o) * NCH + ch] = sm;
    }
}

// ---------------------------------------------------------------------------
// Head: reduce NCH partials -> f = [max(1024), mean(1024)] -> fc1 -> fc2.
__global__ void k_head(const float* __restrict__ fmxp, const float* __restrict__ fsmp,
                       const float* __restrict__ fw1, const float* __restrict__ fb1,
                       const float* __restrict__ g6,  const float* __restrict__ b6,
                       const float* __restrict__ fw2, const float* __restrict__ fb2,
                       const float* __restrict__ g7,  const float* __restrict__ b7,
                       const int* __restrict__ flag, void* __restrict__ out) {
    __shared__ float f[2048];
    __shared__ float t[512];
    int b = blockIdx.x;
    for (int i = threadIdx.x; i < 1024; i += 256) {
        float mx = -FLT_MAX, sm = 0.f;
        for (int ch = 0; ch < NCH; ++ch) {
            mx = fmaxf(mx, fmxp[((size_t)b * 1024 + i) * NCH + ch]);
            sm += fsmp[((size_t)b * 1024 + i) * NCH + ch];
        }
        f[i]        = mx;
        f[1024 + i] = sm * (1.0f / N_PTS);
    }
    __syncthreads();
    const float inv = rsqrtf(1.0f + 1e-5f);
    for (int o = threadIdx.x; o < 512; o += 256) {
        const float* wr = fw1 + (size_t)o * 2048;
        float acc = fb1[o];
        for (int j = 0; j < 2048; ++j) acc += wr[j] * f[j];
        float h = acc * g6[o] * inv + b6[o];
        t[o] = h > 0.f ? h : LRELU_S * h;
    }
    __syncthreads();
    {
        int o = threadIdx.x;
        const float* wr = fw2 + (size_t)o * 512;
        float acc = fb2[o];
        for (int j = 0; j < 512; ++j) acc += wr[j] * t[j];
        float h = acc * g7[o] * inv + b7[o];
        if (*flag) ((bf16*)out)[(size_t)b * 256 + o] = __float2bfloat16(h);
        else       ((float*)out)[(size_t)b * 256 + o] = h;
    }
}

// ---------------------------------------------------------------------------
extern "C" void kernel_launch(void* const* d_in, const int* in_sizes, int n_in,
                              void* d_out, int out_size, void* d_ws, size_t ws_size,
                              hipStream_t stream) {
    static const int wsz[23] = {
        384, 64, 64,   8192, 64, 64,   16384, 128, 128,   65536, 256, 256,
        524288, 1024, 1024,   1048576, 512,   512, 512,   131072, 256,   256, 256
    };
    static const int trows[23] = {64,0,0, 64,0,0, 128,0,0, 256,0,0, 0,0,0, 0,0, 0,0, 0,0, 0,0};
    static const int tcols[23] = { 6,0,0,128,0,0, 128,0,0, 256,0,0, 0,0,0, 0,0, 0,0, 0,0, 0,0};

    WPack wp;
    int total = 0;
    for (int i = 0; i < 23; ++i) {
        wp.src[i] = d_in[i + 1]; wp.off[i] = total; total += wsz[i];
        wp.rows[i] = trows[i]; wp.cols[i] = tcols[i];
    }
    wp.off[23] = total;

    const size_t flag_bytes = 16;
    const size_t x0_bytes   = (size_t)B_SZ * 3 * N_PTS * 4;
    const size_t feat_bytes = (size_t)B_SZ * 512 * N_PTS * 2;
    const size_t idx_bytes  = (size_t)B_SZ * N_PTS * KNN * 4;
    const size_t pool_bytes = (size_t)B_SZ * 1024 * 4 * 2;
    const size_t wf_bytes   = (size_t)total * 4;
    const size_t base_need  = flag_bytes + x0_bytes + feat_bytes + idx_bytes + pool_bytes + wf_bytes;

    const size_t featT_bytes = (size_t)B_SZ * N_PTS * 256 * 2;          //  4 MB
    const size_t xx_bytes    = (size_t)B_SZ * N_PTS * 4;                // 32 KB
    const size_t S_bytes     = (size_t)B_SZ * N_PTS * N_PTS * 4;        // 64 MB
    const size_t full_need   = base_need + featT_bytes + xx_bytes + S_bytes;

    if (ws_size < base_need) return;   // graceful fail
    const bool use_gram = (ws_size >= full_need);

    char* w = (char*)d_ws;
    int*   flag = (int*)w;              w += flag_bytes;
    float* x0   = (float*)w;            w += x0_bytes;
    bf16*  feat = (bf16*)w;             w += feat_bytes;
    int*   idx  = (int*)w;              w += idx_bytes;
    w += pool_bytes;
    float* wf   = (float*)w;            w += wf_bytes;
    bf16*  featT = (bf16*)w;            w += featT_bytes;
    float* xx    = (float*)w;           w += xx_bytes;
    float* S     = (float*)w;

    float* fmxp = (float*)idx;                         // overlay (idx dead after ec4)
    float* fsmp = fmxp + (size_t)B_SZ * 1024 * NCH;

    const int FBS = 512 * N_PTS;

    k_sniff<<<1, 64, 0, stream>>>((const unsigned short*)d_in[0], flag);
    k_repack<<<256, 256, 0, stream>>>(wp, flag, wf, total);
    k_transpose<<<(B_SZ * N_PTS + 255) / 256, 256, 0, stream>>>(d_in[0], flag, x0);

    const float* w1t = wf + wp.off[0],  *g1 = wf + wp.off[1],  *b1 = wf + wp.off[2];
    const float* w2t = wf + wp.off[3],  *g2 = wf + wp.off[4],  *b2 = wf + wp.off[5];
    const float* w3t = wf + wp.off[6],  *g3 = wf + wp.off[7],  *b3 = wf + wp.off[8];
    const float* w4t = wf + wp.off[9],  *g4 = wf + wp.off[10], *b4 = wf + wp.off[11];
    const float* w5  = wf + wp.off[12], *g5 = wf + wp.off[13], *b5 = wf + wp.off[14];
    const float* fw1 = wf + wp.off[15], *fb1 = wf + wp.off[16];
    const float* g6  = wf + wp.off[17], *b6 = wf + wp.off[18];
    const float* fw2 = wf + wp.off[19], *fb2 = wf + wp.off[20];
    const float* g7  = wf + wp.off[21], *b7 = wf + wp.off[22];

    const int GK = B_SZ * N_PTS / 4;   // 2048 blocks
    const int NXX = (B_SZ * N_PTS + 255) / 256;

    // Layer 1 (C=3, fp32): direct kNN always.
    k_knn<float, 3><<<GK, 256, 0, stream>>>(x0, 3 * N_PTS, idx);
    if (use_gram) {
        k_edgeconv<float, 3, 64, true><<<GK, 256, 0, stream>>>(x0, 3 * N_PTS, idx, w1t, g1, b1,
                                                               feat + 0 * N_PTS, FBS, featT, 0);
        // kNN layer 2 on x1 (channels [0,64))
        k_xx<64><<<NXX, 256, 0, stream>>>(featT, 0, xx);
        k_gram<64><<<B_SZ * 256, 256, 0, stream>>>(featT, 0, S);
        k_select<<<GK, 256, 0, stream>>>(S, xx, idx);
        k_edgeconv<bf16, 64, 64, true><<<GK, 256, 0, stream>>>(feat + 0 * N_PTS, FBS, idx, w2t, g2, b2,
                                                               feat + 64 * N_PTS, FBS, featT, 64);
        // kNN layer 3 on x2 (channels [64,128))
        k_xx<64><<<NXX, 256, 0, stream>>>(featT, 64, xx);
        k_gram<64><<<B_SZ * 256, 256, 0, stream>>>(featT, 64, S);
        k_select<<<GK, 256, 0, stream>>>(S, xx, idx);
        k_edgeconv<bf16, 64, 128, true><<<GK, 256, 0, stream>>>(feat + 64 * N_PTS, FBS, idx, w3t, g3, b3,
                                                                feat + 128 * N_PTS, FBS, featT, 128);
        // kNN layer 4 on x3 (channels [128,256))
        k_xx<128><<<NXX, 256, 0, stream>>>(featT, 128, xx);
        k_gram<128><<<B_SZ * 256, 256, 0, stream>>>(featT, 128, S);
        k_select<<<GK, 256, 0, stream>>>(S, xx, idx);
        k_edgeconv<bf16, 128, 256, false><<<GK, 256, 0, stream>>>(feat + 128 * N_PTS, FBS, idx, w4t, g4, b4,
                                                                  feat + 256 * N_PTS, FBS, nullptr, 0);
    } else {
        k_edgeconv<float, 3, 64, false><<<GK, 256, 0, stream>>>(x0, 3 * N_PTS, idx, w1t, g1, b1,
                                                                feat + 0 * N_PTS, FBS, nullptr, 0);
        k_knn<bf16, 64><<<GK, 256, 0, stream>>>(feat + 0 * N_PTS, FBS, idx);
        k_edgeconv<bf16, 64, 64, false><<<GK, 256, 0, stream>>>(feat + 0 * N_PTS, FBS, idx, w2t, g2, b2,
                                                                feat + 64 * N_PTS, FBS, nullptr, 0);
        k_knn<bf16, 64><<<GK, 256, 0, stream>>>(feat + 64 * N_PTS, FBS, idx);
        k_edgeconv<bf16, 64, 128, false><<<GK, 256, 0, stream>>>(feat + 64 * N_PTS, FBS, idx, w3t, g3, b3,
                                                                 feat + 128 * N_PTS, FBS, nullptr, 0);
        k_knn<bf16, 128><<<GK, 256, 0, stream>>>(feat + 128 * N_PTS, FBS, idx);
        k_edgeconv<bf16, 128, 256, false><<<GK, 256, 0, stream>>>(feat + 128 * N_PTS, FBS, idx, w4t, g4, b4,
                                                                  feat + 256 * N_PTS, FBS, nullptr, 0);
    }

    k_conv5pool<<<B_SZ * (1024 / 8) * NCH, 256, 0, stream>>>(feat, w5, g5, b5, fmxp, fsmp);
    k_head<<<B_SZ, 256, 0, stream>>>(fmxp, fsmp, fw1, fb1, g6, b6, fw2, fb2, g7, b7,
                                     flag, d_out);
}

// Round 7
// 1102.617 us; speedup vs baseline: 3.4888x; 1.0628x over previous
//
#include <hip/hip_runtime.h>
#include <hip/hip_bf16.h>
#include <float.h>

#define N_PTS 2048
#define B_SZ  4
#define KNN   20
#define LRELU_S 0.2f

typedef __hip_bfloat16 bf16;
typedef __attribute__((ext_vector_type(8))) short short8v;   // 8 bf16 (4 VGPRs)
typedef __attribute__((ext_vector_type(4))) float floatx4;

__device__ __forceinline__ float b2f(const bf16 v) { return __bfloat162float(v); }
__device__ __forceinline__ float ldf(const float* p) { return *p; }
__device__ __forceinline__ float ldf(const bf16* p)  { return __bfloat162float(*p); }

// ---------------------------------------------------------------------------
// Dtype sniffer (robustness): bf16 (flag=1) vs fp32 (flag=0). Reads 256 B.
__global__ void k_sniff(const unsigned short* __restrict__ pts_hw, int* __restrict__ flag) {
    if (threadIdx.x != 0 || blockIdx.x != 0) return;
    int sane = 0;
    for (int j = 0; j < 64; ++j) {
        unsigned short v = pts_hw[2 * j];
        int e = (v >> 7) & 0xFF;
        if (e >= 100 && e <= 140) ++sane;
    }
    *flag = (sane >= 32) ? 1 : 0;
}

// ---------------------------------------------------------------------------
// Repack 23 weight tensors to fp32; EdgeConv W tensors stored TRANSPOSED.
struct WPack {
    const void* src[23];
    int off[24];
    int rows[23];
    int cols[23];
};

__global__ void k_repack(WPack wp, const int* __restrict__ flag, float* __restrict__ dst, int total) {
    const int isb = *flag;
    for (int i = blockIdx.x * blockDim.x + threadIdx.x; i < total; i += gridDim.x * blockDim.x) {
        int lo = 0, hi = 23;
        while (lo + 1 < hi) { int mid = (lo + hi) >> 1; if (i >= wp.off[mid]) lo = mid; else hi = mid; }
        int j = i - wp.off[lo];
        float v = isb ? b2f(((const bf16*)wp.src[lo])[j]) : ((const float*)wp.src[lo])[j];
        int dj = j;
        int cols = wp.cols[lo];
        if (cols) dj = (j % cols) * wp.rows[lo] + (j / cols);
        dst[wp.off[lo] + dj] = v;
    }
}

// ---------------------------------------------------------------------------
// points (B,N,3) -> x0 (B,3,N) fp32, dtype-dynamic.
__global__ void k_transpose(const void* __restrict__ pts, const int* __restrict__ flag,
                            float* __restrict__ x0) {
    const int isb = *flag;
    int i = blockIdx.x * blockDim.x + threadIdx.x;
    if (i >= B_SZ * N_PTS) return;
    int b = i / N_PTS, n = i % N_PTS;
    for (int c = 0; c < 3; ++c) {
        size_t s = ((size_t)b * N_PTS + n) * 3 + c;
        float v = isb ? b2f(((const bf16*)pts)[s]) : ((const float*)pts)[s];
        x0[((size_t)b * 3 + c) * N_PTS + n] = v;
    }
}

// ---------------------------------------------------------------------------
// 32-candidate row loads (lane chunk), fp32 out. (Used by fallback kNN.)
__device__ __forceinline__ void load32(const float* row, int mbase, float* r) {
    const float4* p = (const float4*)(row + mbase);
#pragma unroll
    for (int i = 0; i < 8; ++i) {
        float4 f = p[i];
        r[4 * i + 0] = f.x; r[4 * i + 1] = f.y; r[4 * i + 2] = f.z; r[4 * i + 3] = f.w;
    }
}
__device__ __forceinline__ void load32(const bf16* row, int mbase, float* r) {
    const uint4* p = (const uint4*)(row + mbase);
#pragma unroll
    for (int i = 0; i < 4; ++i) {
        uint4 u = p[i];
        r[8 * i + 0] = __uint_as_float(u.x << 16);
        r[8 * i + 1] = __uint_as_float(u.x & 0xFFFF0000u);
        r[8 * i + 2] = __uint_as_float(u.y << 16);
        r[8 * i + 3] = __uint_as_float(u.y & 0xFFFF0000u);
        r[8 * i + 4] = __uint_as_float(u.z << 16);
        r[8 * i + 5] = __uint_as_float(u.z & 0xFFFF0000u);
        r[8 * i + 6] = __uint_as_float(u.w << 16);
        r[8 * i + 7] = __uint_as_float(u.w & 0xFFFF0000u);
    }
}

// ---------------------------------------------------------------------------
// kNN (direct): wave-per-query; used for layer 1 (C=3) and as ws fallback.
template<typename T, int C>
__global__ __launch_bounds__(256) void k_knn(const T* __restrict__ x, int bstride,
                                             int* __restrict__ idx) {
    __shared__ float qf[4][C];
    int ib = blockIdx.x;
    int b  = ib / (N_PTS / 4);
    int q0 = (ib % (N_PTS / 4)) * 4;
    const T* xb = x + (size_t)b * bstride;

    for (int t = threadIdx.x; t < 4 * C; t += 256) {
        int pt = t / C, c = t % C;
        qf[pt][c] = ldf(&xb[(size_t)c * N_PTS + (q0 + pt)]);
    }
    __syncthreads();

    int w = threadIdx.x >> 6, lane = threadIdx.x & 63;
    int q = q0 + w;
    int mbase = lane * 32;

    float v[32];
#pragma unroll
    for (int j = 0; j < 32; ++j) v[j] = 0.f;

    for (int c = 0; c < C; ++c) {
        float qc = qf[w][c];
        float r[32];
        load32(xb + (size_t)c * N_PTS, mbase, r);
#pragma unroll
        for (int j = 0; j < 32; ++j) { float t = r[j] - qc; v[j] = fmaf(t, t, v[j]); }
    }

    for (int k = 0; k < KNN; ++k) {
        float bv = FLT_MAX; int bi = 0x7FFFFFFF;
#pragma unroll
        for (int j = 0; j < 32; ++j)
            if (v[j] < bv) { bv = v[j]; bi = mbase + j; }
#pragma unroll
        for (int off = 32; off >= 1; off >>= 1) {
            float ov = __shfl_xor(bv, off);
            int   oi = __shfl_xor(bi, off);
            if (ov < bv || (ov == bv && oi < bi)) { bv = ov; bi = oi; }
        }
        if (lane == 0) idx[((size_t)b * N_PTS + q) * KNN + k] = bi;
        int wl = bi >> 5, wj = bi & 31;
        if (lane == wl) {
#pragma unroll
            for (int j = 0; j < 32; ++j) if (j == wj) v[j] = FLT_MAX;
        }
    }
}

// ---------------------------------------------------------------------------
// Candidate squared norms over a channel slice: xx[b*N+m] = sum_c featT[b,m,c0+c]^2
template<int C>
__global__ void k_xx(const bf16* __restrict__ featT, int c0, float* __restrict__ xx) {
    int i = blockIdx.x * blockDim.x + threadIdx.x;
    if (i >= B_SZ * N_PTS) return;
    const bf16* row = featT + (size_t)i * 256 + c0;
    float s = 0.f;
    for (int c = 0; c < C; c += 8) {
        uint4 u = *(const uint4*)(row + c);
        float v0 = __uint_as_float(u.x << 16), v1 = __uint_as_float(u.x & 0xFFFF0000u);
        float v2 = __uint_as_float(u.y << 16), v3 = __uint_as_float(u.y & 0xFFFF0000u);
        float v4 = __uint_as_float(u.z << 16), v5 = __uint_as_float(u.z & 0xFFFF0000u);
        float v6 = __uint_as_float(u.w << 16), v7 = __uint_as_float(u.w & 0xFFFF0000u);
        s = fmaf(v0, v0, s); s = fmaf(v1, v1, s); s = fmaf(v2, v2, s); s = fmaf(v3, v3, s);
        s = fmaf(v4, v4, s); s = fmaf(v5, v5, s); s = fmaf(v6, v6, s); s = fmaf(v7, v7, s);
    }
    xx[i] = s;
}

// ---------------------------------------------------------------------------
// Gram matrix via MFMA: G[b][n][m] = sum_c X[c][n]*X[c][m], X = featT slice.
template<int C>
__global__ __launch_bounds__(256) void k_gram(const bf16* __restrict__ featT, int c0,
                                              float* __restrict__ G) {
    const int KC = 64;
    __shared__ __align__(16) short At[128 * 72];
    __shared__ __align__(16) short Bt[128 * 72];

    int ib = blockIdx.x;
    int b  = ib >> 8;
    int t  = ib & 255;
    int n0 = (t >> 4) << 7;
    int m0 = (t & 15) << 7;

    int tid = threadIdx.x;
    int w = tid >> 6, lane = tid & 63;
    int rw = (w & 1) * 64, cw = (w >> 1) * 64;
    int lrow = lane & 15, quad = lane >> 4;

    floatx4 acc[4][4];
#pragma unroll
    for (int ri = 0; ri < 4; ++ri)
#pragma unroll
        for (int ci = 0; ci < 4; ++ci) acc[ri][ci] = (floatx4){0.f, 0.f, 0.f, 0.f};

    for (int ck = 0; ck < C; ck += KC) {
        __syncthreads();
        for (int s = tid; s < 1024; s += 256) {
            int row = s >> 3, g = s & 7;
            *(uint4*)&At[row * 72 + g * 8] =
                *(const uint4*)(featT + ((size_t)(b * N_PTS + n0 + row) * 256) + c0 + ck + g * 8);
            *(uint4*)&Bt[row * 72 + g * 8] =
                *(const uint4*)(featT + ((size_t)(b * N_PTS + m0 + row) * 256) + c0 + ck + g * 8);
        }
        __syncthreads();
#pragma unroll
        for (int kk = 0; kk < KC; kk += 32) {
            short8v a[4], bb[4];
#pragma unroll
            for (int ri = 0; ri < 4; ++ri)
                a[ri] = *(const short8v*)&At[(rw + ri * 16 + lrow) * 72 + kk + quad * 8];
#pragma unroll
            for (int ci = 0; ci < 4; ++ci)
                bb[ci] = *(const short8v*)&Bt[(cw + ci * 16 + lrow) * 72 + kk + quad * 8];
#pragma unroll
            for (int ri = 0; ri < 4; ++ri)
#pragma unroll
                for (int ci = 0; ci < 4; ++ci)
                    acc[ri][ci] = __builtin_amdgcn_mfma_f32_16x16x32_bf16(a[ri], bb[ci], acc[ri][ci], 0, 0, 0);
        }
    }

#pragma unroll
    for (int ri = 0; ri < 4; ++ri)
#pragma unroll
        for (int ci = 0; ci < 4; ++ci) {
            int n = n0 + rw + ri * 16 + quad * 4;
            int m = m0 + cw + ci * 16 + lrow;
            float* gp = G + ((size_t)b * N_PTS + n) * N_PTS + m;
#pragma unroll
            for (int reg = 0; reg < 4; ++reg)
                gp[(size_t)reg * N_PTS] = acc[ri][ci][reg];
        }
}

// ---------------------------------------------------------------------------
// Top-K selection on precomputed scores: score = xx[m] - 2*G[q][m].
__global__ __launch_bounds__(256) void k_select(const float* __restrict__ G,
                                                const float* __restrict__ xx,
                                                int* __restrict__ idx) {
    int ib = blockIdx.x;
    int b = ib >> 9;
    int q0 = (ib & 511) * 4;
    int w = threadIdx.x >> 6, lane = threadIdx.x & 63;
    int q = q0 + w;
    const float* grow = G + ((size_t)b * N_PTS + q) * N_PTS;
    const float* xrow = xx + (size_t)b * N_PTS;

    float v[32];
#pragma unroll
    for (int r = 0; r < 8; ++r) {
        float4 g4 = *(const float4*)(grow + r * 256 + (lane << 2));
        float4 x4 = *(const float4*)(xrow + r * 256 + (lane << 2));
        v[4 * r + 0] = fmaf(-2.f, g4.x, x4.x);
        v[4 * r + 1] = fmaf(-2.f, g4.y, x4.y);
        v[4 * r + 2] = fmaf(-2.f, g4.z, x4.z);
        v[4 * r + 3] = fmaf(-2.f, g4.w, x4.w);
    }

    for (int k = 0; k < KNN; ++k) {
        float bv = FLT_MAX; int bi = 0x7FFFFFFF;
#pragma unroll
        for (int j = 0; j < 32; ++j) {
            if (v[j] < bv) { bv = v[j]; bi = ((j >> 2) << 8) + (lane << 2) + (j & 3); }
        }
#pragma unroll
        for (int off = 32; off >= 1; off >>= 1) {
            float ov = __shfl_xor(bv, off);
            int   oi = __shfl_xor(bi, off);
            if (ov < bv || (ov == bv && oi < bi)) { bv = ov; bi = oi; }
        }
        if (lane == 0) idx[((size_t)b * N_PTS + q) * KNN + k] = bi;
        int wl = (bi >> 2) & 63;
        int jj = ((bi >> 8) << 2) | (bi & 3);
        if (lane == wl) {
#pragma unroll
            for (int j = 0; j < 32; ++j) if (j == jj) v[j] = FLT_MAX;
        }
    }
}

// ---------------------------------------------------------------------------
// EdgeConv: wave-per-point, PT=4 points/block, OT=COUT/64 outputs/lane.
// UT: stage neighbor rows from featT (c-contiguous, coalesced) instead of the
// column-major x. K-loop split into NPASS passes so acc[] fits in VGPRs
// (OT=4 needed 80 accs -> spill at 68 VGPRs in round 6). Bit-identical math:
// per-k c-ascending fma order and k-ascending fmax order preserved.
template<typename T, int C, int COUT, bool WF, bool UT>
__global__ __launch_bounds__(256) void k_edgeconv(const T* __restrict__ x, int bstride,
                           const int* __restrict__ idx,
                           const float* __restrict__ Wt,
                           const float* __restrict__ gam,
                           const float* __restrict__ bet,
                           bf16* __restrict__ out, int ostride,
                           bf16* __restrict__ featT, int c0f,
                           const bf16* __restrict__ srcT, int c0s) {
    const int PT = 4;
    const int OT = COUT / 64;
    const int CP = (C + 3) & ~3;
    __shared__ float sh[PT][KNN + 1][CP];

    int ib = blockIdx.x;
    int b  = ib / (N_PTS / PT);
    int n0 = (ib % (N_PTS / PT)) * PT;
    const T* xb = x + (size_t)b * bstride;

    const int TOT = PT * (KNN + 1) * C;
    for (int t = threadIdx.x; t < TOT; t += 256) {
        int pt = t / ((KNN + 1) * C);
        int r  = t % ((KNN + 1) * C);
        int row = r / C, c = r % C;
        int n = n0 + pt;
        int m = (row == 0) ? n
                           : (idx[((size_t)b * N_PTS + n) * KNN + (row - 1)] & (N_PTS - 1));
        if (UT)
            sh[pt][row][c] = b2f(srcT[((size_t)(b * N_PTS + m)) * 256 + c0s + c]);
        else
            sh[pt][row][c] = ldf(&xb[(size_t)c * N_PTS + m]);
    }
    __syncthreads();

    int w = threadIdx.x >> 6, lane = threadIdx.x & 63;
    int n = n0 + w;

    constexpr int KT = (OT >= 4) ? 10 : 20;   // k-tile per pass
    constexpr int NPASS = KNN / KT;

    float base[OT];
    float mx[OT];
#pragma unroll
    for (int j = 0; j < OT; ++j) { base[j] = 0.f; mx[j] = -FLT_MAX; }

    const float inv = rsqrtf(1.0f + 1e-5f);

#pragma unroll
    for (int pass = 0; pass < NPASS; ++pass) {
        float acc[OT][KT];
#pragma unroll
        for (int j = 0; j < OT; ++j)
#pragma unroll
            for (int k = 0; k < KT; ++k) acc[j][k] = 0.f;

        for (int c = 0; c < C; ++c) {
            float xq = sh[w][0][c];
            float w2v[OT];
#pragma unroll
            for (int j = 0; j < OT; ++j)
                w2v[j] = Wt[(size_t)(C + c) * COUT + lane + 64 * j];
            if (pass == 0) {
#pragma unroll
                for (int j = 0; j < OT; ++j) {
                    float w1v = Wt[(size_t)c * COUT + lane + 64 * j];
                    base[j] = fmaf(w1v - w2v[j], xq, base[j]);
                }
            }
#pragma unroll
            for (int k = 0; k < KT; ++k) {
                float nv = sh[w][1 + pass * KT + k][c];
#pragma unroll
                for (int j = 0; j < OT; ++j) acc[j][k] = fmaf(w2v[j], nv, acc[j][k]);
            }
        }

#pragma unroll
        for (int j = 0; j < OT; ++j) {
            int o = lane + 64 * j;
            float scale = gam[o] * inv, bias = bet[o];
#pragma unroll
            for (int k = 0; k < KT; ++k) {
                float h = (base[j] + acc[j][k]) * scale + bias;
                h = h > 0.f ? h : LRELU_S * h;
                mx[j] = fmaxf(mx[j], h);
            }
        }
    }

#pragma unroll
    for (int j = 0; j < OT; ++j) {
        int o = lane + 64 * j;
        bf16 bv = __float2bfloat16(mx[j]);
        out[(size_t)b * ostride + (size_t)o * N_PTS + n] = bv;
        if (WF) featT[((size_t)b * N_PTS + n) * 256 + c0f + o] = bv;
    }
}

// ---------------------------------------------------------------------------
// conv5 (1024x512) + BN + LReLU + max/sum partial pooling over an N-chunk.
#define NCH 2
__global__ __launch_bounds__(256) void k_conv5pool(const bf16* __restrict__ feat,
                            const float* __restrict__ w5,
                            const float* __restrict__ g5,
                            const float* __restrict__ b5,
                            float* __restrict__ fmxp, float* __restrict__ fsmp) {
    const int OT = 8;
    const int NT = 4;
    const int CHN = N_PTS / NCH;
    __shared__ float wl[OT][512];
    __shared__ float rmx[4][OT];
    __shared__ float rsm[4][OT];

    int ib = blockIdx.x;
    int ch = ib % NCH;
    int ot = (ib / NCH) % (1024 / OT);
    int b  = ib / (NCH * (1024 / OT));
    int o0 = ot * OT;
    const bf16* fb = feat + (size_t)b * 512 * N_PTS;

    for (int t = threadIdx.x; t < OT * 512; t += 256) {
        int o = t >> 9, c = t & 511;
        wl[o][c] = w5[(size_t)(o0 + o) * 512 + c];
    }
    __syncthreads();

    const int n0 = ch * CHN + threadIdx.x * NT;

    float acc[OT][NT];
#pragma unroll
    for (int o = 0; o < OT; ++o)
#pragma unroll
        for (int t = 0; t < NT; ++t) acc[o][t] = 0.f;

    for (int c = 0; c < 512; c += 4) {
        float fv[4][NT];
#pragma unroll
        for (int j = 0; j < 4; ++j) {
            uint2 u = *(const uint2*)(fb + (size_t)(c + j) * N_PTS + n0);
            fv[j][0] = __uint_as_float(u.x << 16);
            fv[j][1] = __uint_as_float(u.x & 0xFFFF0000u);
            fv[j][2] = __uint_as_float(u.y << 16);
            fv[j][3] = __uint_as_float(u.y & 0xFFFF0000u);
        }
#pragma unroll
        for (int o = 0; o < OT; ++o) {
            float4 wv = *(const float4*)&wl[o][c];
#pragma unroll
            for (int t = 0; t < NT; ++t) {
                acc[o][t] = fmaf(wv.x, fv[0][t], acc[o][t]);
                acc[o][t] = fmaf(wv.y, fv[1][t], acc[o][t]);
                acc[o][t] = fmaf(wv.z, fv[2][t], acc[o][t]);
                acc[o][t] = fmaf(wv.w, fv[3][t], acc[o][t]);
            }
        }
    }

    const float inv = rsqrtf(1.0f + 1e-5f);
    int w = threadIdx.x >> 6, lane = threadIdx.x & 63;
#pragma unroll
    for (int o = 0; o < OT; ++o) {
        float scale = g5[o0 + o] * inv, bias = b5[o0 + o];
        float mx = -FLT_MAX, sm = 0.f;
#pragma unroll
        for (int t = 0; t < NT; ++t) {
            float h = acc[o][t] * scale + bias;
            h = h > 0.f ? h : LRELU_S * h;
            mx = fmaxf(mx, h);
            sm += h;
        }
#pragma unroll
        for (int off = 32; off >= 1; off >>= 1) {
            mx = fmaxf(mx, __shfl_xor(mx, off));
            sm += __shfl_xor(sm, off);
        }
        if (lane == 0) { rmx[w][o] = mx; rsm[w][o] = sm; }
    }
    __syncthreads();
    if (threadIdx.x < OT) {
        int o = threadIdx.x;
        float mx = -FLT_MAX, sm = 0.f;
#pragma unroll
        for (int ww = 0; ww < 4; ++ww) { mx = fmaxf(mx, rmx[ww][o]); sm += rsm[ww][o]; }
        fmxp[((size_t)b * 1024 + o0 + o) * NCH + ch] = mx;
        fsmp[((size_t)b * 1024 + o0 + o) * NCH + ch] = sm;
    }
}

// ---------------------------------------------------------------------------
// Head: reduce NCH partials -> f = [max(1024), mean(1024)] -> fc1 -> fc2.
__global__ void k_head(const float* __restrict__ fmxp, const float* __restrict__ fsmp,
                       const float* __restrict__ fw1, const float* __restrict__ fb1,
                       const float* __restrict__ g6,  const float* __restrict__ b6,
                       const float* __restrict__ fw2, const float* __restrict__ fb2,
                       const float* __restrict__ g7,  const float* __restrict__ b7,
                       const int* __restrict__ flag, void* __restrict__ out) {
    __shared__ float f[2048];
    __shared__ float t[512];
    int b = blockIdx.x;
    for (int i = threadIdx.x; i < 1024; i += 256) {
        float mx = -FLT_MAX, sm = 0.f;
        for (int ch = 0; ch < NCH; ++ch) {
            mx = fmaxf(mx, fmxp[((size_t)b * 1024 + i) * NCH + ch]);
            sm += fsmp[((size_t)b * 1024 + i) * NCH + ch];
        }
        f[i]        = mx;
        f[1024 + i] = sm * (1.0f / N_PTS);
    }
    __syncthreads();
    const float inv = rsqrtf(1.0f + 1e-5f);
    for (int o = threadIdx.x; o < 512; o += 256) {
        const float* wr = fw1 + (size_t)o * 2048;
        float acc = fb1[o];
        for (int j = 0; j < 2048; ++j) acc += wr[j] * f[j];
        float h = acc * g6[o] * inv + b6[o];
        t[o] = h > 0.f ? h : LRELU_S * h;
    }
    __syncthreads();
    {
        int o = threadIdx.x;
        const float* wr = fw2 + (size_t)o * 512;
        float acc = fb2[o];
        for (int j = 0; j < 512; ++j) acc += wr[j] * t[j];
        float h = acc * g7[o] * inv + b7[o];
        if (*flag) ((bf16*)out)[(size_t)b * 256 + o] = __float2bfloat16(h);
        else       ((float*)out)[(size_t)b * 256 + o] = h;
    }
}

// ---------------------------------------------------------------------------
extern "C" void kernel_launch(void* const* d_in, const int* in_sizes, int n_in,
                              void* d_out, int out_size, void* d_ws, size_t ws_size,
                              hipStream_t stream) {
    static const int wsz[23] = {
        384, 64, 64,   8192, 64, 64,   16384, 128, 128,   65536, 256, 256,
        524288, 1024, 1024,   1048576, 512,   512, 512,   131072, 256,   256, 256
    };
    static const int trows[23] = {64,0,0, 64,0,0, 128,0,0, 256,0,0, 0,0,0, 0,0, 0,0, 0,0, 0,0};
    static const int tcols[23] = { 6,0,0,128,0,0, 128,0,0, 256,0,0, 0,0,0, 0,0, 0,0, 0,0, 0,0};

    WPack wp;
    int total = 0;
    for (int i = 0; i < 23; ++i) {
        wp.src[i] = d_in[i + 1]; wp.off[i] = total; total += wsz[i];
        wp.rows[i] = trows[i]; wp.cols[i] = tcols[i];
    }
    wp.off[23] = total;

    const size_t flag_bytes = 16;
    const size_t x0_bytes   = (size_t)B_SZ * 3 * N_PTS * 4;
    const size_t feat_bytes = (size_t)B_SZ * 512 * N_PTS * 2;
    const size_t idx_bytes  = (size_t)B_SZ * N_PTS * KNN * 4;
    const size_t pool_bytes = (size_t)B_SZ * 1024 * 4 * 2;
    const size_t wf_bytes   = (size_t)total * 4;
    const size_t base_need  = flag_bytes + x0_bytes + feat_bytes + idx_bytes + pool_bytes + wf_bytes;

    const size_t featT_bytes = (size_t)B_SZ * N_PTS * 256 * 2;          //  4 MB
    const size_t xx_bytes    = (size_t)B_SZ * N_PTS * 4;                // 32 KB
    const size_t S_bytes     = (size_t)B_SZ * N_PTS * N_PTS * 4;        // 64 MB
    const size_t full_need   = base_need + featT_bytes + xx_bytes + S_bytes;

    if (ws_size < base_need) return;   // graceful fail
    const bool use_gram = (ws_size >= full_need);

    char* w = (char*)d_ws;
    int*   flag = (int*)w;              w += flag_bytes;
    float* x0   = (float*)w;            w += x0_bytes;
    bf16*  feat = (bf16*)w;             w += feat_bytes;
    int*   idx  = (int*)w;              w += idx_bytes;
    w += pool_bytes;
    float* wf   = (float*)w;            w += wf_bytes;
    bf16*  featT = (bf16*)w;            w += featT_bytes;
    float* xx    = (float*)w;           w += xx_bytes;
    float* S     = (float*)w;

    float* fmxp = (float*)idx;                         // overlay (idx dead after ec4)
    float* fsmp = fmxp + (size_t)B_SZ * 1024 * NCH;

    const int FBS = 512 * N_PTS;

    k_sniff<<<1, 64, 0, stream>>>((const unsigned short*)d_in[0], flag);
    k_repack<<<256, 256, 0, stream>>>(wp, flag, wf, total);
    k_transpose<<<(B_SZ * N_PTS + 255) / 256, 256, 0, stream>>>(d_in[0], flag, x0);

    const float* w1t = wf + wp.off[0],  *g1 = wf + wp.off[1],  *b1 = wf + wp.off[2];
    const float* w2t = wf + wp.off[3],  *g2 = wf + wp.off[4],  *b2 = wf + wp.off[5];
    const float* w3t = wf + wp.off[6],  *g3 = wf + wp.off[7],  *b3 = wf + wp.off[8];
    const float* w4t = wf + wp.off[9],  *g4 = wf + wp.off[10], *b4 = wf + wp.off[11];
    const float* w5  = wf + wp.off[12], *g5 = wf + wp.off[13], *b5 = wf + wp.off[14];
    const float* fw1 = wf + wp.off[15], *fb1 = wf + wp.off[16];
    const float* g6  = wf + wp.off[17], *b6 = wf + wp.off[18];
    const float* fw2 = wf + wp.off[19], *fb2 = wf + wp.off[20];
    const float* g7  = wf + wp.off[21], *b7 = wf + wp.off[22];

    const int GK = B_SZ * N_PTS / 4;   // 2048 blocks
    const int NXX = (B_SZ * N_PTS + 255) / 256;

    // Layer 1 (C=3, fp32): direct kNN always.
    k_knn<float, 3><<<GK, 256, 0, stream>>>(x0, 3 * N_PTS, idx);
    if (use_gram) {
        k_edgeconv<float, 3, 64, true, false><<<GK, 256, 0, stream>>>(
            x0, 3 * N_PTS, idx, w1t, g1, b1, feat + 0 * N_PTS, FBS, featT, 0, nullptr, 0);
        // kNN layer 2 on x1 (channels [0,64))
        k_xx<64><<<NXX, 256, 0, stream>>>(featT, 0, xx);
        k_gram<64><<<B_SZ * 256, 256, 0, stream>>>(featT, 0, S);
        k_select<<<GK, 256, 0, stream>>>(S, xx, idx);
        k_edgeconv<bf16, 64, 64, true, true><<<GK, 256, 0, stream>>>(
            feat + 0 * N_PTS, FBS, idx, w2t, g2, b2, feat + 64 * N_PTS, FBS, featT, 64, featT, 0);
        // kNN layer 3 on x2 (channels [64,128))
        k_xx<64><<<NXX, 256, 0, stream>>>(featT, 64, xx);
        k_gram<64><<<B_SZ * 256, 256, 0, stream>>>(featT, 64, S);
        k_select<<<GK, 256, 0, stream>>>(S, xx, idx);
        k_edgeconv<bf16, 64, 128, true, true><<<GK, 256, 0, stream>>>(
            feat + 64 * N_PTS, FBS, idx, w3t, g3, b3, feat + 128 * N_PTS, FBS, featT, 128, featT, 64);
        // kNN layer 4 on x3 (channels [128,256))
        k_xx<128><<<NXX, 256, 0, stream>>>(featT, 128, xx);
        k_gram<128><<<B_SZ * 256, 256, 0, stream>>>(featT, 128, S);
        k_select<<<GK, 256, 0, stream>>>(S, xx, idx);
        k_edgeconv<bf16, 128, 256, false, true><<<GK, 256, 0, stream>>>(
            feat + 128 * N_PTS, FBS, idx, w4t, g4, b4, feat + 256 * N_PTS, FBS, nullptr, 0, featT, 128);
    } else {
        k_edgeconv<float, 3, 64, false, false><<<GK, 256, 0, stream>>>(
            x0, 3 * N_PTS, idx, w1t, g1, b1, feat + 0 * N_PTS, FBS, nullptr, 0, nullptr, 0);
        k_knn<bf16, 64><<<GK, 256, 0, stream>>>(feat + 0 * N_PTS, FBS, idx);
        k_edgeconv<bf16, 64, 64, false, false><<<GK, 256, 0, stream>>>(
            feat + 0 * N_PTS, FBS, idx, w2t, g2, b2, feat + 64 * N_PTS, FBS, nullptr, 0, nullptr, 0);
        k_knn<bf16, 64><<<GK, 256, 0, stream>>>(feat + 64 * N_PTS, FBS, idx);
        k_edgeconv<bf16, 64, 128, false, false><<<GK, 256, 0, stream>>>(
            feat + 64 * N_PTS, FBS, idx, w3t, g3, b3, feat + 128 * N_PTS, FBS, nullptr, 0, nullptr, 0);
        k_knn<bf16, 128><<<GK, 256, 0, stream>>>(feat + 128 * N_PTS, FBS, idx);
        k_edgeconv<bf16, 128, 256, false, false><<<GK, 256, 0, stream>>>(
            feat + 128 * N_PTS, FBS, idx, w4t, g4, b4, feat + 256 * N_PTS, FBS, nullptr, 0, nullptr, 0);
    }

    k_conv5pool<<<B_SZ * (1024 / 8) * NCH, 256, 0, stream>>>(feat, w5, g5, b5, fmxp, fsmp);
    k_head<<<B_SZ, 256, 0, stream>>>(fmxp, fsmp, fw1, fb1, g6, b6, fw2, fb2, g7, b7,
                                     flag, d_out);
}

// Round 8
// 913.212 us; speedup vs baseline: 4.2124x; 1.2074x over previous
//
#include <hip/hip_runtime.h>
#include <hip/hip_bf16.h>
#include <float.h>

#define N_PTS 2048
#define B_SZ  4
#define KNN   20
#define LRELU_S 0.2f

typedef __hip_bfloat16 bf16;
typedef __attribute__((ext_vector_type(8))) short short8v;   // 8 bf16 (4 VGPRs)
typedef __attribute__((ext_vector_type(4))) float floatx4;

__device__ __forceinline__ float b2f(const bf16 v) { return __bfloat162float(v); }
__device__ __forceinline__ float ldf(const float* p) { return *p; }
__device__ __forceinline__ float ldf(const bf16* p)  { return __bfloat162float(*p); }
__device__ __forceinline__ short8v ld8(const bf16* p) { return *(const short8v*)p; }

// ---------------------------------------------------------------------------
// Dtype sniffer (robustness): bf16 (flag=1) vs fp32 (flag=0). Reads 256 B.
__global__ void k_sniff(const unsigned short* __restrict__ pts_hw, int* __restrict__ flag) {
    if (threadIdx.x != 0 || blockIdx.x != 0) return;
    int sane = 0;
    for (int j = 0; j < 64; ++j) {
        unsigned short v = pts_hw[2 * j];
        int e = (v >> 7) & 0xFF;
        if (e >= 100 && e <= 140) ++sane;
    }
    *flag = (sane >= 32) ? 1 : 0;
}

// ---------------------------------------------------------------------------
// Repack 23 weight tensors to fp32; EdgeConv W tensors stored TRANSPOSED.
struct WPack {
    const void* src[23];
    int off[24];
    int rows[23];
    int cols[23];
};

__global__ void k_repack(WPack wp, const int* __restrict__ flag, float* __restrict__ dst, int total) {
    const int isb = *flag;
    for (int i = blockIdx.x * blockDim.x + threadIdx.x; i < total; i += gridDim.x * blockDim.x) {
        int lo = 0, hi = 23;
        while (lo + 1 < hi) { int mid = (lo + hi) >> 1; if (i >= wp.off[mid]) lo = mid; else hi = mid; }
        int j = i - wp.off[lo];
        float v = isb ? b2f(((const bf16*)wp.src[lo])[j]) : ((const float*)wp.src[lo])[j];
        int dj = j;
        int cols = wp.cols[lo];
        if (cols) dj = (j % cols) * wp.rows[lo] + (j / cols);
        dst[wp.off[lo] + dj] = v;
    }
}

// ---------------------------------------------------------------------------
// Split EdgeConv weights into bf16 hi/lo pairs for MFMA:
// dst = [W2hi | W2lo | Wdhi | Wdlo], each (COUT, C) row-major, Wd = W1 - W2.
template<int C, int COUT>
__global__ void k_wsplit(const void* __restrict__ W, const int* __restrict__ flag,
                         bf16* __restrict__ dst) {
    int i = blockIdx.x * blockDim.x + threadIdx.x;
    if (i >= COUT * C) return;
    int o = i / C, c = i % C;
    const int isb = *flag;
    float w1 = isb ? b2f(((const bf16*)W)[(size_t)o * 2 * C + c])
                   : ((const float*)W)[(size_t)o * 2 * C + c];
    float w2 = isb ? b2f(((const bf16*)W)[(size_t)o * 2 * C + C + c])
                   : ((const float*)W)[(size_t)o * 2 * C + C + c];
    float wd = w1 - w2;
    bf16 h2 = __float2bfloat16(w2);
    bf16 hd = __float2bfloat16(wd);
    dst[i]                = h2;
    dst[COUT * C + i]     = __float2bfloat16(w2 - b2f(h2));
    dst[2 * COUT * C + i] = hd;
    dst[3 * COUT * C + i] = __float2bfloat16(wd - b2f(hd));
}

// ---------------------------------------------------------------------------
// points (B,N,3) -> x0 (B,3,N) fp32, dtype-dynamic.
__global__ void k_transpose(const void* __restrict__ pts, const int* __restrict__ flag,
                            float* __restrict__ x0) {
    const int isb = *flag;
    int i = blockIdx.x * blockDim.x + threadIdx.x;
    if (i >= B_SZ * N_PTS) return;
    int b = i / N_PTS, n = i % N_PTS;
    for (int c = 0; c < 3; ++c) {
        size_t s = ((size_t)b * N_PTS + n) * 3 + c;
        float v = isb ? b2f(((const bf16*)pts)[s]) : ((const float*)pts)[s];
        x0[((size_t)b * 3 + c) * N_PTS + n] = v;
    }
}

// ---------------------------------------------------------------------------
// 32-candidate row loads (lane chunk), fp32 out. (Used by fallback kNN.)
__device__ __forceinline__ void load32(const float* row, int mbase, float* r) {
    const float4* p = (const float4*)(row + mbase);
#pragma unroll
    for (int i = 0; i < 8; ++i) {
        float4 f = p[i];
        r[4 * i + 0] = f.x; r[4 * i + 1] = f.y; r[4 * i + 2] = f.z; r[4 * i + 3] = f.w;
    }
}
__device__ __forceinline__ void load32(const bf16* row, int mbase, float* r) {
    const uint4* p = (const uint4*)(row + mbase);
#pragma unroll
    for (int i = 0; i < 4; ++i) {
        uint4 u = p[i];
        r[8 * i + 0] = __uint_as_float(u.x << 16);
        r[8 * i + 1] = __uint_as_float(u.x & 0xFFFF0000u);
        r[8 * i + 2] = __uint_as_float(u.y << 16);
        r[8 * i + 3] = __uint_as_float(u.y & 0xFFFF0000u);
        r[8 * i + 4] = __uint_as_float(u.z << 16);
        r[8 * i + 5] = __uint_as_float(u.z & 0xFFFF0000u);
        r[8 * i + 6] = __uint_as_float(u.w << 16);
        r[8 * i + 7] = __uint_as_float(u.w & 0xFFFF0000u);
    }
}

// ---------------------------------------------------------------------------
// kNN (direct): wave-per-query; used for layer 1 (C=3) and as ws fallback.
template<typename T, int C>
__global__ __launch_bounds__(256) void k_knn(const T* __restrict__ x, int bstride,
                                             int* __restrict__ idx) {
    __shared__ float qf[4][C];
    int ib = blockIdx.x;
    int b  = ib / (N_PTS / 4);
    int q0 = (ib % (N_PTS / 4)) * 4;
    const T* xb = x + (size_t)b * bstride;

    for (int t = threadIdx.x; t < 4 * C; t += 256) {
        int pt = t / C, c = t % C;
        qf[pt][c] = ldf(&xb[(size_t)c * N_PTS + (q0 + pt)]);
    }
    __syncthreads();

    int w = threadIdx.x >> 6, lane = threadIdx.x & 63;
    int q = q0 + w;
    int mbase = lane * 32;

    float v[32];
#pragma unroll
    for (int j = 0; j < 32; ++j) v[j] = 0.f;

    for (int c = 0; c < C; ++c) {
        float qc = qf[w][c];
        float r[32];
        load32(xb + (size_t)c * N_PTS, mbase, r);
#pragma unroll
        for (int j = 0; j < 32; ++j) { float t = r[j] - qc; v[j] = fmaf(t, t, v[j]); }
    }

    for (int k = 0; k < KNN; ++k) {
        float bv = FLT_MAX; int bi = 0x7FFFFFFF;
#pragma unroll
        for (int j = 0; j < 32; ++j)
            if (v[j] < bv) { bv = v[j]; bi = mbase + j; }
#pragma unroll
        for (int off = 32; off >= 1; off >>= 1) {
            float ov = __shfl_xor(bv, off);
            int   oi = __shfl_xor(bi, off);
            if (ov < bv || (ov == bv && oi < bi)) { bv = ov; bi = oi; }
        }
        if (lane == 0) idx[((size_t)b * N_PTS + q) * KNN + k] = bi;
        int wl = bi >> 5, wj = bi & 31;
        if (lane == wl) {
#pragma unroll
            for (int j = 0; j < 32; ++j) if (j == wj) v[j] = FLT_MAX;
        }
    }
}

// ---------------------------------------------------------------------------
// Candidate squared norms over a channel slice.
template<int C>
__global__ void k_xx(const bf16* __restrict__ featT, int c0, float* __restrict__ xx) {
    int i = blockIdx.x * blockDim.x + threadIdx.x;
    if (i >= B_SZ * N_PTS) return;
    const bf16* row = featT + (size_t)i * 256 + c0;
    float s = 0.f;
    for (int c = 0; c < C; c += 8) {
        uint4 u = *(const uint4*)(row + c);
        float v0 = __uint_as_float(u.x << 16), v1 = __uint_as_float(u.x & 0xFFFF0000u);
        float v2 = __uint_as_float(u.y << 16), v3 = __uint_as_float(u.y & 0xFFFF0000u);
        float v4 = __uint_as_float(u.z << 16), v5 = __uint_as_float(u.z & 0xFFFF0000u);
        float v6 = __uint_as_float(u.w << 16), v7 = __uint_as_float(u.w & 0xFFFF0000u);
        s = fmaf(v0, v0, s); s = fmaf(v1, v1, s); s = fmaf(v2, v2, s); s = fmaf(v3, v3, s);
        s = fmaf(v4, v4, s); s = fmaf(v5, v5, s); s = fmaf(v6, v6, s); s = fmaf(v7, v7, s);
    }
    xx[i] = s;
}

// ---------------------------------------------------------------------------
// Gram matrix via MFMA: G[b][n][m] = sum_c X[c][n]*X[c][m], X = featT slice.
template<int C>
__global__ __launch_bounds__(256) void k_gram(const bf16* __restrict__ featT, int c0,
                                              float* __restrict__ G) {
    const int KC = 64;
    __shared__ __align__(16) short At[128 * 72];
    __shared__ __align__(16) short Bt[128 * 72];

    int ib = blockIdx.x;
    int b  = ib >> 8;
    int t  = ib & 255;
    int n0 = (t >> 4) << 7;
    int m0 = (t & 15) << 7;

    int tid = threadIdx.x;
    int w = tid >> 6, lane = tid & 63;
    int rw = (w & 1) * 64, cw = (w >> 1) * 64;
    int lrow = lane & 15, quad = lane >> 4;

    floatx4 acc[4][4];
#pragma unroll
    for (int ri = 0; ri < 4; ++ri)
#pragma unroll
        for (int ci = 0; ci < 4; ++ci) acc[ri][ci] = (floatx4){0.f, 0.f, 0.f, 0.f};

    for (int ck = 0; ck < C; ck += KC) {
        __syncthreads();
        for (int s = tid; s < 1024; s += 256) {
            int row = s >> 3, g = s & 7;
            *(uint4*)&At[row * 72 + g * 8] =
                *(const uint4*)(featT + ((size_t)(b * N_PTS + n0 + row) * 256) + c0 + ck + g * 8);
            *(uint4*)&Bt[row * 72 + g * 8] =
                *(const uint4*)(featT + ((size_t)(b * N_PTS + m0 + row) * 256) + c0 + ck + g * 8);
        }
        __syncthreads();
#pragma unroll
        for (int kk = 0; kk < KC; kk += 32) {
            short8v a[4], bb[4];
#pragma unroll
            for (int ri = 0; ri < 4; ++ri)
                a[ri] = *(const short8v*)&At[(rw + ri * 16 + lrow) * 72 + kk + quad * 8];
#pragma unroll
            for (int ci = 0; ci < 4; ++ci)
                bb[ci] = *(const short8v*)&Bt[(cw + ci * 16 + lrow) * 72 + kk + quad * 8];
#pragma unroll
            for (int ri = 0; ri < 4; ++ri)
#pragma unroll
                for (int ci = 0; ci < 4; ++ci)
                    acc[ri][ci] = __builtin_amdgcn_mfma_f32_16x16x32_bf16(a[ri], bb[ci], acc[ri][ci], 0, 0, 0);
        }
    }

#pragma unroll
    for (int ri = 0; ri < 4; ++ri)
#pragma unroll
        for (int ci = 0; ci < 4; ++ci) {
            int n = n0 + rw + ri * 16 + quad * 4;
            int m = m0 + cw + ci * 16 + lrow;
            float* gp = G + ((size_t)b * N_PTS + n) * N_PTS + m;
#pragma unroll
            for (int reg = 0; reg < 4; ++reg)
                gp[(size_t)reg * N_PTS] = acc[ri][ci][reg];
        }
}

// ---------------------------------------------------------------------------
// Top-K selection on precomputed scores: score = xx[m] - 2*G[q][m].
__global__ __launch_bounds__(256) void k_select(const float* __restrict__ G,
                                                const float* __restrict__ xx,
                                                int* __restrict__ idx) {
    int ib = blockIdx.x;
    int b = ib >> 9;
    int q0 = (ib & 511) * 4;
    int w = threadIdx.x >> 6, lane = threadIdx.x & 63;
    int q = q0 + w;
    const float* grow = G + ((size_t)b * N_PTS + q) * N_PTS;
    const float* xrow = xx + (size_t)b * N_PTS;

    float v[32];
#pragma unroll
    for (int r = 0; r < 8; ++r) {
        float4 g4 = *(const float4*)(grow + r * 256 + (lane << 2));
        float4 x4 = *(const float4*)(xrow + r * 256 + (lane << 2));
        v[4 * r + 0] = fmaf(-2.f, g4.x, x4.x);
        v[4 * r + 1] = fmaf(-2.f, g4.y, x4.y);
        v[4 * r + 2] = fmaf(-2.f, g4.z, x4.z);
        v[4 * r + 3] = fmaf(-2.f, g4.w, x4.w);
    }

    for (int k = 0; k < KNN; ++k) {
        float bv = FLT_MAX; int bi = 0x7FFFFFFF;
#pragma unroll
        for (int j = 0; j < 32; ++j) {
            if (v[j] < bv) { bv = v[j]; bi = ((j >> 2) << 8) + (lane << 2) + (j & 3); }
        }
#pragma unroll
        for (int off = 32; off >= 1; off >>= 1) {
            float ov = __shfl_xor(bv, off);
            int   oi = __shfl_xor(bi, off);
            if (ov < bv || (ov == bv && oi < bi)) { bv = ov; bi = oi; }
        }
        if (lane == 0) idx[((size_t)b * N_PTS + q) * KNN + k] = bi;
        int wl = (bi >> 2) & 63;
        int jj = ((bi >> 8) << 2) | (bi & 3);
        if (lane == wl) {
#pragma unroll
            for (int j = 0; j < 32; ++j) if (j == jj) v[j] = FLT_MAX;
        }
    }
}

// ---------------------------------------------------------------------------
// EdgeConv via MFMA (gram path, layers 2-4). Per block: 4 points.
//   Y[o][col] = sum_c W2[o][c] * nb[col][c],  col = k*4 + pt  (pt-minor!)
//   base[o][pt] = sum_c Wd[o][c] * xn_pt[c]   (ct tile, cols 0..3 used)
// Weights are bf16 hi/lo pairs (fp32-split): 2 MFMAs per product stream.
// Epilogue: each lane's 5 accumulator cols share pt = lane&3 -> 2 shfl_xor max.
template<int C, int COUT>
__global__ __launch_bounds__(256) void k_ecmfma(
        const int* __restrict__ idx,
        const bf16* __restrict__ srcT, int c0s,
        const bf16* __restrict__ Wsp,       // [W2hi|W2lo|Wdhi|Wdlo], each COUT*C
        const float* __restrict__ gam, const float* __restrict__ bet,
        bf16* __restrict__ out, int ostride,
        bf16* __restrict__ featT, int c0f, int wf) {
    const int MT  = COUT / 64;              // m-tiles per wave (1,2,4)
    const int CP2 = C + 8;                  // LDS row stride (shorts), 16B-mult
    __shared__ __align__(16) short nb[96 * (C + 8)];

    int ib = blockIdx.x;
    int b  = ib / (N_PTS / 4);
    int n0 = (ib % (N_PTS / 4)) * 4;
    int tid = threadIdx.x;

    // Stage 96 rows: 0..79 neighbors (row = k*4+pt), 80..95 centers (dup x4).
    const int G16 = C / 8;
    for (int s = tid; s < 96 * G16; s += 256) {
        int row = s / G16, g = s % G16;
        int m;
        if (row < 80) {
            int k = row >> 2, pt = row & 3;
            m = idx[((size_t)b * N_PTS + n0 + pt) * KNN + k] & (N_PTS - 1);
        } else {
            m = n0 + ((row - 80) & 3);
        }
        *(uint4*)&nb[row * CP2 + g * 8] =
            *(const uint4*)(srcT + ((size_t)(b * N_PTS + m)) * 256 + c0s + g * 8);
    }
    __syncthreads();

    int w = tid >> 6, lane = tid & 63;
    int l15 = lane & 15, quad = lane >> 4;
    int ow = w * (MT * 16);

    const bf16* W2hi = Wsp;
    const bf16* W2lo = Wsp + (size_t)COUT * C;
    const bf16* Wdhi = Wsp + 2 * (size_t)COUT * C;
    const bf16* Wdlo = Wsp + 3 * (size_t)COUT * C;

    floatx4 accN[MT][5];
    floatx4 accC[MT];
#pragma unroll
    for (int mi = 0; mi < MT; ++mi) {
        accC[mi] = (floatx4){0.f, 0.f, 0.f, 0.f};
#pragma unroll
        for (int ni = 0; ni < 5; ++ni) accN[mi][ni] = (floatx4){0.f, 0.f, 0.f, 0.f};
    }

    for (int ck = 0; ck < C; ck += 32) {
        short8v bfr[5], cfr;
#pragma unroll
        for (int ni = 0; ni < 5; ++ni)
            bfr[ni] = *(const short8v*)&nb[(ni * 16 + l15) * CP2 + ck + quad * 8];
        cfr = *(const short8v*)&nb[(80 + l15) * CP2 + ck + quad * 8];
#pragma unroll
        for (int mi = 0; mi < MT; ++mi) {
            int ar = (ow + mi * 16 + l15) * C + ck + quad * 8;
            short8v ah = ld8(W2hi + ar);
            short8v al = ld8(W2lo + ar);
            short8v dh = ld8(Wdhi + ar);
            short8v dl = ld8(Wdlo + ar);
#pragma unroll
            for (int ni = 0; ni < 5; ++ni) {
                accN[mi][ni] = __builtin_amdgcn_mfma_f32_16x16x32_bf16(ah, bfr[ni], accN[mi][ni], 0, 0, 0);
                accN[mi][ni] = __builtin_amdgcn_mfma_f32_16x16x32_bf16(al, bfr[ni], accN[mi][ni], 0, 0, 0);
            }
            accC[mi] = __builtin_amdgcn_mfma_f32_16x16x32_bf16(dh, cfr, accC[mi], 0, 0, 0);
            accC[mi] = __builtin_amdgcn_mfma_f32_16x16x32_bf16(dl, cfr, accC[mi], 0, 0, 0);
        }
    }

    // Epilogue. C-layout: row(M=o) = quad*4+reg, col(N) = lane&15.
    const float inv = rsqrtf(1.0f + 1e-5f);
    int srcl = (lane & 48) + (l15 & 3);     // lane holding base for pt = l15&3
    int pt = l15 & 3;
#pragma unroll
    for (int mi = 0; mi < MT; ++mi) {
#pragma unroll
        for (int r = 0; r < 4; ++r) {
            float bse = __shfl(accC[mi][r], srcl, 64);
            int o = ow + mi * 16 + quad * 4 + r;
            float scale = gam[o] * inv, bias = bet[o];
            float mx = -FLT_MAX;
#pragma unroll
            for (int ni = 0; ni < 5; ++ni) {
                float h = (bse + accN[mi][ni][r]) * scale + bias;
                h = h > 0.f ? h : LRELU_S * h;
                mx = fmaxf(mx, h);
            }
            mx = fmaxf(mx, __shfl_xor(mx, 4));
            mx = fmaxf(mx, __shfl_xor(mx, 8));
            if (l15 < 4) {
                int n = n0 + pt;
                bf16 bv = __float2bfloat16(mx);
                out[(size_t)b * ostride + (size_t)o * N_PTS + n] = bv;
                if (wf) featT[((size_t)(b * N_PTS + n)) * 256 + c0f + o] = bv;
            }
        }
    }
}

// ---------------------------------------------------------------------------
// EdgeConv (VALU): layer 1 (C=3) and ws-fallback path.
template<typename T, int C, int COUT, bool WF, bool UT>
__global__ __launch_bounds__(256) void k_edgeconv(const T* __restrict__ x, int bstride,
                           const int* __restrict__ idx,
                           const float* __restrict__ Wt,
                           const float* __restrict__ gam,
                           const float* __restrict__ bet,
                           bf16* __restrict__ out, int ostride,
                           bf16* __restrict__ featT, int c0f,
                           const bf16* __restrict__ srcT, int c0s) {
    const int PT = 4;
    const int OT = COUT / 64;
    const int CP = (C + 3) & ~3;
    __shared__ float sh[PT][KNN + 1][CP];

    int ib = blockIdx.x;
    int b  = ib / (N_PTS / PT);
    int n0 = (ib % (N_PTS / PT)) * PT;
    const T* xb = x + (size_t)b * bstride;

    const int TOT = PT * (KNN + 1) * C;
    for (int t = threadIdx.x; t < TOT; t += 256) {
        int pt = t / ((KNN + 1) * C);
        int r  = t % ((KNN + 1) * C);
        int row = r / C, c = r % C;
        int n = n0 + pt;
        int m = (row == 0) ? n
                           : (idx[((size_t)b * N_PTS + n) * KNN + (row - 1)] & (N_PTS - 1));
        if (UT)
            sh[pt][row][c] = b2f(srcT[((size_t)(b * N_PTS + m)) * 256 + c0s + c]);
        else
            sh[pt][row][c] = ldf(&xb[(size_t)c * N_PTS + m]);
    }
    __syncthreads();

    int w = threadIdx.x >> 6, lane = threadIdx.x & 63;
    int n = n0 + w;

    constexpr int KT = (OT >= 4) ? 10 : 20;
    constexpr int NPASS = KNN / KT;

    float base[OT];
    float mx[OT];
#pragma unroll
    for (int j = 0; j < OT; ++j) { base[j] = 0.f; mx[j] = -FLT_MAX; }

    const float inv = rsqrtf(1.0f + 1e-5f);

#pragma unroll
    for (int pass = 0; pass < NPASS; ++pass) {
        float acc[OT][KT];
#pragma unroll
        for (int j = 0; j < OT; ++j)
#pragma unroll
            for (int k = 0; k < KT; ++k) acc[j][k] = 0.f;

        for (int c = 0; c < C; ++c) {
            float xq = sh[w][0][c];
            float w2v[OT];
#pragma unroll
            for (int j = 0; j < OT; ++j)
                w2v[j] = Wt[(size_t)(C + c) * COUT + lane + 64 * j];
            if (pass == 0) {
#pragma unroll
                for (int j = 0; j < OT; ++j) {
                    float w1v = Wt[(size_t)c * COUT + lane + 64 * j];
                    base[j] = fmaf(w1v - w2v[j], xq, base[j]);
                }
            }
#pragma unroll
            for (int k = 0; k < KT; ++k) {
                float nv = sh[w][1 + pass * KT + k][c];
#pragma unroll
                for (int j = 0; j < OT; ++j) acc[j][k] = fmaf(w2v[j], nv, acc[j][k]);
            }
        }

#pragma unroll
        for (int j = 0; j < OT; ++j) {
            int o = lane + 64 * j;
            float scale = gam[o] * inv, bias = bet[o];
#pragma unroll
            for (int k = 0; k < KT; ++k) {
                float h = (base[j] + acc[j][k]) * scale + bias;
                h = h > 0.f ? h : LRELU_S * h;
                mx[j] = fmaxf(mx[j], h);
            }
        }
    }

#pragma unroll
    for (int j = 0; j < OT; ++j) {
        int o = lane + 64 * j;
        bf16 bv = __float2bfloat16(mx[j]);
        out[(size_t)b * ostride + (size_t)o * N_PTS + n] = bv;
        if (WF) featT[((size_t)b * N_PTS + n) * 256 + c0f + o] = bv;
    }
}

// ---------------------------------------------------------------------------
// conv5 (1024x512) + BN + LReLU + max/sum partial pooling over an N-chunk.
#define NCH 2
__global__ __launch_bounds__(256) void k_conv5pool(const bf16* __restrict__ feat,
                            const float* __restrict__ w5,
                            const float* __restrict__ g5,
                            const float* __restrict__ b5,
                            float* __restrict__ fmxp, float* __restrict__ fsmp) {
    const int OT = 8;
    const int NT = 4;
    const int CHN = N_PTS / NCH;
    __shared__ float wl[OT][512];
    __shared__ float rmx[4][OT];
    __shared__ float rsm[4][OT];

    int ib = blockIdx.x;
    int ch = ib % NCH;
    int ot = (ib / NCH) % (1024 / OT);
    int b  = ib / (NCH * (1024 / OT));
    int o0 = ot * OT;
    const bf16* fb = feat + (size_t)b * 512 * N_PTS;

    for (int t = threadIdx.x; t < OT * 512; t += 256) {
        int o = t >> 9, c = t & 511;
        wl[o][c] = w5[(size_t)(o0 + o) * 512 + c];
    }
    __syncthreads();

    const int n0 = ch * CHN + threadIdx.x * NT;

    float acc[OT][NT];
#pragma unroll
    for (int o = 0; o < OT; ++o)
#pragma unroll
        for (int t = 0; t < NT; ++t) acc[o][t] = 0.f;

    for (int c = 0; c < 512; c += 4) {
        float fv[4][NT];
#pragma unroll
        for (int j = 0; j < 4; ++j) {
            uint2 u = *(const uint2*)(fb + (size_t)(c + j) * N_PTS + n0);
            fv[j][0] = __uint_as_float(u.x << 16);
            fv[j][1] = __uint_as_float(u.x & 0xFFFF0000u);
            fv[j][2] = __uint_as_float(u.y << 16);
            fv[j][3] = __uint_as_float(u.y & 0xFFFF0000u);
        }
#pragma unroll
        for (int o = 0; o < OT; ++o) {
            float4 wv = *(const float4*)&wl[o][c];
#pragma unroll
            for (int t = 0; t < NT; ++t) {
                acc[o][t] = fmaf(wv.x, fv[0][t], acc[o][t]);
                acc[o][t] = fmaf(wv.y, fv[1][t], acc[o][t]);
                acc[o][t] = fmaf(wv.z, fv[2][t], acc[o][t]);
                acc[o][t] = fmaf(wv.w, fv[3][t], acc[o][t]);
            }
        }
    }

    const float inv = rsqrtf(1.0f + 1e-5f);
    int w = threadIdx.x >> 6, lane = threadIdx.x & 63;
#pragma unroll
    for (int o = 0; o < OT; ++o) {
        float scale = g5[o0 + o] * inv, bias = b5[o0 + o];
        float mx = -FLT_MAX, sm = 0.f;
#pragma unroll
        for (int t = 0; t < NT; ++t) {
            float h = acc[o][t] * scale + bias;
            h = h > 0.f ? h : LRELU_S * h;
            mx = fmaxf(mx, h);
            sm += h;
        }
#pragma unroll
        for (int off = 32; off >= 1; off >>= 1) {
            mx = fmaxf(mx, __shfl_xor(mx, off));
            sm += __shfl_xor(sm, off);
        }
        if (lane == 0) { rmx[w][o] = mx; rsm[w][o] = sm; }
    }
    __syncthreads();
    if (threadIdx.x < OT) {
        int o = threadIdx.x;
        float mx = -FLT_MAX, sm = 0.f;
#pragma unroll
        for (int ww = 0; ww < 4; ++ww) { mx = fmaxf(mx, rmx[ww][o]); sm += rsm[ww][o]; }
        fmxp[((size_t)b * 1024 + o0 + o) * NCH + ch] = mx;
        fsmp[((size_t)b * 1024 + o0 + o) * NCH + ch] = sm;
    }
}

// ---------------------------------------------------------------------------
// Head: reduce NCH partials -> f = [max(1024), mean(1024)] -> fc1 -> fc2.
__global__ void k_head(const float* __restrict__ fmxp, const float* __restrict__ fsmp,
                       const float* __restrict__ fw1, const float* __restrict__ fb1,
                       const float* __restrict__ g6,  const float* __restrict__ b6,
                       const float* __restrict__ fw2, const float* __restrict__ fb2,
                       const float* __restrict__ g7,  const float* __restrict__ b7,
                       const int* __restrict__ flag, void* __restrict__ out) {
    __shared__ float f[2048];
    __shared__ float t[512];
    int b = blockIdx.x;
    for (int i = threadIdx.x; i < 1024; i += 256) {
        float mx = -FLT_MAX, sm = 0.f;
        for (int ch = 0; ch < NCH; ++ch) {
            mx = fmaxf(mx, fmxp[((size_t)b * 1024 + i) * NCH + ch]);
            sm += fsmp[((size_t)b * 1024 + i) * NCH + ch];
        }
        f[i]        = mx;
        f[1024 + i] = sm * (1.0f / N_PTS);
    }
    __syncthreads();
    const float inv = rsqrtf(1.0f + 1e-5f);
    for (int o = threadIdx.x; o < 512; o += 256) {
        const float* wr = fw1 + (size_t)o * 2048;
        float acc = fb1[o];
        for (int j = 0; j < 2048; ++j) acc += wr[j] * f[j];
        float h = acc * g6[o] * inv + b6[o];
        t[o] = h > 0.f ? h : LRELU_S * h;
    }
    __syncthreads();
    {
        int o = threadIdx.x;
        const float* wr = fw2 + (size_t)o * 512;
        float acc = fb2[o];
        for (int j = 0; j < 512; ++j) acc += wr[j] * t[j];
        float h = acc * g7[o] * inv + b7[o];
        if (*flag) ((bf16*)out)[(size_t)b * 256 + o] = __float2bfloat16(h);
        else       ((float*)out)[(size_t)b * 256 + o] = h;
    }
}

// ---------------------------------------------------------------------------
extern "C" void kernel_launch(void* const* d_in, const int* in_sizes, int n_in,
                              void* d_out, int out_size, void* d_ws, size_t ws_size,
                              hipStream_t stream) {
    static const int wsz[23] = {
        384, 64, 64,   8192, 64, 64,   16384, 128, 128,   65536, 256, 256,
        524288, 1024, 1024,   1048576, 512,   512, 512,   131072, 256,   256, 256
    };
    static const int trows[23] = {64,0,0, 64,0,0, 128,0,0, 256,0,0, 0,0,0, 0,0, 0,0, 0,0, 0,0};
    static const int tcols[23] = { 6,0,0,128,0,0, 128,0,0, 256,0,0, 0,0,0, 0,0, 0,0, 0,0, 0,0};

    WPack wp;
    int total = 0;
    for (int i = 0; i < 23; ++i) {
        wp.src[i] = d_in[i + 1]; wp.off[i] = total; total += wsz[i];
        wp.rows[i] = trows[i]; wp.cols[i] = tcols[i];
    }
    wp.off[23] = total;

    const size_t flag_bytes = 16;
    const size_t x0_bytes   = (size_t)B_SZ * 3 * N_PTS * 4;
    const size_t feat_bytes = (size_t)B_SZ * 512 * N_PTS * 2;
    const size_t idx_bytes  = (size_t)B_SZ * N_PTS * KNN * 4;
    const size_t pool_bytes = (size_t)B_SZ * 1024 * 4 * 2;
    const size_t wf_bytes   = (size_t)total * 4;
    const size_t base_need  = flag_bytes + x0_bytes + feat_bytes + idx_bytes + pool_bytes + wf_bytes;

    const size_t featT_bytes = (size_t)B_SZ * N_PTS * 256 * 2;          //  4 MB
    const size_t xx_bytes    = (size_t)B_SZ * N_PTS * 4;                // 32 KB
    const size_t wsp2_elems  = 4 * 64 * 64;
    const size_t wsp3_elems  = 4 * 128 * 64;
    const size_t wsp4_elems  = 4 * 256 * 128;
    const size_t wsp_bytes   = (wsp2_elems + wsp3_elems + wsp4_elems) * 2;   // 360 KB
    const size_t S_bytes     = (size_t)B_SZ * N_PTS * N_PTS * 4;        // 64 MB
    const size_t full_need   = base_need + featT_bytes + xx_bytes + wsp_bytes + S_bytes;

    if (ws_size < base_need) return;   // graceful fail
    const bool use_gram = (ws_size >= full_need);

    char* w = (char*)d_ws;
    int*   flag = (int*)w;              w += flag_bytes;
    float* x0   = (float*)w;            w += x0_bytes;
    bf16*  feat = (bf16*)w;             w += feat_bytes;
    int*   idx  = (int*)w;              w += idx_bytes;
    w += pool_bytes;
    float* wf   = (float*)w;            w += wf_bytes;
    bf16*  featT = (bf16*)w;            w += featT_bytes;
    float* xx    = (float*)w;           w += xx_bytes;
    bf16*  wsp2  = (bf16*)w;            w += wsp2_elems * 2;
    bf16*  wsp3  = (bf16*)w;            w += wsp3_elems * 2;
    bf16*  wsp4  = (bf16*)w;            w += wsp4_elems * 2;
    float* S     = (float*)w;

    float* fmxp = (float*)idx;                         // overlay (idx dead after ec4)
    float* fsmp = fmxp + (size_t)B_SZ * 1024 * NCH;

    const int FBS = 512 * N_PTS;

    k_sniff<<<1, 64, 0, stream>>>((const unsigned short*)d_in[0], flag);
    k_repack<<<256, 256, 0, stream>>>(wp, flag, wf, total);
    k_transpose<<<(B_SZ * N_PTS + 255) / 256, 256, 0, stream>>>(d_in[0], flag, x0);

    const float* w1t = wf + wp.off[0],  *g1 = wf + wp.off[1],  *b1 = wf + wp.off[2];
    const float* w2t = wf + wp.off[3],  *g2 = wf + wp.off[4],  *b2 = wf + wp.off[5];
    const float* w3t = wf + wp.off[6],  *g3 = wf + wp.off[7],  *b3 = wf + wp.off[8];
    const float* w4t = wf + wp.off[9],  *g4 = wf + wp.off[10], *b4 = wf + wp.off[11];
    const float* w5  = wf + wp.off[12], *g5 = wf + wp.off[13], *b5 = wf + wp.off[14];
    const float* fw1 = wf + wp.off[15], *fb1 = wf + wp.off[16];
    const float* g6  = wf + wp.off[17], *b6 = wf + wp.off[18];
    const float* fw2 = wf + wp.off[19], *fb2 = wf + wp.off[20];
    const float* g7  = wf + wp.off[21], *b7 = wf + wp.off[22];

    const int GK = B_SZ * N_PTS / 4;   // 2048 blocks
    const int NXX = (B_SZ * N_PTS + 255) / 256;

    k_knn<float, 3><<<GK, 256, 0, stream>>>(x0, 3 * N_PTS, idx);
    if (use_gram) {
        k_wsplit<64, 64><<<(64 * 64 + 255) / 256, 256, 0, stream>>>(d_in[4], flag, wsp2);
        k_wsplit<64, 128><<<(128 * 64 + 255) / 256, 256, 0, stream>>>(d_in[7], flag, wsp3);
        k_wsplit<128, 256><<<(256 * 128 + 255) / 256, 256, 0, stream>>>(d_in[10], flag, wsp4);

        k_edgeconv<float, 3, 64, true, false><<<GK, 256, 0, stream>>>(
            x0, 3 * N_PTS, idx, w1t, g1, b1, feat + 0 * N_PTS, FBS, featT, 0, nullptr, 0);
        // layer 2
        k_xx<64><<<NXX, 256, 0, stream>>>(featT, 0, xx);
        k_gram<64><<<B_SZ * 256, 256, 0, stream>>>(featT, 0, S);
        k_select<<<GK, 256, 0, stream>>>(S, xx, idx);
        k_ecmfma<64, 64><<<GK, 256, 0, stream>>>(idx, featT, 0, wsp2, g2, b2,
                                                 feat + 64 * N_PTS, FBS, featT, 64, 1);
        // layer 3
        k_xx<64><<<NXX, 256, 0, stream>>>(featT, 64, xx);
        k_gram<64><<<B_SZ * 256, 256, 0, stream>>>(featT, 64, S);
        k_select<<<GK, 256, 0, stream>>>(S, xx, idx);
        k_ecmfma<64, 128><<<GK, 256, 0, stream>>>(idx, featT, 64, wsp3, g3, b3,
                                                  feat + 128 * N_PTS, FBS, featT, 128, 1);
        // layer 4
        k_xx<128><<<NXX, 256, 0, stream>>>(featT, 128, xx);
        k_gram<128><<<B_SZ * 256, 256, 0, stream>>>(featT, 128, S);
        k_select<<<GK, 256, 0, stream>>>(S, xx, idx);
        k_ecmfma<128, 256><<<GK, 256, 0, stream>>>(idx, featT, 128, wsp4, g4, b4,
                                                   feat + 256 * N_PTS, FBS, nullptr, 0, 0);
    } else {
        k_edgeconv<float, 3, 64, false, false><<<GK, 256, 0, stream>>>(
            x0, 3 * N_PTS, idx, w1t, g1, b1, feat + 0 * N_PTS, FBS, nullptr, 0, nullptr, 0);
        k_knn<bf16, 64><<<GK, 256, 0, stream>>>(feat + 0 * N_PTS, FBS, idx);
        k_edgeconv<bf16, 64, 64, false, false><<<GK, 256, 0, stream>>>(
            feat + 0 * N_PTS, FBS, idx, w2t, g2, b2, feat + 64 * N_PTS, FBS, nullptr, 0, nullptr, 0);
        k_knn<bf16, 64><<<GK, 256, 0, stream>>>(feat + 64 * N_PTS, FBS, idx);
        k_edgeconv<bf16, 64, 128, false, false><<<GK, 256, 0, stream>>>(
            feat + 64 * N_PTS, FBS, idx, w3t, g3, b3, feat + 128 * N_PTS, FBS, nullptr, 0, nullptr, 0);
        k_knn<bf16, 128><<<GK, 256, 0, stream>>>(feat + 128 * N_PTS, FBS, idx);
        k_edgeconv<bf16, 128, 256, false, false><<<GK, 256, 0, stream>>>(
            feat + 128 * N_PTS, FBS, idx, w4t, g4, b4, feat + 256 * N_PTS, FBS, nullptr, 0, nullptr, 0);
    }

    k_conv5pool<<<B_SZ * (1024 / 8) * NCH, 256, 0, stream>>>(feat, w5, g5, b5, fmxp, fsmp);
    k_head<<<B_SZ, 256, 0, stream>>>(fmxp, fsmp, fw1, fb1, g6, b6, fw2, fb2, g7, b7,
                                     flag, d_out);
}

// Round 9
// 672.843 us; speedup vs baseline: 5.7173x; 1.3572x over previous
//
#include <hip/hip_runtime.h>
#include <hip/hip_bf16.h>
#include <float.h>

#define N_PTS 2048
#define B_SZ  4
#define KNN   20
#define LRELU_S 0.2f
#define FT    512          // featT row stride (channels)
#define NPOOL 8            // conv5 n-chunk partials

typedef __hip_bfloat16 bf16;
typedef __attribute__((ext_vector_type(8))) short short8v;   // 8 bf16 (4 VGPRs)
typedef __attribute__((ext_vector_type(4))) float floatx4;

__device__ __forceinline__ float b2f(const bf16 v) { return __bfloat162float(v); }
__device__ __forceinline__ float ldf(const float* p) { return *p; }
__device__ __forceinline__ float ldf(const bf16* p)  { return __bfloat162float(*p); }
__device__ __forceinline__ short8v ld8(const bf16* p) { return *(const short8v*)p; }

// ---------------------------------------------------------------------------
// Dtype sniffer (robustness): bf16 (flag=1) vs fp32 (flag=0). Reads 256 B.
__global__ void k_sniff(const unsigned short* __restrict__ pts_hw, int* __restrict__ flag) {
    if (threadIdx.x != 0 || blockIdx.x != 0) return;
    int sane = 0;
    for (int j = 0; j < 64; ++j) {
        unsigned short v = pts_hw[2 * j];
        int e = (v >> 7) & 0xFF;
        if (e >= 100 && e <= 140) ++sane;
    }
    *flag = (sane >= 32) ? 1 : 0;
}

// ---------------------------------------------------------------------------
// Repack 23 weight tensors to fp32; EdgeConv W tensors stored TRANSPOSED.
struct WPack {
    const void* src[23];
    int off[24];
    int rows[23];
    int cols[23];
};

__global__ void k_repack(WPack wp, const int* __restrict__ flag, float* __restrict__ dst, int total) {
    const int isb = *flag;
    for (int i = blockIdx.x * blockDim.x + threadIdx.x; i < total; i += gridDim.x * blockDim.x) {
        int lo = 0, hi = 23;
        while (lo + 1 < hi) { int mid = (lo + hi) >> 1; if (i >= wp.off[mid]) lo = mid; else hi = mid; }
        int j = i - wp.off[lo];
        float v = isb ? b2f(((const bf16*)wp.src[lo])[j]) : ((const float*)wp.src[lo])[j];
        int dj = j;
        int cols = wp.cols[lo];
        if (cols) dj = (j % cols) * wp.rows[lo] + (j / cols);
        dst[wp.off[lo] + dj] = v;
    }
}

// ---------------------------------------------------------------------------
// Split EdgeConv weights into bf16 hi/lo pairs for MFMA:
// dst = [W2hi | W2lo | Wdhi | Wdlo], each (COUT, C) row-major, Wd = W1 - W2.
template<int C, int COUT>
__global__ void k_wsplit(const void* __restrict__ W, const int* __restrict__ flag,
                         bf16* __restrict__ dst) {
    int i = blockIdx.x * blockDim.x + threadIdx.x;
    if (i >= COUT * C) return;
    int o = i / C, c = i % C;
    const int isb = *flag;
    float w1 = isb ? b2f(((const bf16*)W)[(size_t)o * 2 * C + c])
                   : ((const float*)W)[(size_t)o * 2 * C + c];
    float w2 = isb ? b2f(((const bf16*)W)[(size_t)o * 2 * C + C + c])
                   : ((const float*)W)[(size_t)o * 2 * C + C + c];
    float wd = w1 - w2;
    bf16 h2 = __float2bfloat16(w2);
    bf16 hd = __float2bfloat16(wd);
    dst[i]                = h2;
    dst[COUT * C + i]     = __float2bfloat16(w2 - b2f(h2));
    dst[2 * COUT * C + i] = hd;
    dst[3 * COUT * C + i] = __float2bfloat16(wd - b2f(hd));
}

// ---------------------------------------------------------------------------
// Split conv5 weights (1024x512) into bf16 hi/lo: dst = [hi | lo].
__global__ void k_w5split(const void* __restrict__ W, const int* __restrict__ flag,
                          bf16* __restrict__ dst) {
    int i = blockIdx.x * blockDim.x + threadIdx.x;
    if (i >= 1024 * 512) return;
    const int isb = *flag;
    float w = isb ? b2f(((const bf16*)W)[i]) : ((const float*)W)[i];
    bf16 h = __float2bfloat16(w);
    dst[i] = h;
    dst[1024 * 512 + i] = __float2bfloat16(w - b2f(h));
}

// ---------------------------------------------------------------------------
// points (B,N,3) -> x0 (B,3,N) fp32, dtype-dynamic.
__global__ void k_transpose(const void* __restrict__ pts, const int* __restrict__ flag,
                            float* __restrict__ x0) {
    const int isb = *flag;
    int i = blockIdx.x * blockDim.x + threadIdx.x;
    if (i >= B_SZ * N_PTS) return;
    int b = i / N_PTS, n = i % N_PTS;
    for (int c = 0; c < 3; ++c) {
        size_t s = ((size_t)b * N_PTS + n) * 3 + c;
        float v = isb ? b2f(((const bf16*)pts)[s]) : ((const float*)pts)[s];
        x0[((size_t)b * 3 + c) * N_PTS + n] = v;
    }
}

// ---------------------------------------------------------------------------
// 32-candidate row loads (lane chunk), fp32 out. (Used by fallback kNN.)
__device__ __forceinline__ void load32(const float* row, int mbase, float* r) {
    const float4* p = (const float4*)(row + mbase);
#pragma unroll
    for (int i = 0; i < 8; ++i) {
        float4 f = p[i];
        r[4 * i + 0] = f.x; r[4 * i + 1] = f.y; r[4 * i + 2] = f.z; r[4 * i + 3] = f.w;
    }
}
__device__ __forceinline__ void load32(const bf16* row, int mbase, float* r) {
    const uint4* p = (const uint4*)(row + mbase);
#pragma unroll
    for (int i = 0; i < 4; ++i) {
        uint4 u = p[i];
        r[8 * i + 0] = __uint_as_float(u.x << 16);
        r[8 * i + 1] = __uint_as_float(u.x & 0xFFFF0000u);
        r[8 * i + 2] = __uint_as_float(u.y << 16);
        r[8 * i + 3] = __uint_as_float(u.y & 0xFFFF0000u);
        r[8 * i + 4] = __uint_as_float(u.z << 16);
        r[8 * i + 5] = __uint_as_float(u.z & 0xFFFF0000u);
        r[8 * i + 6] = __uint_as_float(u.w << 16);
        r[8 * i + 7] = __uint_as_float(u.w & 0xFFFF0000u);
    }
}

// ---------------------------------------------------------------------------
// kNN (direct): wave-per-query; used for layer 1 (C=3) and as ws fallback.
template<typename T, int C>
__global__ __launch_bounds__(256) void k_knn(const T* __restrict__ x, int bstride,
                                             int* __restrict__ idx) {
    __shared__ float qf[4][C];
    int ib = blockIdx.x;
    int b  = ib / (N_PTS / 4);
    int q0 = (ib % (N_PTS / 4)) * 4;
    const T* xb = x + (size_t)b * bstride;

    for (int t = threadIdx.x; t < 4 * C; t += 256) {
        int pt = t / C, c = t % C;
        qf[pt][c] = ldf(&xb[(size_t)c * N_PTS + (q0 + pt)]);
    }
    __syncthreads();

    int w = threadIdx.x >> 6, lane = threadIdx.x & 63;
    int q = q0 + w;
    int mbase = lane * 32;

    float v[32];
#pragma unroll
    for (int j = 0; j < 32; ++j) v[j] = 0.f;

    for (int c = 0; c < C; ++c) {
        float qc = qf[w][c];
        float r[32];
        load32(xb + (size_t)c * N_PTS, mbase, r);
#pragma unroll
        for (int j = 0; j < 32; ++j) { float t = r[j] - qc; v[j] = fmaf(t, t, v[j]); }
    }

    for (int k = 0; k < KNN; ++k) {
        float bv = FLT_MAX; int bi = 0x7FFFFFFF;
#pragma unroll
        for (int j = 0; j < 32; ++j)
            if (v[j] < bv) { bv = v[j]; bi = mbase + j; }
#pragma unroll
        for (int off = 32; off >= 1; off >>= 1) {
            float ov = __shfl_xor(bv, off);
            int   oi = __shfl_xor(bi, off);
            if (ov < bv || (ov == bv && oi < bi)) { bv = ov; bi = oi; }
        }
        if (lane == 0) idx[((size_t)b * N_PTS + q) * KNN + k] = bi;
        int wl = bi >> 5, wj = bi & 31;
        if (lane == wl) {
#pragma unroll
            for (int j = 0; j < 32; ++j) if (j == wj) v[j] = FLT_MAX;
        }
    }
}

// ---------------------------------------------------------------------------
// Candidate squared norms over a channel slice.
template<int C>
__global__ void k_xx(const bf16* __restrict__ featT, int c0, float* __restrict__ xx) {
    int i = blockIdx.x * blockDim.x + threadIdx.x;
    if (i >= B_SZ * N_PTS) return;
    const bf16* row = featT + (size_t)i * FT + c0;
    float s = 0.f;
    for (int c = 0; c < C; c += 8) {
        uint4 u = *(const uint4*)(row + c);
        float v0 = __uint_as_float(u.x << 16), v1 = __uint_as_float(u.x & 0xFFFF0000u);
        float v2 = __uint_as_float(u.y << 16), v3 = __uint_as_float(u.y & 0xFFFF0000u);
        float v4 = __uint_as_float(u.z << 16), v5 = __uint_as_float(u.z & 0xFFFF0000u);
        float v6 = __uint_as_float(u.w << 16), v7 = __uint_as_float(u.w & 0xFFFF0000u);
        s = fmaf(v0, v0, s); s = fmaf(v1, v1, s); s = fmaf(v2, v2, s); s = fmaf(v3, v3, s);
        s = fmaf(v4, v4, s); s = fmaf(v5, v5, s); s = fmaf(v6, v6, s); s = fmaf(v7, v7, s);
    }
    xx[i] = s;
}

// ---------------------------------------------------------------------------
// Gram matrix via MFMA: G[b][n][m] = sum_c X[c][n]*X[c][m], X = featT slice.
template<int C>
__global__ __launch_bounds__(256) void k_gram(const bf16* __restrict__ featT, int c0,
                                              float* __restrict__ G) {
    const int KC = 64;
    __shared__ __align__(16) short At[128 * 72];
    __shared__ __align__(16) short Bt[128 * 72];

    int ib = blockIdx.x;
    int b  = ib >> 8;
    int t  = ib & 255;
    int n0 = (t >> 4) << 7;
    int m0 = (t & 15) << 7;

    int tid = threadIdx.x;
    int w = tid >> 6, lane = tid & 63;
    int rw = (w & 1) * 64, cw = (w >> 1) * 64;
    int lrow = lane & 15, quad = lane >> 4;

    floatx4 acc[4][4];
#pragma unroll
    for (int ri = 0; ri < 4; ++ri)
#pragma unroll
        for (int ci = 0; ci < 4; ++ci) acc[ri][ci] = (floatx4){0.f, 0.f, 0.f, 0.f};

    for (int ck = 0; ck < C; ck += KC) {
        __syncthreads();
        for (int s = tid; s < 1024; s += 256) {
            int row = s >> 3, g = s & 7;
            *(uint4*)&At[row * 72 + g * 8] =
                *(const uint4*)(featT + ((size_t)(b * N_PTS + n0 + row) * FT) + c0 + ck + g * 8);
            *(uint4*)&Bt[row * 72 + g * 8] =
                *(const uint4*)(featT + ((size_t)(b * N_PTS + m0 + row) * FT) + c0 + ck + g * 8);
        }
        __syncthreads();
#pragma unroll
        for (int kk = 0; kk < KC; kk += 32) {
            short8v a[4], bb[4];
#pragma unroll
            for (int ri = 0; ri < 4; ++ri)
                a[ri] = *(const short8v*)&At[(rw + ri * 16 + lrow) * 72 + kk + quad * 8];
#pragma unroll
            for (int ci = 0; ci < 4; ++ci)
                bb[ci] = *(const short8v*)&Bt[(cw + ci * 16 + lrow) * 72 + kk + quad * 8];
#pragma unroll
            for (int ri = 0; ri < 4; ++ri)
#pragma unroll
                for (int ci = 0; ci < 4; ++ci)
                    acc[ri][ci] = __builtin_amdgcn_mfma_f32_16x16x32_bf16(a[ri], bb[ci], acc[ri][ci], 0, 0, 0);
        }
    }

#pragma unroll
    for (int ri = 0; ri < 4; ++ri)
#pragma unroll
        for (int ci = 0; ci < 4; ++ci) {
            int n = n0 + rw + ri * 16 + quad * 4;
            int m = m0 + cw + ci * 16 + lrow;
            float* gp = G + ((size_t)b * N_PTS + n) * N_PTS + m;
#pragma unroll
            for (int reg = 0; reg < 4; ++reg)
                gp[(size_t)reg * N_PTS] = acc[ri][ci][reg];
        }
}

// ---------------------------------------------------------------------------
// Top-K selection on precomputed scores: score = xx[m] - 2*G[q][m].
__global__ __launch_bounds__(256) void k_select(const float* __restrict__ G,
                                                const float* __restrict__ xx,
                                                int* __restrict__ idx) {
    int ib = blockIdx.x;
    int b = ib >> 9;
    int q0 = (ib & 511) * 4;
    int w = threadIdx.x >> 6, lane = threadIdx.x & 63;
    int q = q0 + w;
    const float* grow = G + ((size_t)b * N_PTS + q) * N_PTS;
    const float* xrow = xx + (size_t)b * N_PTS;

    float v[32];
#pragma unroll
    for (int r = 0; r < 8; ++r) {
        float4 g4 = *(const float4*)(grow + r * 256 + (lane << 2));
        float4 x4 = *(const float4*)(xrow + r * 256 + (lane << 2));
        v[4 * r + 0] = fmaf(-2.f, g4.x, x4.x);
        v[4 * r + 1] = fmaf(-2.f, g4.y, x4.y);
        v[4 * r + 2] = fmaf(-2.f, g4.z, x4.z);
        v[4 * r + 3] = fmaf(-2.f, g4.w, x4.w);
    }

    for (int k = 0; k < KNN; ++k) {
        float bv = FLT_MAX; int bi = 0x7FFFFFFF;
#pragma unroll
        for (int j = 0; j < 32; ++j) {
            if (v[j] < bv) { bv = v[j]; bi = ((j >> 2) << 8) + (lane << 2) + (j & 3); }
        }
#pragma unroll
        for (int off = 32; off >= 1; off >>= 1) {
            float ov = __shfl_xor(bv, off);
            int   oi = __shfl_xor(bi, off);
            if (ov < bv || (ov == bv && oi < bi)) { bv = ov; bi = oi; }
        }
        if (lane == 0) idx[((size_t)b * N_PTS + q) * KNN + k] = bi;
        int wl = (bi >> 2) & 63;
        int jj = ((bi >> 8) << 2) | (bi & 3);
        if (lane == wl) {
#pragma unroll
            for (int j = 0; j < 32; ++j) if (j == jj) v[j] = FLT_MAX;
        }
    }
}

// ---------------------------------------------------------------------------
// EdgeConv via MFMA (gram path, layers 2-4). Per block: 4 points.
template<int C, int COUT>
__global__ __launch_bounds__(256) void k_ecmfma(
        const int* __restrict__ idx,
        const bf16* __restrict__ srcT, int c0s,
        const bf16* __restrict__ Wsp,       // [W2hi|W2lo|Wdhi|Wdlo], each COUT*C
        const float* __restrict__ gam, const float* __restrict__ bet,
        bf16* __restrict__ out, int ostride,
        bf16* __restrict__ featT, int c0f, int wf) {
    const int MT  = COUT / 64;
    const int CP2 = C + 8;
    __shared__ __align__(16) short nb[96 * (C + 8)];

    int ib = blockIdx.x;
    int b  = ib / (N_PTS / 4);
    int n0 = (ib % (N_PTS / 4)) * 4;
    int tid = threadIdx.x;

    const int G16 = C / 8;
    for (int s = tid; s < 96 * G16; s += 256) {
        int row = s / G16, g = s % G16;
        int m;
        if (row < 80) {
            int k = row >> 2, pt = row & 3;
            m = idx[((size_t)b * N_PTS + n0 + pt) * KNN + k] & (N_PTS - 1);
        } else {
            m = n0 + ((row - 80) & 3);
        }
        *(uint4*)&nb[row * CP2 + g * 8] =
            *(const uint4*)(srcT + ((size_t)(b * N_PTS + m)) * FT + c0s + g * 8);
    }
    __syncthreads();

    int w = tid >> 6, lane = tid & 63;
    int l15 = lane & 15, quad = lane >> 4;
    int ow = w * (MT * 16);

    const bf16* W2hi = Wsp;
    const bf16* W2lo = Wsp + (size_t)COUT * C;
    const bf16* Wdhi = Wsp + 2 * (size_t)COUT * C;
    const bf16* Wdlo = Wsp + 3 * (size_t)COUT * C;

    floatx4 accN[MT][5];
    floatx4 accC[MT];
#pragma unroll
    for (int mi = 0; mi < MT; ++mi) {
        accC[mi] = (floatx4){0.f, 0.f, 0.f, 0.f};
#pragma unroll
        for (int ni = 0; ni < 5; ++ni) accN[mi][ni] = (floatx4){0.f, 0.f, 0.f, 0.f};
    }

    for (int ck = 0; ck < C; ck += 32) {
        short8v bfr[5], cfr;
#pragma unroll
        for (int ni = 0; ni < 5; ++ni)
            bfr[ni] = *(const short8v*)&nb[(ni * 16 + l15) * CP2 + ck + quad * 8];
        cfr = *(const short8v*)&nb[(80 + l15) * CP2 + ck + quad * 8];
#pragma unroll
        for (int mi = 0; mi < MT; ++mi) {
            int ar = (ow + mi * 16 + l15) * C + ck + quad * 8;
            short8v ah = ld8(W2hi + ar);
            short8v al = ld8(W2lo + ar);
            short8v dh = ld8(Wdhi + ar);
            short8v dl = ld8(Wdlo + ar);
#pragma unroll
            for (int ni = 0; ni < 5; ++ni) {
                accN[mi][ni] = __builtin_amdgcn_mfma_f32_16x16x32_bf16(ah, bfr[ni], accN[mi][ni], 0, 0, 0);
                accN[mi][ni] = __builtin_amdgcn_mfma_f32_16x16x32_bf16(al, bfr[ni], accN[mi][ni], 0, 0, 0);
            }
            accC[mi] = __builtin_amdgcn_mfma_f32_16x16x32_bf16(dh, cfr, accC[mi], 0, 0, 0);
            accC[mi] = __builtin_amdgcn_mfma_f32_16x16x32_bf16(dl, cfr, accC[mi], 0, 0, 0);
        }
    }

    const float inv = rsqrtf(1.0f + 1e-5f);
    int srcl = (lane & 48) + (l15 & 3);
    int pt = l15 & 3;
#pragma unroll
    for (int mi = 0; mi < MT; ++mi) {
#pragma unroll
        for (int r = 0; r < 4; ++r) {
            float bse = __shfl(accC[mi][r], srcl, 64);
            int o = ow + mi * 16 + quad * 4 + r;
            float scale = gam[o] * inv, bias = bet[o];
            float mx = -FLT_MAX;
#pragma unroll
            for (int ni = 0; ni < 5; ++ni) {
                float h = (bse + accN[mi][ni][r]) * scale + bias;
                h = h > 0.f ? h : LRELU_S * h;
                mx = fmaxf(mx, h);
            }
            mx = fmaxf(mx, __shfl_xor(mx, 4));
            mx = fmaxf(mx, __shfl_xor(mx, 8));
            if (l15 < 4) {
                int n = n0 + pt;
                bf16 bv = __float2bfloat16(mx);
                out[(size_t)b * ostride + (size_t)o * N_PTS + n] = bv;
                if (wf) featT[((size_t)(b * N_PTS + n)) * FT + c0f + o] = bv;
            }
        }
    }
}

// ---------------------------------------------------------------------------
// EdgeConv (VALU): layer 1 (C=3) and ws-fallback path.
template<typename T, int C, int COUT, bool WF>
__global__ __launch_bounds__(256) void k_edgeconv(const T* __restrict__ x, int bstride,
                           const int* __restrict__ idx,
                           const float* __restrict__ Wt,
                           const float* __restrict__ gam,
                           const float* __restrict__ bet,
                           bf16* __restrict__ out, int ostride,
                           bf16* __restrict__ featT, int c0f) {
    const int PT = 4;
    const int OT = COUT / 64;
    const int CP = (C + 3) & ~3;
    __shared__ float sh[PT][KNN + 1][CP];

    int ib = blockIdx.x;
    int b  = ib / (N_PTS / PT);
    int n0 = (ib % (N_PTS / PT)) * PT;
    const T* xb = x + (size_t)b * bstride;

    const int TOT = PT * (KNN + 1) * C;
    for (int t = threadIdx.x; t < TOT; t += 256) {
        int pt = t / ((KNN + 1) * C);
        int r  = t % ((KNN + 1) * C);
        int row = r / C, c = r % C;
        int n = n0 + pt;
        int m = (row == 0) ? n
                           : (idx[((size_t)b * N_PTS + n) * KNN + (row - 1)] & (N_PTS - 1));
        sh[pt][row][c] = ldf(&xb[(size_t)c * N_PTS + m]);
    }
    __syncthreads();

    int w = threadIdx.x >> 6, lane = threadIdx.x & 63;
    int n = n0 + w;

    constexpr int KT = (OT >= 4) ? 10 : 20;
    constexpr int NPASS = KNN / KT;

    float base[OT];
    float mx[OT];
#pragma unroll
    for (int j = 0; j < OT; ++j) { base[j] = 0.f; mx[j] = -FLT_MAX; }

    const float inv = rsqrtf(1.0f + 1e-5f);

#pragma unroll
    for (int pass = 0; pass < NPASS; ++pass) {
        float acc[OT][KT];
#pragma unroll
        for (int j = 0; j < OT; ++j)
#pragma unroll
            for (int k = 0; k < KT; ++k) acc[j][k] = 0.f;

        for (int c = 0; c < C; ++c) {
            float xq = sh[w][0][c];
            float w2v[OT];
#pragma unroll
            for (int j = 0; j < OT; ++j)
                w2v[j] = Wt[(size_t)(C + c) * COUT + lane + 64 * j];
            if (pass == 0) {
#pragma unroll
                for (int j = 0; j < OT; ++j) {
                    float w1v = Wt[(size_t)c * COUT + lane + 64 * j];
                    base[j] = fmaf(w1v - w2v[j], xq, base[j]);
                }
            }
#pragma unroll
            for (int k = 0; k < KT; ++k) {
                float nv = sh[w][1 + pass * KT + k][c];
#pragma unroll
                for (int j = 0; j < OT; ++j) acc[j][k] = fmaf(w2v[j], nv, acc[j][k]);
            }
        }

#pragma unroll
        for (int j = 0; j < OT; ++j) {
            int o = lane + 64 * j;
            float scale = gam[o] * inv, bias = bet[o];
#pragma unroll
            for (int k = 0; k < KT; ++k) {
                float h = (base[j] + acc[j][k]) * scale + bias;
                h = h > 0.f ? h : LRELU_S * h;
                mx[j] = fmaxf(mx[j], h);
            }
        }
    }

#pragma unroll
    for (int j = 0; j < OT; ++j) {
        int o = lane + 64 * j;
        bf16 bv = __float2bfloat16(mx[j]);
        out[(size_t)b * ostride + (size_t)o * N_PTS + n] = bv;
        if (WF) featT[((size_t)b * N_PTS + n) * FT + c0f + o] = bv;
    }
}

// ---------------------------------------------------------------------------
// conv5 via MFMA: Y (1024 x 2048/batch) = W5(hi/lo) x featT^T, fused BN +
// LReLU + max/sum pooling over the n-tile. Block: 64o x 256n, 4 waves split n.
__global__ __launch_bounds__(256) void k_conv5mfma(
        const bf16* __restrict__ featT, const bf16* __restrict__ w5sp,
        const float* __restrict__ g5, const float* __restrict__ b5,
        float* __restrict__ fmxp, float* __restrict__ fsmp) {
    __shared__ float rmx[4][64];
    __shared__ float rsm[4][64];

    int ib = blockIdx.x;                 // B * 16 * 8
    int b  = ib / 128;
    int rem = ib % 128;
    int o0 = (rem >> 3) * 64;
    int nt = rem & 7;
    int tid = threadIdx.x;
    int w = tid >> 6, lane = tid & 63;
    int l15 = lane & 15, quad = lane >> 4;
    int nbase = nt * 256 + w * 64;

    const bf16* Whi = w5sp;
    const bf16* Wlo = w5sp + 1024 * 512;
    const bf16* fb  = featT + (size_t)b * N_PTS * FT;

    floatx4 acc[4][4];
#pragma unroll
    for (int mi = 0; mi < 4; ++mi)
#pragma unroll
        for (int ni = 0; ni < 4; ++ni) acc[mi][ni] = (floatx4){0.f, 0.f, 0.f, 0.f};

    for (int kk = 0; kk < 512; kk += 32) {
        short8v bfr[4];
#pragma unroll
        for (int ni = 0; ni < 4; ++ni)
            bfr[ni] = ld8(fb + (size_t)(nbase + ni * 16 + l15) * FT + kk + quad * 8);
#pragma unroll
        for (int mi = 0; mi < 4; ++mi) {
            size_t ar = (size_t)(o0 + mi * 16 + l15) * 512 + kk + quad * 8;
            short8v ah = ld8(Whi + ar);
            short8v al = ld8(Wlo + ar);
#pragma unroll
            for (int ni = 0; ni < 4; ++ni) {
                acc[mi][ni] = __builtin_amdgcn_mfma_f32_16x16x32_bf16(ah, bfr[ni], acc[mi][ni], 0, 0, 0);
                acc[mi][ni] = __builtin_amdgcn_mfma_f32_16x16x32_bf16(al, bfr[ni], acc[mi][ni], 0, 0, 0);
            }
        }
    }

    const float inv = rsqrtf(1.0f + 1e-5f);
#pragma unroll
    for (int mi = 0; mi < 4; ++mi) {
#pragma unroll
        for (int r = 0; r < 4; ++r) {
            int o = o0 + mi * 16 + quad * 4 + r;
            float scale = g5[o] * inv, bias = b5[o];
            float mx = -FLT_MAX, sm = 0.f;
#pragma unroll
            for (int ni = 0; ni < 4; ++ni) {
                float h = acc[mi][ni][r] * scale + bias;
                h = h > 0.f ? h : LRELU_S * h;
                mx = fmaxf(mx, h);
                sm += h;
            }
#pragma unroll
            for (int off = 1; off <= 8; off <<= 1) {
                mx = fmaxf(mx, __shfl_xor(mx, off));
                sm += __shfl_xor(sm, off);
            }
            if (l15 == 0) {
                rmx[w][mi * 16 + quad * 4 + r] = mx;
                rsm[w][mi * 16 + quad * 4 + r] = sm;
            }
        }
    }
    __syncthreads();
    if (tid < 64) {
        float mx = -FLT_MAX, sm = 0.f;
#pragma unroll
        for (int ww = 0; ww < 4; ++ww) { mx = fmaxf(mx, rmx[ww][tid]); sm += rsm[ww][tid]; }
        fmxp[((size_t)b * 1024 + o0 + tid) * NPOOL + nt] = mx;
        fsmp[((size_t)b * 1024 + o0 + tid) * NPOOL + nt] = sm;
    }
}

// ---------------------------------------------------------------------------
// Pool partial reduce -> fvec (B, 2048) = [max(1024) | mean(1024)].
__global__ void k_pool(const float* __restrict__ fmxp, const float* __restrict__ fsmp,
                       float* __restrict__ fvec) {
    int i = blockIdx.x * blockDim.x + threadIdx.x;
    if (i >= B_SZ * 1024) return;
    int b = i >> 10, o = i & 1023;
    float mx = -FLT_MAX, sm = 0.f;
    for (int ch = 0; ch < NPOOL; ++ch) {
        mx = fmaxf(mx, fmxp[(size_t)i * NPOOL + ch]);
        sm += fsmp[(size_t)i * NPOOL + ch];
    }
    fvec[(size_t)b * 2048 + o] = mx;
    fvec[(size_t)b * 2048 + 1024 + o] = sm * (1.0f / N_PTS);
}

// ---------------------------------------------------------------------------
// fc1: block per (b,o): t[b,o] = lrelu(bn(fw1[o] . fvec[b] + fb1[o])).
__global__ __launch_bounds__(256) void k_fc1(const float* __restrict__ fvec,
        const float* __restrict__ fw1, const float* __restrict__ fb1,
        const float* __restrict__ g6,  const float* __restrict__ b6,
        float* __restrict__ tbuf) {
    __shared__ float red[4];
    int ib = blockIdx.x;
    int b = ib >> 9, o = ib & 511;
    const float* wr = fw1 + (size_t)o * 2048;
    const float* fv = fvec + (size_t)b * 2048;
    int tid = threadIdx.x;
    float s = 0.f;
    for (int j = tid; j < 2048; j += 256) s = fmaf(wr[j], fv[j], s);
#pragma unroll
    for (int off = 32; off >= 1; off >>= 1) s += __shfl_xor(s, off);
    if ((tid & 63) == 0) red[tid >> 6] = s;
    __syncthreads();
    if (tid == 0) {
        float acc = fb1[o] + red[0] + red[1] + red[2] + red[3];
        float h = acc * g6[o] * rsqrtf(1.0f + 1e-5f) + b6[o];
        tbuf[(size_t)b * 512 + o] = h > 0.f ? h : LRELU_S * h;
    }
}

// ---------------------------------------------------------------------------
// fc2: block per (b,o): out[b,o] = bn(fw2[o] . t[b] + fb2[o]).
__global__ __launch_bounds__(256) void k_fc2(const float* __restrict__ tbuf,
        const float* __restrict__ fw2, const float* __restrict__ fb2,
        const float* __restrict__ g7,  const float* __restrict__ b7,
        const int* __restrict__ flag, void* __restrict__ out) {
    __shared__ float red[4];
    int ib = blockIdx.x;
    int b = ib >> 8, o = ib & 255;
    const float* wr = fw2 + (size_t)o * 512;
    const float* tv = tbuf + (size_t)b * 512;
    int tid = threadIdx.x;
    float s = fmaf(wr[tid], tv[tid], wr[tid + 256] * tv[tid + 256]);
#pragma unroll
    for (int off = 32; off >= 1; off >>= 1) s += __shfl_xor(s, off);
    if ((tid & 63) == 0) red[tid >> 6] = s;
    __syncthreads();
    if (tid == 0) {
        float acc = fb2[o] + red[0] + red[1] + red[2] + red[3];
        float h = acc * g7[o] * rsqrtf(1.0f + 1e-5f) + b7[o];
        if (*flag) ((bf16*)out)[(size_t)b * 256 + o] = __float2bfloat16(h);
        else       ((float*)out)[(size_t)b * 256 + o] = h;
    }
}

// ---------------------------------------------------------------------------
// Fallback conv5 (VALU) + head, used when ws too small for the gram path.
#define NCH 2
__global__ __launch_bounds__(256) void k_conv5pool(const bf16* __restrict__ feat,
                            const float* __restrict__ w5,
                            const float* __restrict__ g5,
                            const float* __restrict__ b5,
                            float* __restrict__ fmxp, float* __restrict__ fsmp) {
    const int OT = 8;
    const int NT = 4;
    const int CHN = N_PTS / NCH;
    __shared__ float wl[OT][512];
    __shared__ float rmx[4][OT];
    __shared__ float rsm[4][OT];

    int ib = blockIdx.x;
    int ch = ib % NCH;
    int ot = (ib / NCH) % (1024 / OT);
    int b  = ib / (NCH * (1024 / OT));
    int o0 = ot * OT;
    const bf16* fb = feat + (size_t)b * 512 * N_PTS;

    for (int t = threadIdx.x; t < OT * 512; t += 256) {
        int o = t >> 9, c = t & 511;
        wl[o][c] = w5[(size_t)(o0 + o) * 512 + c];
    }
    __syncthreads();

    const int n0 = ch * CHN + threadIdx.x * NT;

    float acc[OT][NT];
#pragma unroll
    for (int o = 0; o < OT; ++o)
#pragma unroll
        for (int t = 0; t < NT; ++t) acc[o][t] = 0.f;

    for (int c = 0; c < 512; c += 4) {
        float fv[4][NT];
#pragma unroll
        for (int j = 0; j < 4; ++j) {
            uint2 u = *(const uint2*)(fb + (size_t)(c + j) * N_PTS + n0);
            fv[j][0] = __uint_as_float(u.x << 16);
            fv[j][1] = __uint_as_float(u.x & 0xFFFF0000u);
            fv[j][2] = __uint_as_float(u.y << 16);
            fv[j][3] = __uint_as_float(u.y & 0xFFFF0000u);
        }
#pragma unroll
        for (int o = 0; o < OT; ++o) {
            float4 wv = *(const float4*)&wl[o][c];
#pragma unroll
            for (int t = 0; t < NT; ++t) {
                acc[o][t] = fmaf(wv.x, fv[0][t], acc[o][t]);
                acc[o][t] = fmaf(wv.y, fv[1][t], acc[o][t]);
                acc[o][t] = fmaf(wv.z, fv[2][t], acc[o][t]);
                acc[o][t] = fmaf(wv.w, fv[3][t], acc[o][t]);
            }
        }
    }

    const float inv = rsqrtf(1.0f + 1e-5f);
    int w = threadIdx.x >> 6, lane = threadIdx.x & 63;
#pragma unroll
    for (int o = 0; o < OT; ++o) {
        float scale = g5[o0 + o] * inv, bias = b5[o0 + o];
        float mx = -FLT_MAX, sm = 0.f;
#pragma unroll
        for (int t = 0; t < NT; ++t) {
            float h = acc[o][t] * scale + bias;
            h = h > 0.f ? h : LRELU_S * h;
            mx = fmaxf(mx, h);
            sm += h;
        }
#pragma unroll
        for (int off = 32; off >= 1; off >>= 1) {
            mx = fmaxf(mx, __shfl_xor(mx, off));
            sm += __shfl_xor(sm, off);
        }
        if (lane == 0) { rmx[w][o] = mx; rsm[w][o] = sm; }
    }
    __syncthreads();
    if (threadIdx.x < OT) {
        int o = threadIdx.x;
        float mx = -FLT_MAX, sm = 0.f;
#pragma unroll
        for (int ww = 0; ww < 4; ++ww) { mx = fmaxf(mx, rmx[ww][o]); sm += rsm[ww][o]; }
        fmxp[((size_t)b * 1024 + o0 + o) * NCH + ch] = mx;
        fsmp[((size_t)b * 1024 + o0 + o) * NCH + ch] = sm;
    }
}

__global__ void k_head(const float* __restrict__ fmxp, const float* __restrict__ fsmp,
                       const float* __restrict__ fw1, const float* __restrict__ fb1,
                       const float* __restrict__ g6,  const float* __restrict__ b6,
                       const float* __restrict__ fw2, const float* __restrict__ fb2,
                       const float* __restrict__ g7,  const float* __restrict__ b7,
                       const int* __restrict__ flag, void* __restrict__ out) {
    __shared__ float f[2048];
    __shared__ float t[512];
    int b = blockIdx.x;
    for (int i = threadIdx.x; i < 1024; i += 256) {
        float mx = -FLT_MAX, sm = 0.f;
        for (int ch = 0; ch < NCH; ++ch) {
            mx = fmaxf(mx, fmxp[((size_t)b * 1024 + i) * NCH + ch]);
            sm += fsmp[((size_t)b * 1024 + i) * NCH + ch];
        }
        f[i]        = mx;
        f[1024 + i] = sm * (1.0f / N_PTS);
    }
    __syncthreads();
    const float inv = rsqrtf(1.0f + 1e-5f);
    for (int o = threadIdx.x; o < 512; o += 256) {
        const float* wr = fw1 + (size_t)o * 2048;
        float acc = fb1[o];
        for (int j = 0; j < 2048; ++j) acc += wr[j] * f[j];
        float h = acc * g6[o] * inv + b6[o];
        t[o] = h > 0.f ? h : LRELU_S * h;
    }
    __syncthreads();
    {
        int o = threadIdx.x;
        const float* wr = fw2 + (size_t)o * 512;
        float acc = fb2[o];
        for (int j = 0; j < 512; ++j) acc += wr[j] * t[j];
        float h = acc * g7[o] * inv + b7[o];
        if (*flag) ((bf16*)out)[(size_t)b * 256 + o] = __float2bfloat16(h);
        else       ((float*)out)[(size_t)b * 256 + o] = h;
    }
}

// ---------------------------------------------------------------------------
extern "C" void kernel_launch(void* const* d_in, const int* in_sizes, int n_in,
                              void* d_out, int out_size, void* d_ws, size_t ws_size,
                              hipStream_t stream) {
    static const int wsz[23] = {
        384, 64, 64,   8192, 64, 64,   16384, 128, 128,   65536, 256, 256,
        524288, 1024, 1024,   1048576, 512,   512, 512,   131072, 256,   256, 256
    };
    static const int trows[23] = {64,0,0, 64,0,0, 128,0,0, 256,0,0, 0,0,0, 0,0, 0,0, 0,0, 0,0};
    static const int tcols[23] = { 6,0,0,128,0,0, 128,0,0, 256,0,0, 0,0,0, 0,0, 0,0, 0,0, 0,0};

    WPack wp;
    int total = 0;
    for (int i = 0; i < 23; ++i) {
        wp.src[i] = d_in[i + 1]; wp.off[i] = total; total += wsz[i];
        wp.rows[i] = trows[i]; wp.cols[i] = tcols[i];
    }
    wp.off[23] = total;

    const size_t flag_bytes = 16;
    const size_t x0_bytes   = (size_t)B_SZ * 3 * N_PTS * 4;
    const size_t feat_bytes = (size_t)B_SZ * 512 * N_PTS * 2;
    const size_t idx_bytes  = (size_t)B_SZ * N_PTS * KNN * 4;
    const size_t pool_bytes = (size_t)B_SZ * 1024 * 4 * 2;
    const size_t wf_bytes   = (size_t)total * 4;
    const size_t base_need  = flag_bytes + x0_bytes + feat_bytes + idx_bytes + pool_bytes + wf_bytes;

    const size_t featT_bytes = (size_t)B_SZ * N_PTS * FT * 2;           //  8 MB
    const size_t xx_bytes    = (size_t)B_SZ * N_PTS * 4;
    const size_t wsp2_elems  = 4 * 64 * 64;
    const size_t wsp3_elems  = 4 * 128 * 64;
    const size_t wsp4_elems  = 4 * 256 * 128;
    const size_t w5sp_elems  = 2 * 1024 * 512;
    const size_t wsp_bytes   = (wsp2_elems + wsp3_elems + wsp4_elems + w5sp_elems) * 2;
    const size_t S_bytes     = (size_t)B_SZ * N_PTS * N_PTS * 4;        // 64 MB
    const size_t full_need   = base_need + featT_bytes + xx_bytes + wsp_bytes + S_bytes;

    if (ws_size < base_need) return;   // graceful fail
    const bool use_gram = (ws_size >= full_need);

    char* w = (char*)d_ws;
    int*   flag = (int*)w;              w += flag_bytes;
    float* x0   = (float*)w;            w += x0_bytes;
    bf16*  feat = (bf16*)w;             w += feat_bytes;
    int*   idx  = (int*)w;              w += idx_bytes;
    w += pool_bytes;
    float* wf   = (float*)w;            w += wf_bytes;
    bf16*  featT = (bf16*)w;            w += featT_bytes;
    float* xx    = (float*)w;           w += xx_bytes;
    bf16*  wsp2  = (bf16*)w;            w += wsp2_elems * 2;
    bf16*  wsp3  = (bf16*)w;            w += wsp3_elems * 2;
    bf16*  wsp4  = (bf16*)w;            w += wsp4_elems * 2;
    bf16*  w5sp  = (bf16*)w;            w += w5sp_elems * 2;
    float* S     = (float*)w;

    // overlays in the idx region (idx dead after ec4):
    float* fmxp = (float*)idx;                               // B*1024*NPOOL
    float* fsmp = fmxp + (size_t)B_SZ * 1024 * NPOOL;        // B*1024*NPOOL
    float* fvec = fsmp + (size_t)B_SZ * 1024 * NPOOL;        // B*2048
    float* tbuf = fvec + (size_t)B_SZ * 2048;                // B*512

    const int FBS = 512 * N_PTS;

    k_sniff<<<1, 64, 0, stream>>>((const unsigned short*)d_in[0], flag);
    k_repack<<<256, 256, 0, stream>>>(wp, flag, wf, total);
    k_transpose<<<(B_SZ * N_PTS + 255) / 256, 256, 0, stream>>>(d_in[0], flag, x0);

    const float* w1t = wf + wp.off[0],  *g1 = wf + wp.off[1],  *b1 = wf + wp.off[2];
    const float* w2t = wf + wp.off[3],  *g2 = wf + wp.off[4],  *b2 = wf + wp.off[5];
    const float* w3t = wf + wp.off[6],  *g3 = wf + wp.off[7],  *b3 = wf + wp.off[8];
    const float* w4t = wf + wp.off[9],  *g4 = wf + wp.off[10], *b4 = wf + wp.off[11];
    const float* w5  = wf + wp.off[12], *g5 = wf + wp.off[13], *b5 = wf + wp.off[14];
    const float* fw1 = wf + wp.off[15], *fb1 = wf + wp.off[16];
    const float* g6  = wf + wp.off[17], *b6 = wf + wp.off[18];
    const float* fw2 = wf + wp.off[19], *fb2 = wf + wp.off[20];
    const float* g7  = wf + wp.off[21], *b7 = wf + wp.off[22];

    const int GK = B_SZ * N_PTS / 4;   // 2048 blocks
    const int NXX = (B_SZ * N_PTS + 255) / 256;

    k_knn<float, 3><<<GK, 256, 0, stream>>>(x0, 3 * N_PTS, idx);
    if (use_gram) {
        k_wsplit<64, 64><<<(64 * 64 + 255) / 256, 256, 0, stream>>>(d_in[4], flag, wsp2);
        k_wsplit<64, 128><<<(128 * 64 + 255) / 256, 256, 0, stream>>>(d_in[7], flag, wsp3);
        k_wsplit<128, 256><<<(256 * 128 + 255) / 256, 256, 0, stream>>>(d_in[10], flag, wsp4);
        k_w5split<<<(1024 * 512 + 255) / 256, 256, 0, stream>>>(d_in[13], flag, w5sp);

        k_edgeconv<float, 3, 64, true><<<GK, 256, 0, stream>>>(
            x0, 3 * N_PTS, idx, w1t, g1, b1, feat + 0 * N_PTS, FBS, featT, 0);
        // layer 2
        k_xx<64><<<NXX, 256, 0, stream>>>(featT, 0, xx);
        k_gram<64><<<B_SZ * 256, 256, 0, stream>>>(featT, 0, S);
        k_select<<<GK, 256, 0, stream>>>(S, xx, idx);
        k_ecmfma<64, 64><<<GK, 256, 0, stream>>>(idx, featT, 0, wsp2, g2, b2,
                                                 feat + 64 * N_PTS, FBS, featT, 64, 1);
        // layer 3
        k_xx<64><<<NXX, 256, 0, stream>>>(featT, 64, xx);
        k_gram<64><<<B_SZ * 256, 256, 0, stream>>>(featT, 64, S);
        k_select<<<GK, 256, 0, stream>>>(S, xx, idx);
        k_ecmfma<64, 128><<<GK, 256, 0, stream>>>(idx, featT, 64, wsp3, g3, b3,
                                                  feat + 128 * N_PTS, FBS, featT, 128, 1);
        // layer 4 (writes featT channels [256,512) for conv5)
        k_xx<128><<<NXX, 256, 0, stream>>>(featT, 128, xx);
        k_gram<128><<<B_SZ * 256, 256, 0, stream>>>(featT, 128, S);
        k_select<<<GK, 256, 0, stream>>>(S, xx, idx);
        k_ecmfma<128, 256><<<GK, 256, 0, stream>>>(idx, featT, 128, wsp4, g4, b4,
                                                   feat + 256 * N_PTS, FBS, featT, 256, 1);

        // conv5 MFMA + pooling partials, then head GEMVs
        k_conv5mfma<<<B_SZ * 128, 256, 0, stream>>>(featT, w5sp, g5, b5, fmxp, fsmp);
        k_pool<<<(B_SZ * 1024 + 255) / 256, 256, 0, stream>>>(fmxp, fsmp, fvec);
        k_fc1<<<B_SZ * 512, 256, 0, stream>>>(fvec, fw1, fb1, g6, b6, tbuf);
        k_fc2<<<B_SZ * 256, 256, 0, stream>>>(tbuf, fw2, fb2, g7, b7, flag, d_out);
    } else {
        k_edgeconv<float, 3, 64, false><<<GK, 256, 0, stream>>>(
            x0, 3 * N_PTS, idx, w1t, g1, b1, feat + 0 * N_PTS, FBS, nullptr, 0);
        k_knn<bf16, 64><<<GK, 256, 0, stream>>>(feat + 0 * N_PTS, FBS, idx);
        k_edgeconv<bf16, 64, 64, false><<<GK, 256, 0, stream>>>(
            feat + 0 * N_PTS, FBS, idx, w2t, g2, b2, feat + 64 * N_PTS, FBS, nullptr, 0);
        k_knn<bf16, 64><<<GK, 256, 0, stream>>>(feat + 64 * N_PTS, FBS, idx);
        k_edgeconv<bf16, 64, 128, false><<<GK, 256, 0, stream>>>(
            feat + 64 * N_PTS, FBS, idx, w3t, g3, b3, feat + 128 * N_PTS, FBS, nullptr, 0);
        k_knn<bf16, 128><<<GK, 256, 0, stream>>>(feat + 128 * N_PTS, FBS, idx);
        k_edgeconv<bf16, 128, 256, false><<<GK, 256, 0, stream>>>(
            feat + 128 * N_PTS, FBS, idx, w4t, g4, b4, feat + 256 * N_PTS, FBS, nullptr, 0);

        k_conv5pool<<<B_SZ * (1024 / 8) * NCH, 256, 0, stream>>>(feat, w5, g5, b5, fmxp, fsmp);
        k_head<<<B_SZ, 256, 0, stream>>>(fmxp, fsmp, fw1, fb1, g6, b6, fw2, fb2, g7, b7,
                                         flag, d_out);
    }
}

// Round 10
// 616.065 us; speedup vs baseline: 6.2442x; 1.0922x over previous
//
#include <hip/hip_runtime.h>
#include <hip/hip_bf16.h>
#include <float.h>

#define N_PTS 2048
#define B_SZ  4
#define KNN   20
#define LRELU_S 0.2f
#define FT    512          // featT row stride (channels)
#define NPOOL 8            // conv5 n-chunk partials

typedef __hip_bfloat16 bf16;
typedef __attribute__((ext_vector_type(8))) short short8v;   // 8 bf16 (4 VGPRs)
typedef __attribute__((ext_vector_type(4))) float floatx4;

__device__ __forceinline__ float b2f(const bf16 v) { return __bfloat162float(v); }
__device__ __forceinline__ float ldf(const float* p) { return *p; }
__device__ __forceinline__ float ldf(const bf16* p)  { return __bfloat162float(*p); }
__device__ __forceinline__ short8v ld8(const bf16* p) { return *(const short8v*)p; }

// ---------------------------------------------------------------------------
// Dtype sniffer (robustness): bf16 (flag=1) vs fp32 (flag=0). Reads 256 B.
__global__ void k_sniff(const unsigned short* __restrict__ pts_hw, int* __restrict__ flag) {
    if (threadIdx.x != 0 || blockIdx.x != 0) return;
    int sane = 0;
    for (int j = 0; j < 64; ++j) {
        unsigned short v = pts_hw[2 * j];
        int e = (v >> 7) & 0xFF;
        if (e >= 100 && e <= 140) ++sane;
    }
    *flag = (sane >= 32) ? 1 : 0;
}

// ---------------------------------------------------------------------------
// Repack 23 weight tensors to fp32; EdgeConv W tensors stored TRANSPOSED.
struct WPack {
    const void* src[23];
    int off[24];
    int rows[23];
    int cols[23];
};

__global__ void k_repack(WPack wp, const int* __restrict__ flag, float* __restrict__ dst, int total) {
    const int isb = *flag;
    for (int i = blockIdx.x * blockDim.x + threadIdx.x; i < total; i += gridDim.x * blockDim.x) {
        int lo = 0, hi = 23;
        while (lo + 1 < hi) { int mid = (lo + hi) >> 1; if (i >= wp.off[mid]) lo = mid; else hi = mid; }
        int j = i - wp.off[lo];
        float v = isb ? b2f(((const bf16*)wp.src[lo])[j]) : ((const float*)wp.src[lo])[j];
        int dj = j;
        int cols = wp.cols[lo];
        if (cols) dj = (j % cols) * wp.rows[lo] + (j / cols);
        dst[wp.off[lo] + dj] = v;
    }
}

// ---------------------------------------------------------------------------
// Split EdgeConv weights into bf16 hi/lo pairs for MFMA:
// dst = [W2hi | W2lo | Wdhi | Wdlo], each (COUT, C) row-major, Wd = W1 - W2.
template<int C, int COUT>
__global__ void k_wsplit(const void* __restrict__ W, const int* __restrict__ flag,
                         bf16* __restrict__ dst) {
    int i = blockIdx.x * blockDim.x + threadIdx.x;
    if (i >= COUT * C) return;
    int o = i / C, c = i % C;
    const int isb = *flag;
    float w1 = isb ? b2f(((const bf16*)W)[(size_t)o * 2 * C + c])
                   : ((const float*)W)[(size_t)o * 2 * C + c];
    float w2 = isb ? b2f(((const bf16*)W)[(size_t)o * 2 * C + C + c])
                   : ((const float*)W)[(size_t)o * 2 * C + C + c];
    float wd = w1 - w2;
    bf16 h2 = __float2bfloat16(w2);
    bf16 hd = __float2bfloat16(wd);
    dst[i]                = h2;
    dst[COUT * C + i]     = __float2bfloat16(w2 - b2f(h2));
    dst[2 * COUT * C + i] = hd;
    dst[3 * COUT * C + i] = __float2bfloat16(wd - b2f(hd));
}

// ---------------------------------------------------------------------------
// Split conv5 weights (1024x512) into bf16 hi/lo: dst = [hi | lo].
__global__ void k_w5split(const void* __restrict__ W, const int* __restrict__ flag,
                          bf16* __restrict__ dst) {
    int i = blockIdx.x * blockDim.x + threadIdx.x;
    if (i >= 1024 * 512) return;
    const int isb = *flag;
    float w = isb ? b2f(((const bf16*)W)[i]) : ((const float*)W)[i];
    bf16 h = __float2bfloat16(w);
    dst[i] = h;
    dst[1024 * 512 + i] = __float2bfloat16(w - b2f(h));
}

// ---------------------------------------------------------------------------
// points (B,N,3) -> x0 (B,3,N) fp32, dtype-dynamic.
__global__ void k_transpose(const void* __restrict__ pts, const int* __restrict__ flag,
                            float* __restrict__ x0) {
    const int isb = *flag;
    int i = blockIdx.x * blockDim.x + threadIdx.x;
    if (i >= B_SZ * N_PTS) return;
    int b = i / N_PTS, n = i % N_PTS;
    for (int c = 0; c < 3; ++c) {
        size_t s = ((size_t)b * N_PTS + n) * 3 + c;
        float v = isb ? b2f(((const bf16*)pts)[s]) : ((const float*)pts)[s];
        x0[((size_t)b * 3 + c) * N_PTS + n] = v;
    }
}

// ---------------------------------------------------------------------------
// 32-candidate row loads (lane chunk), fp32 out. (Used by fallback kNN.)
__device__ __forceinline__ void load32(const float* row, int mbase, float* r) {
    const float4* p = (const float4*)(row + mbase);
#pragma unroll
    for (int i = 0; i < 8; ++i) {
        float4 f = p[i];
        r[4 * i + 0] = f.x; r[4 * i + 1] = f.y; r[4 * i + 2] = f.z; r[4 * i + 3] = f.w;
    }
}
__device__ __forceinline__ void load32(const bf16* row, int mbase, float* r) {
    const uint4* p = (const uint4*)(row + mbase);
#pragma unroll
    for (int i = 0; i < 4; ++i) {
        uint4 u = p[i];
        r[8 * i + 0] = __uint_as_float(u.x << 16);
        r[8 * i + 1] = __uint_as_float(u.x & 0xFFFF0000u);
        r[8 * i + 2] = __uint_as_float(u.y << 16);
        r[8 * i + 3] = __uint_as_float(u.y & 0xFFFF0000u);
        r[8 * i + 4] = __uint_as_float(u.z << 16);
        r[8 * i + 5] = __uint_as_float(u.z & 0xFFFF0000u);
        r[8 * i + 6] = __uint_as_float(u.w << 16);
        r[8 * i + 7] = __uint_as_float(u.w & 0xFFFF0000u);
    }
}

// ---------------------------------------------------------------------------
// kNN (direct): wave-per-query; used for layer 1 (C=3) and as ws fallback.
template<typename T, int C>
__global__ __launch_bounds__(256) void k_knn(const T* __restrict__ x, int bstride,
                                             int* __restrict__ idx) {
    __shared__ float qf[4][C];
    int ib = blockIdx.x;
    int b  = ib / (N_PTS / 4);
    int q0 = (ib % (N_PTS / 4)) * 4;
    const T* xb = x + (size_t)b * bstride;

    for (int t = threadIdx.x; t < 4 * C; t += 256) {
        int pt = t / C, c = t % C;
        qf[pt][c] = ldf(&xb[(size_t)c * N_PTS + (q0 + pt)]);
    }
    __syncthreads();

    int w = threadIdx.x >> 6, lane = threadIdx.x & 63;
    int q = q0 + w;
    int mbase = lane * 32;

    float v[32];
#pragma unroll
    for (int j = 0; j < 32; ++j) v[j] = 0.f;

    for (int c = 0; c < C; ++c) {
        float qc = qf[w][c];
        float r[32];
        load32(xb + (size_t)c * N_PTS, mbase, r);
#pragma unroll
        for (int j = 0; j < 32; ++j) { float t = r[j] - qc; v[j] = fmaf(t, t, v[j]); }
    }

    for (int k = 0; k < KNN; ++k) {
        float bv = FLT_MAX; int bi = 0x7FFFFFFF;
#pragma unroll
        for (int j = 0; j < 32; ++j)
            if (v[j] < bv) { bv = v[j]; bi = mbase + j; }
#pragma unroll
        for (int off = 32; off >= 1; off >>= 1) {
            float ov = __shfl_xor(bv, off);
            int   oi = __shfl_xor(bi, off);
            if (ov < bv || (ov == bv && oi < bi)) { bv = ov; bi = oi; }
        }
        if (lane == 0) idx[((size_t)b * N_PTS + q) * KNN + k] = bi;
        int wl = bi >> 5, wj = bi & 31;
        if (lane == wl) {
#pragma unroll
            for (int j = 0; j < 32; ++j) if (j == wj) v[j] = FLT_MAX;
        }
    }
}

// ---------------------------------------------------------------------------
// Candidate squared norms over a channel slice.
template<int C>
__global__ void k_xx(const bf16* __restrict__ featT, int c0, float* __restrict__ xx) {
    int i = blockIdx.x * blockDim.x + threadIdx.x;
    if (i >= B_SZ * N_PTS) return;
    const bf16* row = featT + (size_t)i * FT + c0;
    float s = 0.f;
    for (int c = 0; c < C; c += 8) {
        uint4 u = *(const uint4*)(row + c);
        float v0 = __uint_as_float(u.x << 16), v1 = __uint_as_float(u.x & 0xFFFF0000u);
        float v2 = __uint_as_float(u.y << 16), v3 = __uint_as_float(u.y & 0xFFFF0000u);
        float v4 = __uint_as_float(u.z << 16), v5 = __uint_as_float(u.z & 0xFFFF0000u);
        float v6 = __uint_as_float(u.w << 16), v7 = __uint_as_float(u.w & 0xFFFF0000u);
        s = fmaf(v0, v0, s); s = fmaf(v1, v1, s); s = fmaf(v2, v2, s); s = fmaf(v3, v3, s);
        s = fmaf(v4, v4, s); s = fmaf(v5, v5, s); s = fmaf(v6, v6, s); s = fmaf(v7, v7, s);
    }
    xx[i] = s;
}

// ---------------------------------------------------------------------------
// Gram matrix via MFMA: G[b][n][m] = sum_c X[c][n]*X[c][m], X = featT slice.
template<int C>
__global__ __launch_bounds__(256) void k_gram(const bf16* __restrict__ featT, int c0,
                                              float* __restrict__ G) {
    const int KC = 64;
    __shared__ __align__(16) short At[128 * 72];
    __shared__ __align__(16) short Bt[128 * 72];

    int ib = blockIdx.x;
    int b  = ib >> 8;
    int t  = ib & 255;
    int n0 = (t >> 4) << 7;
    int m0 = (t & 15) << 7;

    int tid = threadIdx.x;
    int w = tid >> 6, lane = tid & 63;
    int rw = (w & 1) * 64, cw = (w >> 1) * 64;
    int lrow = lane & 15, quad = lane >> 4;

    floatx4 acc[4][4];
#pragma unroll
    for (int ri = 0; ri < 4; ++ri)
#pragma unroll
        for (int ci = 0; ci < 4; ++ci) acc[ri][ci] = (floatx4){0.f, 0.f, 0.f, 0.f};

    for (int ck = 0; ck < C; ck += KC) {
        __syncthreads();
        for (int s = tid; s < 1024; s += 256) {
            int row = s >> 3, g = s & 7;
            *(uint4*)&At[row * 72 + g * 8] =
                *(const uint4*)(featT + ((size_t)(b * N_PTS + n0 + row) * FT) + c0 + ck + g * 8);
            *(uint4*)&Bt[row * 72 + g * 8] =
                *(const uint4*)(featT + ((size_t)(b * N_PTS + m0 + row) * FT) + c0 + ck + g * 8);
        }
        __syncthreads();
#pragma unroll
        for (int kk = 0; kk < KC; kk += 32) {
            short8v a[4], bb[4];
#pragma unroll
            for (int ri = 0; ri < 4; ++ri)
                a[ri] = *(const short8v*)&At[(rw + ri * 16 + lrow) * 72 + kk + quad * 8];
#pragma unroll
            for (int ci = 0; ci < 4; ++ci)
                bb[ci] = *(const short8v*)&Bt[(cw + ci * 16 + lrow) * 72 + kk + quad * 8];
#pragma unroll
            for (int ri = 0; ri < 4; ++ri)
#pragma unroll
                for (int ci = 0; ci < 4; ++ci)
                    acc[ri][ci] = __builtin_amdgcn_mfma_f32_16x16x32_bf16(a[ri], bb[ci], acc[ri][ci], 0, 0, 0);
        }
    }

#pragma unroll
    for (int ri = 0; ri < 4; ++ri)
#pragma unroll
        for (int ci = 0; ci < 4; ++ci) {
            int n = n0 + rw + ri * 16 + quad * 4;
            int m = m0 + cw + ci * 16 + lrow;
            float* gp = G + ((size_t)b * N_PTS + n) * N_PTS + m;
#pragma unroll
            for (int reg = 0; reg < 4; ++reg)
                gp[(size_t)reg * N_PTS] = acc[ri][ci][reg];
        }
}

// ---------------------------------------------------------------------------
// Top-K selection on precomputed scores: score = xx[m] - 2*G[q][m].
__global__ __launch_bounds__(256) void k_select(const float* __restrict__ G,
                                                const float* __restrict__ xx,
                                                int* __restrict__ idx) {
    int ib = blockIdx.x;
    int b = ib >> 9;
    int q0 = (ib & 511) * 4;
    int w = threadIdx.x >> 6, lane = threadIdx.x & 63;
    int q = q0 + w;
    const float* grow = G + ((size_t)b * N_PTS + q) * N_PTS;
    const float* xrow = xx + (size_t)b * N_PTS;

    float v[32];
#pragma unroll
    for (int r = 0; r < 8; ++r) {
        float4 g4 = *(const float4*)(grow + r * 256 + (lane << 2));
        float4 x4 = *(const float4*)(xrow + r * 256 + (lane << 2));
        v[4 * r + 0] = fmaf(-2.f, g4.x, x4.x);
        v[4 * r + 1] = fmaf(-2.f, g4.y, x4.y);
        v[4 * r + 2] = fmaf(-2.f, g4.z, x4.z);
        v[4 * r + 3] = fmaf(-2.f, g4.w, x4.w);
    }

    for (int k = 0; k < KNN; ++k) {
        float bv = FLT_MAX; int bi = 0x7FFFFFFF;
#pragma unroll
        for (int j = 0; j < 32; ++j) {
            if (v[j] < bv) { bv = v[j]; bi = ((j >> 2) << 8) + (lane << 2) + (j & 3); }
        }
#pragma unroll
        for (int off = 32; off >= 1; off >>= 1) {
            float ov = __shfl_xor(bv, off);
            int   oi = __shfl_xor(bi, off);
            if (ov < bv || (ov == bv && oi < bi)) { bv = ov; bi = oi; }
        }
        if (lane == 0) idx[((size_t)b * N_PTS + q) * KNN + k] = bi;
        int wl = (bi >> 2) & 63;
        int jj = ((bi >> 8) << 2) | (bi & 3);
        if (lane == wl) {
#pragma unroll
            for (int j = 0; j < 32; ++j) if (j == jj) v[j] = FLT_MAX;
        }
    }
}

// ---------------------------------------------------------------------------
// Dense point transform via MFMA (EdgeConv linear part, all points at once):
// Y[i][0..COUT)      = W2 . x_i   (hi/lo split)
// Y[i][COUT..2COUT)  = Wd . x_i   (Wd = W1 - W2)
// i = b*N+n over all 8192 points; x_i = featT row slice [c0, c0+C).
// Block: 128 (M) x 128 (N) tile, 4 waves of 64x64; B staged in LDS (gram
// pattern), A (weights) ld8 direct from global (hot in L2, reused widely).
template<int COUT, int C>
__global__ __launch_bounds__(256) void k_xform(const bf16* __restrict__ featT, int c0,
                                               const bf16* __restrict__ Wsp,
                                               float* __restrict__ Y) {
    const int M2 = 2 * COUT;
    const int KC = 64;
    __shared__ __align__(16) short Bt[128 * 72];

    int ib = blockIdx.x;
    int nt = ib & 63;                    // 8192/128 n-tiles
    int mt = ib >> 6;                    // M2/128 m-tiles
    int tid = threadIdx.x;
    int w = tid >> 6, lane = tid & 63;
    int rw = (w & 1) * 64, cw = (w >> 1) * 64;
    int l15 = lane & 15, quad = lane >> 4;

    floatx4 acc[4][4];
#pragma unroll
    for (int ri = 0; ri < 4; ++ri)
#pragma unroll
        for (int ci = 0; ci < 4; ++ci) acc[ri][ci] = (floatx4){0.f, 0.f, 0.f, 0.f};

    for (int ck = 0; ck < C; ck += KC) {
        __syncthreads();
        for (int s = tid; s < 1024; s += 256) {
            int row = s >> 3, g = s & 7;
            *(uint4*)&Bt[row * 72 + g * 8] =
                *(const uint4*)(featT + (size_t)(nt * 128 + row) * FT + c0 + ck + g * 8);
        }
        __syncthreads();
#pragma unroll
        for (int kk = 0; kk < KC; kk += 32) {
            short8v bfr[4];
#pragma unroll
            for (int ci = 0; ci < 4; ++ci)
                bfr[ci] = *(const short8v*)&Bt[(cw + ci * 16 + l15) * 72 + kk + quad * 8];
#pragma unroll
            for (int ri = 0; ri < 4; ++ri) {
                int mrow = mt * 128 + rw + ri * 16 + l15;
                int base = (mrow < COUT) ? mrow : (mrow + COUT);   // W2 rows / Wd rows
                const bf16* hi = Wsp + (size_t)base * C + ck + kk + quad * 8;
                short8v ah = ld8(hi);
                short8v al = ld8(hi + (size_t)COUT * C);
#pragma unroll
                for (int ci = 0; ci < 4; ++ci) {
                    acc[ri][ci] = __builtin_amdgcn_mfma_f32_16x16x32_bf16(ah, bfr[ci], acc[ri][ci], 0, 0, 0);
                    acc[ri][ci] = __builtin_amdgcn_mfma_f32_16x16x32_bf16(al, bfr[ci], acc[ri][ci], 0, 0, 0);
                }
            }
        }
    }

#pragma unroll
    for (int ri = 0; ri < 4; ++ri)
#pragma unroll
        for (int ci = 0; ci < 4; ++ci) {
            int n = nt * 128 + cw + ci * 16 + l15;
            int m = mt * 128 + rw + ri * 16 + quad * 4;
            *(floatx4*)(Y + (size_t)n * M2 + m) = acc[ri][ci];
        }
}

// ---------------------------------------------------------------------------
// Gather-max epilogue: out[o][n] = max_k lrelu((Yd[n][o] + Y2[m_k][o])*s + b),
// m_k = idx[n][k]. One wave per point; coalesced fp32 row reads (L2-hot Y).
// Writes featT only (row-major bf16, coalesced).
template<int COUT>
__global__ __launch_bounds__(256) void k_gmax(const float* __restrict__ Y,
        const int* __restrict__ idx,
        const float* __restrict__ gam, const float* __restrict__ bet,
        bf16* __restrict__ featT, int c0f) {
    const int M2 = 2 * COUT;
    const int OT = COUT / 64;
    int i = blockIdx.x * 4 + (threadIdx.x >> 6);   // point index b*N+n
    int lane = threadIdx.x & 63;
    int b = i >> 11;

    const float inv = rsqrtf(1.0f + 1e-5f);
    float yd[OT], scale[OT], bias[OT], mx[OT];
#pragma unroll
    for (int j = 0; j < OT; ++j) {
        int o = lane + 64 * j;
        yd[j]    = Y[(size_t)i * M2 + COUT + o];
        scale[j] = gam[o] * inv;
        bias[j]  = bet[o];
        mx[j]    = -FLT_MAX;
    }

    const int* ip = idx + (size_t)i * KNN;
    const float* Yb = Y + ((size_t)b * N_PTS) * M2;
#pragma unroll 4
    for (int k = 0; k < KNN; ++k) {
        int m = ip[k] & (N_PTS - 1);
        const float* yr = Yb + (size_t)m * M2;
#pragma unroll
        for (int j = 0; j < OT; ++j) {
            float h = (yd[j] + yr[lane + 64 * j]) * scale[j] + bias[j];
            h = h > 0.f ? h : LRELU_S * h;
            mx[j] = fmaxf(mx[j], h);
        }
    }
#pragma unroll
    for (int j = 0; j < OT; ++j)
        featT[(size_t)i * FT + c0f + lane + 64 * j] = __float2bfloat16(mx[j]);
}

// ---------------------------------------------------------------------------
// EdgeConv (VALU): layer 1 (C=3) and ws-fallback path.
template<typename T, int C, int COUT, bool WF>
__global__ __launch_bounds__(256) void k_edgeconv(const T* __restrict__ x, int bstride,
                           const int* __restrict__ idx,
                           const float* __restrict__ Wt,
                           const float* __restrict__ gam,
                           const float* __restrict__ bet,
                           bf16* __restrict__ out, int ostride,
                           bf16* __restrict__ featT, int c0f) {
    const int PT = 4;
    const int OT = COUT / 64;
    const int CP = (C + 3) & ~3;
    __shared__ float sh[PT][KNN + 1][CP];

    int ib = blockIdx.x;
    int b  = ib / (N_PTS / PT);
    int n0 = (ib % (N_PTS / PT)) * PT;
    const T* xb = x + (size_t)b * bstride;

    const int TOT = PT * (KNN + 1) * C;
    for (int t = threadIdx.x; t < TOT; t += 256) {
        int pt = t / ((KNN + 1) * C);
        int r  = t % ((KNN + 1) * C);
        int row = r / C, c = r % C;
        int n = n0 + pt;
        int m = (row == 0) ? n
                           : (idx[((size_t)b * N_PTS + n) * KNN + (row - 1)] & (N_PTS - 1));
        sh[pt][row][c] = ldf(&xb[(size_t)c * N_PTS + m]);
    }
    __syncthreads();

    int w = threadIdx.x >> 6, lane = threadIdx.x & 63;
    int n = n0 + w;

    constexpr int KT = (OT >= 4) ? 10 : 20;
    constexpr int NPASS = KNN / KT;

    float base[OT];
    float mx[OT];
#pragma unroll
    for (int j = 0; j < OT; ++j) { base[j] = 0.f; mx[j] = -FLT_MAX; }

    const float inv = rsqrtf(1.0f + 1e-5f);

#pragma unroll
    for (int pass = 0; pass < NPASS; ++pass) {
        float acc[OT][KT];
#pragma unroll
        for (int j = 0; j < OT; ++j)
#pragma unroll
            for (int k = 0; k < KT; ++k) acc[j][k] = 0.f;

        for (int c = 0; c < C; ++c) {
            float xq = sh[w][0][c];
            float w2v[OT];
#pragma unroll
            for (int j = 0; j < OT; ++j)
                w2v[j] = Wt[(size_t)(C + c) * COUT + lane + 64 * j];
            if (pass == 0) {
#pragma unroll
                for (int j = 0; j < OT; ++j) {
                    float w1v = Wt[(size_t)c * COUT + lane + 64 * j];
                    base[j] = fmaf(w1v - w2v[j], xq, base[j]);
                }
            }
#pragma unroll
            for (int k = 0; k < KT; ++k) {
                float nv = sh[w][1 + pass * KT + k][c];
#pragma unroll
                for (int j = 0; j < OT; ++j) acc[j][k] = fmaf(w2v[j], nv, acc[j][k]);
            }
        }

#pragma unroll
        for (int j = 0; j < OT; ++j) {
            int o = lane + 64 * j;
            float scale = gam[o] * inv, bias = bet[o];
#pragma unroll
            for (int k = 0; k < KT; ++k) {
                float h = (base[j] + acc[j][k]) * scale + bias;
                h = h > 0.f ? h : LRELU_S * h;
                mx[j] = fmaxf(mx[j], h);
            }
        }
    }

#pragma unroll
    for (int j = 0; j < OT; ++j) {
        int o = lane + 64 * j;
        bf16 bv = __float2bfloat16(mx[j]);
        out[(size_t)b * ostride + (size_t)o * N_PTS + n] = bv;
        if (WF) featT[((size_t)b * N_PTS + n) * FT + c0f + o] = bv;
    }
}

// ---------------------------------------------------------------------------
// conv5 via MFMA: Y (1024 x 2048/batch) = W5(hi/lo) x featT^T, fused BN +
// LReLU + max/sum pooling over the n-tile. Block: 64o x 256n, 4 waves split n.
__global__ __launch_bounds__(256) void k_conv5mfma(
        const bf16* __restrict__ featT, const bf16* __restrict__ w5sp,
        const float* __restrict__ g5, const float* __restrict__ b5,
        float* __restrict__ fmxp, float* __restrict__ fsmp) {
    __shared__ float rmx[4][64];
    __shared__ float rsm[4][64];

    int ib = blockIdx.x;                 // B * 16 * 8
    int b  = ib / 128;
    int rem = ib % 128;
    int o0 = (rem >> 3) * 64;
    int nt = rem & 7;
    int tid = threadIdx.x;
    int w = tid >> 6, lane = tid & 63;
    int l15 = lane & 15, quad = lane >> 4;
    int nbase = nt * 256 + w * 64;

    const bf16* Whi = w5sp;
    const bf16* Wlo = w5sp + 1024 * 512;
    const bf16* fb  = featT + (size_t)b * N_PTS * FT;

    floatx4 acc[4][4];
#pragma unroll
    for (int mi = 0; mi < 4; ++mi)
#pragma unroll
        for (int ni = 0; ni < 4; ++ni) acc[mi][ni] = (floatx4){0.f, 0.f, 0.f, 0.f};

    for (int kk = 0; kk < 512; kk += 32) {
        short8v bfr[4];
#pragma unroll
        for (int ni = 0; ni < 4; ++ni)
            bfr[ni] = ld8(fb + (size_t)(nbase + ni * 16 + l15) * FT + kk + quad * 8);
#pragma unroll
        for (int mi = 0; mi < 4; ++mi) {
            size_t ar = (size_t)(o0 + mi * 16 + l15) * 512 + kk + quad * 8;
            short8v ah = ld8(Whi + ar);
            short8v al = ld8(Wlo + ar);
#pragma unroll
            for (int ni = 0; ni < 4; ++ni) {
                acc[mi][ni] = __builtin_amdgcn_mfma_f32_16x16x32_bf16(ah, bfr[ni], acc[mi][ni], 0, 0, 0);
                acc[mi][ni] = __builtin_amdgcn_mfma_f32_16x16x32_bf16(al, bfr[ni], acc[mi][ni], 0, 0, 0);
            }
        }
    }

    const float inv = rsqrtf(1.0f + 1e-5f);
#pragma unroll
    for (int mi = 0; mi < 4; ++mi) {
#pragma unroll
        for (int r = 0; r < 4; ++r) {
            int o = o0 + mi * 16 + quad * 4 + r;
            float scale = g5[o] * inv, bias = b5[o];
            float mx = -FLT_MAX, sm = 0.f;
#pragma unroll
            for (int ni = 0; ni < 4; ++ni) {
                float h = acc[mi][ni][r] * scale + bias;
                h = h > 0.f ? h : LRELU_S * h;
                mx = fmaxf(mx, h);
                sm += h;
            }
#pragma unroll
            for (int off = 1; off <= 8; off <<= 1) {
                mx = fmaxf(mx, __shfl_xor(mx, off));
                sm += __shfl_xor(sm, off);
            }
            if (l15 == 0) {
                rmx[w][mi * 16 + quad * 4 + r] = mx;
                rsm[w][mi * 16 + quad * 4 + r] = sm;
            }
        }
    }
    __syncthreads();
    if (tid < 64) {
        float mx = -FLT_MAX, sm = 0.f;
#pragma unroll
        for (int ww = 0; ww < 4; ++ww) { mx = fmaxf(mx, rmx[ww][tid]); sm += rsm[ww][tid]; }
        fmxp[((size_t)b * 1024 + o0 + tid) * NPOOL + nt] = mx;
        fsmp[((size_t)b * 1024 + o0 + tid) * NPOOL + nt] = sm;
    }
}

// ---------------------------------------------------------------------------
// Pool partial reduce -> fvec (B, 2048) = [max(1024) | mean(1024)].
__global__ void k_pool(const float* __restrict__ fmxp, const float* __restrict__ fsmp,
                       float* __restrict__ fvec) {
    int i = blockIdx.x * blockDim.x + threadIdx.x;
    if (i >= B_SZ * 1024) return;
    int b = i >> 10, o = i & 1023;
    float mx = -FLT_MAX, sm = 0.f;
    for (int ch = 0; ch < NPOOL; ++ch) {
        mx = fmaxf(mx, fmxp[(size_t)i * NPOOL + ch]);
        sm += fsmp[(size_t)i * NPOOL + ch];
    }
    fvec[(size_t)b * 2048 + o] = mx;
    fvec[(size_t)b * 2048 + 1024 + o] = sm * (1.0f / N_PTS);
}

// ---------------------------------------------------------------------------
// fc1: block per (b,o): t[b,o] = lrelu(bn(fw1[o] . fvec[b] + fb1[o])).
__global__ __launch_bounds__(256) void k_fc1(const float* __restrict__ fvec,
        const float* __restrict__ fw1, const float* __restrict__ fb1,
        const float* __restrict__ g6,  const float* __restrict__ b6,
        float* __restrict__ tbuf) {
    __shared__ float red[4];
    int ib = blockIdx.x;
    int b = ib >> 9, o = ib & 511;
    const float* wr = fw1 + (size_t)o * 2048;
    const float* fv = fvec + (size_t)b * 2048;
    int tid = threadIdx.x;
    float s = 0.f;
    for (int j = tid; j < 2048; j += 256) s = fmaf(wr[j], fv[j], s);
#pragma unroll
    for (int off = 32; off >= 1; off >>= 1) s += __shfl_xor(s, off);
    if ((tid & 63) == 0) red[tid >> 6] = s;
    __syncthreads();
    if (tid == 0) {
        float acc = fb1[o] + red[0] + red[1] + red[2] + red[3];
        float h = acc * g6[o] * rsqrtf(1.0f + 1e-5f) + b6[o];
        tbuf[(size_t)b * 512 + o] = h > 0.f ? h : LRELU_S * h;
    }
}

// ---------------------------------------------------------------------------
// fc2: block per (b,o): out[b,o] = bn(fw2[o] . t[b] + fb2[o]).
__global__ __launch_bounds__(256) void k_fc2(const float* __restrict__ tbuf,
        const float* __restrict__ fw2, const float* __restrict__ fb2,
        const float* __restrict__ g7,  const float* __restrict__ b7,
        const int* __restrict__ flag, void* __restrict__ out) {
    __shared__ float red[4];
    int ib = blockIdx.x;
    int b = ib >> 8, o = ib & 255;
    const float* wr = fw2 + (size_t)o * 512;
    const float* tv = tbuf + (size_t)b * 512;
    int tid = threadIdx.x;
    float s = fmaf(wr[tid], tv[tid], wr[tid + 256] * tv[tid + 256]);
#pragma unroll
    for (int off = 32; off >= 1; off >>= 1) s += __shfl_xor(s, off);
    if ((tid & 63) == 0) red[tid >> 6] = s;
    __syncthreads();
    if (tid == 0) {
        float acc = fb2[o] + red[0] + red[1] + red[2] + red[3];
        float h = acc * g7[o] * rsqrtf(1.0f + 1e-5f) + b7[o];
        if (*flag) ((bf16*)out)[(size_t)b * 256 + o] = __float2bfloat16(h);
        else       ((float*)out)[(size_t)b * 256 + o] = h;
    }
}

// ---------------------------------------------------------------------------
// Fallback conv5 (VALU) + head, used when ws too small for the gram path.
#define NCH 2
__global__ __launch_bounds__(256) void k_conv5pool(const bf16* __restrict__ feat,
                            const float* __restrict__ w5,
                            const float* __restrict__ g5,
                            const float* __restrict__ b5,
                            float* __restrict__ fmxp, float* __restrict__ fsmp) {
    const int OT = 8;
    const int NT = 4;
    const int CHN = N_PTS / NCH;
    __shared__ float wl[OT][512];
    __shared__ float rmx[4][OT];
    __shared__ float rsm[4][OT];

    int ib = blockIdx.x;
    int ch = ib % NCH;
    int ot = (ib / NCH) % (1024 / OT);
    int b  = ib / (NCH * (1024 / OT));
    int o0 = ot * OT;
    const bf16* fb = feat + (size_t)b * 512 * N_PTS;

    for (int t = threadIdx.x; t < OT * 512; t += 256) {
        int o = t >> 9, c = t & 511;
        wl[o][c] = w5[(size_t)(o0 + o) * 512 + c];
    }
    __syncthreads();

    const int n0 = ch * CHN + threadIdx.x * NT;

    float acc[OT][NT];
#pragma unroll
    for (int o = 0; o < OT; ++o)
#pragma unroll
        for (int t = 0; t < NT; ++t) acc[o][t] = 0.f;

    for (int c = 0; c < 512; c += 4) {
        float fv[4][NT];
#pragma unroll
        for (int j = 0; j < 4; ++j) {
            uint2 u = *(const uint2*)(fb + (size_t)(c + j) * N_PTS + n0);
            fv[j][0] = __uint_as_float(u.x << 16);
            fv[j][1] = __uint_as_float(u.x & 0xFFFF0000u);
            fv[j][2] = __uint_as_float(u.y << 16);
            fv[j][3] = __uint_as_float(u.y & 0xFFFF0000u);
        }
#pragma unroll
        for (int o = 0; o < OT; ++o) {
            float4 wv = *(const float4*)&wl[o][c];
#pragma unroll
            for (int t = 0; t < NT; ++t) {
                acc[o][t] = fmaf(wv.x, fv[0][t], acc[o][t]);
                acc[o][t] = fmaf(wv.y, fv[1][t], acc[o][t]);
                acc[o][t] = fmaf(wv.z, fv[2][t], acc[o][t]);
                acc[o][t] = fmaf(wv.w, fv[3][t], acc[o][t]);
            }
        }
    }

    const float inv = rsqrtf(1.0f + 1e-5f);
    int w = threadIdx.x >> 6, lane = threadIdx.x & 63;
#pragma unroll
    for (int o = 0; o < OT; ++o) {
        float scale = g5[o0 + o] * inv, bias = b5[o0 + o];
        float mx = -FLT_MAX, sm = 0.f;
#pragma unroll
        for (int t = 0; t < NT; ++t) {
            float h = acc[o][t] * scale + bias;
            h = h > 0.f ? h : LRELU_S * h;
            mx = fmaxf(mx, h);
            sm += h;
        }
#pragma unroll
        for (int off = 32; off >= 1; off >>= 1) {
            mx = fmaxf(mx, __shfl_xor(mx, off));
            sm += __shfl_xor(sm, off);
        }
        if (lane == 0) { rmx[w][o] = mx; rsm[w][o] = sm; }
    }
    __syncthreads();
    if (threadIdx.x < OT) {
        int o = threadIdx.x;
        float mx = -FLT_MAX, sm = 0.f;
#pragma unroll
        for (int ww = 0; ww < 4; ++ww) { mx = fmaxf(mx, rmx[ww][o]); sm += rsm[ww][o]; }
        fmxp[((size_t)b * 1024 + o0 + o) * NCH + ch] = mx;
        fsmp[((size_t)b * 1024 + o0 + o) * NCH + ch] = sm;
    }
}

__global__ void k_head(const float* __restrict__ fmxp, const float* __restrict__ fsmp,
                       const float* __restrict__ fw1, const float* __restrict__ fb1,
                       const float* __restrict__ g6,  const float* __restrict__ b6,
                       const float* __restrict__ fw2, const float* __restrict__ fb2,
                       const float* __restrict__ g7,  const float* __restrict__ b7,
                       const int* __restrict__ flag, void* __restrict__ out) {
    __shared__ float f[2048];
    __shared__ float t[512];
    int b = blockIdx.x;
    for (int i = threadIdx.x; i < 1024; i += 256) {
        float mx = -FLT_MAX, sm = 0.f;
        for (int ch = 0; ch < NCH; ++ch) {
            mx = fmaxf(mx, fmxp[((size_t)b * 1024 + i) * NCH + ch]);
            sm += fsmp[((size_t)b * 1024 + i) * NCH + ch];
        }
        f[i]        = mx;
        f[1024 + i] = sm * (1.0f / N_PTS);
    }
    __syncthreads();
    const float inv = rsqrtf(1.0f + 1e-5f);
    for (int o = threadIdx.x; o < 512; o += 256) {
        const float* wr = fw1 + (size_t)o * 2048;
        float acc = fb1[o];
        for (int j = 0; j < 2048; ++j) acc += wr[j] * f[j];
        float h = acc * g6[o] * inv + b6[o];
        t[o] = h > 0.f ? h : LRELU_S * h;
    }
    __syncthreads();
    {
        int o = threadIdx.x;
        const float* wr = fw2 + (size_t)o * 512;
        float acc = fb2[o];
        for (int j = 0; j < 512; ++j) acc += wr[j] * t[j];
        float h = acc * g7[o] * inv + b7[o];
        if (*flag) ((bf16*)out)[(size_t)b * 256 + o] = __float2bfloat16(h);
        else       ((float*)out)[(size_t)b * 256 + o] = h;
    }
}

// ---------------------------------------------------------------------------
extern "C" void kernel_launch(void* const* d_in, const int* in_sizes, int n_in,
                              void* d_out, int out_size, void* d_ws, size_t ws_size,
                              hipStream_t stream) {
    static const int wsz[23] = {
        384, 64, 64,   8192, 64, 64,   16384, 128, 128,   65536, 256, 256,
        524288, 1024, 1024,   1048576, 512,   512, 512,   131072, 256,   256, 256
    };
    static const int trows[23] = {64,0,0, 64,0,0, 128,0,0, 256,0,0, 0,0,0, 0,0, 0,0, 0,0, 0,0};
    static const int tcols[23] = { 6,0,0,128,0,0, 128,0,0, 256,0,0, 0,0,0, 0,0, 0,0, 0,0, 0,0};

    WPack wp;
    int total = 0;
    for (int i = 0; i < 23; ++i) {
        wp.src[i] = d_in[i + 1]; wp.off[i] = total; total += wsz[i];
        wp.rows[i] = trows[i]; wp.cols[i] = tcols[i];
    }
    wp.off[23] = total;

    const size_t flag_bytes = 16;
    const size_t x0_bytes   = (size_t)B_SZ * 3 * N_PTS * 4;
    const size_t feat_bytes = (size_t)B_SZ * 512 * N_PTS * 2;
    const size_t idx_bytes  = (size_t)B_SZ * N_PTS * KNN * 4;
    const size_t pool_bytes = (size_t)B_SZ * 1024 * 4 * 2;
    const size_t wf_bytes   = (size_t)total * 4;
    const size_t base_need  = flag_bytes + x0_bytes + feat_bytes + idx_bytes + pool_bytes + wf_bytes;

    const size_t featT_bytes = (size_t)B_SZ * N_PTS * FT * 2;           //  8 MB
    const size_t xx_bytes    = (size_t)B_SZ * N_PTS * 4;
    const size_t wsp2_elems  = 4 * 64 * 64;
    const size_t wsp3_elems  = 4 * 128 * 64;
    const size_t wsp4_elems  = 4 * 256 * 128;
    const size_t w5sp_elems  = 2 * 1024 * 512;
    const size_t wsp_bytes   = (wsp2_elems + wsp3_elems + wsp4_elems + w5sp_elems) * 2;
    const size_t S_bytes     = (size_t)B_SZ * N_PTS * N_PTS * 4;        // 64 MB (also holds Y)
    const size_t full_need   = base_need + featT_bytes + xx_bytes + wsp_bytes + S_bytes;

    if (ws_size < base_need) return;   // graceful fail
    const bool use_gram = (ws_size >= full_need);

    char* w = (char*)d_ws;
    int*   flag = (int*)w;              w += flag_bytes;
    float* x0   = (float*)w;            w += x0_bytes;
    bf16*  feat = (bf16*)w;             w += feat_bytes;
    int*   idx  = (int*)w;              w += idx_bytes;
    w += pool_bytes;
    float* wf   = (float*)w;            w += wf_bytes;
    bf16*  featT = (bf16*)w;            w += featT_bytes;
    float* xx    = (float*)w;           w += xx_bytes;
    bf16*  wsp2  = (bf16*)w;            w += wsp2_elems * 2;
    bf16*  wsp3  = (bf16*)w;            w += wsp3_elems * 2;
    bf16*  wsp4  = (bf16*)w;            w += wsp4_elems * 2;
    bf16*  w5sp  = (bf16*)w;            w += w5sp_elems * 2;
    float* S     = (float*)w;           // gram scores; reused as Y after select

    // overlays in the idx region (idx dead after ec4):
    float* fmxp = (float*)idx;                               // B*1024*NPOOL
    float* fsmp = fmxp + (size_t)B_SZ * 1024 * NPOOL;        // B*1024*NPOOL
    float* fvec = fsmp + (size_t)B_SZ * 1024 * NPOOL;        // B*2048
    float* tbuf = fvec + (size_t)B_SZ * 2048;                // B*512

    const int FBS = 512 * N_PTS;

    k_sniff<<<1, 64, 0, stream>>>((const unsigned short*)d_in[0], flag);
    k_repack<<<256, 256, 0, stream>>>(wp, flag, wf, total);
    k_transpose<<<(B_SZ * N_PTS + 255) / 256, 256, 0, stream>>>(d_in[0], flag, x0);

    const float* w1t = wf + wp.off[0],  *g1 = wf + wp.off[1],  *b1 = wf + wp.off[2];
    const float* w2t = wf + wp.off[3],  *g2 = wf + wp.off[4],  *b2 = wf + wp.off[5];
    const float* w3t = wf + wp.off[6],  *g3 = wf + wp.off[7],  *b3 = wf + wp.off[8];
    const float* w4t = wf + wp.off[9],  *g4 = wf + wp.off[10], *b4 = wf + wp.off[11];
    const float* w5  = wf + wp.off[12], *g5 = wf + wp.off[13], *b5 = wf + wp.off[14];
    const float* fw1 = wf + wp.off[15], *fb1 = wf + wp.off[16];
    const float* g6  = wf + wp.off[17], *b6 = wf + wp.off[18];
    const float* fw2 = wf + wp.off[19], *fb2 = wf + wp.off[20];
    const float* g7  = wf + wp.off[21], *b7 = wf + wp.off[22];

    const int GK = B_SZ * N_PTS / 4;   // 2048 blocks
    const int NXX = (B_SZ * N_PTS + 255) / 256;

    k_knn<float, 3><<<GK, 256, 0, stream>>>(x0, 3 * N_PTS, idx);
    if (use_gram) {
        k_wsplit<64, 64><<<(64 * 64 + 255) / 256, 256, 0, stream>>>(d_in[4], flag, wsp2);
        k_wsplit<64, 128><<<(128 * 64 + 255) / 256, 256, 0, stream>>>(d_in[7], flag, wsp3);
        k_wsplit<128, 256><<<(256 * 128 + 255) / 256, 256, 0, stream>>>(d_in[10], flag, wsp4);
        k_w5split<<<(1024 * 512 + 255) / 256, 256, 0, stream>>>(d_in[13], flag, w5sp);

        k_edgeconv<float, 3, 64, true><<<GK, 256, 0, stream>>>(
            x0, 3 * N_PTS, idx, w1t, g1, b1, feat + 0 * N_PTS, FBS, featT, 0);
        // layer 2: kNN on x1 (channels [0,64)), then xform+gmax
        k_xx<64><<<NXX, 256, 0, stream>>>(featT, 0, xx);
        k_gram<64><<<B_SZ * 256, 256, 0, stream>>>(featT, 0, S);
        k_select<<<GK, 256, 0, stream>>>(S, xx, idx);
        k_xform<64, 64><<<64, 256, 0, stream>>>(featT, 0, wsp2, S);
        k_gmax<64><<<GK, 256, 0, stream>>>(S, idx, g2, b2, featT, 64);
        // layer 3
        k_xx<64><<<NXX, 256, 0, stream>>>(featT, 64, xx);
        k_gram<64><<<B_SZ * 256, 256, 0, stream>>>(featT, 64, S);
        k_select<<<GK, 256, 0, stream>>>(S, xx, idx);
        k_xform<128, 64><<<128, 256, 0, stream>>>(featT, 64, wsp3, S);
        k_gmax<128><<<GK, 256, 0, stream>>>(S, idx, g3, b3, featT, 128);
        // layer 4 (writes featT channels [256,512) for conv5)
        k_xx<128><<<NXX, 256, 0, stream>>>(featT, 128, xx);
        k_gram<128><<<B_SZ * 256, 256, 0, stream>>>(featT, 128, S);
        k_select<<<GK, 256, 0, stream>>>(S, xx, idx);
        k_xform<256, 128><<<256, 256, 0, stream>>>(featT, 128, wsp4, S);
        k_gmax<256><<<GK, 256, 0, stream>>>(S, idx, g4, b4, featT, 256);

        // conv5 MFMA + pooling partials, then head GEMVs
        k_conv5mfma<<<B_SZ * 128, 256, 0, stream>>>(featT, w5sp, g5, b5, fmxp, fsmp);
        k_pool<<<(B_SZ * 1024 + 255) / 256, 256, 0, stream>>>(fmxp, fsmp, fvec);
        k_fc1<<<B_SZ * 512, 256, 0, stream>>>(fvec, fw1, fb1, g6, b6, tbuf);
        k_fc2<<<B_SZ * 256, 256, 0, stream>>>(tbuf, fw2, fb2, g7, b7, flag, d_out);
    } else {
        k_edgeconv<float, 3, 64, false><<<GK, 256, 0, stream>>>(
            x0, 3 * N_PTS, idx, w1t, g1, b1, feat + 0 * N_PTS, FBS, nullptr, 0);
        k_knn<bf16, 64><<<GK, 256, 0, stream>>>(feat + 0 * N_PTS, FBS, idx);
        k_edgeconv<bf16, 64, 64, false><<<GK, 256, 0, stream>>>(
            feat + 0 * N_PTS, FBS, idx, w2t, g2, b2, feat + 64 * N_PTS, FBS, nullptr, 0);
        k_knn<bf16, 64><<<GK, 256, 0, stream>>>(feat + 64 * N_PTS, FBS, idx);
        k_edgeconv<bf16, 64, 128, false><<<GK, 256, 0, stream>>>(
            feat + 64 * N_PTS, FBS, idx, w3t, g3, b3, feat + 128 * N_PTS, FBS, nullptr, 0);
        k_knn<bf16, 128><<<GK, 256, 0, stream>>>(feat + 128 * N_PTS, FBS, idx);
        k_edgeconv<bf16, 128, 256, false><<<GK, 256, 0, stream>>>(
            feat + 128 * N_PTS, FBS, idx, w4t, g4, b4, feat + 256 * N_PTS, FBS, nullptr, 0);

        k_conv5pool<<<B_SZ * (1024 / 8) * NCH, 256, 0, stream>>>(feat, w5, g5, b5, fmxp, fsmp);
        k_head<<<B_SZ, 256, 0, stream>>>(fmxp, fsmp, fw1, fb1, g6, b6, fw2, fb2, g7, b7,
                                         flag, d_out);
    }
}

// Round 11
// 519.992 us; speedup vs baseline: 7.3979x; 1.1848x over previous
//
#include <hip/hip_runtime.h>
#include <hip/hip_bf16.h>
#include <float.h>

#define N_PTS 2048
#define B_SZ  4
#define KNN   20
#define LRELU_S 0.2f
#define FT    512          // featT row stride (channels)
#define NPOOL 8            // conv5 n-chunk partials

typedef __hip_bfloat16 bf16;
typedef __attribute__((ext_vector_type(8))) short short8v;   // 8 bf16 (4 VGPRs)
typedef __attribute__((ext_vector_type(4))) float floatx4;

__device__ __forceinline__ float b2f(const bf16 v) { return __bfloat162float(v); }
__device__ __forceinline__ float ldf(const float* p) { return *p; }
__device__ __forceinline__ float ldf(const bf16* p)  { return __bfloat162float(*p); }
__device__ __forceinline__ short8v ld8(const bf16* p) { return *(const short8v*)p; }
__device__ __forceinline__ unsigned umin(unsigned a, unsigned b) { return a < b ? a : b; }

// ---------------------------------------------------------------------------
// Dtype sniffer (robustness): bf16 (flag=1) vs fp32 (flag=0). Reads 256 B.
__global__ void k_sniff(const unsigned short* __restrict__ pts_hw, int* __restrict__ flag) {
    if (threadIdx.x != 0 || blockIdx.x != 0) return;
    int sane = 0;
    for (int j = 0; j < 64; ++j) {
        unsigned short v = pts_hw[2 * j];
        int e = (v >> 7) & 0xFF;
        if (e >= 100 && e <= 140) ++sane;
    }
    *flag = (sane >= 32) ? 1 : 0;
}

// ---------------------------------------------------------------------------
// Repack 23 weight tensors to fp32; EdgeConv W tensors stored TRANSPOSED.
struct WPack {
    const void* src[23];
    int off[24];
    int rows[23];
    int cols[23];
};

__global__ void k_repack(WPack wp, const int* __restrict__ flag, float* __restrict__ dst, int total) {
    const int isb = *flag;
    for (int i = blockIdx.x * blockDim.x + threadIdx.x; i < total; i += gridDim.x * blockDim.x) {
        int lo = 0, hi = 23;
        while (lo + 1 < hi) { int mid = (lo + hi) >> 1; if (i >= wp.off[mid]) lo = mid; else hi = mid; }
        int j = i - wp.off[lo];
        float v = isb ? b2f(((const bf16*)wp.src[lo])[j]) : ((const float*)wp.src[lo])[j];
        int dj = j;
        int cols = wp.cols[lo];
        if (cols) dj = (j % cols) * wp.rows[lo] + (j / cols);
        dst[wp.off[lo] + dj] = v;
    }
}

// ---------------------------------------------------------------------------
// Split EdgeConv weights into bf16 hi/lo pairs for MFMA:
// dst = [W2hi | W2lo | Wdhi | Wdlo], each (COUT, C) row-major, Wd = W1 - W2.
template<int C, int COUT>
__global__ void k_wsplit(const void* __restrict__ W, const int* __restrict__ flag,
                         bf16* __restrict__ dst) {
    int i = blockIdx.x * blockDim.x + threadIdx.x;
    if (i >= COUT * C) return;
    int o = i / C, c = i % C;
    const int isb = *flag;
    float w1 = isb ? b2f(((const bf16*)W)[(size_t)o * 2 * C + c])
                   : ((const float*)W)[(size_t)o * 2 * C + c];
    float w2 = isb ? b2f(((const bf16*)W)[(size_t)o * 2 * C + C + c])
                   : ((const float*)W)[(size_t)o * 2 * C + C + c];
    float wd = w1 - w2;
    bf16 h2 = __float2bfloat16(w2);
    bf16 hd = __float2bfloat16(wd);
    dst[i]                = h2;
    dst[COUT * C + i]     = __float2bfloat16(w2 - b2f(h2));
    dst[2 * COUT * C + i] = hd;
    dst[3 * COUT * C + i] = __float2bfloat16(wd - b2f(hd));
}

// ---------------------------------------------------------------------------
// Split conv5 weights (1024x512) into bf16 hi/lo: dst = [hi | lo].
__global__ void k_w5split(const void* __restrict__ W, const int* __restrict__ flag,
                          bf16* __restrict__ dst) {
    int i = blockIdx.x * blockDim.x + threadIdx.x;
    if (i >= 1024 * 512) return;
    const int isb = *flag;
    float w = isb ? b2f(((const bf16*)W)[i]) : ((const float*)W)[i];
    bf16 h = __float2bfloat16(w);
    dst[i] = h;
    dst[1024 * 512 + i] = __float2bfloat16(w - b2f(h));
}

// ---------------------------------------------------------------------------
// points (B,N,3) -> x0 (B,3,N) fp32, dtype-dynamic.
__global__ void k_transpose(const void* __restrict__ pts, const int* __restrict__ flag,
                            float* __restrict__ x0) {
    const int isb = *flag;
    int i = blockIdx.x * blockDim.x + threadIdx.x;
    if (i >= B_SZ * N_PTS) return;
    int b = i / N_PTS, n = i % N_PTS;
    for (int c = 0; c < 3; ++c) {
        size_t s = ((size_t)b * N_PTS + n) * 3 + c;
        float v = isb ? b2f(((const bf16*)pts)[s]) : ((const float*)pts)[s];
        x0[((size_t)b * 3 + c) * N_PTS + n] = v;
    }
}

// ---------------------------------------------------------------------------
// 32-candidate row loads (lane chunk), fp32 out.
__device__ __forceinline__ void load32(const float* row, int mbase, float* r) {
    const float4* p = (const float4*)(row + mbase);
#pragma unroll
    for (int i = 0; i < 8; ++i) {
        float4 f = p[i];
        r[4 * i + 0] = f.x; r[4 * i + 1] = f.y; r[4 * i + 2] = f.z; r[4 * i + 3] = f.w;
    }
}
__device__ __forceinline__ void load32(const bf16* row, int mbase, float* r) {
    const uint4* p = (const uint4*)(row + mbase);
#pragma unroll
    for (int i = 0; i < 4; ++i) {
        uint4 u = p[i];
        r[8 * i + 0] = __uint_as_float(u.x << 16);
        r[8 * i + 1] = __uint_as_float(u.x & 0xFFFF0000u);
        r[8 * i + 2] = __uint_as_float(u.y << 16);
        r[8 * i + 3] = __uint_as_float(u.y & 0xFFFF0000u);
        r[8 * i + 4] = __uint_as_float(u.z << 16);
        r[8 * i + 5] = __uint_as_float(u.z & 0xFFFF0000u);
        r[8 * i + 6] = __uint_as_float(u.w << 16);
        r[8 * i + 7] = __uint_as_float(u.w & 0xFFFF0000u);
    }
}

// ---------------------------------------------------------------------------
// Packed-key top-20 for two queries per wave.
// key = (nonneg-fp32 bits & ~2047) | candidate_index(11b): u32-monotone, index
// tie-break = lowest index, unique keys. Ascending extraction: filter
// key >= prev (prev = last_winner+1) replaces per-round clear.
__device__ __forceinline__ void select20x2(const unsigned* ka, const unsigned* kb,
                                           int* outA, int* outB, int lane) {
    unsigned pa = 0u, pb = 0u;
#pragma unroll 1
    for (int k = 0; k < KNN; ++k) {
        unsigned a0 = 0xFFFFFFFFu, a1 = a0, a2 = a0, a3 = a0;
        unsigned b0 = a0, b1 = a0, b2 = a0, b3 = a0;
#pragma unroll
        for (int j = 0; j < 32; j += 4) {
            unsigned ta0 = (ka[j]     >= pa) ? ka[j]     : 0xFFFFFFFFu;
            unsigned ta1 = (ka[j + 1] >= pa) ? ka[j + 1] : 0xFFFFFFFFu;
            unsigned ta2 = (ka[j + 2] >= pa) ? ka[j + 2] : 0xFFFFFFFFu;
            unsigned ta3 = (ka[j + 3] >= pa) ? ka[j + 3] : 0xFFFFFFFFu;
            unsigned tb0 = (kb[j]     >= pb) ? kb[j]     : 0xFFFFFFFFu;
            unsigned tb1 = (kb[j + 1] >= pb) ? kb[j + 1] : 0xFFFFFFFFu;
            unsigned tb2 = (kb[j + 2] >= pb) ? kb[j + 2] : 0xFFFFFFFFu;
            unsigned tb3 = (kb[j + 3] >= pb) ? kb[j + 3] : 0xFFFFFFFFu;
            a0 = umin(a0, ta0); a1 = umin(a1, ta1); a2 = umin(a2, ta2); a3 = umin(a3, ta3);
            b0 = umin(b0, tb0); b1 = umin(b1, tb1); b2 = umin(b2, tb2); b3 = umin(b3, tb3);
        }
        unsigned va = umin(umin(a0, a1), umin(a2, a3));
        unsigned vb = umin(umin(b0, b1), umin(b2, b3));
#pragma unroll
        for (int off = 32; off >= 1; off >>= 1) {
            va = umin(va, (unsigned)__shfl_xor((int)va, off));
            vb = umin(vb, (unsigned)__shfl_xor((int)vb, off));
        }
        if (lane == 0) { outA[k] = (int)(va & 2047u); outB[k] = (int)(vb & 2047u); }
        pa = va + 1u;
        pb = vb + 1u;
    }
}

// ---------------------------------------------------------------------------
// Layer-1 kNN (C=3, fp32) with packed-key selection, 2 queries/wave.
__global__ __launch_bounds__(256) void k_knn3(const float* __restrict__ x0,
                                              int* __restrict__ idx) {
    __shared__ float qf[8][3];
    int ib = blockIdx.x;                   // B*N/8
    int b  = ib / (N_PTS / 8);
    int q0 = (ib % (N_PTS / 8)) * 8;
    const float* xb = x0 + (size_t)b * 3 * N_PTS;

    if (threadIdx.x < 24) {
        int q = threadIdx.x / 3, c = threadIdx.x % 3;
        qf[q][c] = xb[(size_t)c * N_PTS + q0 + q];
    }
    __syncthreads();

    int w = threadIdx.x >> 6, lane = threadIdx.x & 63;
    int qa = q0 + 2 * w;
    int mbase = lane * 32;

    float da[32], db[32];
#pragma unroll
    for (int j = 0; j < 32; ++j) { da[j] = 0.f; db[j] = 0.f; }
#pragma unroll
    for (int c = 0; c < 3; ++c) {
        float r[32];
        load32(xb + (size_t)c * N_PTS, mbase, r);
        float qac = qf[2 * w][c], qbc = qf[2 * w + 1][c];
#pragma unroll
        for (int j = 0; j < 32; ++j) {
            float ta = r[j] - qac; da[j] = fmaf(ta, ta, da[j]);
            float tb = r[j] - qbc; db[j] = fmaf(tb, tb, db[j]);
        }
    }
    unsigned ka[32], kb[32];
#pragma unroll
    for (int j = 0; j < 32; ++j) {
        ka[j] = (__float_as_uint(da[j]) & 0xFFFFF800u) | (unsigned)(mbase + j);
        kb[j] = (__float_as_uint(db[j]) & 0xFFFFF800u) | (unsigned)(mbase + j);
    }
    select20x2(ka, kb, idx + ((size_t)b * N_PTS + qa) * KNN,
               idx + ((size_t)b * N_PTS + qa + 1) * KNN, lane);
}

// ---------------------------------------------------------------------------
// Score-based top-20 (gram path): dist = xx[m] - 2G[q][m] + xx[q], clamped >=0.
// 2 queries/wave, packed keys.
__global__ __launch_bounds__(256) void k_select2(const float* __restrict__ G,
                                                 const float* __restrict__ xx,
                                                 int* __restrict__ idx) {
    int ib = blockIdx.x;                   // B*N/8
    int b  = ib / (N_PTS / 8);
    int q0 = (ib % (N_PTS / 8)) * 8;
    int w = threadIdx.x >> 6, lane = threadIdx.x & 63;
    int qa = q0 + 2 * w;
    const float* gA = G + ((size_t)b * N_PTS + qa) * N_PTS;
    const float* gB = gA + N_PTS;
    const float* xr = xx + (size_t)b * N_PTS;
    float xqa = xr[qa], xqb = xr[qa + 1];

    unsigned ka[32], kb[32];
#pragma unroll
    for (int r = 0; r < 8; ++r) {
        int m0 = r * 256 + (lane << 2);
        float4 x4 = *(const float4*)(xr + m0);
        float4 a4 = *(const float4*)(gA + m0);
        float4 b4 = *(const float4*)(gB + m0);
        float s;
        s = fmaf(-2.f, a4.x, x4.x) + xqa; s = fmaxf(s, 0.f);
        ka[4 * r + 0] = (__float_as_uint(s) & 0xFFFFF800u) | (unsigned)(m0 + 0);
        s = fmaf(-2.f, a4.y, x4.y) + xqa; s = fmaxf(s, 0.f);
        ka[4 * r + 1] = (__float_as_uint(s) & 0xFFFFF800u) | (unsigned)(m0 + 1);
        s = fmaf(-2.f, a4.z, x4.z) + xqa; s = fmaxf(s, 0.f);
        ka[4 * r + 2] = (__float_as_uint(s) & 0xFFFFF800u) | (unsigned)(m0 + 2);
        s = fmaf(-2.f, a4.w, x4.w) + xqa; s = fmaxf(s, 0.f);
        ka[4 * r + 3] = (__float_as_uint(s) & 0xFFFFF800u) | (unsigned)(m0 + 3);
        s = fmaf(-2.f, b4.x, x4.x) + xqb; s = fmaxf(s, 0.f);
        kb[4 * r + 0] = (__float_as_uint(s) & 0xFFFFF800u) | (unsigned)(m0 + 0);
        s = fmaf(-2.f, b4.y, x4.y) + xqb; s = fmaxf(s, 0.f);
        kb[4 * r + 1] = (__float_as_uint(s) & 0xFFFFF800u) | (unsigned)(m0 + 1);
        s = fmaf(-2.f, b4.z, x4.z) + xqb; s = fmaxf(s, 0.f);
        kb[4 * r + 2] = (__float_as_uint(s) & 0xFFFFF800u) | (unsigned)(m0 + 2);
        s = fmaf(-2.f, b4.w, x4.w) + xqb; s = fmaxf(s, 0.f);
        kb[4 * r + 3] = (__float_as_uint(s) & 0xFFFFF800u) | (unsigned)(m0 + 3);
    }
    select20x2(ka, kb, idx + ((size_t)b * N_PTS + qa) * KNN,
               idx + ((size_t)b * N_PTS + qa + 1) * KNN, lane);
}

// ---------------------------------------------------------------------------
// kNN (direct, fallback path): wave-per-query.
template<typename T, int C>
__global__ __launch_bounds__(256) void k_knn(const T* __restrict__ x, int bstride,
                                             int* __restrict__ idx) {
    __shared__ float qf[4][C];
    int ib = blockIdx.x;
    int b  = ib / (N_PTS / 4);
    int q0 = (ib % (N_PTS / 4)) * 4;
    const T* xb = x + (size_t)b * bstride;

    for (int t = threadIdx.x; t < 4 * C; t += 256) {
        int pt = t / C, c = t % C;
        qf[pt][c] = ldf(&xb[(size_t)c * N_PTS + (q0 + pt)]);
    }
    __syncthreads();

    int w = threadIdx.x >> 6, lane = threadIdx.x & 63;
    int q = q0 + w;
    int mbase = lane * 32;

    float v[32];
#pragma unroll
    for (int j = 0; j < 32; ++j) v[j] = 0.f;

    for (int c = 0; c < C; ++c) {
        float qc = qf[w][c];
        float r[32];
        load32(xb + (size_t)c * N_PTS, mbase, r);
#pragma unroll
        for (int j = 0; j < 32; ++j) { float t = r[j] - qc; v[j] = fmaf(t, t, v[j]); }
    }

    for (int k = 0; k < KNN; ++k) {
        float bv = FLT_MAX; int bi = 0x7FFFFFFF;
#pragma unroll
        for (int j = 0; j < 32; ++j)
            if (v[j] < bv) { bv = v[j]; bi = mbase + j; }
#pragma unroll
        for (int off = 32; off >= 1; off >>= 1) {
            float ov = __shfl_xor(bv, off);
            int   oi = __shfl_xor(bi, off);
            if (ov < bv || (ov == bv && oi < bi)) { bv = ov; bi = oi; }
        }
        if (lane == 0) idx[((size_t)b * N_PTS + q) * KNN + k] = bi;
        int wl = bi >> 5, wj = bi & 31;
        if (lane == wl) {
#pragma unroll
            for (int j = 0; j < 32; ++j) if (j == wj) v[j] = FLT_MAX;
        }
    }
}

// ---------------------------------------------------------------------------
// Candidate squared norms over a channel slice.
template<int C>
__global__ void k_xx(const bf16* __restrict__ featT, int c0, float* __restrict__ xx) {
    int i = blockIdx.x * blockDim.x + threadIdx.x;
    if (i >= B_SZ * N_PTS) return;
    const bf16* row = featT + (size_t)i * FT + c0;
    float s = 0.f;
    for (int c = 0; c < C; c += 8) {
        uint4 u = *(const uint4*)(row + c);
        float v0 = __uint_as_float(u.x << 16), v1 = __uint_as_float(u.x & 0xFFFF0000u);
        float v2 = __uint_as_float(u.y << 16), v3 = __uint_as_float(u.y & 0xFFFF0000u);
        float v4 = __uint_as_float(u.z << 16), v5 = __uint_as_float(u.z & 0xFFFF0000u);
        float v6 = __uint_as_float(u.w << 16), v7 = __uint_as_float(u.w & 0xFFFF0000u);
        s = fmaf(v0, v0, s); s = fmaf(v1, v1, s); s = fmaf(v2, v2, s); s = fmaf(v3, v3, s);
        s = fmaf(v4, v4, s); s = fmaf(v5, v5, s); s = fmaf(v6, v6, s); s = fmaf(v7, v7, s);
    }
    xx[i] = s;
}

// ---------------------------------------------------------------------------
// Gram matrix via MFMA: G[b][n][m] = sum_c X[c][n]*X[c][m], X = featT slice.
template<int C>
__global__ __launch_bounds__(256) void k_gram(const bf16* __restrict__ featT, int c0,
                                              float* __restrict__ G) {
    const int KC = 64;
    __shared__ __align__(16) short At[128 * 72];
    __shared__ __align__(16) short Bt[128 * 72];

    int ib = blockIdx.x;
    int b  = ib >> 8;
    int t  = ib & 255;
    int n0 = (t >> 4) << 7;
    int m0 = (t & 15) << 7;

    int tid = threadIdx.x;
    int w = tid >> 6, lane = tid & 63;
    int rw = (w & 1) * 64, cw = (w >> 1) * 64;
    int lrow = lane & 15, quad = lane >> 4;

    floatx4 acc[4][4];
#pragma unroll
    for (int ri = 0; ri < 4; ++ri)
#pragma unroll
        for (int ci = 0; ci < 4; ++ci) acc[ri][ci] = (floatx4){0.f, 0.f, 0.f, 0.f};

    for (int ck = 0; ck < C; ck += KC) {
        __syncthreads();
        for (int s = tid; s < 1024; s += 256) {
            int row = s >> 3, g = s & 7;
            *(uint4*)&At[row * 72 + g * 8] =
                *(const uint4*)(featT + ((size_t)(b * N_PTS + n0 + row) * FT) + c0 + ck + g * 8);
            *(uint4*)&Bt[row * 72 + g * 8] =
                *(const uint4*)(featT + ((size_t)(b * N_PTS + m0 + row) * FT) + c0 + ck + g * 8);
        }
        __syncthreads();
#pragma unroll
        for (int kk = 0; kk < KC; kk += 32) {
            short8v a[4], bb[4];
#pragma unroll
            for (int ri = 0; ri < 4; ++ri)
                a[ri] = *(const short8v*)&At[(rw + ri * 16 + lrow) * 72 + kk + quad * 8];
#pragma unroll
            for (int ci = 0; ci < 4; ++ci)
                bb[ci] = *(const short8v*)&Bt[(cw + ci * 16 + lrow) * 72 + kk + quad * 8];
#pragma unroll
            for (int ri = 0; ri < 4; ++ri)
#pragma unroll
                for (int ci = 0; ci < 4; ++ci)
                    acc[ri][ci] = __builtin_amdgcn_mfma_f32_16x16x32_bf16(a[ri], bb[ci], acc[ri][ci], 0, 0, 0);
        }
    }

#pragma unroll
    for (int ri = 0; ri < 4; ++ri)
#pragma unroll
        for (int ci = 0; ci < 4; ++ci) {
            int n = n0 + rw + ri * 16 + quad * 4;
            int m = m0 + cw + ci * 16 + lrow;
            float* gp = G + ((size_t)b * N_PTS + n) * N_PTS + m;
#pragma unroll
            for (int reg = 0; reg < 4; ++reg)
                gp[(size_t)reg * N_PTS] = acc[ri][ci][reg];
        }
}

// ---------------------------------------------------------------------------
// Dense point transform via MFMA (EdgeConv linear part, all points at once):
// Y[i][0..COUT) = W2 . x_i ; Y[i][COUT..2COUT) = Wd . x_i  (hi/lo split).
template<int COUT, int C>
__global__ __launch_bounds__(256) void k_xform(const bf16* __restrict__ featT, int c0,
                                               const bf16* __restrict__ Wsp,
                                               float* __restrict__ Y) {
    const int M2 = 2 * COUT;
    const int KC = 64;
    __shared__ __align__(16) short Bt[128 * 72];

    int ib = blockIdx.x;
    int nt = ib & 63;
    int mt = ib >> 6;
    int tid = threadIdx.x;
    int w = tid >> 6, lane = tid & 63;
    int rw = (w & 1) * 64, cw = (w >> 1) * 64;
    int l15 = lane & 15, quad = lane >> 4;

    floatx4 acc[4][4];
#pragma unroll
    for (int ri = 0; ri < 4; ++ri)
#pragma unroll
        for (int ci = 0; ci < 4; ++ci) acc[ri][ci] = (floatx4){0.f, 0.f, 0.f, 0.f};

    for (int ck = 0; ck < C; ck += KC) {
        __syncthreads();
        for (int s = tid; s < 1024; s += 256) {
            int row = s >> 3, g = s & 7;
            *(uint4*)&Bt[row * 72 + g * 8] =
                *(const uint4*)(featT + (size_t)(nt * 128 + row) * FT + c0 + ck + g * 8);
        }
        __syncthreads();
#pragma unroll
        for (int kk = 0; kk < KC; kk += 32) {
            short8v bfr[4];
#pragma unroll
            for (int ci = 0; ci < 4; ++ci)
                bfr[ci] = *(const short8v*)&Bt[(cw + ci * 16 + l15) * 72 + kk + quad * 8];
#pragma unroll
            for (int ri = 0; ri < 4; ++ri) {
                int mrow = mt * 128 + rw + ri * 16 + l15;
                int base = (mrow < COUT) ? mrow : (mrow + COUT);
                const bf16* hi = Wsp + (size_t)base * C + ck + kk + quad * 8;
                short8v ah = ld8(hi);
                short8v al = ld8(hi + (size_t)COUT * C);
#pragma unroll
                for (int ci = 0; ci < 4; ++ci) {
                    acc[ri][ci] = __builtin_amdgcn_mfma_f32_16x16x32_bf16(ah, bfr[ci], acc[ri][ci], 0, 0, 0);
                    acc[ri][ci] = __builtin_amdgcn_mfma_f32_16x16x32_bf16(al, bfr[ci], acc[ri][ci], 0, 0, 0);
                }
            }
        }
    }

#pragma unroll
    for (int ri = 0; ri < 4; ++ri)
#pragma unroll
        for (int ci = 0; ci < 4; ++ci) {
            int n = nt * 128 + cw + ci * 16 + l15;
            int m = mt * 128 + rw + ri * 16 + quad * 4;
            *(floatx4*)(Y + (size_t)n * M2 + m) = acc[ri][ci];
        }
}

// ---------------------------------------------------------------------------
// Gather-max epilogue: out[o][n] = max_k lrelu((Yd[n][o] + Y2[m_k][o])*s + b).
template<int COUT>
__global__ __launch_bounds__(256) void k_gmax(const float* __restrict__ Y,
        const int* __restrict__ idx,
        const float* __restrict__ gam, const float* __restrict__ bet,
        bf16* __restrict__ featT, int c0f) {
    const int M2 = 2 * COUT;
    const int OT = COUT / 64;
    int i = blockIdx.x * 4 + (threadIdx.x >> 6);
    int lane = threadIdx.x & 63;
    int b = i >> 11;

    const float inv = rsqrtf(1.0f + 1e-5f);
    float yd[OT], scale[OT], bias[OT], mx[OT];
#pragma unroll
    for (int j = 0; j < OT; ++j) {
        int o = lane + 64 * j;
        yd[j]    = Y[(size_t)i * M2 + COUT + o];
        scale[j] = gam[o] * inv;
        bias[j]  = bet[o];
        mx[j]    = -FLT_MAX;
    }

    const int* ip = idx + (size_t)i * KNN;
    const float* Yb = Y + ((size_t)b * N_PTS) * M2;
#pragma unroll 4
    for (int k = 0; k < KNN; ++k) {
        int m = ip[k] & (N_PTS - 1);
        const float* yr = Yb + (size_t)m * M2;
#pragma unroll
        for (int j = 0; j < OT; ++j) {
            float h = (yd[j] + yr[lane + 64 * j]) * scale[j] + bias[j];
            h = h > 0.f ? h : LRELU_S * h;
            mx[j] = fmaxf(mx[j], h);
        }
    }
#pragma unroll
    for (int j = 0; j < OT; ++j)
        featT[(size_t)i * FT + c0f + lane + 64 * j] = __float2bfloat16(mx[j]);
}

// ---------------------------------------------------------------------------
// EdgeConv (VALU): layer 1 (C=3) and ws-fallback path.
template<typename T, int C, int COUT, bool WF>
__global__ __launch_bounds__(256) void k_edgeconv(const T* __restrict__ x, int bstride,
                           const int* __restrict__ idx,
                           const float* __restrict__ Wt,
                           const float* __restrict__ gam,
                           const float* __restrict__ bet,
                           bf16* __restrict__ out, int ostride,
                           bf16* __restrict__ featT, int c0f) {
    const int PT = 4;
    const int OT = COUT / 64;
    const int CP = (C + 3) & ~3;
    __shared__ float sh[PT][KNN + 1][CP];

    int ib = blockIdx.x;
    int b  = ib / (N_PTS / PT);
    int n0 = (ib % (N_PTS / PT)) * PT;
    const T* xb = x + (size_t)b * bstride;

    const int TOT = PT * (KNN + 1) * C;
    for (int t = threadIdx.x; t < TOT; t += 256) {
        int pt = t / ((KNN + 1) * C);
        int r  = t % ((KNN + 1) * C);
        int row = r / C, c = r % C;
        int n = n0 + pt;
        int m = (row == 0) ? n
                           : (idx[((size_t)b * N_PTS + n) * KNN + (row - 1)] & (N_PTS - 1));
        sh[pt][row][c] = ldf(&xb[(size_t)c * N_PTS + m]);
    }
    __syncthreads();

    int w = threadIdx.x >> 6, lane = threadIdx.x & 63;
    int n = n0 + w;

    constexpr int KT = (OT >= 4) ? 10 : 20;
    constexpr int NPASS = KNN / KT;

    float base[OT];
    float mx[OT];
#pragma unroll
    for (int j = 0; j < OT; ++j) { base[j] = 0.f; mx[j] = -FLT_MAX; }

    const float inv = rsqrtf(1.0f + 1e-5f);

#pragma unroll
    for (int pass = 0; pass < NPASS; ++pass) {
        float acc[OT][KT];
#pragma unroll
        for (int j = 0; j < OT; ++j)
#pragma unroll
            for (int k = 0; k < KT; ++k) acc[j][k] = 0.f;

        for (int c = 0; c < C; ++c) {
            float xq = sh[w][0][c];
            float w2v[OT];
#pragma unroll
            for (int j = 0; j < OT; ++j)
                w2v[j] = Wt[(size_t)(C + c) * COUT + lane + 64 * j];
            if (pass == 0) {
#pragma unroll
                for (int j = 0; j < OT; ++j) {
                    float w1v = Wt[(size_t)c * COUT + lane + 64 * j];
                    base[j] = fmaf(w1v - w2v[j], xq, base[j]);
                }
            }
#pragma unroll
            for (int k = 0; k < KT; ++k) {
                float nv = sh[w][1 + pass * KT + k][c];
#pragma unroll
                for (int j = 0; j < OT; ++j) acc[j][k] = fmaf(w2v[j], nv, acc[j][k]);
            }
        }

#pragma unroll
        for (int j = 0; j < OT; ++j) {
            int o = lane + 64 * j;
            float scale = gam[o] * inv, bias = bet[o];
#pragma unroll
            for (int k = 0; k < KT; ++k) {
                float h = (base[j] + acc[j][k]) * scale + bias;
                h = h > 0.f ? h : LRELU_S * h;
                mx[j] = fmaxf(mx[j], h);
            }
        }
    }

#pragma unroll
    for (int j = 0; j < OT; ++j) {
        int o = lane + 64 * j;
        bf16 bv = __float2bfloat16(mx[j]);
        out[(size_t)b * ostride + (size_t)o * N_PTS + n] = bv;
        if (WF) featT[((size_t)b * N_PTS + n) * FT + c0f + o] = bv;
    }
}

// ---------------------------------------------------------------------------
// conv5 via MFMA + fused BN/LReLU + max/sum pooling partials.
__global__ __launch_bounds__(256) void k_conv5mfma(
        const bf16* __restrict__ featT, const bf16* __restrict__ w5sp,
        const float* __restrict__ g5, const float* __restrict__ b5,
        float* __restrict__ fmxp, float* __restrict__ fsmp) {
    __shared__ float rmx[4][64];
    __shared__ float rsm[4][64];

    int ib = blockIdx.x;
    int b  = ib / 128;
    int rem = ib % 128;
    int o0 = (rem >> 3) * 64;
    int nt = rem & 7;
    int tid = threadIdx.x;
    int w = tid >> 6, lane = tid & 63;
    int l15 = lane & 15, quad = lane >> 4;
    int nbase = nt * 256 + w * 64;

    const bf16* Whi = w5sp;
    const bf16* Wlo = w5sp + 1024 * 512;
    const bf16* fb  = featT + (size_t)b * N_PTS * FT;

    floatx4 acc[4][4];
#pragma unroll
    for (int mi = 0; mi < 4; ++mi)
#pragma unroll
        for (int ni = 0; ni < 4; ++ni) acc[mi][ni] = (floatx4){0.f, 0.f, 0.f, 0.f};

    for (int kk = 0; kk < 512; kk += 32) {
        short8v bfr[4];
#pragma unroll
        for (int ni = 0; ni < 4; ++ni)
            bfr[ni] = ld8(fb + (size_t)(nbase + ni * 16 + l15) * FT + kk + quad * 8);
#pragma unroll
        for (int mi = 0; mi < 4; ++mi) {
            size_t ar = (size_t)(o0 + mi * 16 + l15) * 512 + kk + quad * 8;
            short8v ah = ld8(Whi + ar);
            short8v al = ld8(Wlo + ar);
#pragma unroll
            for (int ni = 0; ni < 4; ++ni) {
                acc[mi][ni] = __builtin_amdgcn_mfma_f32_16x16x32_bf16(ah, bfr[ni], acc[mi][ni], 0, 0, 0);
                acc[mi][ni] = __builtin_amdgcn_mfma_f32_16x16x32_bf16(al, bfr[ni], acc[mi][ni], 0, 0, 0);
            }
        }
    }

    const float inv = rsqrtf(1.0f + 1e-5f);
#pragma unroll
    for (int mi = 0; mi < 4; ++mi) {
#pragma unroll
        for (int r = 0; r < 4; ++r) {
            int o = o0 + mi * 16 + quad * 4 + r;
            float scale = g5[o] * inv, bias = b5[o];
            float mx = -FLT_MAX, sm = 0.f;
#pragma unroll
            for (int ni = 0; ni < 4; ++ni) {
                float h = acc[mi][ni][r] * scale + bias;
                h = h > 0.f ? h : LRELU_S * h;
                mx = fmaxf(mx, h);
                sm += h;
            }
#pragma unroll
            for (int off = 1; off <= 8; off <<= 1) {
                mx = fmaxf(mx, __shfl_xor(mx, off));
                sm += __shfl_xor(sm, off);
            }
            if (l15 == 0) {
                rmx[w][mi * 16 + quad * 4 + r] = mx;
                rsm[w][mi * 16 + quad * 4 + r] = sm;
            }
        }
    }
    __syncthreads();
    if (tid < 64) {
        float mx = -FLT_MAX, sm = 0.f;
#pragma unroll
        for (int ww = 0; ww < 4; ++ww) { mx = fmaxf(mx, rmx[ww][tid]); sm += rsm[ww][tid]; }
        fmxp[((size_t)b * 1024 + o0 + tid) * NPOOL + nt] = mx;
        fsmp[((size_t)b * 1024 + o0 + tid) * NPOOL + nt] = sm;
    }
}

// ---------------------------------------------------------------------------
// Pool partial reduce -> fvec (B, 2048) = [max(1024) | mean(1024)].
__global__ void k_pool(const float* __restrict__ fmxp, const float* __restrict__ fsmp,
                       float* __restrict__ fvec) {
    int i = blockIdx.x * blockDim.x + threadIdx.x;
    if (i >= B_SZ * 1024) return;
    int b = i >> 10, o = i & 1023;
    float mx = -FLT_MAX, sm = 0.f;
    for (int ch = 0; ch < NPOOL; ++ch) {
        mx = fmaxf(mx, fmxp[(size_t)i * NPOOL + ch]);
        sm += fsmp[(size_t)i * NPOOL + ch];
    }
    fvec[(size_t)b * 2048 + o] = mx;
    fvec[(size_t)b * 2048 + 1024 + o] = sm * (1.0f / N_PTS);
}

// ---------------------------------------------------------------------------
// fc1: block per (b,o).
__global__ __launch_bounds__(256) void k_fc1(const float* __restrict__ fvec,
        const float* __restrict__ fw1, const float* __restrict__ fb1,
        const float* __restrict__ g6,  const float* __restrict__ b6,
        float* __restrict__ tbuf) {
    __shared__ float red[4];
    int ib = blockIdx.x;
    int b = ib >> 9, o = ib & 511;
    const float* wr = fw1 + (size_t)o * 2048;
    const float* fv = fvec + (size_t)b * 2048;
    int tid = threadIdx.x;
    float s = 0.f;
    for (int j = tid; j < 2048; j += 256) s = fmaf(wr[j], fv[j], s);
#pragma unroll
    for (int off = 32; off >= 1; off >>= 1) s += __shfl_xor(s, off);
    if ((tid & 63) == 0) red[tid >> 6] = s;
    __syncthreads();
    if (tid == 0) {
        float acc = fb1[o] + red[0] + red[1] + red[2] + red[3];
        float h = acc * g6[o] * rsqrtf(1.0f + 1e-5f) + b6[o];
        tbuf[(size_t)b * 512 + o] = h > 0.f ? h : LRELU_S * h;
    }
}

// ---------------------------------------------------------------------------
// fc2: block per (b,o).
__global__ __launch_bounds__(256) void k_fc2(const float* __restrict__ tbuf,
        const float* __restrict__ fw2, const float* __restrict__ fb2,
        const float* __restrict__ g7,  const float* __restrict__ b7,
        const int* __restrict__ flag, void* __restrict__ out) {
    __shared__ float red[4];
    int ib = blockIdx.x;
    int b = ib >> 8, o = ib & 255;
    const float* wr = fw2 + (size_t)o * 512;
    const float* tv = tbuf + (size_t)b * 512;
    int tid = threadIdx.x;
    float s = fmaf(wr[tid], tv[tid], wr[tid + 256] * tv[tid + 256]);
#pragma unroll
    for (int off = 32; off >= 1; off >>= 1) s += __shfl_xor(s, off);
    if ((tid & 63) == 0) red[tid >> 6] = s;
    __syncthreads();
    if (tid == 0) {
        float acc = fb2[o] + red[0] + red[1] + red[2] + red[3];
        float h = acc * g7[o] * rsqrtf(1.0f + 1e-5f) + b7[o];
        if (*flag) ((bf16*)out)[(size_t)b * 256 + o] = __float2bfloat16(h);
        else       ((float*)out)[(size_t)b * 256 + o] = h;
    }
}

// ---------------------------------------------------------------------------
// Fallback conv5 (VALU) + head, used when ws too small for the gram path.
#define NCH 2
__global__ __launch_bounds__(256) void k_conv5pool(const bf16* __restrict__ feat,
                            const float* __restrict__ w5,
                            const float* __restrict__ g5,
                            const float* __restrict__ b5,
                            float* __restrict__ fmxp, float* __restrict__ fsmp) {
    const int OT = 8;
    const int NT = 4;
    const int CHN = N_PTS / NCH;
    __shared__ float wl[OT][512];
    __shared__ float rmx[4][OT];
    __shared__ float rsm[4][OT];

    int ib = blockIdx.x;
    int ch = ib % NCH;
    int ot = (ib / NCH) % (1024 / OT);
    int b  = ib / (NCH * (1024 / OT));
    int o0 = ot * OT;
    const bf16* fb = feat + (size_t)b * 512 * N_PTS;

    for (int t = threadIdx.x; t < OT * 512; t += 256) {
        int o = t >> 9, c = t & 511;
        wl[o][c] = w5[(size_t)(o0 + o) * 512 + c];
    }
    __syncthreads();

    const int n0 = ch * CHN + threadIdx.x * NT;

    float acc[OT][NT];
#pragma unroll
    for (int o = 0; o < OT; ++o)
#pragma unroll
        for (int t = 0; t < NT; ++t) acc[o][t] = 0.f;

    for (int c = 0; c < 512; c += 4) {
        float fv[4][NT];
#pragma unroll
        for (int j = 0; j < 4; ++j) {
            uint2 u = *(const uint2*)(fb + (size_t)(c + j) * N_PTS + n0);
            fv[j][0] = __uint_as_float(u.x << 16);
            fv[j][1] = __uint_as_float(u.x & 0xFFFF0000u);
            fv[j][2] = __uint_as_float(u.y << 16);
            fv[j][3] = __uint_as_float(u.y & 0xFFFF0000u);
        }
#pragma unroll
        for (int o = 0; o < OT; ++o) {
            float4 wv = *(const float4*)&wl[o][c];
#pragma unroll
            for (int t = 0; t < NT; ++t) {
                acc[o][t] = fmaf(wv.x, fv[0][t], acc[o][t]);
                acc[o][t] = fmaf(wv.y, fv[1][t], acc[o][t]);
                acc[o][t] = fmaf(wv.z, fv[2][t], acc[o][t]);
                acc[o][t] = fmaf(wv.w, fv[3][t], acc[o][t]);
            }
        }
    }

    const float inv = rsqrtf(1.0f + 1e-5f);
    int w = threadIdx.x >> 6, lane = threadIdx.x & 63;
#pragma unroll
    for (int o = 0; o < OT; ++o) {
        float scale = g5[o0 + o] * inv, bias = b5[o0 + o];
        float mx = -FLT_MAX, sm = 0.f;
#pragma unroll
        for (int t = 0; t < NT; ++t) {
            float h = acc[o][t] * scale + bias;
            h = h > 0.f ? h : LRELU_S * h;
            mx = fmaxf(mx, h);
            sm += h;
        }
#pragma unroll
        for (int off = 32; off >= 1; off >>= 1) {
            mx = fmaxf(mx, __shfl_xor(mx, off));
            sm += __shfl_xor(sm, off);
        }
        if (lane == 0) { rmx[w][o] = mx; rsm[w][o] = sm; }
    }
    __syncthreads();
    if (threadIdx.x < OT) {
        int o = threadIdx.x;
        float mx = -FLT_MAX, sm = 0.f;
#pragma unroll
        for (int ww = 0; ww < 4; ++ww) { mx = fmaxf(mx, rmx[ww][o]); sm += rsm[ww][o]; }
        fmxp[((size_t)b * 1024 + o0 + o) * NCH + ch] = mx;
        fsmp[((size_t)b * 1024 + o0 + o) * NCH + ch] = sm;
    }
}

__global__ void k_head(const float* __restrict__ fmxp, const float* __restrict__ fsmp,
                       const float* __restrict__ fw1, const float* __restrict__ fb1,
                       const float* __restrict__ g6,  const float* __restrict__ b6,
                       const float* __restrict__ fw2, const float* __restrict__ fb2,
                       const float* __restrict__ g7,  const float* __restrict__ b7,
                       const int* __restrict__ flag, void* __restrict__ out) {
    __shared__ float f[2048];
    __shared__ float t[512];
    int b = blockIdx.x;
    for (int i = threadIdx.x; i < 1024; i += 256) {
        float mx = -FLT_MAX, sm = 0.f;
        for (int ch = 0; ch < NCH; ++ch) {
            mx = fmaxf(mx, fmxp[((size_t)b * 1024 + i) * NCH + ch]);
            sm += fsmp[((size_t)b * 1024 + i) * NCH + ch];
        }
        f[i]        = mx;
        f[1024 + i] = sm * (1.0f / N_PTS);
    }
    __syncthreads();
    const float inv = rsqrtf(1.0f + 1e-5f);
    for (int o = threadIdx.x; o < 512; o += 256) {
        const float* wr = fw1 + (size_t)o * 2048;
        float acc = fb1[o];
        for (int j = 0; j < 2048; ++j) acc += wr[j] * f[j];
        float h = acc * g6[o] * inv + b6[o];
        t[o] = h > 0.f ? h : LRELU_S * h;
    }
    __syncthreads();
    {
        int o = threadIdx.x;
        const float* wr = fw2 + (size_t)o * 512;
        float acc = fb2[o];
        for (int j = 0; j < 512; ++j) acc += wr[j] * t[j];
        float h = acc * g7[o] * inv + b7[o];
        if (*flag) ((bf16*)out)[(size_t)b * 256 + o] = __float2bfloat16(h);
        else       ((float*)out)[(size_t)b * 256 + o] = h;
    }
}

// ---------------------------------------------------------------------------
extern "C" void kernel_launch(void* const* d_in, const int* in_sizes, int n_in,
                              void* d_out, int out_size, void* d_ws, size_t ws_size,
                              hipStream_t stream) {
    static const int wsz[23] = {
        384, 64, 64,   8192, 64, 64,   16384, 128, 128,   65536, 256, 256,
        524288, 1024, 1024,   1048576, 512,   512, 512,   131072, 256,   256, 256
    };
    static const int trows[23] = {64,0,0, 64,0,0, 128,0,0, 256,0,0, 0,0,0, 0,0, 0,0, 0,0, 0,0};
    static const int tcols[23] = { 6,0,0,128,0,0, 128,0,0, 256,0,0, 0,0,0, 0,0, 0,0, 0,0, 0,0};

    WPack wp;
    int total = 0;
    for (int i = 0; i < 23; ++i) {
        wp.src[i] = d_in[i + 1]; wp.off[i] = total; total += wsz[i];
        wp.rows[i] = trows[i]; wp.cols[i] = tcols[i];
    }
    wp.off[23] = total;

    const size_t flag_bytes = 16;
    const size_t x0_bytes   = (size_t)B_SZ * 3 * N_PTS * 4;
    const size_t feat_bytes = (size_t)B_SZ * 512 * N_PTS * 2;
    const size_t idx_bytes  = (size_t)B_SZ * N_PTS * KNN * 4;
    const size_t pool_bytes = (size_t)B_SZ * 1024 * 4 * 2;
    const size_t wf_bytes   = (size_t)total * 4;
    const size_t base_need  = flag_bytes + x0_bytes + feat_bytes + idx_bytes + pool_bytes + wf_bytes;

    const size_t featT_bytes = (size_t)B_SZ * N_PTS * FT * 2;           //  8 MB
    const size_t xx_bytes    = (size_t)B_SZ * N_PTS * 4;
    const size_t wsp2_elems  = 4 * 64 * 64;
    const size_t wsp3_elems  = 4 * 128 * 64;
    const size_t wsp4_elems  = 4 * 256 * 128;
    const size_t w5sp_elems  = 2 * 1024 * 512;
    const size_t wsp_bytes   = (wsp2_elems + wsp3_elems + wsp4_elems + w5sp_elems) * 2;
    const size_t S_bytes     = (size_t)B_SZ * N_PTS * N_PTS * 4;        // 64 MB (also holds Y)
    const size_t full_need   = base_need + featT_bytes + xx_bytes + wsp_bytes + S_bytes;

    if (ws_size < base_need) return;   // graceful fail
    const bool use_gram = (ws_size >= full_need);

    char* w = (char*)d_ws;
    int*   flag = (int*)w;              w += flag_bytes;
    float* x0   = (float*)w;            w += x0_bytes;
    bf16*  feat = (bf16*)w;             w += feat_bytes;
    int*   idx  = (int*)w;              w += idx_bytes;
    w += pool_bytes;
    float* wf   = (float*)w;            w += wf_bytes;
    bf16*  featT = (bf16*)w;            w += featT_bytes;
    float* xx    = (float*)w;           w += xx_bytes;
    bf16*  wsp2  = (bf16*)w;            w += wsp2_elems * 2;
    bf16*  wsp3  = (bf16*)w;            w += wsp3_elems * 2;
    bf16*  wsp4  = (bf16*)w;            w += wsp4_elems * 2;
    bf16*  w5sp  = (bf16*)w;            w += w5sp_elems * 2;
    float* S     = (float*)w;           // gram scores; reused as Y after select

    // overlays in the idx region (idx dead after ec4):
    float* fmxp = (float*)idx;                               // B*1024*NPOOL
    float* fsmp = fmxp + (size_t)B_SZ * 1024 * NPOOL;        // B*1024*NPOOL
    float* fvec = fsmp + (size_t)B_SZ * 1024 * NPOOL;        // B*2048
    float* tbuf = fvec + (size_t)B_SZ * 2048;                // B*512

    const int FBS = 512 * N_PTS;

    k_sniff<<<1, 64, 0, stream>>>((const unsigned short*)d_in[0], flag);
    k_repack<<<256, 256, 0, stream>>>(wp, flag, wf, total);
    k_transpose<<<(B_SZ * N_PTS + 255) / 256, 256, 0, stream>>>(d_in[0], flag, x0);

    const float* w1t = wf + wp.off[0],  *g1 = wf + wp.off[1],  *b1 = wf + wp.off[2];
    const float* w2t = wf + wp.off[3],  *g2 = wf + wp.off[4],  *b2 = wf + wp.off[5];
    const float* w3t = wf + wp.off[6],  *g3 = wf + wp.off[7],  *b3 = wf + wp.off[8];
    const float* w4t = wf + wp.off[9],  *g4 = wf + wp.off[10], *b4 = wf + wp.off[11];
    const float* w5  = wf + wp.off[12], *g5 = wf + wp.off[13], *b5 = wf + wp.off[14];
    const float* fw1 = wf + wp.off[15], *fb1 = wf + wp.off[16];
    const float* g6  = wf + wp.off[17], *b6 = wf + wp.off[18];
    const float* fw2 = wf + wp.off[19], *fb2 = wf + wp.off[20];
    const float* g7  = wf + wp.off[21], *b7 = wf + wp.off[22];

    const int GK = B_SZ * N_PTS / 4;    // 2048 blocks
    const int G8 = B_SZ * N_PTS / 8;    // 1024 blocks (2 queries/wave kernels)
    const int NXX = (B_SZ * N_PTS + 255) / 256;

    if (use_gram) {
        k_wsplit<64, 64><<<(64 * 64 + 255) / 256, 256, 0, stream>>>(d_in[4], flag, wsp2);
        k_wsplit<64, 128><<<(128 * 64 + 255) / 256, 256, 0, stream>>>(d_in[7], flag, wsp3);
        k_wsplit<128, 256><<<(256 * 128 + 255) / 256, 256, 0, stream>>>(d_in[10], flag, wsp4);
        k_w5split<<<(1024 * 512 + 255) / 256, 256, 0, stream>>>(d_in[13], flag, w5sp);

        k_knn3<<<G8, 256, 0, stream>>>(x0, idx);
        k_edgeconv<float, 3, 64, true><<<GK, 256, 0, stream>>>(
            x0, 3 * N_PTS, idx, w1t, g1, b1, feat + 0 * N_PTS, FBS, featT, 0);
        // layer 2
        k_xx<64><<<NXX, 256, 0, stream>>>(featT, 0, xx);
        k_gram<64><<<B_SZ * 256, 256, 0, stream>>>(featT, 0, S);
        k_select2<<<G8, 256, 0, stream>>>(S, xx, idx);
        k_xform<64, 64><<<64, 256, 0, stream>>>(featT, 0, wsp2, S);
        k_gmax<64><<<GK, 256, 0, stream>>>(S, idx, g2, b2, featT, 64);
        // layer 3
        k_xx<64><<<NXX, 256, 0, stream>>>(featT, 64, xx);
        k_gram<64><<<B_SZ * 256, 256, 0, stream>>>(featT, 64, S);
        k_select2<<<G8, 256, 0, stream>>>(S, xx, idx);
        k_xform<128, 64><<<128, 256, 0, stream>>>(featT, 64, wsp3, S);
        k_gmax<128><<<GK, 256, 0, stream>>>(S, idx, g3, b3, featT, 128);
        // layer 4 (writes featT channels [256,512) for conv5)
        k_xx<128><<<NXX, 256, 0, stream>>>(featT, 128, xx);
        k_gram<128><<<B_SZ * 256, 256, 0, stream>>>(featT, 128, S);
        k_select2<<<G8, 256, 0, stream>>>(S, xx, idx);
        k_xform<256, 128><<<256, 256, 0, stream>>>(featT, 128, wsp4, S);
        k_gmax<256><<<GK, 256, 0, stream>>>(S, idx, g4, b4, featT, 256);

        // conv5 MFMA + pooling partials, then head GEMVs
        k_conv5mfma<<<B_SZ * 128, 256, 0, stream>>>(featT, w5sp, g5, b5, fmxp, fsmp);
        k_pool<<<(B_SZ * 1024 + 255) / 256, 256, 0, stream>>>(fmxp, fsmp, fvec);
        k_fc1<<<B_SZ * 512, 256, 0, stream>>>(fvec, fw1, fb1, g6, b6, tbuf);
        k_fc2<<<B_SZ * 256, 256, 0, stream>>>(tbuf, fw2, fb2, g7, b7, flag, d_out);
    } else {
        k_knn<float, 3><<<GK, 256, 0, stream>>>(x0, 3 * N_PTS, idx);
        k_edgeconv<float, 3, 64, false><<<GK, 256, 0, stream>>>(
            x0, 3 * N_PTS, idx, w1t, g1, b1, feat + 0 * N_PTS, FBS, nullptr, 0);
        k_knn<bf16, 64><<<GK, 256, 0, stream>>>(feat + 0 * N_PTS, FBS, idx);
        k_edgeconv<bf16, 64, 64, false><<<GK, 256, 0, stream>>>(
            feat + 0 * N_PTS, FBS, idx, w2t, g2, b2, feat + 64 * N_PTS, FBS, nullptr, 0);
        k_knn<bf16, 64><<<GK, 256, 0, stream>>>(feat + 64 * N_PTS, FBS, idx);
        k_edgeconv<bf16, 64, 128, false><<<GK, 256, 0, stream>>>(
            feat + 64 * N_PTS, FBS, idx, w3t, g3, b3, feat + 128 * N_PTS, FBS, nullptr, 0);
        k_knn<bf16, 128><<<GK, 256, 0, stream>>>(feat + 128 * N_PTS, FBS, idx);
        k_edgeconv<bf16, 128, 256, false><<<GK, 256, 0, stream>>>(
            feat + 128 * N_PTS, FBS, idx, w4t, g4, b4, feat + 256 * N_PTS, FBS, nullptr, 0);

        k_conv5pool<<<B_SZ * (1024 / 8) * NCH, 256, 0, stream>>>(feat, w5, g5, b5, fmxp, fsmp);
        k_head<<<B_SZ, 256, 0, stream>>>(fmxp, fsmp, fw1, fb1, g6, b6, fw2, fb2, g7, b7,
                                         flag, d_out);
    }
}

// Round 12
// 472.723 us; speedup vs baseline: 8.1376x; 1.1000x over previous
//
#include <hip/hip_runtime.h>
#include <hip/hip_bf16.h>
#include <float.h>

#define N_PTS 2048
#define B_SZ  4
#define KNN   20
#define LRELU_S 0.2f
#define FT    512          // featT row stride (channels)
#define NPOOL 8            // conv5 n-chunk partials

typedef __hip_bfloat16 bf16;
typedef __attribute__((ext_vector_type(8))) short short8v;   // 8 bf16 (4 VGPRs)
typedef __attribute__((ext_vector_type(4))) float floatx4;

__device__ __forceinline__ float b2f(const bf16 v) { return __bfloat162float(v); }
__device__ __forceinline__ float ldf(const float* p) { return *p; }
__device__ __forceinline__ float ldf(const bf16* p)  { return __bfloat162float(*p); }
__device__ __forceinline__ short8v ld8(const bf16* p) { return *(const short8v*)p; }
__device__ __forceinline__ unsigned umin(unsigned a, unsigned b) { return a < b ? a : b; }

// ---------------------------------------------------------------------------
// Dtype sniffer (robustness): bf16 (flag=1) vs fp32 (flag=0). Reads 256 B.
__global__ void k_sniff(const unsigned short* __restrict__ pts_hw, int* __restrict__ flag) {
    if (threadIdx.x != 0 || blockIdx.x != 0) return;
    int sane = 0;
    for (int j = 0; j < 64; ++j) {
        unsigned short v = pts_hw[2 * j];
        int e = (v >> 7) & 0xFF;
        if (e >= 100 && e <= 140) ++sane;
    }
    *flag = (sane >= 32) ? 1 : 0;
}

// ---------------------------------------------------------------------------
// Repack first `limit` elements of the weight tensors to fp32 (EdgeConv W
// transposed). Gram path only needs tensors 0..14 (fc weights read raw).
struct WPack {
    const void* src[23];
    int off[24];
    int rows[23];
    int cols[23];
};

__global__ void k_repack(WPack wp, const int* __restrict__ flag, float* __restrict__ dst, int limit) {
    const int isb = *flag;
    int i = blockIdx.x * blockDim.x + threadIdx.x;
    if (i >= limit) return;
    int lo = 0, hi = 23;
    while (lo + 1 < hi) { int mid = (lo + hi) >> 1; if (i >= wp.off[mid]) lo = mid; else hi = mid; }
    int j = i - wp.off[lo];
    float v = isb ? b2f(((const bf16*)wp.src[lo])[j]) : ((const float*)wp.src[lo])[j];
    int dj = j;
    int cols = wp.cols[lo];
    if (cols) dj = (j % cols) * wp.rows[lo] + (j / cols);
    dst[wp.off[lo] + dj] = v;
}

// ---------------------------------------------------------------------------
// Split EdgeConv weights into bf16 hi/lo pairs for MFMA:
// dst = [W2hi | W2lo | Wdhi | Wdlo], each (COUT, C) row-major, Wd = W1 - W2.
template<int C, int COUT>
__global__ void k_wsplit(const void* __restrict__ W, const int* __restrict__ flag,
                         bf16* __restrict__ dst) {
    int i = blockIdx.x * blockDim.x + threadIdx.x;
    if (i >= COUT * C) return;
    int o = i / C, c = i % C;
    const int isb = *flag;
    float w1 = isb ? b2f(((const bf16*)W)[(size_t)o * 2 * C + c])
                   : ((const float*)W)[(size_t)o * 2 * C + c];
    float w2 = isb ? b2f(((const bf16*)W)[(size_t)o * 2 * C + C + c])
                   : ((const float*)W)[(size_t)o * 2 * C + C + c];
    float wd = w1 - w2;
    bf16 h2 = __float2bfloat16(w2);
    bf16 hd = __float2bfloat16(wd);
    dst[i]                = h2;
    dst[COUT * C + i]     = __float2bfloat16(w2 - b2f(h2));
    dst[2 * COUT * C + i] = hd;
    dst[3 * COUT * C + i] = __float2bfloat16(wd - b2f(hd));
}

// ---------------------------------------------------------------------------
// Split conv5 weights (1024x512) into bf16 hi/lo: dst = [hi | lo].
__global__ void k_w5split(const void* __restrict__ W, const int* __restrict__ flag,
                          bf16* __restrict__ dst) {
    int i = blockIdx.x * blockDim.x + threadIdx.x;
    if (i >= 1024 * 512) return;
    const int isb = *flag;
    float w = isb ? b2f(((const bf16*)W)[i]) : ((const float*)W)[i];
    bf16 h = __float2bfloat16(w);
    dst[i] = h;
    dst[1024 * 512 + i] = __float2bfloat16(w - b2f(h));
}

// ---------------------------------------------------------------------------
// points (B,N,3) -> x0 (B,3,N) fp32, dtype-dynamic.
__global__ void k_transpose(const void* __restrict__ pts, const int* __restrict__ flag,
                            float* __restrict__ x0) {
    const int isb = *flag;
    int i = blockIdx.x * blockDim.x + threadIdx.x;
    if (i >= B_SZ * N_PTS) return;
    int b = i / N_PTS, n = i % N_PTS;
    for (int c = 0; c < 3; ++c) {
        size_t s = ((size_t)b * N_PTS + n) * 3 + c;
        float v = isb ? b2f(((const bf16*)pts)[s]) : ((const float*)pts)[s];
        x0[((size_t)b * 3 + c) * N_PTS + n] = v;
    }
}

// ---------------------------------------------------------------------------
// 32-candidate row loads (lane chunk), fp32 out.
__device__ __forceinline__ void load32(const float* row, int mbase, float* r) {
    const float4* p = (const float4*)(row + mbase);
#pragma unroll
    for (int i = 0; i < 8; ++i) {
        float4 f = p[i];
        r[4 * i + 0] = f.x; r[4 * i + 1] = f.y; r[4 * i + 2] = f.z; r[4 * i + 3] = f.w;
    }
}
__device__ __forceinline__ void load32(const bf16* row, int mbase, float* r) {
    const uint4* p = (const uint4*)(row + mbase);
#pragma unroll
    for (int i = 0; i < 4; ++i) {
        uint4 u = p[i];
        r[8 * i + 0] = __uint_as_float(u.x << 16);
        r[8 * i + 1] = __uint_as_float(u.x & 0xFFFF0000u);
        r[8 * i + 2] = __uint_as_float(u.y << 16);
        r[8 * i + 3] = __uint_as_float(u.y & 0xFFFF0000u);
        r[8 * i + 4] = __uint_as_float(u.z << 16);
        r[8 * i + 5] = __uint_as_float(u.z & 0xFFFF0000u);
        r[8 * i + 6] = __uint_as_float(u.w << 16);
        r[8 * i + 7] = __uint_as_float(u.w & 0xFFFF0000u);
    }
}

// ---------------------------------------------------------------------------
// Packed-key top-20 for two queries per wave.
__device__ __forceinline__ void select20x2(const unsigned* ka, const unsigned* kb,
                                           int* outA, int* outB, int lane) {
    unsigned pa = 0u, pb = 0u;
#pragma unroll 1
    for (int k = 0; k < KNN; ++k) {
        unsigned a0 = 0xFFFFFFFFu, a1 = a0, a2 = a0, a3 = a0;
        unsigned b0 = a0, b1 = a0, b2 = a0, b3 = a0;
#pragma unroll
        for (int j = 0; j < 32; j += 4) {
            unsigned ta0 = (ka[j]     >= pa) ? ka[j]     : 0xFFFFFFFFu;
            unsigned ta1 = (ka[j + 1] >= pa) ? ka[j + 1] : 0xFFFFFFFFu;
            unsigned ta2 = (ka[j + 2] >= pa) ? ka[j + 2] : 0xFFFFFFFFu;
            unsigned ta3 = (ka[j + 3] >= pa) ? ka[j + 3] : 0xFFFFFFFFu;
            unsigned tb0 = (kb[j]     >= pb) ? kb[j]     : 0xFFFFFFFFu;
            unsigned tb1 = (kb[j + 1] >= pb) ? kb[j + 1] : 0xFFFFFFFFu;
            unsigned tb2 = (kb[j + 2] >= pb) ? kb[j + 2] : 0xFFFFFFFFu;
            unsigned tb3 = (kb[j + 3] >= pb) ? kb[j + 3] : 0xFFFFFFFFu;
            a0 = umin(a0, ta0); a1 = umin(a1, ta1); a2 = umin(a2, ta2); a3 = umin(a3, ta3);
            b0 = umin(b0, tb0); b1 = umin(b1, tb1); b2 = umin(b2, tb2); b3 = umin(b3, tb3);
        }
        unsigned va = umin(umin(a0, a1), umin(a2, a3));
        unsigned vb = umin(umin(b0, b1), umin(b2, b3));
#pragma unroll
        for (int off = 32; off >= 1; off >>= 1) {
            va = umin(va, (unsigned)__shfl_xor((int)va, off));
            vb = umin(vb, (unsigned)__shfl_xor((int)vb, off));
        }
        if (lane == 0) { outA[k] = (int)(va & 2047u); outB[k] = (int)(vb & 2047u); }
        pa = va + 1u;
        pb = vb + 1u;
    }
}

// ---------------------------------------------------------------------------
// Layer-1 kNN (C=3, fp32) with packed-key selection, 2 queries/wave.
__global__ __launch_bounds__(256) void k_knn3(const float* __restrict__ x0,
                                              int* __restrict__ idx) {
    __shared__ float qf[8][3];
    int ib = blockIdx.x;
    int b  = ib / (N_PTS / 8);
    int q0 = (ib % (N_PTS / 8)) * 8;
    const float* xb = x0 + (size_t)b * 3 * N_PTS;

    if (threadIdx.x < 24) {
        int q = threadIdx.x / 3, c = threadIdx.x % 3;
        qf[q][c] = xb[(size_t)c * N_PTS + q0 + q];
    }
    __syncthreads();

    int w = threadIdx.x >> 6, lane = threadIdx.x & 63;
    int qa = q0 + 2 * w;
    int mbase = lane * 32;

    float da[32], db[32];
#pragma unroll
    for (int j = 0; j < 32; ++j) { da[j] = 0.f; db[j] = 0.f; }
#pragma unroll
    for (int c = 0; c < 3; ++c) {
        float r[32];
        load32(xb + (size_t)c * N_PTS, mbase, r);
        float qac = qf[2 * w][c], qbc = qf[2 * w + 1][c];
#pragma unroll
        for (int j = 0; j < 32; ++j) {
            float ta = r[j] - qac; da[j] = fmaf(ta, ta, da[j]);
            float tb = r[j] - qbc; db[j] = fmaf(tb, tb, db[j]);
        }
    }
    unsigned ka[32], kb[32];
#pragma unroll
    for (int j = 0; j < 32; ++j) {
        ka[j] = (__float_as_uint(da[j]) & 0xFFFFF800u) | (unsigned)(mbase + j);
        kb[j] = (__float_as_uint(db[j]) & 0xFFFFF800u) | (unsigned)(mbase + j);
    }
    select20x2(ka, kb, idx + ((size_t)b * N_PTS + qa) * KNN,
               idx + ((size_t)b * N_PTS + qa + 1) * KNN, lane);
}

// ---------------------------------------------------------------------------
// Score-based top-20 (gram path): dist = xx[m] - 2G[q][m] + xx[q], clamped >=0.
__global__ __launch_bounds__(256) void k_select2(const float* __restrict__ G,
                                                 const float* __restrict__ xx,
                                                 int* __restrict__ idx) {
    int ib = blockIdx.x;
    int b  = ib / (N_PTS / 8);
    int q0 = (ib % (N_PTS / 8)) * 8;
    int w = threadIdx.x >> 6, lane = threadIdx.x & 63;
    int qa = q0 + 2 * w;
    const float* gA = G + ((size_t)b * N_PTS + qa) * N_PTS;
    const float* gB = gA + N_PTS;
    const float* xr = xx + (size_t)b * N_PTS;
    float xqa = xr[qa], xqb = xr[qa + 1];

    unsigned ka[32], kb[32];
#pragma unroll
    for (int r = 0; r < 8; ++r) {
        int m0 = r * 256 + (lane << 2);
        float4 x4 = *(const float4*)(xr + m0);
        float4 a4 = *(const float4*)(gA + m0);
        float4 b4 = *(const float4*)(gB + m0);
        float s;
        s = fmaf(-2.f, a4.x, x4.x) + xqa; s = fmaxf(s, 0.f);
        ka[4 * r + 0] = (__float_as_uint(s) & 0xFFFFF800u) | (unsigned)(m0 + 0);
        s = fmaf(-2.f, a4.y, x4.y) + xqa; s = fmaxf(s, 0.f);
        ka[4 * r + 1] = (__float_as_uint(s) & 0xFFFFF800u) | (unsigned)(m0 + 1);
        s = fmaf(-2.f, a4.z, x4.z) + xqa; s = fmaxf(s, 0.f);
        ka[4 * r + 2] = (__float_as_uint(s) & 0xFFFFF800u) | (unsigned)(m0 + 2);
        s = fmaf(-2.f, a4.w, x4.w) + xqa; s = fmaxf(s, 0.f);
        ka[4 * r + 3] = (__float_as_uint(s) & 0xFFFFF800u) | (unsigned)(m0 + 3);
        s = fmaf(-2.f, b4.x, x4.x) + xqb; s = fmaxf(s, 0.f);
        kb[4 * r + 0] = (__float_as_uint(s) & 0xFFFFF800u) | (unsigned)(m0 + 0);
        s = fmaf(-2.f, b4.y, x4.y) + xqb; s = fmaxf(s, 0.f);
        kb[4 * r + 1] = (__float_as_uint(s) & 0xFFFFF800u) | (unsigned)(m0 + 1);
        s = fmaf(-2.f, b4.z, x4.z) + xqb; s = fmaxf(s, 0.f);
        kb[4 * r + 2] = (__float_as_uint(s) & 0xFFFFF800u) | (unsigned)(m0 + 2);
        s = fmaf(-2.f, b4.w, x4.w) + xqb; s = fmaxf(s, 0.f);
        kb[4 * r + 3] = (__float_as_uint(s) & 0xFFFFF800u) | (unsigned)(m0 + 3);
    }
    select20x2(ka, kb, idx + ((size_t)b * N_PTS + qa) * KNN,
               idx + ((size_t)b * N_PTS + qa + 1) * KNN, lane);
}

// ---------------------------------------------------------------------------
// kNN (direct, fallback path): wave-per-query.
template<typename T, int C>
__global__ __launch_bounds__(256) void k_knn(const T* __restrict__ x, int bstride,
                                             int* __restrict__ idx) {
    __shared__ float qf[4][C];
    int ib = blockIdx.x;
    int b  = ib / (N_PTS / 4);
    int q0 = (ib % (N_PTS / 4)) * 4;
    const T* xb = x + (size_t)b * bstride;

    for (int t = threadIdx.x; t < 4 * C; t += 256) {
        int pt = t / C, c = t % C;
        qf[pt][c] = ldf(&xb[(size_t)c * N_PTS + (q0 + pt)]);
    }
    __syncthreads();

    int w = threadIdx.x >> 6, lane = threadIdx.x & 63;
    int q = q0 + w;
    int mbase = lane * 32;

    float v[32];
#pragma unroll
    for (int j = 0; j < 32; ++j) v[j] = 0.f;

    for (int c = 0; c < C; ++c) {
        float qc = qf[w][c];
        float r[32];
        load32(xb + (size_t)c * N_PTS, mbase, r);
#pragma unroll
        for (int j = 0; j < 32; ++j) { float t = r[j] - qc; v[j] = fmaf(t, t, v[j]); }
    }

    for (int k = 0; k < KNN; ++k) {
        float bv = FLT_MAX; int bi = 0x7FFFFFFF;
#pragma unroll
        for (int j = 0; j < 32; ++j)
            if (v[j] < bv) { bv = v[j]; bi = mbase + j; }
#pragma unroll
        for (int off = 32; off >= 1; off >>= 1) {
            float ov = __shfl_xor(bv, off);
            int   oi = __shfl_xor(bi, off);
            if (ov < bv || (ov == bv && oi < bi)) { bv = ov; bi = oi; }
        }
        if (lane == 0) idx[((size_t)b * N_PTS + q) * KNN + k] = bi;
        int wl = bi >> 5, wj = bi & 31;
        if (lane == wl) {
#pragma unroll
            for (int j = 0; j < 32; ++j) if (j == wj) v[j] = FLT_MAX;
        }
    }
}

// ---------------------------------------------------------------------------
// Candidate squared norms over a channel slice.
template<int C>
__global__ void k_xx(const bf16* __restrict__ featT, int c0, float* __restrict__ xx) {
    int i = blockIdx.x * blockDim.x + threadIdx.x;
    if (i >= B_SZ * N_PTS) return;
    const bf16* row = featT + (size_t)i * FT + c0;
    float s = 0.f;
    for (int c = 0; c < C; c += 8) {
        uint4 u = *(const uint4*)(row + c);
        float v0 = __uint_as_float(u.x << 16), v1 = __uint_as_float(u.x & 0xFFFF0000u);
        float v2 = __uint_as_float(u.y << 16), v3 = __uint_as_float(u.y & 0xFFFF0000u);
        float v4 = __uint_as_float(u.z << 16), v5 = __uint_as_float(u.z & 0xFFFF0000u);
        float v6 = __uint_as_float(u.w << 16), v7 = __uint_as_float(u.w & 0xFFFF0000u);
        s = fmaf(v0, v0, s); s = fmaf(v1, v1, s); s = fmaf(v2, v2, s); s = fmaf(v3, v3, s);
        s = fmaf(v4, v4, s); s = fmaf(v5, v5, s); s = fmaf(v6, v6, s); s = fmaf(v7, v7, s);
    }
    xx[i] = s;
}

// ---------------------------------------------------------------------------
// Gram matrix via MFMA: G[b][n][m] = sum_c X[c][n]*X[c][m], X = featT slice.
template<int C>
__global__ __launch_bounds__(256) void k_gram(const bf16* __restrict__ featT, int c0,
                                              float* __restrict__ G) {
    const int KC = 64;
    __shared__ __align__(16) short At[128 * 72];
    __shared__ __align__(16) short Bt[128 * 72];

    int ib = blockIdx.x;
    int b  = ib >> 8;
    int t  = ib & 255;
    int n0 = (t >> 4) << 7;
    int m0 = (t & 15) << 7;

    int tid = threadIdx.x;
    int w = tid >> 6, lane = tid & 63;
    int rw = (w & 1) * 64, cw = (w >> 1) * 64;
    int lrow = lane & 15, quad = lane >> 4;

    floatx4 acc[4][4];
#pragma unroll
    for (int ri = 0; ri < 4; ++ri)
#pragma unroll
        for (int ci = 0; ci < 4; ++ci) acc[ri][ci] = (floatx4){0.f, 0.f, 0.f, 0.f};

    for (int ck = 0; ck < C; ck += KC) {
        __syncthreads();
        for (int s = tid; s < 1024; s += 256) {
            int row = s >> 3, g = s & 7;
            *(uint4*)&At[row * 72 + g * 8] =
                *(const uint4*)(featT + ((size_t)(b * N_PTS + n0 + row) * FT) + c0 + ck + g * 8);
            *(uint4*)&Bt[row * 72 + g * 8] =
                *(const uint4*)(featT + ((size_t)(b * N_PTS + m0 + row) * FT) + c0 + ck + g * 8);
        }
        __syncthreads();
#pragma unroll
        for (int kk = 0; kk < KC; kk += 32) {
            short8v a[4], bb[4];
#pragma unroll
            for (int ri = 0; ri < 4; ++ri)
                a[ri] = *(const short8v*)&At[(rw + ri * 16 + lrow) * 72 + kk + quad * 8];
#pragma unroll
            for (int ci = 0; ci < 4; ++ci)
                bb[ci] = *(const short8v*)&Bt[(cw + ci * 16 + lrow) * 72 + kk + quad * 8];
#pragma unroll
            for (int ri = 0; ri < 4; ++ri)
#pragma unroll
                for (int ci = 0; ci < 4; ++ci)
                    acc[ri][ci] = __builtin_amdgcn_mfma_f32_16x16x32_bf16(a[ri], bb[ci], acc[ri][ci], 0, 0, 0);
        }
    }

#pragma unroll
    for (int ri = 0; ri < 4; ++ri)
#pragma unroll
        for (int ci = 0; ci < 4; ++ci) {
            int n = n0 + rw + ri * 16 + quad * 4;
            int m = m0 + cw + ci * 16 + lrow;
            float* gp = G + ((size_t)b * N_PTS + n) * N_PTS + m;
#pragma unroll
            for (int reg = 0; reg < 4; ++reg)
                gp[(size_t)reg * N_PTS] = acc[ri][ci][reg];
        }
}

// ---------------------------------------------------------------------------
// Dense point transform via MFMA (EdgeConv linear part, all points at once):
// Y[i][0..COUT) = W2 . x_i ; Y[i][COUT..2COUT) = Wd . x_i  (hi/lo split).
template<int COUT, int C>
__global__ __launch_bounds__(256) void k_xform(const bf16* __restrict__ featT, int c0,
                                               const bf16* __restrict__ Wsp,
                                               float* __restrict__ Y) {
    const int M2 = 2 * COUT;
    const int KC = 64;
    __shared__ __align__(16) short Bt[128 * 72];

    int ib = blockIdx.x;
    int nt = ib & 63;
    int mt = ib >> 6;
    int tid = threadIdx.x;
    int w = tid >> 6, lane = tid & 63;
    int rw = (w & 1) * 64, cw = (w >> 1) * 64;
    int l15 = lane & 15, quad = lane >> 4;

    floatx4 acc[4][4];
#pragma unroll
    for (int ri = 0; ri < 4; ++ri)
#pragma unroll
        for (int ci = 0; ci < 4; ++ci) acc[ri][ci] = (floatx4){0.f, 0.f, 0.f, 0.f};

    for (int ck = 0; ck < C; ck += KC) {
        __syncthreads();
        for (int s = tid; s < 1024; s += 256) {
            int row = s >> 3, g = s & 7;
            *(uint4*)&Bt[row * 72 + g * 8] =
                *(const uint4*)(featT + (size_t)(nt * 128 + row) * FT + c0 + ck + g * 8);
        }
        __syncthreads();
#pragma unroll
        for (int kk = 0; kk < KC; kk += 32) {
            short8v bfr[4];
#pragma unroll
            for (int ci = 0; ci < 4; ++ci)
                bfr[ci] = *(const short8v*)&Bt[(cw + ci * 16 + l15) * 72 + kk + quad * 8];
#pragma unroll
            for (int ri = 0; ri < 4; ++ri) {
                int mrow = mt * 128 + rw + ri * 16 + l15;
                int base = (mrow < COUT) ? mrow : (mrow + COUT);
                const bf16* hi = Wsp + (size_t)base * C + ck + kk + quad * 8;
                short8v ah = ld8(hi);
                short8v al = ld8(hi + (size_t)COUT * C);
#pragma unroll
                for (int ci = 0; ci < 4; ++ci) {
                    acc[ri][ci] = __builtin_amdgcn_mfma_f32_16x16x32_bf16(ah, bfr[ci], acc[ri][ci], 0, 0, 0);
                    acc[ri][ci] = __builtin_amdgcn_mfma_f32_16x16x32_bf16(al, bfr[ci], acc[ri][ci], 0, 0, 0);
                }
            }
        }
    }

#pragma unroll
    for (int ri = 0; ri < 4; ++ri)
#pragma unroll
        for (int ci = 0; ci < 4; ++ci) {
            int n = nt * 128 + cw + ci * 16 + l15;
            int m = mt * 128 + rw + ri * 16 + quad * 4;
            *(floatx4*)(Y + (size_t)n * M2 + m) = acc[ri][ci];
        }
}

// ---------------------------------------------------------------------------
// Gather-max epilogue: out[o][n] = max_k lrelu((Yd[n][o] + Y2[m_k][o])*s + b).
template<int COUT>
__global__ __launch_bounds__(256) void k_gmax(const float* __restrict__ Y,
        const int* __restrict__ idx,
        const float* __restrict__ gam, const float* __restrict__ bet,
        bf16* __restrict__ featT, int c0f) {
    const int M2 = 2 * COUT;
    const int OT = COUT / 64;
    int i = blockIdx.x * 4 + (threadIdx.x >> 6);
    int lane = threadIdx.x & 63;
    int b = i >> 11;

    const float inv = rsqrtf(1.0f + 1e-5f);
    float yd[OT], scale[OT], bias[OT], mx[OT];
#pragma unroll
    for (int j = 0; j < OT; ++j) {
        int o = lane + 64 * j;
        yd[j]    = Y[(size_t)i * M2 + COUT + o];
        scale[j] = gam[o] * inv;
        bias[j]  = bet[o];
        mx[j]    = -FLT_MAX;
    }

    const int* ip = idx + (size_t)i * KNN;
    const float* Yb = Y + ((size_t)b * N_PTS) * M2;
#pragma unroll 4
    for (int k = 0; k < KNN; ++k) {
        int m = ip[k] & (N_PTS - 1);
        const float* yr = Yb + (size_t)m * M2;
#pragma unroll
        for (int j = 0; j < OT; ++j) {
            float h = (yd[j] + yr[lane + 64 * j]) * scale[j] + bias[j];
            h = h > 0.f ? h : LRELU_S * h;
            mx[j] = fmaxf(mx[j], h);
        }
    }
#pragma unroll
    for (int j = 0; j < OT; ++j)
        featT[(size_t)i * FT + c0f + lane + 64 * j] = __float2bfloat16(mx[j]);
}

// ---------------------------------------------------------------------------
// EdgeConv (VALU): layer 1 (C=3) and ws-fallback path.
template<typename T, int C, int COUT, bool WF>
__global__ __launch_bounds__(256) void k_edgeconv(const T* __restrict__ x, int bstride,
                           const int* __restrict__ idx,
                           const float* __restrict__ Wt,
                           const float* __restrict__ gam,
                           const float* __restrict__ bet,
                           bf16* __restrict__ out, int ostride,
                           bf16* __restrict__ featT, int c0f) {
    const int PT = 4;
    const int OT = COUT / 64;
    const int CP = (C + 3) & ~3;
    __shared__ float sh[PT][KNN + 1][CP];

    int ib = blockIdx.x;
    int b  = ib / (N_PTS / PT);
    int n0 = (ib % (N_PTS / PT)) * PT;
    const T* xb = x + (size_t)b * bstride;

    const int TOT = PT * (KNN + 1) * C;
    for (int t = threadIdx.x; t < TOT; t += 256) {
        int pt = t / ((KNN + 1) * C);
        int r  = t % ((KNN + 1) * C);
        int row = r / C, c = r % C;
        int n = n0 + pt;
        int m = (row == 0) ? n
                           : (idx[((size_t)b * N_PTS + n) * KNN + (row - 1)] & (N_PTS - 1));
        sh[pt][row][c] = ldf(&xb[(size_t)c * N_PTS + m]);
    }
    __syncthreads();

    int w = threadIdx.x >> 6, lane = threadIdx.x & 63;
    int n = n0 + w;

    constexpr int KT = (OT >= 4) ? 10 : 20;
    constexpr int NPASS = KNN / KT;

    float base[OT];
    float mx[OT];
#pragma unroll
    for (int j = 0; j < OT; ++j) { base[j] = 0.f; mx[j] = -FLT_MAX; }

    const float inv = rsqrtf(1.0f + 1e-5f);

#pragma unroll
    for (int pass = 0; pass < NPASS; ++pass) {
        float acc[OT][KT];
#pragma unroll
        for (int j = 0; j < OT; ++j)
#pragma unroll
            for (int k = 0; k < KT; ++k) acc[j][k] = 0.f;

        for (int c = 0; c < C; ++c) {
            float xq = sh[w][0][c];
            float w2v[OT];
#pragma unroll
            for (int j = 0; j < OT; ++j)
                w2v[j] = Wt[(size_t)(C + c) * COUT + lane + 64 * j];
            if (pass == 0) {
#pragma unroll
                for (int j = 0; j < OT; ++j) {
                    float w1v = Wt[(size_t)c * COUT + lane + 64 * j];
                    base[j] = fmaf(w1v - w2v[j], xq, base[j]);
                }
            }
#pragma unroll
            for (int k = 0; k < KT; ++k) {
                float nv = sh[w][1 + pass * KT + k][c];
#pragma unroll
                for (int j = 0; j < OT; ++j) acc[j][k] = fmaf(w2v[j], nv, acc[j][k]);
            }
        }

#pragma unroll
        for (int j = 0; j < OT; ++j) {
            int o = lane + 64 * j;
            float scale = gam[o] * inv, bias = bet[o];
#pragma unroll
            for (int k = 0; k < KT; ++k) {
                float h = (base[j] + acc[j][k]) * scale + bias;
                h = h > 0.f ? h : LRELU_S * h;
                mx[j] = fmaxf(mx[j], h);
            }
        }
    }

#pragma unroll
    for (int j = 0; j < OT; ++j) {
        int o = lane + 64 * j;
        bf16 bv = __float2bfloat16(mx[j]);
        out[(size_t)b * ostride + (size_t)o * N_PTS + n] = bv;
        if (WF) featT[((size_t)b * N_PTS + n) * FT + c0f + o] = bv;
    }
}

// ---------------------------------------------------------------------------
// conv5 via MFMA, LDS-staged A (weight hi/lo tiles) and B (featT rows),
// fused BN/LReLU + max/sum pooling partials. Block: 64o x 256n, 4 waves.
// Same ck/kk/hi-lo accumulation order as round 11 -> bit-identical.
__global__ __launch_bounds__(256) void k_conv5mfma(
        const bf16* __restrict__ featT, const bf16* __restrict__ w5sp,
        const float* __restrict__ g5, const float* __restrict__ b5,
        float* __restrict__ fmxp, float* __restrict__ fsmp) {
    __shared__ __align__(16) short Bt[256 * 72];   // 36 KB
    __shared__ __align__(16) short Ah[64 * 72];    //  9 KB
    __shared__ __align__(16) short Al[64 * 72];    //  9 KB
    __shared__ float rmx[4][64];
    __shared__ float rsm[4][64];

    int ib = blockIdx.x;                 // B * 16 * 8
    int b  = ib / 128;
    int rem = ib % 128;
    int o0 = (rem >> 3) * 64;
    int nt = rem & 7;
    int tid = threadIdx.x;
    int w = tid >> 6, lane = tid & 63;
    int l15 = lane & 15, quad = lane >> 4;

    const bf16* Whi = w5sp;
    const bf16* Wlo = w5sp + 1024 * 512;
    const bf16* fb  = featT + (size_t)b * N_PTS * FT;
    const int nbase0 = nt * 256;

    floatx4 acc[4][4];
#pragma unroll
    for (int mi = 0; mi < 4; ++mi)
#pragma unroll
        for (int ni = 0; ni < 4; ++ni) acc[mi][ni] = (floatx4){0.f, 0.f, 0.f, 0.f};

    for (int ck = 0; ck < 512; ck += 64) {
        __syncthreads();
        for (int s = tid; s < 2048; s += 256) {          // B: 256 rows x 64k
            int row = s >> 3, g = s & 7;
            *(uint4*)&Bt[row * 72 + g * 8] =
                *(const uint4*)(fb + (size_t)(nbase0 + row) * FT + ck + g * 8);
        }
        for (int s = tid; s < 512; s += 256) {           // A hi/lo: 64 rows x 64k
            int row = s >> 3, g = s & 7;
            *(uint4*)&Ah[row * 72 + g * 8] =
                *(const uint4*)(Whi + (size_t)(o0 + row) * 512 + ck + g * 8);
            *(uint4*)&Al[row * 72 + g * 8] =
                *(const uint4*)(Wlo + (size_t)(o0 + row) * 512 + ck + g * 8);
        }
        __syncthreads();
#pragma unroll
        for (int kk = 0; kk < 64; kk += 32) {
            short8v bfr[4], ah[4], al[4];
#pragma unroll
            for (int ni = 0; ni < 4; ++ni)
                bfr[ni] = *(const short8v*)&Bt[(w * 64 + ni * 16 + l15) * 72 + kk + quad * 8];
#pragma unroll
            for (int mi = 0; mi < 4; ++mi) {
                ah[mi] = *(const short8v*)&Ah[(mi * 16 + l15) * 72 + kk + quad * 8];
                al[mi] = *(const short8v*)&Al[(mi * 16 + l15) * 72 + kk + quad * 8];
            }
#pragma unroll
            for (int mi = 0; mi < 4; ++mi)
#pragma unroll
                for (int ni = 0; ni < 4; ++ni) {
                    acc[mi][ni] = __builtin_amdgcn_mfma_f32_16x16x32_bf16(ah[mi], bfr[ni], acc[mi][ni], 0, 0, 0);
                    acc[mi][ni] = __builtin_amdgcn_mfma_f32_16x16x32_bf16(al[mi], bfr[ni], acc[mi][ni], 0, 0, 0);
                }
        }
    }

    const float inv = rsqrtf(1.0f + 1e-5f);
#pragma unroll
    for (int mi = 0; mi < 4; ++mi) {
#pragma unroll
        for (int r = 0; r < 4; ++r) {
            int o = o0 + mi * 16 + quad * 4 + r;
            float scale = g5[o] * inv, bias = b5[o];
            float mx = -FLT_MAX, sm = 0.f;
#pragma unroll
            for (int ni = 0; ni < 4; ++ni) {
                float h = acc[mi][ni][r] * scale + bias;
                h = h > 0.f ? h : LRELU_S * h;
                mx = fmaxf(mx, h);
                sm += h;
            }
#pragma unroll
            for (int off = 1; off <= 8; off <<= 1) {
                mx = fmaxf(mx, __shfl_xor(mx, off));
                sm += __shfl_xor(sm, off);
            }
            if (l15 == 0) {
                rmx[w][mi * 16 + quad * 4 + r] = mx;
                rsm[w][mi * 16 + quad * 4 + r] = sm;
            }
        }
    }
    __syncthreads();
    if (tid < 64) {
        float mx = -FLT_MAX, sm = 0.f;
#pragma unroll
        for (int ww = 0; ww < 4; ++ww) { mx = fmaxf(mx, rmx[ww][tid]); sm += rsm[ww][tid]; }
        fmxp[((size_t)b * 1024 + o0 + tid) * NPOOL + nt] = mx;
        fsmp[((size_t)b * 1024 + o0 + tid) * NPOOL + nt] = sm;
    }
}

// ---------------------------------------------------------------------------
// Pool partial reduce -> fvec (B, 2048) = [max(1024) | mean(1024)].
__global__ void k_pool(const float* __restrict__ fmxp, const float* __restrict__ fsmp,
                       float* __restrict__ fvec) {
    int i = blockIdx.x * blockDim.x + threadIdx.x;
    if (i >= B_SZ * 1024) return;
    int b = i >> 10, o = i & 1023;
    float mx = -FLT_MAX, sm = 0.f;
    for (int ch = 0; ch < NPOOL; ++ch) {
        mx = fmaxf(mx, fmxp[(size_t)i * NPOOL + ch]);
        sm += fsmp[(size_t)i * NPOOL + ch];
    }
    fvec[(size_t)b * 2048 + o] = mx;
    fvec[(size_t)b * 2048 + 1024 + o] = sm * (1.0f / N_PTS);
}

// ---------------------------------------------------------------------------
// fc1 (raw-dtype weights): block per (b,o).
__global__ __launch_bounds__(256) void k_fc1(const float* __restrict__ fvec,
        const void* __restrict__ fw1, const void* __restrict__ fb1,
        const void* __restrict__ g6,  const void* __restrict__ b6,
        const int* __restrict__ flag, float* __restrict__ tbuf) {
    __shared__ float red[4];
    int ib = blockIdx.x;
    int b = ib >> 9, o = ib & 511;
    const float* fv = fvec + (size_t)b * 2048;
    int tid = threadIdx.x;
    const int isb = *flag;
    float s = 0.f;
    if (isb) {
        const bf16* wr = (const bf16*)fw1 + (size_t)o * 2048;
        for (int j = tid; j < 2048; j += 256) s = fmaf(b2f(wr[j]), fv[j], s);
    } else {
        const float* wr = (const float*)fw1 + (size_t)o * 2048;
        for (int j = tid; j < 2048; j += 256) s = fmaf(wr[j], fv[j], s);
    }
#pragma unroll
    for (int off = 32; off >= 1; off >>= 1) s += __shfl_xor(s, off);
    if ((tid & 63) == 0) red[tid >> 6] = s;
    __syncthreads();
    if (tid == 0) {
        float fb = isb ? b2f(((const bf16*)fb1)[o]) : ((const float*)fb1)[o];
        float gg = isb ? b2f(((const bf16*)g6)[o])  : ((const float*)g6)[o];
        float bb = isb ? b2f(((const bf16*)b6)[o])  : ((const float*)b6)[o];
        float acc = fb + red[0] + red[1] + red[2] + red[3];
        float h = acc * gg * rsqrtf(1.0f + 1e-5f) + bb;
        tbuf[(size_t)b * 512 + o] = h > 0.f ? h : LRELU_S * h;
    }
}

// ---------------------------------------------------------------------------
// fc2 (raw-dtype weights): block per (b,o).
__global__ __launch_bounds__(256) void k_fc2(const float* __restrict__ tbuf,
        const void* __restrict__ fw2, const void* __restrict__ fb2,
        const void* __restrict__ g7,  const void* __restrict__ b7,
        const int* __restrict__ flag, void* __restrict__ out) {
    __shared__ float red[4];
    int ib = blockIdx.x;
    int b = ib >> 8, o = ib & 255;
    const float* tv = tbuf + (size_t)b * 512;
    int tid = threadIdx.x;
    const int isb = *flag;
    float s;
    if (isb) {
        const bf16* wr = (const bf16*)fw2 + (size_t)o * 512;
        s = fmaf(b2f(wr[tid]), tv[tid], b2f(wr[tid + 256]) * tv[tid + 256]);
    } else {
        const float* wr = (const float*)fw2 + (size_t)o * 512;
        s = fmaf(wr[tid], tv[tid], wr[tid + 256] * tv[tid + 256]);
    }
#pragma unroll
    for (int off = 32; off >= 1; off >>= 1) s += __shfl_xor(s, off);
    if ((tid & 63) == 0) red[tid >> 6] = s;
    __syncthreads();
    if (tid == 0) {
        float fb = isb ? b2f(((const bf16*)fb2)[o]) : ((const float*)fb2)[o];
        float gg = isb ? b2f(((const bf16*)g7)[o])  : ((const float*)g7)[o];
        float bb = isb ? b2f(((const bf16*)b7)[o])  : ((const float*)b7)[o];
        float acc = fb + red[0] + red[1] + red[2] + red[3];
        float h = acc * gg * rsqrtf(1.0f + 1e-5f) + bb;
        if (isb) ((bf16*)out)[(size_t)b * 256 + o] = __float2bfloat16(h);
        else     ((float*)out)[(size_t)b * 256 + o] = h;
    }
}

// ---------------------------------------------------------------------------
// Fallback conv5 (VALU) + head, used when ws too small for the gram path.
#define NCH 2
__global__ __launch_bounds__(256) void k_conv5pool(const bf16* __restrict__ feat,
                            const float* __restrict__ w5,
                            const float* __restrict__ g5,
                            const float* __restrict__ b5,
                            float* __restrict__ fmxp, float* __restrict__ fsmp) {
    const int OT = 8;
    const int NT = 4;
    const int CHN = N_PTS / NCH;
    __shared__ float wl[OT][512];
    __shared__ float rmx[4][OT];
    __shared__ float rsm[4][OT];

    int ib = blockIdx.x;
    int ch = ib % NCH;
    int ot = (ib / NCH) % (1024 / OT);
    int b  = ib / (NCH * (1024 / OT));
    int o0 = ot * OT;
    const bf16* fb = feat + (size_t)b * 512 * N_PTS;

    for (int t = threadIdx.x; t < OT * 512; t += 256) {
        int o = t >> 9, c = t & 511;
        wl[o][c] = w5[(size_t)(o0 + o) * 512 + c];
    }
    __syncthreads();

    const int n0 = ch * CHN + threadIdx.x * NT;

    float acc[OT][NT];
#pragma unroll
    for (int o = 0; o < OT; ++o)
#pragma unroll
        for (int t = 0; t < NT; ++t) acc[o][t] = 0.f;

    for (int c = 0; c < 512; c += 4) {
        float fv[4][NT];
#pragma unroll
        for (int j = 0; j < 4; ++j) {
            uint2 u = *(const uint2*)(fb + (size_t)(c + j) * N_PTS + n0);
            fv[j][0] = __uint_as_float(u.x << 16);
            fv[j][1] = __uint_as_float(u.x & 0xFFFF0000u);
            fv[j][2] = __uint_as_float(u.y << 16);
            fv[j][3] = __uint_as_float(u.y & 0xFFFF0000u);
        }
#pragma unroll
        for (int o = 0; o < OT; ++o) {
            float4 wv = *(const float4*)&wl[o][c];
#pragma unroll
            for (int t = 0; t < NT; ++t) {
                acc[o][t] = fmaf(wv.x, fv[0][t], acc[o][t]);
                acc[o][t] = fmaf(wv.y, fv[1][t], acc[o][t]);
                acc[o][t] = fmaf(wv.z, fv[2][t], acc[o][t]);
                acc[o][t] = fmaf(wv.w, fv[3][t], acc[o][t]);
            }
        }
    }

    const float inv = rsqrtf(1.0f + 1e-5f);
    int w = threadIdx.x >> 6, lane = threadIdx.x & 63;
#pragma unroll
    for (int o = 0; o < OT; ++o) {
        float scale = g5[o0 + o] * inv, bias = b5[o0 + o];
        float mx = -FLT_MAX, sm = 0.f;
#pragma unroll
        for (int t = 0; t < NT; ++t) {
            float h = acc[o][t] * scale + bias;
            h = h > 0.f ? h : LRELU_S * h;
            mx = fmaxf(mx, h);
            sm += h;
        }
#pragma unroll
        for (int off = 32; off >= 1; off >>= 1) {
            mx = fmaxf(mx, __shfl_xor(mx, off));
            sm += __shfl_xor(sm, off);
        }
        if (lane == 0) { rmx[w][o] = mx; rsm[w][o] = sm; }
    }
    __syncthreads();
    if (threadIdx.x < OT) {
        int o = threadIdx.x;
        float mx = -FLT_MAX, sm = 0.f;
#pragma unroll
        for (int ww = 0; ww < 4; ++ww) { mx = fmaxf(mx, rmx[ww][o]); sm += rsm[ww][o]; }
        fmxp[((size_t)b * 1024 + o0 + o) * NCH + ch] = mx;
        fsmp[((size_t)b * 1024 + o0 + o) * NCH + ch] = sm;
    }
}

__global__ void k_head(const float* __restrict__ fmxp, const float* __restrict__ fsmp,
                       const float* __restrict__ fw1, const float* __restrict__ fb1,
                       const float* __restrict__ g6,  const float* __restrict__ b6,
                       const float* __restrict__ fw2, const float* __restrict__ fb2,
                       const float* __restrict__ g7,  const float* __restrict__ b7,
                       const int* __restrict__ flag, void* __restrict__ out) {
    __shared__ float f[2048];
    __shared__ float t[512];
    int b = blockIdx.x;
    for (int i = threadIdx.x; i < 1024; i += 256) {
        float mx = -FLT_MAX, sm = 0.f;
        for (int ch = 0; ch < NCH; ++ch) {
            mx = fmaxf(mx, fmxp[((size_t)b * 1024 + i) * NCH + ch]);
            sm += fsmp[((size_t)b * 1024 + i) * NCH + ch];
        }
        f[i]        = mx;
        f[1024 + i] = sm * (1.0f / N_PTS);
    }
    __syncthreads();
    const float inv = rsqrtf(1.0f + 1e-5f);
    for (int o = threadIdx.x; o < 512; o += 256) {
        const float* wr = fw1 + (size_t)o * 2048;
        float acc = fb1[o];
        for (int j = 0; j < 2048; ++j) acc += wr[j] * f[j];
        float h = acc * g6[o] * inv + b6[o];
        t[o] = h > 0.f ? h : LRELU_S * h;
    }
    __syncthreads();
    {
        int o = threadIdx.x;
        const float* wr = fw2 + (size_t)o * 512;
        float acc = fb2[o];
        for (int j = 0; j < 512; ++j) acc += wr[j] * t[j];
        float h = acc * g7[o] * inv + b7[o];
        if (*flag) ((bf16*)out)[(size_t)b * 256 + o] = __float2bfloat16(h);
        else       ((float*)out)[(size_t)b * 256 + o] = h;
    }
}

// ---------------------------------------------------------------------------
extern "C" void kernel_launch(void* const* d_in, const int* in_sizes, int n_in,
                              void* d_out, int out_size, void* d_ws, size_t ws_size,
                              hipStream_t stream) {
    static const int wsz[23] = {
        384, 64, 64,   8192, 64, 64,   16384, 128, 128,   65536, 256, 256,
        524288, 1024, 1024,   1048576, 512,   512, 512,   131072, 256,   256, 256
    };
    static const int trows[23] = {64,0,0, 64,0,0, 128,0,0, 256,0,0, 0,0,0, 0,0, 0,0, 0,0, 0,0};
    static const int tcols[23] = { 6,0,0,128,0,0, 128,0,0, 256,0,0, 0,0,0, 0,0, 0,0, 0,0, 0,0};

    WPack wp;
    int total = 0;
    for (int i = 0; i < 23; ++i) {
        wp.src[i] = d_in[i + 1]; wp.off[i] = total; total += wsz[i];
        wp.rows[i] = trows[i]; wp.cols[i] = tcols[i];
    }
    wp.off[23] = total;

    const size_t flag_bytes = 16;
    const size_t x0_bytes   = (size_t)B_SZ * 3 * N_PTS * 4;
    const size_t feat_bytes = (size_t)B_SZ * 512 * N_PTS * 2;
    const size_t idx_bytes  = (size_t)B_SZ * N_PTS * KNN * 4;
    const size_t pool_bytes = (size_t)B_SZ * 1024 * 4 * 2;
    const size_t wf_bytes   = (size_t)total * 4;
    const size_t base_need  = flag_bytes + x0_bytes + feat_bytes + idx_bytes + pool_bytes + wf_bytes;

    const size_t featT_bytes = (size_t)B_SZ * N_PTS * FT * 2;           //  8 MB
    const size_t xx_bytes    = (size_t)B_SZ * N_PTS * 4;
    const size_t wsp2_elems  = 4 * 64 * 64;
    const size_t wsp3_elems  = 4 * 128 * 64;
    const size_t wsp4_elems  = 4 * 256 * 128;
    const size_t w5sp_elems  = 2 * 1024 * 512;
    const size_t wsp_bytes   = (wsp2_elems + wsp3_elems + wsp4_elems + w5sp_elems) * 2;
    const size_t S_bytes     = (size_t)B_SZ * N_PTS * N_PTS * 4;        // 64 MB (also holds Y)
    const size_t full_need   = base_need + featT_bytes + xx_bytes + wsp_bytes + S_bytes;

    if (ws_size < base_need) return;   // graceful fail
    const bool use_gram = (ws_size >= full_need);

    char* w = (char*)d_ws;
    int*   flag = (int*)w;              w += flag_bytes;
    float* x0   = (float*)w;            w += x0_bytes;
    bf16*  feat = (bf16*)w;             w += feat_bytes;
    int*   idx  = (int*)w;              w += idx_bytes;
    w += pool_bytes;
    float* wf   = (float*)w;            w += wf_bytes;
    bf16*  featT = (bf16*)w;            w += featT_bytes;
    float* xx    = (float*)w;           w += xx_bytes;
    bf16*  wsp2  = (bf16*)w;            w += wsp2_elems * 2;
    bf16*  wsp3  = (bf16*)w;            w += wsp3_elems * 2;
    bf16*  wsp4  = (bf16*)w;            w += wsp4_elems * 2;
    bf16*  w5sp  = (bf16*)w;            w += w5sp_elems * 2;
    float* S     = (float*)w;           // gram scores; reused as Y after select

    // overlays in the idx region (idx dead after ec4):
    float* fmxp = (float*)idx;                               // B*1024*NPOOL
    float* fsmp = fmxp + (size_t)B_SZ * 1024 * NPOOL;        // B*1024*NPOOL
    float* fvec = fsmp + (size_t)B_SZ * 1024 * NPOOL;        // B*2048
    float* tbuf = fvec + (size_t)B_SZ * 2048;                // B*512

    const int FBS = 512 * N_PTS;

    k_sniff<<<1, 64, 0, stream>>>((const unsigned short*)d_in[0], flag);
    // gram path only needs tensors 0..14 repacked (fc weights read raw)
    const int rlimit = use_gram ? wp.off[15] : total;
    k_repack<<<(rlimit + 255) / 256, 256, 0, stream>>>(wp, flag, wf, rlimit);
    k_transpose<<<(B_SZ * N_PTS + 255) / 256, 256, 0, stream>>>(d_in[0], flag, x0);

    const float* w1t = wf + wp.off[0],  *g1 = wf + wp.off[1],  *b1 = wf + wp.off[2];
    const float* w2t = wf + wp.off[3],  *g2 = wf + wp.off[4],  *b2 = wf + wp.off[5];
    const float* w3t = wf + wp.off[6],  *g3 = wf + wp.off[7],  *b3 = wf + wp.off[8];
    const float* w4t = wf + wp.off[9],  *g4 = wf + wp.off[10], *b4 = wf + wp.off[11];
    const float* w5  = wf + wp.off[12], *g5 = wf + wp.off[13], *b5 = wf + wp.off[14];
    const float* fw1 = wf + wp.off[15], *fb1 = wf + wp.off[16];
    const float* g6  = wf + wp.off[17], *b6 = wf + wp.off[18];
    const float* fw2 = wf + wp.off[19], *fb2 = wf + wp.off[20];
    const float* g7  = wf + wp.off[21], *b7 = wf + wp.off[22];

    const int GK = B_SZ * N_PTS / 4;    // 2048 blocks
    const int G8 = B_SZ * N_PTS / 8;    // 1024 blocks (2 queries/wave kernels)
    const int NXX = (B_SZ * N_PTS + 255) / 256;

    if (use_gram) {
        k_wsplit<64, 64><<<(64 * 64 + 255) / 256, 256, 0, stream>>>(d_in[4], flag, wsp2);
        k_wsplit<64, 128><<<(128 * 64 + 255) / 256, 256, 0, stream>>>(d_in[7], flag, wsp3);
        k_wsplit<128, 256><<<(256 * 128 + 255) / 256, 256, 0, stream>>>(d_in[10], flag, wsp4);
        k_w5split<<<(1024 * 512 + 255) / 256, 256, 0, stream>>>(d_in[13], flag, w5sp);

        k_knn3<<<G8, 256, 0, stream>>>(x0, idx);
        k_edgeconv<float, 3, 64, true><<<GK, 256, 0, stream>>>(
            x0, 3 * N_PTS, idx, w1t, g1, b1, feat + 0 * N_PTS, FBS, featT, 0);
        // layer 2
        k_xx<64><<<NXX, 256, 0, stream>>>(featT, 0, xx);
        k_gram<64><<<B_SZ * 256, 256, 0, stream>>>(featT, 0, S);
        k_select2<<<G8, 256, 0, stream>>>(S, xx, idx);
        k_xform<64, 64><<<64, 256, 0, stream>>>(featT, 0, wsp2, S);
        k_gmax<64><<<GK, 256, 0, stream>>>(S, idx, g2, b2, featT, 64);
        // layer 3
        k_xx<64><<<NXX, 256, 0, stream>>>(featT, 64, xx);
        k_gram<64><<<B_SZ * 256, 256, 0, stream>>>(featT, 64, S);
        k_select2<<<G8, 256, 0, stream>>>(S, xx, idx);
        k_xform<128, 64><<<128, 256, 0, stream>>>(featT, 64, wsp3, S);
        k_gmax<128><<<GK, 256, 0, stream>>>(S, idx, g3, b3, featT, 128);
        // layer 4 (writes featT channels [256,512) for conv5)
        k_xx<128><<<NXX, 256, 0, stream>>>(featT, 128, xx);
        k_gram<128><<<B_SZ * 256, 256, 0, stream>>>(featT, 128, S);
        k_select2<<<G8, 256, 0, stream>>>(S, xx, idx);
        k_xform<256, 128><<<256, 256, 0, stream>>>(featT, 128, wsp4, S);
        k_gmax<256><<<GK, 256, 0, stream>>>(S, idx, g4, b4, featT, 256);

        // conv5 MFMA + pooling partials, then head GEMVs (raw fc weights)
        k_conv5mfma<<<B_SZ * 128, 256, 0, stream>>>(featT, w5sp, g5, b5, fmxp, fsmp);
        k_pool<<<(B_SZ * 1024 + 255) / 256, 256, 0, stream>>>(fmxp, fsmp, fvec);
        k_fc1<<<B_SZ * 512, 256, 0, stream>>>(fvec, d_in[16], d_in[17], d_in[18], d_in[19],
                                              flag, tbuf);
        k_fc2<<<B_SZ * 256, 256, 0, stream>>>(tbuf, d_in[20], d_in[21], d_in[22], d_in[23],
                                              flag, d_out);
    } else {
        k_knn<float, 3><<<GK, 256, 0, stream>>>(x0, 3 * N_PTS, idx);
        k_edgeconv<float, 3, 64, false><<<GK, 256, 0, stream>>>(
            x0, 3 * N_PTS, idx, w1t, g1, b1, feat + 0 * N_PTS, FBS, nullptr, 0);
        k_knn<bf16, 64><<<GK, 256, 0, stream>>>(feat + 0 * N_PTS, FBS, idx);
        k_edgeconv<bf16, 64, 64, false><<<GK, 256, 0, stream>>>(
            feat + 0 * N_PTS, FBS, idx, w2t, g2, b2, feat + 64 * N_PTS, FBS, nullptr, 0);
        k_knn<bf16, 64><<<GK, 256, 0, stream>>>(feat + 64 * N_PTS, FBS, idx);
        k_edgeconv<bf16, 64, 128, false><<<GK, 256, 0, stream>>>(
            feat + 64 * N_PTS, FBS, idx, w3t, g3, b3, feat + 128 * N_PTS, FBS, nullptr, 0);
        k_knn<bf16, 128><<<GK, 256, 0, stream>>>(feat + 128 * N_PTS, FBS, idx);
        k_edgeconv<bf16, 128, 256, false><<<GK, 256, 0, stream>>>(
            feat + 128 * N_PTS, FBS, idx, w4t, g4, b4, feat + 256 * N_PTS, FBS, nullptr, 0);

        k_conv5pool<<<B_SZ * (1024 / 8) * NCH, 256, 0, stream>>>(feat, w5, g5, b5, fmxp, fsmp);
        k_head<<<B_SZ, 256, 0, stream>>>(fmxp, fsmp, fw1, fb1, g6, b6, fw2, fb2, g7, b7,
                                         flag, d_out);
    }
}

// Round 13
// 409.120 us; speedup vs baseline: 9.4027x; 1.1555x over previous
//
#include <hip/hip_runtime.h>
#include <hip/hip_bf16.h>
#include <float.h>

#define N_PTS 2048
#define B_SZ  4
#define KNN   20
#define LRELU_S 0.2f
#define FT    512          // featT row stride (channels)
#define NPOOL 8            // conv5 n-chunk partials

typedef __hip_bfloat16 bf16;
typedef __attribute__((ext_vector_type(8))) short short8v;   // 8 bf16 (4 VGPRs)
typedef __attribute__((ext_vector_type(4))) float floatx4;

__device__ __forceinline__ float b2f(const bf16 v) { return __bfloat162float(v); }
__device__ __forceinline__ float ldf(const float* p) { return *p; }
__device__ __forceinline__ float ldf(const bf16* p)  { return __bfloat162float(*p); }
__device__ __forceinline__ short8v ld8(const bf16* p) { return *(const short8v*)p; }
__device__ __forceinline__ unsigned umin(unsigned a, unsigned b) { return a < b ? a : b; }

// ---------------------------------------------------------------------------
// Dtype sniffer (robustness): bf16 (flag=1) vs fp32 (flag=0). Reads 256 B.
__global__ void k_sniff(const unsigned short* __restrict__ pts_hw, int* __restrict__ flag) {
    if (threadIdx.x != 0 || blockIdx.x != 0) return;
    int sane = 0;
    for (int j = 0; j < 64; ++j) {
        unsigned short v = pts_hw[2 * j];
        int e = (v >> 7) & 0xFF;
        if (e >= 100 && e <= 140) ++sane;
    }
    *flag = (sane >= 32) ? 1 : 0;
}

// ---------------------------------------------------------------------------
// Repack first `limit` elements of the weight tensors to fp32 (EdgeConv W
// transposed). Gram path only needs tensors 0..14 (fc weights read raw).
struct WPack {
    const void* src[23];
    int off[24];
    int rows[23];
    int cols[23];
};

__global__ void k_repack(WPack wp, const int* __restrict__ flag, float* __restrict__ dst, int limit) {
    const int isb = *flag;
    int i = blockIdx.x * blockDim.x + threadIdx.x;
    if (i >= limit) return;
    int lo = 0, hi = 23;
    while (lo + 1 < hi) { int mid = (lo + hi) >> 1; if (i >= wp.off[mid]) lo = mid; else hi = mid; }
    int j = i - wp.off[lo];
    float v = isb ? b2f(((const bf16*)wp.src[lo])[j]) : ((const float*)wp.src[lo])[j];
    int dj = j;
    int cols = wp.cols[lo];
    if (cols) dj = (j % cols) * wp.rows[lo] + (j / cols);
    dst[wp.off[lo] + dj] = v;
}

// ---------------------------------------------------------------------------
// Split EdgeConv weights into bf16 hi/lo pairs for MFMA:
// dst = [W2hi | W2lo | Wdhi | Wdlo], each (COUT, C) row-major, Wd = W1 - W2.
template<int C, int COUT>
__global__ void k_wsplit(const void* __restrict__ W, const int* __restrict__ flag,
                         bf16* __restrict__ dst) {
    int i = blockIdx.x * blockDim.x + threadIdx.x;
    if (i >= COUT * C) return;
    int o = i / C, c = i % C;
    const int isb = *flag;
    float w1 = isb ? b2f(((const bf16*)W)[(size_t)o * 2 * C + c])
                   : ((const float*)W)[(size_t)o * 2 * C + c];
    float w2 = isb ? b2f(((const bf16*)W)[(size_t)o * 2 * C + C + c])
                   : ((const float*)W)[(size_t)o * 2 * C + C + c];
    float wd = w1 - w2;
    bf16 h2 = __float2bfloat16(w2);
    bf16 hd = __float2bfloat16(wd);
    dst[i]                = h2;
    dst[COUT * C + i]     = __float2bfloat16(w2 - b2f(h2));
    dst[2 * COUT * C + i] = hd;
    dst[3 * COUT * C + i] = __float2bfloat16(wd - b2f(hd));
}

// ---------------------------------------------------------------------------
// Split conv5 weights (1024x512) into bf16 hi/lo: dst = [hi | lo].
__global__ void k_w5split(const void* __restrict__ W, const int* __restrict__ flag,
                          bf16* __restrict__ dst) {
    int i = blockIdx.x * blockDim.x + threadIdx.x;
    if (i >= 1024 * 512) return;
    const int isb = *flag;
    float w = isb ? b2f(((const bf16*)W)[i]) : ((const float*)W)[i];
    bf16 h = __float2bfloat16(w);
    dst[i] = h;
    dst[1024 * 512 + i] = __float2bfloat16(w - b2f(h));
}

// ---------------------------------------------------------------------------
// points (B,N,3) -> x0 (B,3,N) fp32, dtype-dynamic.
__global__ void k_transpose(const void* __restrict__ pts, const int* __restrict__ flag,
                            float* __restrict__ x0) {
    const int isb = *flag;
    int i = blockIdx.x * blockDim.x + threadIdx.x;
    if (i >= B_SZ * N_PTS) return;
    int b = i / N_PTS, n = i % N_PTS;
    for (int c = 0; c < 3; ++c) {
        size_t s = ((size_t)b * N_PTS + n) * 3 + c;
        float v = isb ? b2f(((const bf16*)pts)[s]) : ((const float*)pts)[s];
        x0[((size_t)b * 3 + c) * N_PTS + n] = v;
    }
}

// ---------------------------------------------------------------------------
// 32-candidate row loads (lane chunk), fp32 out.
__device__ __forceinline__ void load32(const float* row, int mbase, float* r) {
    const float4* p = (const float4*)(row + mbase);
#pragma unroll
    for (int i = 0; i < 8; ++i) {
        float4 f = p[i];
        r[4 * i + 0] = f.x; r[4 * i + 1] = f.y; r[4 * i + 2] = f.z; r[4 * i + 3] = f.w;
    }
}
__device__ __forceinline__ void load32(const bf16* row, int mbase, float* r) {
    const uint4* p = (const uint4*)(row + mbase);
#pragma unroll
    for (int i = 0; i < 4; ++i) {
        uint4 u = p[i];
        r[8 * i + 0] = __uint_as_float(u.x << 16);
        r[8 * i + 1] = __uint_as_float(u.x & 0xFFFF0000u);
        r[8 * i + 2] = __uint_as_float(u.y << 16);
        r[8 * i + 3] = __uint_as_float(u.y & 0xFFFF0000u);
        r[8 * i + 4] = __uint_as_float(u.z << 16);
        r[8 * i + 5] = __uint_as_float(u.z & 0xFFFF0000u);
        r[8 * i + 6] = __uint_as_float(u.w << 16);
        r[8 * i + 7] = __uint_as_float(u.w & 0xFFFF0000u);
    }
}

// ---------------------------------------------------------------------------
// Packed-key top-20 for two queries per wave, cached per-lane sorted top-2.
// key = (nonneg-fp32 bits & ~2047) | index(11b): u32-monotone, unique keys,
// tie -> lowest index. Extraction is ascending; a lane's cached top-2 stays
// valid until its own entries are consumed; refill (rare) re-scans with
// filter key > last-winner, which is exact under ascending extraction.
// Produces a sequence identical to the full per-round re-scan version.
__device__ __forceinline__ void s2ins(unsigned k, unsigned& m1, unsigned& m2) {
    unsigned lo = umin(m1, k);
    unsigned hi = (m1 < k) ? k : m1;
    m1 = lo;
    m2 = umin(m2, hi);
}

__device__ __forceinline__ void select20x2(const unsigned* ka, const unsigned* kb,
                                           int* outA, int* outB, int lane) {
    const unsigned SENT = 0xFFFFFFFFu;
    unsigned a1 = SENT, a2 = SENT, b1 = SENT, b2 = SENT;
#pragma unroll
    for (int j = 0; j < 32; ++j) {
        s2ins(ka[j], a1, a2);
        s2ins(kb[j], b1, b2);
    }
#pragma unroll 1
    for (int k = 0; k < KNN; ++k) {
        unsigned va = a1, vb = b1;
#pragma unroll
        for (int off = 32; off >= 1; off >>= 1) {
            va = umin(va, (unsigned)__shfl_xor((int)va, off));
            vb = umin(vb, (unsigned)__shfl_xor((int)vb, off));
        }
        if (lane == 0) { outA[k] = (int)(va & 2047u); outB[k] = (int)(vb & 2047u); }
        // consume winner on its (unique) owner lane
        if (a1 == va) { a1 = a2; a2 = SENT; }
        if (b1 == vb) { b1 = b2; b2 = SENT; }
        // refill if this lane exhausted its cached pair (rare)
        if (a1 == SENT) {
#pragma unroll
            for (int j = 0; j < 32; ++j) {
                unsigned t = (ka[j] > va) ? ka[j] : SENT;
                s2ins(t, a1, a2);
            }
        }
        if (b1 == SENT) {
#pragma unroll
            for (int j = 0; j < 32; ++j) {
                unsigned t = (kb[j] > vb) ? kb[j] : SENT;
                s2ins(t, b1, b2);
            }
        }
    }
}

// ---------------------------------------------------------------------------
// Layer-1 kNN (C=3, fp32) with packed-key selection, 2 queries/wave.
__global__ __launch_bounds__(256) void k_knn3(const float* __restrict__ x0,
                                              int* __restrict__ idx) {
    __shared__ float qf[8][3];
    int ib = blockIdx.x;
    int b  = ib / (N_PTS / 8);
    int q0 = (ib % (N_PTS / 8)) * 8;
    const float* xb = x0 + (size_t)b * 3 * N_PTS;

    if (threadIdx.x < 24) {
        int q = threadIdx.x / 3, c = threadIdx.x % 3;
        qf[q][c] = xb[(size_t)c * N_PTS + q0 + q];
    }
    __syncthreads();

    int w = threadIdx.x >> 6, lane = threadIdx.x & 63;
    int qa = q0 + 2 * w;
    int mbase = lane * 32;

    float da[32], db[32];
#pragma unroll
    for (int j = 0; j < 32; ++j) { da[j] = 0.f; db[j] = 0.f; }
#pragma unroll
    for (int c = 0; c < 3; ++c) {
        float r[32];
        load32(xb + (size_t)c * N_PTS, mbase, r);
        float qac = qf[2 * w][c], qbc = qf[2 * w + 1][c];
#pragma unroll
        for (int j = 0; j < 32; ++j) {
            float ta = r[j] - qac; da[j] = fmaf(ta, ta, da[j]);
            float tb = r[j] - qbc; db[j] = fmaf(tb, tb, db[j]);
        }
    }
    unsigned ka[32], kb[32];
#pragma unroll
    for (int j = 0; j < 32; ++j) {
        ka[j] = (__float_as_uint(da[j]) & 0xFFFFF800u) | (unsigned)(mbase + j);
        kb[j] = (__float_as_uint(db[j]) & 0xFFFFF800u) | (unsigned)(mbase + j);
    }
    select20x2(ka, kb, idx + ((size_t)b * N_PTS + qa) * KNN,
               idx + ((size_t)b * N_PTS + qa + 1) * KNN, lane);
}

// ---------------------------------------------------------------------------
// Score-based top-20 (gram path): dist = xx[m] - 2G[q][m] + xx[q], clamped >=0.
__global__ __launch_bounds__(256) void k_select2(const float* __restrict__ G,
                                                 const float* __restrict__ xx,
                                                 int* __restrict__ idx) {
    int ib = blockIdx.x;
    int b  = ib / (N_PTS / 8);
    int q0 = (ib % (N_PTS / 8)) * 8;
    int w = threadIdx.x >> 6, lane = threadIdx.x & 63;
    int qa = q0 + 2 * w;
    const float* gA = G + ((size_t)b * N_PTS + qa) * N_PTS;
    const float* gB = gA + N_PTS;
    const float* xr = xx + (size_t)b * N_PTS;
    float xqa = xr[qa], xqb = xr[qa + 1];

    unsigned ka[32], kb[32];
#pragma unroll
    for (int r = 0; r < 8; ++r) {
        int m0 = r * 256 + (lane << 2);
        float4 x4 = *(const float4*)(xr + m0);
        float4 a4 = *(const float4*)(gA + m0);
        float4 b4 = *(const float4*)(gB + m0);
        float s;
        s = fmaf(-2.f, a4.x, x4.x) + xqa; s = fmaxf(s, 0.f);
        ka[4 * r + 0] = (__float_as_uint(s) & 0xFFFFF800u) | (unsigned)(m0 + 0);
        s = fmaf(-2.f, a4.y, x4.y) + xqa; s = fmaxf(s, 0.f);
        ka[4 * r + 1] = (__float_as_uint(s) & 0xFFFFF800u) | (unsigned)(m0 + 1);
        s = fmaf(-2.f, a4.z, x4.z) + xqa; s = fmaxf(s, 0.f);
        ka[4 * r + 2] = (__float_as_uint(s) & 0xFFFFF800u) | (unsigned)(m0 + 2);
        s = fmaf(-2.f, a4.w, x4.w) + xqa; s = fmaxf(s, 0.f);
        ka[4 * r + 3] = (__float_as_uint(s) & 0xFFFFF800u) | (unsigned)(m0 + 3);
        s = fmaf(-2.f, b4.x, x4.x) + xqb; s = fmaxf(s, 0.f);
        kb[4 * r + 0] = (__float_as_uint(s) & 0xFFFFF800u) | (unsigned)(m0 + 0);
        s = fmaf(-2.f, b4.y, x4.y) + xqb; s = fmaxf(s, 0.f);
        kb[4 * r + 1] = (__float_as_uint(s) & 0xFFFFF800u) | (unsigned)(m0 + 1);
        s = fmaf(-2.f, b4.z, x4.z) + xqb; s = fmaxf(s, 0.f);
        kb[4 * r + 2] = (__float_as_uint(s) & 0xFFFFF800u) | (unsigned)(m0 + 2);
        s = fmaf(-2.f, b4.w, x4.w) + xqb; s = fmaxf(s, 0.f);
        kb[4 * r + 3] = (__float_as_uint(s) & 0xFFFFF800u) | (unsigned)(m0 + 3);
    }
    select20x2(ka, kb, idx + ((size_t)b * N_PTS + qa) * KNN,
               idx + ((size_t)b * N_PTS + qa + 1) * KNN, lane);
}

// ---------------------------------------------------------------------------
// kNN (direct, fallback path): wave-per-query.
template<typename T, int C>
__global__ __launch_bounds__(256) void k_knn(const T* __restrict__ x, int bstride,
                                             int* __restrict__ idx) {
    __shared__ float qf[4][C];
    int ib = blockIdx.x;
    int b  = ib / (N_PTS / 4);
    int q0 = (ib % (N_PTS / 4)) * 4;
    const T* xb = x + (size_t)b * bstride;

    for (int t = threadIdx.x; t < 4 * C; t += 256) {
        int pt = t / C, c = t % C;
        qf[pt][c] = ldf(&xb[(size_t)c * N_PTS + (q0 + pt)]);
    }
    __syncthreads();

    int w = threadIdx.x >> 6, lane = threadIdx.x & 63;
    int q = q0 + w;
    int mbase = lane * 32;

    float v[32];
#pragma unroll
    for (int j = 0; j < 32; ++j) v[j] = 0.f;

    for (int c = 0; c < C; ++c) {
        float qc = qf[w][c];
        float r[32];
        load32(xb + (size_t)c * N_PTS, mbase, r);
#pragma unroll
        for (int j = 0; j < 32; ++j) { float t = r[j] - qc; v[j] = fmaf(t, t, v[j]); }
    }

    for (int k = 0; k < KNN; ++k) {
        float bv = FLT_MAX; int bi = 0x7FFFFFFF;
#pragma unroll
        for (int j = 0; j < 32; ++j)
            if (v[j] < bv) { bv = v[j]; bi = mbase + j; }
#pragma unroll
        for (int off = 32; off >= 1; off >>= 1) {
            float ov = __shfl_xor(bv, off);
            int   oi = __shfl_xor(bi, off);
            if (ov < bv || (ov == bv && oi < bi)) { bv = ov; bi = oi; }
        }
        if (lane == 0) idx[((size_t)b * N_PTS + q) * KNN + k] = bi;
        int wl = bi >> 5, wj = bi & 31;
        if (lane == wl) {
#pragma unroll
            for (int j = 0; j < 32; ++j) if (j == wj) v[j] = FLT_MAX;
        }
    }
}

// ---------------------------------------------------------------------------
// Candidate squared norms over a channel slice.
template<int C>
__global__ void k_xx(const bf16* __restrict__ featT, int c0, float* __restrict__ xx) {
    int i = blockIdx.x * blockDim.x + threadIdx.x;
    if (i >= B_SZ * N_PTS) return;
    const bf16* row = featT + (size_t)i * FT + c0;
    float s = 0.f;
    for (int c = 0; c < C; c += 8) {
        uint4 u = *(const uint4*)(row + c);
        float v0 = __uint_as_float(u.x << 16), v1 = __uint_as_float(u.x & 0xFFFF0000u);
        float v2 = __uint_as_float(u.y << 16), v3 = __uint_as_float(u.y & 0xFFFF0000u);
        float v4 = __uint_as_float(u.z << 16), v5 = __uint_as_float(u.z & 0xFFFF0000u);
        float v6 = __uint_as_float(u.w << 16), v7 = __uint_as_float(u.w & 0xFFFF0000u);
        s = fmaf(v0, v0, s); s = fmaf(v1, v1, s); s = fmaf(v2, v2, s); s = fmaf(v3, v3, s);
        s = fmaf(v4, v4, s); s = fmaf(v5, v5, s); s = fmaf(v6, v6, s); s = fmaf(v7, v7, s);
    }
    xx[i] = s;
}

// ---------------------------------------------------------------------------
// Gram matrix via MFMA: G[b][n][m] = sum_c X[c][n]*X[c][m], X = featT slice.
template<int C>
__global__ __launch_bounds__(256) void k_gram(const bf16* __restrict__ featT, int c0,
                                              float* __restrict__ G) {
    const int KC = 64;
    __shared__ __align__(16) short At[128 * 72];
    __shared__ __align__(16) short Bt[128 * 72];

    int ib = blockIdx.x;
    int b  = ib >> 8;
    int t  = ib & 255;
    int n0 = (t >> 4) << 7;
    int m0 = (t & 15) << 7;

    int tid = threadIdx.x;
    int w = tid >> 6, lane = tid & 63;
    int rw = (w & 1) * 64, cw = (w >> 1) * 64;
    int lrow = lane & 15, quad = lane >> 4;

    floatx4 acc[4][4];
#pragma unroll
    for (int ri = 0; ri < 4; ++ri)
#pragma unroll
        for (int ci = 0; ci < 4; ++ci) acc[ri][ci] = (floatx4){0.f, 0.f, 0.f, 0.f};

    for (int ck = 0; ck < C; ck += KC) {
        __syncthreads();
        for (int s = tid; s < 1024; s += 256) {
            int row = s >> 3, g = s & 7;
            *(uint4*)&At[row * 72 + g * 8] =
                *(const uint4*)(featT + ((size_t)(b * N_PTS + n0 + row) * FT) + c0 + ck + g * 8);
            *(uint4*)&Bt[row * 72 + g * 8] =
                *(const uint4*)(featT + ((size_t)(b * N_PTS + m0 + row) * FT) + c0 + ck + g * 8);
        }
        __syncthreads();
#pragma unroll
        for (int kk = 0; kk < KC; kk += 32) {
            short8v a[4], bb[4];
#pragma unroll
            for (int ri = 0; ri < 4; ++ri)
                a[ri] = *(const short8v*)&At[(rw + ri * 16 + lrow) * 72 + kk + quad * 8];
#pragma unroll
            for (int ci = 0; ci < 4; ++ci)
                bb[ci] = *(const short8v*)&Bt[(cw + ci * 16 + lrow) * 72 + kk + quad * 8];
#pragma unroll
            for (int ri = 0; ri < 4; ++ri)
#pragma unroll
                for (int ci = 0; ci < 4; ++ci)
                    acc[ri][ci] = __builtin_amdgcn_mfma_f32_16x16x32_bf16(a[ri], bb[ci], acc[ri][ci], 0, 0, 0);
        }
    }

#pragma unroll
    for (int ri = 0; ri < 4; ++ri)
#pragma unroll
        for (int ci = 0; ci < 4; ++ci) {
            int n = n0 + rw + ri * 16 + quad * 4;
            int m = m0 + cw + ci * 16 + lrow;
            float* gp = G + ((size_t)b * N_PTS + n) * N_PTS + m;
#pragma unroll
            for (int reg = 0; reg < 4; ++reg)
                gp[(size_t)reg * N_PTS] = acc[ri][ci][reg];
        }
}

// ---------------------------------------------------------------------------
// Dense point transform via MFMA (EdgeConv linear part, all points at once):
// Y[i][0..COUT) = W2 . x_i ; Y[i][COUT..2COUT) = Wd . x_i  (hi/lo split).
template<int COUT, int C>
__global__ __launch_bounds__(256) void k_xform(const bf16* __restrict__ featT, int c0,
                                               const bf16* __restrict__ Wsp,
                                               float* __restrict__ Y) {
    const int M2 = 2 * COUT;
    const int KC = 64;
    __shared__ __align__(16) short Bt[128 * 72];

    int ib = blockIdx.x;
    int nt = ib & 63;
    int mt = ib >> 6;
    int tid = threadIdx.x;
    int w = tid >> 6, lane = tid & 63;
    int rw = (w & 1) * 64, cw = (w >> 1) * 64;
    int l15 = lane & 15, quad = lane >> 4;

    floatx4 acc[4][4];
#pragma unroll
    for (int ri = 0; ri < 4; ++ri)
#pragma unroll
        for (int ci = 0; ci < 4; ++ci) acc[ri][ci] = (floatx4){0.f, 0.f, 0.f, 0.f};

    for (int ck = 0; ck < C; ck += KC) {
        __syncthreads();
        for (int s = tid; s < 1024; s += 256) {
            int row = s >> 3, g = s & 7;
            *(uint4*)&Bt[row * 72 + g * 8] =
                *(const uint4*)(featT + (size_t)(nt * 128 + row) * FT + c0 + ck + g * 8);
        }
        __syncthreads();
#pragma unroll
        for (int kk = 0; kk < KC; kk += 32) {
            short8v bfr[4];
#pragma unroll
            for (int ci = 0; ci < 4; ++ci)
                bfr[ci] = *(const short8v*)&Bt[(cw + ci * 16 + l15) * 72 + kk + quad * 8];
#pragma unroll
            for (int ri = 0; ri < 4; ++ri) {
                int mrow = mt * 128 + rw + ri * 16 + l15;
                int base = (mrow < COUT) ? mrow : (mrow + COUT);
                const bf16* hi = Wsp + (size_t)base * C + ck + kk + quad * 8;
                short8v ah = ld8(hi);
                short8v al = ld8(hi + (size_t)COUT * C);
#pragma unroll
                for (int ci = 0; ci < 4; ++ci) {
                    acc[ri][ci] = __builtin_amdgcn_mfma_f32_16x16x32_bf16(ah, bfr[ci], acc[ri][ci], 0, 0, 0);
                    acc[ri][ci] = __builtin_amdgcn_mfma_f32_16x16x32_bf16(al, bfr[ci], acc[ri][ci], 0, 0, 0);
                }
            }
        }
    }

#pragma unroll
    for (int ri = 0; ri < 4; ++ri)
#pragma unroll
        for (int ci = 0; ci < 4; ++ci) {
            int n = nt * 128 + cw + ci * 16 + l15;
            int m = mt * 128 + rw + ri * 16 + quad * 4;
            *(floatx4*)(Y + (size_t)n * M2 + m) = acc[ri][ci];
        }
}

// ---------------------------------------------------------------------------
// Gather-max epilogue: out[o][n] = max_k lrelu((Yd[n][o] + Y2[m_k][o])*s + b).
template<int COUT>
__global__ __launch_bounds__(256) void k_gmax(const float* __restrict__ Y,
        const int* __restrict__ idx,
        const float* __restrict__ gam, const float* __restrict__ bet,
        bf16* __restrict__ featT, int c0f) {
    const int M2 = 2 * COUT;
    const int OT = COUT / 64;
    int i = blockIdx.x * 4 + (threadIdx.x >> 6);
    int lane = threadIdx.x & 63;
    int b = i >> 11;

    const float inv = rsqrtf(1.0f + 1e-5f);
    float yd[OT], scale[OT], bias[OT], mx[OT];
#pragma unroll
    for (int j = 0; j < OT; ++j) {
        int o = lane + 64 * j;
        yd[j]    = Y[(size_t)i * M2 + COUT + o];
        scale[j] = gam[o] * inv;
        bias[j]  = bet[o];
        mx[j]    = -FLT_MAX;
    }

    const int* ip = idx + (size_t)i * KNN;
    const float* Yb = Y + ((size_t)b * N_PTS) * M2;
#pragma unroll 4
    for (int k = 0; k < KNN; ++k) {
        int m = ip[k] & (N_PTS - 1);
        const float* yr = Yb + (size_t)m * M2;
#pragma unroll
        for (int j = 0; j < OT; ++j) {
            float h = (yd[j] + yr[lane + 64 * j]) * scale[j] + bias[j];
            h = h > 0.f ? h : LRELU_S * h;
            mx[j] = fmaxf(mx[j], h);
        }
    }
#pragma unroll
    for (int j = 0; j < OT; ++j)
        featT[(size_t)i * FT + c0f + lane + 64 * j] = __float2bfloat16(mx[j]);
}

// ---------------------------------------------------------------------------
// EdgeConv (VALU): layer 1 (C=3) and ws-fallback path.
template<typename T, int C, int COUT, bool WF>
__global__ __launch_bounds__(256) void k_edgeconv(const T* __restrict__ x, int bstride,
                           const int* __restrict__ idx,
                           const float* __restrict__ Wt,
                           const float* __restrict__ gam,
                           const float* __restrict__ bet,
                           bf16* __restrict__ out, int ostride,
                           bf16* __restrict__ featT, int c0f) {
    const int PT = 4;
    const int OT = COUT / 64;
    const int CP = (C + 3) & ~3;
    __shared__ float sh[PT][KNN + 1][CP];

    int ib = blockIdx.x;
    int b  = ib / (N_PTS / PT);
    int n0 = (ib % (N_PTS / PT)) * PT;
    const T* xb = x + (size_t)b * bstride;

    const int TOT = PT * (KNN + 1) * C;
    for (int t = threadIdx.x; t < TOT; t += 256) {
        int pt = t / ((KNN + 1) * C);
        int r  = t % ((KNN + 1) * C);
        int row = r / C, c = r % C;
        int n = n0 + pt;
        int m = (row == 0) ? n
                           : (idx[((size_t)b * N_PTS + n) * KNN + (row - 1)] & (N_PTS - 1));
        sh[pt][row][c] = ldf(&xb[(size_t)c * N_PTS + m]);
    }
    __syncthreads();

    int w = threadIdx.x >> 6, lane = threadIdx.x & 63;
    int n = n0 + w;

    constexpr int KT = (OT >= 4) ? 10 : 20;
    constexpr int NPASS = KNN / KT;

    float base[OT];
    float mx[OT];
#pragma unroll
    for (int j = 0; j < OT; ++j) { base[j] = 0.f; mx[j] = -FLT_MAX; }

    const float inv = rsqrtf(1.0f + 1e-5f);

#pragma unroll
    for (int pass = 0; pass < NPASS; ++pass) {
        float acc[OT][KT];
#pragma unroll
        for (int j = 0; j < OT; ++j)
#pragma unroll
            for (int k = 0; k < KT; ++k) acc[j][k] = 0.f;

        for (int c = 0; c < C; ++c) {
            float xq = sh[w][0][c];
            float w2v[OT];
#pragma unroll
            for (int j = 0; j < OT; ++j)
                w2v[j] = Wt[(size_t)(C + c) * COUT + lane + 64 * j];
            if (pass == 0) {
#pragma unroll
                for (int j = 0; j < OT; ++j) {
                    float w1v = Wt[(size_t)c * COUT + lane + 64 * j];
                    base[j] = fmaf(w1v - w2v[j], xq, base[j]);
                }
            }
#pragma unroll
            for (int k = 0; k < KT; ++k) {
                float nv = sh[w][1 + pass * KT + k][c];
#pragma unroll
                for (int j = 0; j < OT; ++j) acc[j][k] = fmaf(w2v[j], nv, acc[j][k]);
            }
        }

#pragma unroll
        for (int j = 0; j < OT; ++j) {
            int o = lane + 64 * j;
            float scale = gam[o] * inv, bias = bet[o];
#pragma unroll
            for (int k = 0; k < KT; ++k) {
                float h = (base[j] + acc[j][k]) * scale + bias;
                h = h > 0.f ? h : LRELU_S * h;
                mx[j] = fmaxf(mx[j], h);
            }
        }
    }

#pragma unroll
    for (int j = 0; j < OT; ++j) {
        int o = lane + 64 * j;
        bf16 bv = __float2bfloat16(mx[j]);
        out[(size_t)b * ostride + (size_t)o * N_PTS + n] = bv;
        if (WF) featT[((size_t)b * N_PTS + n) * FT + c0f + o] = bv;
    }
}

// ---------------------------------------------------------------------------
// conv5 via MFMA, LDS-staged A (weight hi/lo tiles) and B (featT rows),
// fused BN/LReLU + max/sum pooling partials. Block: 64o x 256n, 4 waves.
__global__ __launch_bounds__(256) void k_conv5mfma(
        const bf16* __restrict__ featT, const bf16* __restrict__ w5sp,
        const float* __restrict__ g5, const float* __restrict__ b5,
        float* __restrict__ fmxp, float* __restrict__ fsmp) {
    __shared__ __align__(16) short Bt[256 * 72];   // 36 KB
    __shared__ __align__(16) short Ah[64 * 72];    //  9 KB
    __shared__ __align__(16) short Al[64 * 72];    //  9 KB
    __shared__ float rmx[4][64];
    __shared__ float rsm[4][64];

    int ib = blockIdx.x;                 // B * 16 * 8
    int b  = ib / 128;
    int rem = ib % 128;
    int o0 = (rem >> 3) * 64;
    int nt = rem & 7;
    int tid = threadIdx.x;
    int w = tid >> 6, lane = tid & 63;
    int l15 = lane & 15, quad = lane >> 4;

    const bf16* Whi = w5sp;
    const bf16* Wlo = w5sp + 1024 * 512;
    const bf16* fb  = featT + (size_t)b * N_PTS * FT;
    const int nbase0 = nt * 256;

    floatx4 acc[4][4];
#pragma unroll
    for (int mi = 0; mi < 4; ++mi)
#pragma unroll
        for (int ni = 0; ni < 4; ++ni) acc[mi][ni] = (floatx4){0.f, 0.f, 0.f, 0.f};

    for (int ck = 0; ck < 512; ck += 64) {
        __syncthreads();
        for (int s = tid; s < 2048; s += 256) {          // B: 256 rows x 64k
            int row = s >> 3, g = s & 7;
            *(uint4*)&Bt[row * 72 + g * 8] =
                *(const uint4*)(fb + (size_t)(nbase0 + row) * FT + ck + g * 8);
        }
        for (int s = tid; s < 512; s += 256) {           // A hi/lo: 64 rows x 64k
            int row = s >> 3, g = s & 7;
            *(uint4*)&Ah[row * 72 + g * 8] =
                *(const uint4*)(Whi + (size_t)(o0 + row) * 512 + ck + g * 8);
            *(uint4*)&Al[row * 72 + g * 8] =
                *(const uint4*)(Wlo + (size_t)(o0 + row) * 512 + ck + g * 8);
        }
        __syncthreads();
#pragma unroll
        for (int kk = 0; kk < 64; kk += 32) {
            short8v bfr[4], ah[4], al[4];
#pragma unroll
            for (int ni = 0; ni < 4; ++ni)
                bfr[ni] = *(const short8v*)&Bt[(w * 64 + ni * 16 + l15) * 72 + kk + quad * 8];
#pragma unroll
            for (int mi = 0; mi < 4; ++mi) {
                ah[mi] = *(const short8v*)&Ah[(mi * 16 + l15) * 72 + kk + quad * 8];
                al[mi] = *(const short8v*)&Al[(mi * 16 + l15) * 72 + kk + quad * 8];
            }
#pragma unroll
            for (int mi = 0; mi < 4; ++mi)
#pragma unroll
                for (int ni = 0; ni < 4; ++ni) {
                    acc[mi][ni] = __builtin_amdgcn_mfma_f32_16x16x32_bf16(ah[mi], bfr[ni], acc[mi][ni], 0, 0, 0);
                    acc[mi][ni] = __builtin_amdgcn_mfma_f32_16x16x32_bf16(al[mi], bfr[ni], acc[mi][ni], 0, 0, 0);
                }
        }
    }

    const float inv = rsqrtf(1.0f + 1e-5f);
#pragma unroll
    for (int mi = 0; mi < 4; ++mi) {
#pragma unroll
        for (int r = 0; r < 4; ++r) {
            int o = o0 + mi * 16 + quad * 4 + r;
            float scale = g5[o] * inv, bias = b5[o];
            float mx = -FLT_MAX, sm = 0.f;
#pragma unroll
            for (int ni = 0; ni < 4; ++ni) {
                float h = acc[mi][ni][r] * scale + bias;
                h = h > 0.f ? h : LRELU_S * h;
                mx = fmaxf(mx, h);
                sm += h;
            }
#pragma unroll
            for (int off = 1; off <= 8; off <<= 1) {
                mx = fmaxf(mx, __shfl_xor(mx, off));
                sm += __shfl_xor(sm, off);
            }
            if (l15 == 0) {
                rmx[w][mi * 16 + quad * 4 + r] = mx;
                rsm[w][mi * 16 + quad * 4 + r] = sm;
            }
        }
    }
    __syncthreads();
    if (tid < 64) {
        float mx = -FLT_MAX, sm = 0.f;
#pragma unroll
        for (int ww = 0; ww < 4; ++ww) { mx = fmaxf(mx, rmx[ww][tid]); sm += rsm[ww][tid]; }
        fmxp[((size_t)b * 1024 + o0 + tid) * NPOOL + nt] = mx;
        fsmp[((size_t)b * 1024 + o0 + tid) * NPOOL + nt] = sm;
    }
}

// ---------------------------------------------------------------------------
// Pool partial reduce -> fvec (B, 2048) = [max(1024) | mean(1024)].
__global__ void k_pool(const float* __restrict__ fmxp, const float* __restrict__ fsmp,
                       float* __restrict__ fvec) {
    int i = blockIdx.x * blockDim.x + threadIdx.x;
    if (i >= B_SZ * 1024) return;
    int b = i >> 10, o = i & 1023;
    float mx = -FLT_MAX, sm = 0.f;
    for (int ch = 0; ch < NPOOL; ++ch) {
        mx = fmaxf(mx, fmxp[(size_t)i * NPOOL + ch]);
        sm += fsmp[(size_t)i * NPOOL + ch];
    }
    fvec[(size_t)b * 2048 + o] = mx;
    fvec[(size_t)b * 2048 + 1024 + o] = sm * (1.0f / N_PTS);
}

// ---------------------------------------------------------------------------
// fc1 (raw-dtype weights): block per (b,o).
__global__ __launch_bounds__(256) void k_fc1(const float* __restrict__ fvec,
        const void* __restrict__ fw1, const void* __restrict__ fb1,
        const void* __restrict__ g6,  const void* __restrict__ b6,
        const int* __restrict__ flag, float* __restrict__ tbuf) {
    __shared__ float red[4];
    int ib = blockIdx.x;
    int b = ib >> 9, o = ib & 511;
    const float* fv = fvec + (size_t)b * 2048;
    int tid = threadIdx.x;
    const int isb = *flag;
    float s = 0.f;
    if (isb) {
        const bf16* wr = (const bf16*)fw1 + (size_t)o * 2048;
        for (int j = tid; j < 2048; j += 256) s = fmaf(b2f(wr[j]), fv[j], s);
    } else {
        const float* wr = (const float*)fw1 + (size_t)o * 2048;
        for (int j = tid; j < 2048; j += 256) s = fmaf(wr[j], fv[j], s);
    }
#pragma unroll
    for (int off = 32; off >= 1; off >>= 1) s += __shfl_xor(s, off);
    if ((tid & 63) == 0) red[tid >> 6] = s;
    __syncthreads();
    if (tid == 0) {
        float fb = isb ? b2f(((const bf16*)fb1)[o]) : ((const float*)fb1)[o];
        float gg = isb ? b2f(((const bf16*)g6)[o])  : ((const float*)g6)[o];
        float bb = isb ? b2f(((const bf16*)b6)[o])  : ((const float*)b6)[o];
        float acc = fb + red[0] + red[1] + red[2] + red[3];
        float h = acc * gg * rsqrtf(1.0f + 1e-5f) + bb;
        tbuf[(size_t)b * 512 + o] = h > 0.f ? h : LRELU_S * h;
    }
}

// ---------------------------------------------------------------------------
// fc2 (raw-dtype weights): block per (b,o).
__global__ __launch_bounds__(256) void k_fc2(const float* __restrict__ tbuf,
        const void* __restrict__ fw2, const void* __restrict__ fb2,
        const void* __restrict__ g7,  const void* __restrict__ b7,
        const int* __restrict__ flag, void* __restrict__ out) {
    __shared__ float red[4];
    int ib = blockIdx.x;
    int b = ib >> 8, o = ib & 255;
    const float* tv = tbuf + (size_t)b * 512;
    int tid = threadIdx.x;
    const int isb = *flag;
    float s;
    if (isb) {
        const bf16* wr = (const bf16*)fw2 + (size_t)o * 512;
        s = fmaf(b2f(wr[tid]), tv[tid], b2f(wr[tid + 256]) * tv[tid + 256]);
    } else {
        const float* wr = (const float*)fw2 + (size_t)o * 512;
        s = fmaf(wr[tid], tv[tid], wr[tid + 256] * tv[tid + 256]);
    }
#pragma unroll
    for (int off = 32; off >= 1; off >>= 1) s += __shfl_xor(s, off);
    if ((tid & 63) == 0) red[tid >> 6] = s;
    __syncthreads();
    if (tid == 0) {
        float fb = isb ? b2f(((const bf16*)fb2)[o]) : ((const float*)fb2)[o];
        float gg = isb ? b2f(((const bf16*)g7)[o])  : ((const float*)g7)[o];
        float bb = isb ? b2f(((const bf16*)b7)[o])  : ((const float*)b7)[o];
        float acc = fb + red[0] + red[1] + red[2] + red[3];
        float h = acc * gg * rsqrtf(1.0f + 1e-5f) + bb;
        if (isb) ((bf16*)out)[(size_t)b * 256 + o] = __float2bfloat16(h);
        else     ((float*)out)[(size_t)b * 256 + o] = h;
    }
}

// ---------------------------------------------------------------------------
// Fallback conv5 (VALU) + head, used when ws too small for the gram path.
#define NCH 2
__global__ __launch_bounds__(256) void k_conv5pool(const bf16* __restrict__ feat,
                            const float* __restrict__ w5,
                            const float* __restrict__ g5,
                            const float* __restrict__ b5,
                            float* __restrict__ fmxp, float* __restrict__ fsmp) {
    const int OT = 8;
    const int NT = 4;
    const int CHN = N_PTS / NCH;
    __shared__ float wl[OT][512];
    __shared__ float rmx[4][OT];
    __shared__ float rsm[4][OT];

    int ib = blockIdx.x;
    int ch = ib % NCH;
    int ot = (ib / NCH) % (1024 / OT);
    int b  = ib / (NCH * (1024 / OT));
    int o0 = ot * OT;
    const bf16* fb = feat + (size_t)b * 512 * N_PTS;

    for (int t = threadIdx.x; t < OT * 512; t += 256) {
        int o = t >> 9, c = t & 511;
        wl[o][c] = w5[(size_t)(o0 + o) * 512 + c];
    }
    __syncthreads();

    const int n0 = ch * CHN + threadIdx.x * NT;

    float acc[OT][NT];
#pragma unroll
    for (int o = 0; o < OT; ++o)
#pragma unroll
        for (int t = 0; t < NT; ++t) acc[o][t] = 0.f;

    for (int c = 0; c < 512; c += 4) {
        float fv[4][NT];
#pragma unroll
        for (int j = 0; j < 4; ++j) {
            uint2 u = *(const uint2*)(fb + (size_t)(c + j) * N_PTS + n0);
            fv[j][0] = __uint_as_float(u.x << 16);
            fv[j][1] = __uint_as_float(u.x & 0xFFFF0000u);
            fv[j][2] = __uint_as_float(u.y << 16);
            fv[j][3] = __uint_as_float(u.y & 0xFFFF0000u);
        }
#pragma unroll
        for (int o = 0; o < OT; ++o) {
            float4 wv = *(const float4*)&wl[o][c];
#pragma unroll
            for (int t = 0; t < NT; ++t) {
                acc[o][t] = fmaf(wv.x, fv[0][t], acc[o][t]);
                acc[o][t] = fmaf(wv.y, fv[1][t], acc[o][t]);
                acc[o][t] = fmaf(wv.z, fv[2][t], acc[o][t]);
                acc[o][t] = fmaf(wv.w, fv[3][t], acc[o][t]);
            }
        }
    }

    const float inv = rsqrtf(1.0f + 1e-5f);
    int w = threadIdx.x >> 6, lane = threadIdx.x & 63;
#pragma unroll
    for (int o = 0; o < OT; ++o) {
        float scale = g5[o0 + o] * inv, bias = b5[o0 + o];
        float mx = -FLT_MAX, sm = 0.f;
#pragma unroll
        for (int t = 0; t < NT; ++t) {
            float h = acc[o][t] * scale + bias;
            h = h > 0.f ? h : LRELU_S * h;
            mx = fmaxf(mx, h);
            sm += h;
        }
#pragma unroll
        for (int off = 32; off >= 1; off >>= 1) {
            mx = fmaxf(mx, __shfl_xor(mx, off));
            sm += __shfl_xor(sm, off);
        }
        if (lane == 0) { rmx[w][o] = mx; rsm[w][o] = sm; }
    }
    __syncthreads();
    if (threadIdx.x < OT) {
        int o = threadIdx.x;
        float mx = -FLT_MAX, sm = 0.f;
#pragma unroll
        for (int ww = 0; ww < 4; ++ww) { mx = fmaxf(mx, rmx[ww][o]); sm += rsm[ww][o]; }
        fmxp[((size_t)b * 1024 + o0 + o) * NCH + ch] = mx;
        fsmp[((size_t)b * 1024 + o0 + o) * NCH + ch] = sm;
    }
}

__global__ void k_head(const float* __restrict__ fmxp, const float* __restrict__ fsmp,
                       const float* __restrict__ fw1, const float* __restrict__ fb1,
                       const float* __restrict__ g6,  const float* __restrict__ b6,
                       const float* __restrict__ fw2, const float* __restrict__ fb2,
                       const float* __restrict__ g7,  const float* __restrict__ b7,
                       const int* __restrict__ flag, void* __restrict__ out) {
    __shared__ float f[2048];
    __shared__ float t[512];
    int b = blockIdx.x;
    for (int i = threadIdx.x; i < 1024; i += 256) {
        float mx = -FLT_MAX, sm = 0.f;
        for (int ch = 0; ch < NCH; ++ch) {
            mx = fmaxf(mx, fmxp[((size_t)b * 1024 + i) * NCH + ch]);
            sm += fsmp[((size_t)b * 1024 + i) * NCH + ch];
        }
        f[i]        = mx;
        f[1024 + i] = sm * (1.0f / N_PTS);
    }
    __syncthreads();
    const float inv = rsqrtf(1.0f + 1e-5f);
    for (int o = threadIdx.x; o < 512; o += 256) {
        const float* wr = fw1 + (size_t)o * 2048;
        float acc = fb1[o];
        for (int j = 0; j < 2048; ++j) acc += wr[j] * f[j];
        float h = acc * g6[o] * inv + b6[o];
        t[o] = h > 0.f ? h : LRELU_S * h;
    }
    __syncthreads();
    {
        int o = threadIdx.x;
        const float* wr = fw2 + (size_t)o * 512;
        float acc = fb2[o];
        for (int j = 0; j < 512; ++j) acc += wr[j] * t[j];
        float h = acc * g7[o] * inv + b7[o];
        if (*flag) ((bf16*)out)[(size_t)b * 256 + o] = __float2bfloat16(h);
        else       ((float*)out)[(size_t)b * 256 + o] = h;
    }
}

// ---------------------------------------------------------------------------
extern "C" void kernel_launch(void* const* d_in, const int* in_sizes, int n_in,
                              void* d_out, int out_size, void* d_ws, size_t ws_size,
                              hipStream_t stream) {
    static const int wsz[23] = {
        384, 64, 64,   8192, 64, 64,   16384, 128, 128,   65536, 256, 256,
        524288, 1024, 1024,   1048576, 512,   512, 512,   131072, 256,   256, 256
    };
    static const int trows[23] = {64,0,0, 64,0,0, 128,0,0, 256,0,0, 0,0,0, 0,0, 0,0, 0,0, 0,0};
    static const int tcols[23] = { 6,0,0,128,0,0, 128,0,0, 256,0,0, 0,0,0, 0,0, 0,0, 0,0, 0,0};

    WPack wp;
    int total = 0;
    for (int i = 0; i < 23; ++i) {
        wp.src[i] = d_in[i + 1]; wp.off[i] = total; total += wsz[i];
        wp.rows[i] = trows[i]; wp.cols[i] = tcols[i];
    }
    wp.off[23] = total;

    const size_t flag_bytes = 16;
    const size_t x0_bytes   = (size_t)B_SZ * 3 * N_PTS * 4;
    const size_t feat_bytes = (size_t)B_SZ * 512 * N_PTS * 2;
    const size_t idx_bytes  = (size_t)B_SZ * N_PTS * KNN * 4;
    const size_t pool_bytes = (size_t)B_SZ * 1024 * 4 * 2;
    const size_t wf_bytes   = (size_t)total * 4;
    const size_t base_need  = flag_bytes + x0_bytes + feat_bytes + idx_bytes + pool_bytes + wf_bytes;

    const size_t featT_bytes = (size_t)B_SZ * N_PTS * FT * 2;           //  8 MB
    const size_t xx_bytes    = (size_t)B_SZ * N_PTS * 4;
    const size_t wsp2_elems  = 4 * 64 * 64;
    const size_t wsp3_elems  = 4 * 128 * 64;
    const size_t wsp4_elems  = 4 * 256 * 128;
    const size_t w5sp_elems  = 2 * 1024 * 512;
    const size_t wsp_bytes   = (wsp2_elems + wsp3_elems + wsp4_elems + w5sp_elems) * 2;
    const size_t S_bytes     = (size_t)B_SZ * N_PTS * N_PTS * 4;        // 64 MB (also holds Y)
    const size_t full_need   = base_need + featT_bytes + xx_bytes + wsp_bytes + S_bytes;

    if (ws_size < base_need) return;   // graceful fail
    const bool use_gram = (ws_size >= full_need);

    char* w = (char*)d_ws;
    int*   flag = (int*)w;              w += flag_bytes;
    float* x0   = (float*)w;            w += x0_bytes;
    bf16*  feat = (bf16*)w;             w += feat_bytes;
    int*   idx  = (int*)w;              w += idx_bytes;
    w += pool_bytes;
    float* wf   = (float*)w;            w += wf_bytes;
    bf16*  featT = (bf16*)w;            w += featT_bytes;
    float* xx    = (float*)w;           w += xx_bytes;
    bf16*  wsp2  = (bf16*)w;            w += wsp2_elems * 2;
    bf16*  wsp3  = (bf16*)w;            w += wsp3_elems * 2;
    bf16*  wsp4  = (bf16*)w;            w += wsp4_elems * 2;
    bf16*  w5sp  = (bf16*)w;            w += w5sp_elems * 2;
    float* S     = (float*)w;           // gram scores; reused as Y after select

    // overlays in the idx region (idx dead after ec4):
    float* fmxp = (float*)idx;                               // B*1024*NPOOL
    float* fsmp = fmxp + (size_t)B_SZ * 1024 * NPOOL;        // B*1024*NPOOL
    float* fvec = fsmp + (size_t)B_SZ * 1024 * NPOOL;        // B*2048
    float* tbuf = fvec + (size_t)B_SZ * 2048;                // B*512

    const int FBS = 512 * N_PTS;

    k_sniff<<<1, 64, 0, stream>>>((const unsigned short*)d_in[0], flag);
    const int rlimit = use_gram ? wp.off[15] : total;
    k_repack<<<(rlimit + 255) / 256, 256, 0, stream>>>(wp, flag, wf, rlimit);
    k_transpose<<<(B_SZ * N_PTS + 255) / 256, 256, 0, stream>>>(d_in[0], flag, x0);

    const float* w1t = wf + wp.off[0],  *g1 = wf + wp.off[1],  *b1 = wf + wp.off[2];
    const float* w2t = wf + wp.off[3],  *g2 = wf + wp.off[4],  *b2 = wf + wp.off[5];
    const float* w3t = wf + wp.off[6],  *g3 = wf + wp.off[7],  *b3 = wf + wp.off[8];
    const float* w4t = wf + wp.off[9],  *g4 = wf + wp.off[10], *b4 = wf + wp.off[11];
    const float* w5  = wf + wp.off[12], *g5 = wf + wp.off[13], *b5 = wf + wp.off[14];
    const float* fw1 = wf + wp.off[15], *fb1 = wf + wp.off[16];
    const float* g6  = wf + wp.off[17], *b6 = wf + wp.off[18];
    const float* fw2 = wf + wp.off[19], *fb2 = wf + wp.off[20];
    const float* g7  = wf + wp.off[21], *b7 = wf + wp.off[22];

    const int GK = B_SZ * N_PTS / 4;    // 2048 blocks
    const int G8 = B_SZ * N_PTS / 8;    // 1024 blocks (2 queries/wave kernels)
    const int NXX = (B_SZ * N_PTS + 255) / 256;

    if (use_gram) {
        k_wsplit<64, 64><<<(64 * 64 + 255) / 256, 256, 0, stream>>>(d_in[4], flag, wsp2);
        k_wsplit<64, 128><<<(128 * 64 + 255) / 256, 256, 0, stream>>>(d_in[7], flag, wsp3);
        k_wsplit<128, 256><<<(256 * 128 + 255) / 256, 256, 0, stream>>>(d_in[10], flag, wsp4);
        k_w5split<<<(1024 * 512 + 255) / 256, 256, 0, stream>>>(d_in[13], flag, w5sp);

        k_knn3<<<G8, 256, 0, stream>>>(x0, idx);
        k_edgeconv<float, 3, 64, true><<<GK, 256, 0, stream>>>(
            x0, 3 * N_PTS, idx, w1t, g1, b1, feat + 0 * N_PTS, FBS, featT, 0);
        // layer 2
        k_xx<64><<<NXX, 256, 0, stream>>>(featT, 0, xx);
        k_gram<64><<<B_SZ * 256, 256, 0, stream>>>(featT, 0, S);
        k_select2<<<G8, 256, 0, stream>>>(S, xx, idx);
        k_xform<64, 64><<<64, 256, 0, stream>>>(featT, 0, wsp2, S);
        k_gmax<64><<<GK, 256, 0, stream>>>(S, idx, g2, b2, featT, 64);
        // layer 3
        k_xx<64><<<NXX, 256, 0, stream>>>(featT, 64, xx);
        k_gram<64><<<B_SZ * 256, 256, 0, stream>>>(featT, 64, S);
        k_select2<<<G8, 256, 0, stream>>>(S, xx, idx);
        k_xform<128, 64><<<128, 256, 0, stream>>>(featT, 64, wsp3, S);
        k_gmax<128><<<GK, 256, 0, stream>>>(S, idx, g3, b3, featT, 128);
        // layer 4 (writes featT channels [256,512) for conv5)
        k_xx<128><<<NXX, 256, 0, stream>>>(featT, 128, xx);
        k_gram<128><<<B_SZ * 256, 256, 0, stream>>>(featT, 128, S);
        k_select2<<<G8, 256, 0, stream>>>(S, xx, idx);
        k_xform<256, 128><<<256, 256, 0, stream>>>(featT, 128, wsp4, S);
        k_gmax<256><<<GK, 256, 0, stream>>>(S, idx, g4, b4, featT, 256);

        // conv5 MFMA + pooling partials, then head GEMVs (raw fc weights)
        k_conv5mfma<<<B_SZ * 128, 256, 0, stream>>>(featT, w5sp, g5, b5, fmxp, fsmp);
        k_pool<<<(B_SZ * 1024 + 255) / 256, 256, 0, stream>>>(fmxp, fsmp, fvec);
        k_fc1<<<B_SZ * 512, 256, 0, stream>>>(fvec, d_in[16], d_in[17], d_in[18], d_in[19],
                                              flag, tbuf);
        k_fc2<<<B_SZ * 256, 256, 0, stream>>>(tbuf, d_in[20], d_in[21], d_in[22], d_in[23],
                                              flag, d_out);
    } else {
        k_knn<float, 3><<<GK, 256, 0, stream>>>(x0, 3 * N_PTS, idx);
        k_edgeconv<float, 3, 64, false><<<GK, 256, 0, stream>>>(
            x0, 3 * N_PTS, idx, w1t, g1, b1, feat + 0 * N_PTS, FBS, nullptr, 0);
        k_knn<bf16, 64><<<GK, 256, 0, stream>>>(feat + 0 * N_PTS, FBS, idx);
        k_edgeconv<bf16, 64, 64, false><<<GK, 256, 0, stream>>>(
            feat + 0 * N_PTS, FBS, idx, w2t, g2, b2, feat + 64 * N_PTS, FBS, nullptr, 0);
        k_knn<bf16, 64><<<GK, 256, 0, stream>>>(feat + 64 * N_PTS, FBS, idx);
        k_edgeconv<bf16, 64, 128, false><<<GK, 256, 0, stream>>>(
            feat + 64 * N_PTS, FBS, idx, w3t, g3, b3, feat + 128 * N_PTS, FBS, nullptr, 0);
        k_knn<bf16, 128><<<GK, 256, 0, stream>>>(feat + 128 * N_PTS, FBS, idx);
        k_edgeconv<bf16, 128, 256, false><<<GK, 256, 0, stream>>>(
            feat + 128 * N_PTS, FBS, idx, w4t, g4, b4, feat + 256 * N_PTS, FBS, nullptr, 0);

        k_conv5pool<<<B_SZ * (1024 / 8) * NCH, 256, 0, stream>>>(feat, w5, g5, b5, fmxp, fsmp);
        k_head<<<B_SZ, 256, 0, stream>>>(fmxp, fsmp, fw1, fb1, g6, b6, fw2, fb2, g7, b7,
                                         flag, d_out);
    }
}